// Round 6
// baseline (1934.165 us; speedup 1.0000x reference)
//
#include <hip/hip_runtime.h>
#include <hip/hip_bf16.h>
#include <hip/hip_fp16.h>
#include <math.h>

#define NQ 8192
#define NA 32768
#define NE 500000
#define F_IN 128
#define E_E2Q 131072
#define E_E2E 800000
#define E_E2A 262144
#define E_Q2A 32768
#define N_POS 8192
#define N_NEG 24576

#define NT_TOTAL (NQ + NA + NE)                      // 540960
#define E_TOTAL (E_E2Q + E_E2E + E_E2A + E_Q2A)      // 1225984
#define NBLK_SCAN ((NT_TOTAL + 1023) / 1024)         // 529
#define CDIV(a, b) (((a) + (b) - 1) / (b))

// dst node index space: [question: 0) [answer: NQ) [entity: NQ+NA)
#define BASE_Q 0
#define BASE_A NQ
#define BASE_E (NQ + NA)
// src (kvpack) index space: [question: 0) [entity: NQ)
#define SRC_Q 0
#define SRC_E NQ

// in-proj block counts (BM=256) for bstats layout
#define NBQ CDIV(NQ, 256)    // 32
#define NBA CDIV(NA, 256)    // 128
#define NBE CDIV(NE, 256)    // 1954

// ---------------- utility ----------------

__global__ void fill_kernel(float* __restrict__ p, float v, size_t n) {
  size_t i = (size_t)blockIdx.x * blockDim.x + threadIdx.x;
  size_t stride = (size_t)gridDim.x * blockDim.x;
  for (; i < n; i += stride) p[i] = v;
}

// ---------------- fp32 GEMM, TMxTN microtile ----------------
// ACT 0: C = A@B + bias (fp32)
// ACT 1: C = relu(...), + per-block column sum/sumsq -> bstats[blk][128]
// ACT 2: C = g*(...) + (1-g)*(resscale⊙res + resshift)
// ACT 3 (BN=192): kqv epilogue -> pack_out fp16 [k|v], qt_out fp32 (no C)

template <int BM, int BN, int TM, int TN, int KTOT, int ACT>
__global__ __launch_bounds__((BM / TM) * (BN / TN)) void gemm_fp32(
    const float* __restrict__ A, int lda, const float* __restrict__ colscale,
    const float* __restrict__ B, int ldb,
    const float* __restrict__ bias,
    float* __restrict__ C, int ldc, int M,
    const float* __restrict__ res, int ldres,
    const float* __restrict__ resscale, const float* __restrict__ resshift,
    const float* __restrict__ skip_ptr, int skip_idx,
    float* __restrict__ bstats, __half* __restrict__ pack_out,
    float* __restrict__ qt_out)
{
  constexpr int NTHR = (BM / TM) * (BN / TN);
  constexpr int CT = BN / TN;
  __shared__ __align__(16) float As[16][BM + 4];
  __shared__ __align__(16) float Bs[16][BN + 4];
  __shared__ float s1[BN], s2[BN];
  int tid = threadIdx.x;
  int tx = tid % CT, ty = tid / CT;
  int row0 = blockIdx.x * BM;
  float acc[TM][TN] = {};
  for (int k0 = 0; k0 < KTOT; k0 += 16) {
    for (int i4 = tid; i4 < BM * 4; i4 += NTHR) {
      int m = i4 >> 2, kq = (i4 & 3) * 4;
      int gr = row0 + m;
      float4 a4 = make_float4(0.f, 0.f, 0.f, 0.f);
      if (gr < M) a4 = *(const float4*)&A[(size_t)gr * lda + k0 + kq];
      if (colscale) {
        float4 cs = *(const float4*)&colscale[k0 + kq];
        a4.x *= cs.x; a4.y *= cs.y; a4.z *= cs.z; a4.w *= cs.w;
      }
      As[kq + 0][m] = a4.x; As[kq + 1][m] = a4.y;
      As[kq + 2][m] = a4.z; As[kq + 3][m] = a4.w;
    }
    for (int i4 = tid; i4 < BN * 4; i4 += NTHR) {
      int kb = i4 / (BN / 4), n4 = (i4 % (BN / 4)) * 4;
      *(float4*)&Bs[kb][n4] = *(const float4*)&B[(size_t)(k0 + kb) * ldb + n4];
    }
    __syncthreads();
#pragma unroll
    for (int kk = 0; kk < 16; ++kk) {
      float a[TM], b[TN];
#pragma unroll
      for (int i = 0; i < TM; i += 4) {
        float4 t4 = *(const float4*)&As[kk][ty * TM + i];
        a[i] = t4.x; a[i + 1] = t4.y; a[i + 2] = t4.z; a[i + 3] = t4.w;
      }
#pragma unroll
      for (int j = 0; j < TN; j += 4) {
        float4 t4 = *(const float4*)&Bs[kk][tx * TN + j];
        b[j] = t4.x; b[j + 1] = t4.y; b[j + 2] = t4.z; b[j + 3] = t4.w;
      }
#pragma unroll
      for (int i = 0; i < TM; ++i)
#pragma unroll
        for (int j = 0; j < TN; ++j)
          acc[i][j] = fmaf(a[i], b[j], acc[i][j]);
    }
    __syncthreads();
  }
  // epilogue
  float bia[TN];
#pragma unroll
  for (int j = 0; j < TN; j += 4) {
    float4 t4 = *(const float4*)&bias[tx * TN + j];
    bia[j] = t4.x; bia[j + 1] = t4.y; bia[j + 2] = t4.z; bia[j + 3] = t4.w;
  }

  if (ACT == 3) {
#pragma unroll
    for (int i = 0; i < TM; ++i) {
      int row = row0 + ty * TM + i;
      if (row >= M) break;
#pragma unroll
      for (int j = 0; j < TN; ++j) {
        int c = tx * TN + j;
        float x = acc[i][j] + bia[j];
        if (c < 64) pack_out[(size_t)row * 128 + c] = __float2half(x);
        else if (c < 128) qt_out[(size_t)row * 64 + (c - 64)] = x;
        else pack_out[(size_t)row * 128 + 64 + (c - 128)] = __float2half(x);
      }
    }
    return;
  }

  float g = 1.f, gb = 0.f;
  if (ACT == 2) { g = 1.f / (1.f + expf(-skip_ptr[skip_idx])); gb = 1.f - g; }
  float rsc[TN], rsh[TN];
  if (ACT == 2) {
#pragma unroll
    for (int j = 0; j < TN; j += 4) {
      float4 t4 = *(const float4*)&resscale[tx * TN + j];
      rsc[j] = t4.x; rsc[j + 1] = t4.y; rsc[j + 2] = t4.z; rsc[j + 3] = t4.w;
      float4 u4 = *(const float4*)&resshift[tx * TN + j];
      rsh[j] = u4.x; rsh[j + 1] = u4.y; rsh[j + 2] = u4.z; rsh[j + 3] = u4.w;
    }
  }
  float ps1[TN] = {}, ps2[TN] = {};
#pragma unroll
  for (int i = 0; i < TM; ++i) {
    int row = row0 + ty * TM + i;
    if (row >= M) break;
#pragma unroll
    for (int j = 0; j < TN; j += 4) {
      float v[4];
      float4 rv = make_float4(0.f, 0.f, 0.f, 0.f);
      if (ACT == 2) rv = *(const float4*)&res[(size_t)row * ldres + tx * TN + j];
      float rvv[4] = {rv.x, rv.y, rv.z, rv.w};
#pragma unroll
      for (int c = 0; c < 4; ++c) {
        float x = acc[i][j + c] + bia[j + c];
        if (ACT == 1) {
          x = fmaxf(x, 0.f);
          ps1[j + c] += x;
          ps2[j + c] += x * x;
        }
        if (ACT == 2) x = g * x + gb * (rsc[j + c] * rvv[c] + rsh[j + c]);
        v[c] = x;
      }
      *(float4*)&C[(size_t)row * ldc + tx * TN + j] =
          make_float4(v[0], v[1], v[2], v[3]);
    }
  }
  if (ACT == 1) {
    if (tid < BN) { s1[tid] = 0.f; s2[tid] = 0.f; }
    __syncthreads();
#pragma unroll
    for (int j = 0; j < TN; ++j) {
      atomicAdd(&s1[tx * TN + j], ps1[j]);
      atomicAdd(&s2[tx * TN + j], ps2[j]);
    }
    __syncthreads();
    if (tid < BN) {
      bstats[(size_t)blockIdx.x * 128 + tid] = s1[tid];
      bstats[(size_t)blockIdx.x * 128 + 64 + tid] = s2[tid];
    }
  }
}

// ---------------- BN: reduce per-block stats, finalize scale/shift ----------------

__global__ void stats_reduce(const float* __restrict__ bstats, float* __restrict__ stats) {
  int t = blockIdx.x;            // 0=q 1=a 2=e
  int c = threadIdx.x;           // 0..127
  int nb = (t == 0) ? NBQ : (t == 1) ? NBA : NBE;
  int base = (t == 0) ? 0 : (t == 1) ? NBQ : (NBQ + NBA);
  float s = 0.f;
  for (int i = 0; i < nb; ++i) s += bstats[(size_t)(base + i) * 128 + c];
  stats[t * 128 + c] = s;
}

__global__ void bn_finalize(const float* __restrict__ stats,
                            const float* __restrict__ gamma, const float* __restrict__ beta,
                            float* __restrict__ scale, float* __restrict__ shift) {
  int t = threadIdx.x;
  if (t >= 192) return;
  int ty = t >> 6, c = t & 63;
  float invN = (ty == 0) ? (1.f / NQ) : (ty == 1) ? (1.f / NA) : (1.f / NE);
  float mu = stats[ty * 128 + c] * invN;
  float var = stats[ty * 128 + 64 + c] * invN - mu * mu;
  float rs = rsqrtf(var + 1e-5f);
  float gm = gamma[ty * 64 + c];
  scale[t] = gm * rs;
  shift[t] = beta[ty * 64 + c] - gm * mu * rs;
}

// bias2[t][n] = b_kqv[t][n] + sum_k shift[t][k] * W_kqv[t][k][n]
__global__ void kqv_bias2(const float* __restrict__ b_kqv, const float* __restrict__ W_kqv,
                          const float* __restrict__ shift, float* __restrict__ bias2) {
  int t = blockIdx.x, n = threadIdx.x;
  float s = b_kqv[t * 192 + n];
  for (int k = 0; k < 64; ++k)
    s += shift[t * 64 + k] * W_kqv[(size_t)t * 64 * 192 + k * 192 + n];
  bias2[t * 192 + n] = s;
}

// ---------------- weight prep: fold A_k into q-columns of W_kqv ----------------
// Wq[64][192] = [k | qt(rel0) | v]   (question)
// We[64][192] = [k | qt(rel1) | v]   (entity)
// Wa[64][128] = [qt(rel2) | qt(rel3)] (answer)
// bias_big[512] = [q:192 | e:192 | a:128]

__global__ void wprep(const float* __restrict__ W_kqv, const float* __restrict__ bias2,
                      const float* __restrict__ A_k,
                      float* __restrict__ Wq, float* __restrict__ We, float* __restrict__ Wa,
                      float* __restrict__ bias_big) {
  int j = blockIdx.x;   // 0..511
  int c = threadIdx.x;  // 0..63
  int t, jj, ldw, bofs;
  float* W;
  if (j < 192)      { t = 0; jj = j;       W = Wq; ldw = 192; bofs = 0; }
  else if (j < 384) { t = 2; jj = j - 192; W = We; ldw = 192; bofs = 192; }
  else              { t = 1; jj = j - 384; W = Wa; ldw = 128; bofs = 384; }
  const float* Wt = W_kqv + (size_t)t * 64 * 192;
  const float* b2 = bias2 + t * 192;
  bool isqt = false;
  int rel = 0, h = 0, d = 0;
  if (t == 1) { isqt = true; rel = (jj < 64) ? 2 : 3; h = (jj & 63) >> 5; d = jj & 31; }
  else if (jj >= 64 && jj < 128) {
    isqt = true; rel = (t == 0) ? 0 : 1; h = (jj - 64) >> 5; d = jj & 31;
  }
  float wv, bv;
  if (isqt) {
    const float* Ar = A_k + ((size_t)rel * 2048 + h * 1024 + d * 32);
    float s = 0.f, sb = 0.f;
    for (int ff = 0; ff < 32; ++ff) {
      float a = Ar[ff];
      s = fmaf(a, Wt[(size_t)c * 192 + 64 + h * 32 + ff], s);
      sb = fmaf(a, b2[64 + h * 32 + ff], sb);
    }
    wv = s; bv = sb;
  } else {
    wv = Wt[(size_t)c * 192 + jj];
    bv = b2[jj];
  }
  W[(size_t)c * ldw + jj] = wv;
  if (c == 0) bias_big[bofs + jj] = bv;
}

// ---------------- CSR build ----------------

__global__ void hist_kernel(const int* __restrict__ dst, int E,
                            unsigned* __restrict__ cnt, int base) {
  int i = blockIdx.x * blockDim.x + threadIdx.x;
  int stride = gridDim.x * blockDim.x;
  for (; i < E; i += stride) atomicAdd(&cnt[base + dst[i]], 1u);
}

__global__ __launch_bounds__(256) void scan1(unsigned* __restrict__ arr, int n,
                                             unsigned* __restrict__ bsums) {
  __shared__ unsigned sh[256];
  int t = threadIdx.x;
  int base = blockIdx.x * 1024 + t * 4;
  unsigned v[4];
  unsigned s = 0;
#pragma unroll
  for (int j = 0; j < 4; ++j) {
    v[j] = (base + j < n) ? arr[base + j] : 0u;
    s += v[j];
  }
  sh[t] = s;
  __syncthreads();
  for (int off = 1; off < 256; off <<= 1) {
    unsigned x = (t >= off) ? sh[t - off] : 0u;
    __syncthreads();
    sh[t] += x;
    __syncthreads();
  }
  unsigned run = sh[t] - s;
#pragma unroll
  for (int j = 0; j < 4; ++j) {
    if (base + j < n) arr[base + j] = run;
    run += v[j];
  }
  if (t == 255) bsums[blockIdx.x] = sh[255];
}

__global__ __launch_bounds__(256) void scan2(unsigned* __restrict__ bsums, int nb) {
  __shared__ unsigned sh[256];
  __shared__ unsigned carry;
  int t = threadIdx.x;
  if (t == 0) carry = 0;
  __syncthreads();
  for (int chunk = 0; chunk < nb; chunk += 256) {
    int i = chunk + t;
    unsigned v = (i < nb) ? bsums[i] : 0u;
    sh[t] = v;
    __syncthreads();
    for (int off = 1; off < 256; off <<= 1) {
      unsigned x = (t >= off) ? sh[t - off] : 0u;
      __syncthreads();
      sh[t] += x;
      __syncthreads();
    }
    unsigned inc = sh[t];
    unsigned c = carry;
    __syncthreads();
    if (i < nb) bsums[i] = c + inc - v;
    if (t == 255) carry = c + sh[255];
    __syncthreads();
  }
}

__global__ __launch_bounds__(256) void scan3(unsigned* __restrict__ arr,
                                             const unsigned* __restrict__ bsums,
                                             unsigned* __restrict__ cursor, int n) {
  int t = threadIdx.x;
  int base = blockIdx.x * 1024 + t * 4;
  unsigned add = bsums[blockIdx.x];
#pragma unroll
  for (int j = 0; j < 4; ++j) {
    int idx = base + j;
    if (idx < n) {
      unsigned r = arr[idx] + add;
      arr[idx] = r;
      cursor[idx] = r;
    }
  }
}

// payload = src index in kvpack space | slot<<20
__global__ void scatter_kernel(const int* __restrict__ src, const int* __restrict__ dst, int E,
                               unsigned* __restrict__ cursor, unsigned* __restrict__ eidx,
                               int dstbase, int srcbase, unsigned slot) {
  int i = blockIdx.x * blockDim.x + threadIdx.x;
  int stride = gridDim.x * blockDim.x;
  for (; i < E; i += stride) {
    unsigned pos = atomicAdd(&cursor[dstbase + dst[i]], 1u);
    eidx[pos] = (unsigned)(srcbase + src[i]) | (slot << 20);
  }
}

// ---------------- gather: softmax-weighted aggregation per dst node ----------------
// kvpack rows: 256B contiguous = [k fp16 x64 | v fp16 x64] -> 2 cache lines/edge.

template <int NREL>
__global__ __launch_bounds__(256) void gather_kernel(
    int N, int nodebase,
    const unsigned* __restrict__ row_start, const unsigned* __restrict__ row_end,
    const unsigned* __restrict__ eidx,
    const __half* __restrict__ kvpack,
    const float* __restrict__ qtbase, int qtstride, int qt1off,
    const float* __restrict__ Av0, const float* __restrict__ Av1,
    const float* __restrict__ prel0, const float* __restrict__ prel1,
    float* __restrict__ agg)
{
  int lane = threadIdx.x & 63;
  int h = lane >> 5, f = lane & 31;
  float av0[32], av1[32];
#pragma unroll
  for (int dd = 0; dd < 32; ++dd) av0[dd] = Av0[h * 1024 + dd * 32 + f];
  if (NREL == 2) {
#pragma unroll
    for (int dd = 0; dd < 32; ++dd) av1[dd] = Av1[h * 1024 + dd * 32 + f];
  }
  const float isd = 0.17677669529663687f;
  float pr0 = prel0[h] * isd;
  float pr1 = (NREL == 2) ? prel1[h] * isd : 0.f;

  int wid = (int)((blockIdx.x * blockDim.x + threadIdx.x) >> 6);
  int nw = (int)((gridDim.x * blockDim.x) >> 6);
  for (int n = wid; n < N; n += nw) {
    float qt0v = qtbase[(size_t)n * qtstride + lane];
    float qt1v = (NREL == 2) ? qtbase[(size_t)n * qtstride + qt1off + lane] : 0.f;
    unsigned i0 = row_start[nodebase + n];
    unsigned i1 = row_end[nodebase + n];
    float vs0 = 0.f, vs1 = 0.f, ss = 0.f;
    unsigned i = i0;
    for (; i + 2 <= i1; i += 2) {
      unsigned p1 = eidx[i], p2 = eidx[i + 1];
      unsigned s1i = p1 & 0xFFFFFu, s2i = p2 & 0xFFFFFu;
      bool r1 = (NREL == 2) && (p1 >> 20);
      bool r2 = (NREL == 2) && (p2 >> 20);
      const __half* kv1 = kvpack + (size_t)s1i * 128;
      const __half* kv2 = kvpack + (size_t)s2i * 128;
      float k1 = __half2float(kv1[lane]);
      float v1 = __half2float(kv1[64 + lane]);
      float k2 = __half2float(kv2[lane]);
      float v2 = __half2float(kv2[64 + lane]);
      float sa = k1 * (r1 ? qt1v : qt0v);
      float sb = k2 * (r2 ? qt1v : qt0v);
#pragma unroll
      for (int off = 16; off > 0; off >>= 1) {
        sa += __shfl_xor(sa, off, 32);
        sb += __shfl_xor(sb, off, 32);
      }
      float w1 = expf(sa * (r1 ? pr1 : pr0));
      float w2 = expf(sb * (r2 ? pr1 : pr0));
      ss += w1 + w2;
      if (NREL == 2) {
        float wv1 = w1 * v1, wv2 = w2 * v2;
        vs0 += (r1 ? 0.f : wv1) + (r2 ? 0.f : wv2);
        vs1 += (r1 ? wv1 : 0.f) + (r2 ? wv2 : 0.f);
      } else {
        vs0 = fmaf(w1, v1, vs0);
        vs0 = fmaf(w2, v2, vs0);
      }
    }
    if (i < i1) {
      unsigned p1 = eidx[i];
      unsigned s1i = p1 & 0xFFFFFu;
      bool r1 = (NREL == 2) && (p1 >> 20);
      const __half* kv1 = kvpack + (size_t)s1i * 128;
      float k1 = __half2float(kv1[lane]);
      float v1 = __half2float(kv1[64 + lane]);
      float sa = k1 * (r1 ? qt1v : qt0v);
#pragma unroll
      for (int off = 16; off > 0; off >>= 1) sa += __shfl_xor(sa, off, 32);
      float w1 = expf(sa * (r1 ? pr1 : pr0));
      ss += w1;
      if (NREL == 2) {
        float wv1 = w1 * v1;
        vs0 += r1 ? 0.f : wv1;
        vs1 += r1 ? wv1 : 0.f;
      } else {
        vs0 = fmaf(w1, v1, vs0);
      }
    }
    // A_v transform: 4 parallel partial chains
    float o0 = 0.f, o1 = 0.f, o2 = 0.f, o3 = 0.f;
#pragma unroll
    for (int dd = 0; dd < 8; ++dd) {
      o0 = fmaf(av0[dd], __shfl(vs0, dd, 32), o0);
      o1 = fmaf(av0[dd + 8], __shfl(vs0, dd + 8, 32), o1);
      o2 = fmaf(av0[dd + 16], __shfl(vs0, dd + 16, 32), o2);
      o3 = fmaf(av0[dd + 24], __shfl(vs0, dd + 24, 32), o3);
    }
    if (NREL == 2) {
#pragma unroll
      for (int dd = 0; dd < 8; ++dd) {
        o0 = fmaf(av1[dd], __shfl(vs1, dd, 32), o0);
        o1 = fmaf(av1[dd + 8], __shfl(vs1, dd + 8, 32), o1);
        o2 = fmaf(av1[dd + 16], __shfl(vs1, dd + 16, 32), o2);
        o3 = fmaf(av1[dd + 24], __shfl(vs1, dd + 24, 32), o3);
      }
    }
    float o = (o0 + o1) + (o2 + o3);
    float val = (ss > 0.f) ? o / ss : 0.f;
    val = 0.5f * val * (1.f + erff(val * 0.70710678118654752f));
    agg[((size_t)(nodebase + n)) * 64 + lane] = val;
  }
}

// ---------------- final predictions ----------------

__global__ void pred_kernel(const int* __restrict__ qi, const int* __restrict__ ai, int Np,
                            const float* __restrict__ zq, const float* __restrict__ za,
                            float* __restrict__ outp) {
  int i = blockIdx.x * blockDim.x + threadIdx.x;
  if (i >= Np) return;
  const float4* a = (const float4*)(zq + (size_t)qi[i] * 64);
  const float4* b = (const float4*)(za + (size_t)ai[i] * 64);
  float ssum = 0.f;
#pragma unroll
  for (int j = 0; j < 16; ++j) {
    float4 x = a[j], y = b[j];
    ssum += x.x * y.x + x.y * y.y + x.z * y.z + x.w * y.w;
  }
  outp[i] = ssum;
}

// ---------------- host launch ----------------

extern "C" void kernel_launch(void* const* d_in, const int* in_sizes, int n_in,
                              void* d_out, int out_size, void* d_ws, size_t ws_size,
                              hipStream_t stream) {
  const float* xq = (const float*)d_in[0];
  const float* xa = (const float*)d_in[1];
  const float* xe = (const float*)d_in[2];
  const int* e_e2q = (const int*)d_in[3];
  const int* e_e2e = (const int*)d_in[4];
  const int* e_e2a = (const int*)d_in[5];
  const int* e_q2a = (const int*)d_in[6];
  const int* pos_idx = (const int*)d_in[7];
  const int* neg_idx = (const int*)d_in[8];
  const float* W_in = (const float*)d_in[9];
  const float* b_in = (const float*)d_in[10];
  const float* bn_gamma = (const float*)d_in[11];
  const float* bn_beta = (const float*)d_in[12];
  const float* W_kqv = (const float*)d_in[13];
  const float* b_kqv = (const float*)d_in[14];
  const float* A_k = (const float*)d_in[15];
  const float* A_v = (const float*)d_in[16];
  const float* p_rel = (const float*)d_in[17];
  const float* W_out = (const float*)d_in[18];
  const float* b_out = (const float*)d_in[19];
  const float* skip = (const float*)d_in[20];
  float* out = (float*)d_out;

  float* ws = (float*)d_ws;
  size_t off = 0;
  float* y_all = ws;           off += (size_t)NT_TOTAL * 64;
  __half* kvpack = (__half*)(ws + off); off += (size_t)(NQ + NE) * 64;  // 128 halves/row
  float* qt_qe = ws + off;     off += (size_t)(NQ + NE) * 64;
  float* kqv_a = ws + off;     off += (size_t)NA * 128;
  float* agg_all = ws + off;   off += (size_t)NT_TOTAL * 64;
  float* stats = ws + off;     off += 384;
  float* scale = ws + off;     off += 192;
  float* shift = ws + off;     off += 192;
  float* bias2 = ws + off;     off += 576;
  float* Wq = ws + off;        off += 64 * 192;
  float* We = ws + off;        off += 64 * 192;
  float* Wa = ws + off;        off += 64 * 128;
  float* bias_big = ws + off;  off += 512;
  float* bstats = ws + off;    off += (size_t)(NBQ + NBA + NBE) * 128;
  unsigned* row_start = (unsigned*)(ws + off); off += NT_TOTAL;
  unsigned* cursor = (unsigned*)(ws + off);    off += NT_TOTAL;
  unsigned* bsums = (unsigned*)(ws + off);     off += 1024;
  unsigned* eidx = (unsigned*)(ws + off);      off += E_TOTAL;

  const int Ns[3] = {NQ, NA, NE};
  const float* xs[3] = {xq, xa, xe};
  float* ybase[3] = {y_all, y_all + (size_t)NQ * 64, y_all + (size_t)(NQ + NA) * 64};
  float* aggbase[3] = {agg_all, agg_all + (size_t)NQ * 64, agg_all + (size_t)(NQ + NA) * 64};
  float* zq_out = out + (N_POS + N_NEG);
  float* zbase[3] = {zq_out, zq_out + (size_t)NQ * 64, zq_out + (size_t)(NQ + NA) * 64};
  const int bb[3] = {0, NBQ, NBQ + NBA};

  fill_kernel<<<dim3(128), dim3(256), 0, stream>>>((float*)row_start, 0.f, NT_TOTAL);

  // ---- in-proj + relu -> y, with fused per-block BN stats ----
  for (int t = 0; t < 3; ++t) {
    gemm_fp32<256, 64, 8, 8, 128, 1><<<dim3(CDIV(Ns[t], 256)), dim3(256), 0, stream>>>(
        xs[t], F_IN, nullptr, W_in + (size_t)t * F_IN * 64, 64, b_in + t * 64,
        ybase[t], 64, Ns[t], nullptr, 0, nullptr, nullptr, nullptr, 0,
        bstats + (size_t)bb[t] * 128, nullptr, nullptr);
  }
  stats_reduce<<<dim3(3), dim3(128), 0, stream>>>(bstats, stats);
  bn_finalize<<<dim3(1), dim3(192), 0, stream>>>(stats, bn_gamma, bn_beta, scale, shift);
  kqv_bias2<<<dim3(3), dim3(192), 0, stream>>>(b_kqv, W_kqv, shift, bias2);
  wprep<<<dim3(512), dim3(64), 0, stream>>>(W_kqv, bias2, A_k, Wq, We, Wa, bias_big);

  // ---- kqv projections (BN + A_k folded; q/e write fp16 kv-pack + fp32 qt) ----
  gemm_fp32<128, 192, 8, 12, 64, 3><<<dim3(CDIV(NQ, 128)), dim3(256), 0, stream>>>(
      ybase[0], 64, scale, Wq, 192, bias_big, nullptr, 0, NQ,
      nullptr, 0, nullptr, nullptr, nullptr, 0, nullptr, kvpack, qt_qe);
  gemm_fp32<128, 192, 8, 12, 64, 3><<<dim3(CDIV(NE, 128)), dim3(256), 0, stream>>>(
      ybase[2], 64, scale + 128, We, 192, bias_big + 192, nullptr, 0, NE,
      nullptr, 0, nullptr, nullptr, nullptr, 0, nullptr,
      kvpack + (size_t)NQ * 128, qt_qe + (size_t)NQ * 64);
  gemm_fp32<128, 128, 8, 8, 64, 0><<<dim3(CDIV(NA, 128)), dim3(256), 0, stream>>>(
      ybase[1], 64, scale + 64, Wa, 128, bias_big + 384, kqv_a, 128, NA,
      nullptr, 0, nullptr, nullptr, nullptr, 0, nullptr, nullptr, nullptr);

  // ---- CSR build ----
  struct Rel { const int* ei; int E; int srcbase; int dstbase; unsigned slot; };
  Rel rels[4] = {{e_e2q, E_E2Q, SRC_E, BASE_Q, 0u},
                 {e_e2e, E_E2E, SRC_E, BASE_E, 0u},
                 {e_e2a, E_E2A, SRC_E, BASE_A, 0u},
                 {e_q2a, E_Q2A, SRC_Q, BASE_A, 1u}};
  for (int r = 0; r < 4; ++r) {
    int blocks = CDIV(rels[r].E, 256); if (blocks > 2048) blocks = 2048;
    hist_kernel<<<dim3(blocks), dim3(256), 0, stream>>>(rels[r].ei + rels[r].E, rels[r].E,
                                                        row_start, rels[r].dstbase);
  }
  scan1<<<dim3(NBLK_SCAN), dim3(256), 0, stream>>>(row_start, NT_TOTAL, bsums);
  scan2<<<dim3(1), dim3(256), 0, stream>>>(bsums, NBLK_SCAN);
  scan3<<<dim3(NBLK_SCAN), dim3(256), 0, stream>>>(row_start, bsums, cursor, NT_TOTAL);
  for (int r = 0; r < 4; ++r) {
    int blocks = CDIV(rels[r].E, 256); if (blocks > 2048) blocks = 2048;
    scatter_kernel<<<dim3(blocks), dim3(256), 0, stream>>>(
        rels[r].ei, rels[r].ei + rels[r].E, rels[r].E, cursor, eidx,
        rels[r].dstbase, rels[r].srcbase, rels[r].slot);
  }

  // ---- gathers ----
  gather_kernel<1><<<dim3(CDIV(NQ, 4)), dim3(256), 0, stream>>>(
      NQ, BASE_Q, row_start, cursor, eidx, kvpack,
      qt_qe, 64, 0, A_v, A_v, p_rel, p_rel, agg_all);
  gather_kernel<1><<<dim3(4096), dim3(256), 0, stream>>>(
      NE, BASE_E, row_start, cursor, eidx, kvpack,
      qt_qe + (size_t)NQ * 64, 64, 0, A_v + 1 * 2048, A_v + 1 * 2048,
      p_rel + 2, p_rel + 2, agg_all);
  gather_kernel<2><<<dim3(CDIV(NA, 4)), dim3(256), 0, stream>>>(
      NA, BASE_A, row_start, cursor, eidx, kvpack,
      kqv_a, 128, 64, A_v + 2 * 2048, A_v + 3 * 2048, p_rel + 4, p_rel + 6, agg_all);

  // ---- out projection + skip blend ----
  for (int t = 0; t < 3; ++t) {
    gemm_fp32<256, 64, 8, 8, 64, 2><<<dim3(CDIV(Ns[t], 256)), dim3(256), 0, stream>>>(
        aggbase[t], 64, nullptr, W_out + (size_t)t * 64 * 64, 64, b_out + t * 64,
        zbase[t], 64, Ns[t], ybase[t], 64, scale + t * 64, shift + t * 64, skip, t,
        nullptr, nullptr, nullptr);
  }

  // ---- predictions ----
  pred_kernel<<<dim3(CDIV(N_POS, 256)), dim3(256), 0, stream>>>(
      pos_idx, pos_idx + N_POS, N_POS, zbase[0], zbase[1], out);
  pred_kernel<<<dim3(CDIV(N_NEG, 256)), dim3(256), 0, stream>>>(
      neg_idx, neg_idx + N_NEG, N_NEG, zbase[0], zbase[1], out + N_POS);
}

// Round 7
// 1386.587 us; speedup vs baseline: 1.3949x; 1.3949x over previous
//
#include <hip/hip_runtime.h>
#include <hip/hip_bf16.h>
#include <hip/hip_fp16.h>
#include <math.h>

#define NQ 8192
#define NA 32768
#define NE 500000
#define F_IN 128
#define E_E2Q 131072
#define E_E2E 800000
#define E_E2A 262144
#define E_Q2A 32768
#define N_POS 8192
#define N_NEG 24576

#define NT_TOTAL (NQ + NA + NE)                      // 540960
#define E_TOTAL (E_E2Q + E_E2E + E_E2A + E_Q2A)      // 1225984
#define NBLK_SCAN ((NT_TOTAL + 1023) / 1024)         // 529
#define CDIV(a, b) (((a) + (b) - 1) / (b))

// dst node index space: [question: 0) [answer: NQ) [entity: NQ+NA)
#define BASE_Q 0
#define BASE_A NQ
#define BASE_E (NQ + NA)
// src (kvpack) index space: [question: 0) [entity: NQ)
#define SRC_Q 0
#define SRC_E NQ

// in-proj block counts (BM=256) for bstats layout
#define NBQ CDIV(NQ, 256)    // 32
#define NBA CDIV(NA, 256)    // 128
#define NBE CDIV(NE, 256)    // 1954

// ---------------- utility ----------------

__global__ void fill_kernel(float* __restrict__ p, float v, size_t n) {
  size_t i = (size_t)blockIdx.x * blockDim.x + threadIdx.x;
  size_t stride = (size_t)gridDim.x * blockDim.x;
  for (; i < n; i += stride) p[i] = v;
}

// ---------------- fp32 GEMM, TMxTN microtile ----------------
// ACT 0: C = A@B + bias (fp32)
// ACT 1: C = relu(...), + per-block column sum/sumsq -> bstats[blk][128]
// ACT 2: C = g*(...) + (1-g)*(resscale⊙res + resshift)
// ACT 3 (BN=192): kqv epilogue -> pack_out fp16 [k|v], qt_out fp32 (no C)

template <int BM, int BN, int TM, int TN, int KTOT, int ACT>
__global__ __launch_bounds__((BM / TM) * (BN / TN)) void gemm_fp32(
    const float* __restrict__ A, int lda, const float* __restrict__ colscale,
    const float* __restrict__ B, int ldb,
    const float* __restrict__ bias,
    float* __restrict__ C, int ldc, int M,
    const float* __restrict__ res, int ldres,
    const float* __restrict__ resscale, const float* __restrict__ resshift,
    const float* __restrict__ skip_ptr, int skip_idx,
    float* __restrict__ bstats, __half* __restrict__ pack_out,
    float* __restrict__ qt_out)
{
  constexpr int NTHR = (BM / TM) * (BN / TN);
  constexpr int CT = BN / TN;
  __shared__ __align__(16) float As[16][BM + 4];
  __shared__ __align__(16) float Bs[16][BN + 4];
  __shared__ float s1[BN], s2[BN];
  int tid = threadIdx.x;
  int tx = tid % CT, ty = tid / CT;
  int row0 = blockIdx.x * BM;
  float acc[TM][TN] = {};
  for (int k0 = 0; k0 < KTOT; k0 += 16) {
    for (int i4 = tid; i4 < BM * 4; i4 += NTHR) {
      int m = i4 >> 2, kq = (i4 & 3) * 4;
      int gr = row0 + m;
      float4 a4 = make_float4(0.f, 0.f, 0.f, 0.f);
      if (gr < M) a4 = *(const float4*)&A[(size_t)gr * lda + k0 + kq];
      if (colscale) {
        float4 cs = *(const float4*)&colscale[k0 + kq];
        a4.x *= cs.x; a4.y *= cs.y; a4.z *= cs.z; a4.w *= cs.w;
      }
      As[kq + 0][m] = a4.x; As[kq + 1][m] = a4.y;
      As[kq + 2][m] = a4.z; As[kq + 3][m] = a4.w;
    }
    for (int i4 = tid; i4 < BN * 4; i4 += NTHR) {
      int kb = i4 / (BN / 4), n4 = (i4 % (BN / 4)) * 4;
      *(float4*)&Bs[kb][n4] = *(const float4*)&B[(size_t)(k0 + kb) * ldb + n4];
    }
    __syncthreads();
#pragma unroll
    for (int kk = 0; kk < 16; ++kk) {
      float a[TM], b[TN];
#pragma unroll
      for (int i = 0; i < TM; i += 4) {
        float4 t4 = *(const float4*)&As[kk][ty * TM + i];
        a[i] = t4.x; a[i + 1] = t4.y; a[i + 2] = t4.z; a[i + 3] = t4.w;
      }
#pragma unroll
      for (int j = 0; j < TN; j += 4) {
        float4 t4 = *(const float4*)&Bs[kk][tx * TN + j];
        b[j] = t4.x; b[j + 1] = t4.y; b[j + 2] = t4.z; b[j + 3] = t4.w;
      }
#pragma unroll
      for (int i = 0; i < TM; ++i)
#pragma unroll
        for (int j = 0; j < TN; ++j)
          acc[i][j] = fmaf(a[i], b[j], acc[i][j]);
    }
    __syncthreads();
  }
  // epilogue
  float bia[TN];
#pragma unroll
  for (int j = 0; j < TN; j += 4) {
    float4 t4 = *(const float4*)&bias[tx * TN + j];
    bia[j] = t4.x; bia[j + 1] = t4.y; bia[j + 2] = t4.z; bia[j + 3] = t4.w;
  }

  if (ACT == 3) {
#pragma unroll
    for (int i = 0; i < TM; ++i) {
      int row = row0 + ty * TM + i;
      if (row >= M) break;
#pragma unroll
      for (int j = 0; j < TN; ++j) {
        int c = tx * TN + j;
        float x = acc[i][j] + bia[j];
        if (c < 64) pack_out[(size_t)row * 128 + c] = __float2half(x);
        else if (c < 128) qt_out[(size_t)row * 64 + (c - 64)] = x;
        else pack_out[(size_t)row * 128 + 64 + (c - 128)] = __float2half(x);
      }
    }
    return;
  }

  float g = 1.f, gb = 0.f;
  if (ACT == 2) { g = 1.f / (1.f + expf(-skip_ptr[skip_idx])); gb = 1.f - g; }
  float rsc[TN], rsh[TN];
  if (ACT == 2) {
#pragma unroll
    for (int j = 0; j < TN; j += 4) {
      float4 t4 = *(const float4*)&resscale[tx * TN + j];
      rsc[j] = t4.x; rsc[j + 1] = t4.y; rsc[j + 2] = t4.z; rsc[j + 3] = t4.w;
      float4 u4 = *(const float4*)&resshift[tx * TN + j];
      rsh[j] = u4.x; rsh[j + 1] = u4.y; rsh[j + 2] = u4.z; rsh[j + 3] = u4.w;
    }
  }
  float ps1[TN] = {}, ps2[TN] = {};
#pragma unroll
  for (int i = 0; i < TM; ++i) {
    int row = row0 + ty * TM + i;
    if (row >= M) break;
#pragma unroll
    for (int j = 0; j < TN; j += 4) {
      float v[4];
      float4 rv = make_float4(0.f, 0.f, 0.f, 0.f);
      if (ACT == 2) rv = *(const float4*)&res[(size_t)row * ldres + tx * TN + j];
      float rvv[4] = {rv.x, rv.y, rv.z, rv.w};
#pragma unroll
      for (int c = 0; c < 4; ++c) {
        float x = acc[i][j + c] + bia[j + c];
        if (ACT == 1) {
          x = fmaxf(x, 0.f);
          ps1[j + c] += x;
          ps2[j + c] += x * x;
        }
        if (ACT == 2) x = g * x + gb * (rsc[j + c] * rvv[c] + rsh[j + c]);
        v[c] = x;
      }
      *(float4*)&C[(size_t)row * ldc + tx * TN + j] =
          make_float4(v[0], v[1], v[2], v[3]);
    }
  }
  if (ACT == 1) {
    if (tid < BN) { s1[tid] = 0.f; s2[tid] = 0.f; }
    __syncthreads();
#pragma unroll
    for (int j = 0; j < TN; ++j) {
      atomicAdd(&s1[tx * TN + j], ps1[j]);
      atomicAdd(&s2[tx * TN + j], ps2[j]);
    }
    __syncthreads();
    if (tid < BN) {
      bstats[(size_t)blockIdx.x * 128 + tid] = s1[tid];
      bstats[(size_t)blockIdx.x * 128 + 64 + tid] = s2[tid];
    }
  }
}

// ---------------- BN: reduce per-block stats (1 block per type×column) ----------------

__global__ __launch_bounds__(256) void stats_reduce(const float* __restrict__ bstats,
                                                    float* __restrict__ stats) {
  __shared__ float sh[256];
  int t = blockIdx.x >> 7;        // 0=q 1=a 2=e
  int c = blockIdx.x & 127;       // 0..127
  int nb = (t == 0) ? NBQ : (t == 1) ? NBA : NBE;
  int base = (t == 0) ? 0 : (t == 1) ? NBQ : (NBQ + NBA);
  float s = 0.f;
  for (int i = threadIdx.x; i < nb; i += 256)
    s += bstats[(size_t)(base + i) * 128 + c];
  sh[threadIdx.x] = s;
  __syncthreads();
  for (int off2 = 128; off2 > 0; off2 >>= 1) {
    if (threadIdx.x < off2) sh[threadIdx.x] += sh[threadIdx.x + off2];
    __syncthreads();
  }
  if (threadIdx.x == 0) stats[t * 128 + c] = sh[0];
}

__global__ void bn_finalize(const float* __restrict__ stats,
                            const float* __restrict__ gamma, const float* __restrict__ beta,
                            float* __restrict__ scale, float* __restrict__ shift) {
  int t = threadIdx.x;
  if (t >= 192) return;
  int ty = t >> 6, c = t & 63;
  float invN = (ty == 0) ? (1.f / NQ) : (ty == 1) ? (1.f / NA) : (1.f / NE);
  float mu = stats[ty * 128 + c] * invN;
  float var = stats[ty * 128 + 64 + c] * invN - mu * mu;
  float rs = rsqrtf(var + 1e-5f);
  float gm = gamma[ty * 64 + c];
  scale[t] = gm * rs;
  shift[t] = beta[ty * 64 + c] - gm * mu * rs;
}

// bias2[t][n] = b_kqv[t][n] + sum_k shift[t][k] * W_kqv[t][k][n]
__global__ void kqv_bias2(const float* __restrict__ b_kqv, const float* __restrict__ W_kqv,
                          const float* __restrict__ shift, float* __restrict__ bias2) {
  int t = blockIdx.x, n = threadIdx.x;
  float s = b_kqv[t * 192 + n];
  for (int k = 0; k < 64; ++k)
    s += shift[t * 64 + k] * W_kqv[(size_t)t * 64 * 192 + k * 192 + n];
  bias2[t * 192 + n] = s;
}

// ---------------- weight prep: fold A_k into q-columns of W_kqv ----------------
// Wq[64][192] = [k | qt(rel0) | v]   (question)
// We[64][192] = [k | qt(rel1) | v]   (entity)
// Wa[64][128] = [qt(rel2) | qt(rel3)] (answer)
// bias_big[512] = [q:192 | e:192 | a:128]

__global__ void wprep(const float* __restrict__ W_kqv, const float* __restrict__ bias2,
                      const float* __restrict__ A_k,
                      float* __restrict__ Wq, float* __restrict__ We, float* __restrict__ Wa,
                      float* __restrict__ bias_big) {
  int j = blockIdx.x;   // 0..511
  int c = threadIdx.x;  // 0..63
  int t, jj, ldw, bofs;
  float* W;
  if (j < 192)      { t = 0; jj = j;       W = Wq; ldw = 192; bofs = 0; }
  else if (j < 384) { t = 2; jj = j - 192; W = We; ldw = 192; bofs = 192; }
  else              { t = 1; jj = j - 384; W = Wa; ldw = 128; bofs = 384; }
  const float* Wt = W_kqv + (size_t)t * 64 * 192;
  const float* b2 = bias2 + t * 192;
  bool isqt = false;
  int rel = 0, h = 0, d = 0;
  if (t == 1) { isqt = true; rel = (jj < 64) ? 2 : 3; h = (jj & 63) >> 5; d = jj & 31; }
  else if (jj >= 64 && jj < 128) {
    isqt = true; rel = (t == 0) ? 0 : 1; h = (jj - 64) >> 5; d = jj & 31;
  }
  float wv, bv;
  if (isqt) {
    const float* Ar = A_k + ((size_t)rel * 2048 + h * 1024 + d * 32);
    float s = 0.f, sb = 0.f;
    for (int ff = 0; ff < 32; ++ff) {
      float a = Ar[ff];
      s = fmaf(a, Wt[(size_t)c * 192 + 64 + h * 32 + ff], s);
      sb = fmaf(a, b2[64 + h * 32 + ff], sb);
    }
    wv = s; bv = sb;
  } else {
    wv = Wt[(size_t)c * 192 + jj];
    bv = b2[jj];
  }
  W[(size_t)c * ldw + jj] = wv;
  if (c == 0) bias_big[bofs + jj] = bv;
}

// ---------------- CSR build ----------------

__global__ void hist_kernel(const int* __restrict__ dst, int E,
                            unsigned* __restrict__ cnt, int base) {
  int i = blockIdx.x * blockDim.x + threadIdx.x;
  int stride = gridDim.x * blockDim.x;
  for (; i < E; i += stride) atomicAdd(&cnt[base + dst[i]], 1u);
}

__global__ __launch_bounds__(256) void scan1(unsigned* __restrict__ arr, int n,
                                             unsigned* __restrict__ bsums) {
  __shared__ unsigned sh[256];
  int t = threadIdx.x;
  int base = blockIdx.x * 1024 + t * 4;
  unsigned v[4];
  unsigned s = 0;
#pragma unroll
  for (int j = 0; j < 4; ++j) {
    v[j] = (base + j < n) ? arr[base + j] : 0u;
    s += v[j];
  }
  sh[t] = s;
  __syncthreads();
  for (int off = 1; off < 256; off <<= 1) {
    unsigned x = (t >= off) ? sh[t - off] : 0u;
    __syncthreads();
    sh[t] += x;
    __syncthreads();
  }
  unsigned run = sh[t] - s;
#pragma unroll
  for (int j = 0; j < 4; ++j) {
    if (base + j < n) arr[base + j] = run;
    run += v[j];
  }
  if (t == 255) bsums[blockIdx.x] = sh[255];
}

__global__ __launch_bounds__(256) void scan2(unsigned* __restrict__ bsums, int nb) {
  __shared__ unsigned sh[256];
  __shared__ unsigned carry;
  int t = threadIdx.x;
  if (t == 0) carry = 0;
  __syncthreads();
  for (int chunk = 0; chunk < nb; chunk += 256) {
    int i = chunk + t;
    unsigned v = (i < nb) ? bsums[i] : 0u;
    sh[t] = v;
    __syncthreads();
    for (int off = 1; off < 256; off <<= 1) {
      unsigned x = (t >= off) ? sh[t - off] : 0u;
      __syncthreads();
      sh[t] += x;
      __syncthreads();
    }
    unsigned inc = sh[t];
    unsigned c = carry;
    __syncthreads();
    if (i < nb) bsums[i] = c + inc - v;
    if (t == 255) carry = c + sh[255];
    __syncthreads();
  }
}

__global__ __launch_bounds__(256) void scan3(unsigned* __restrict__ arr,
                                             const unsigned* __restrict__ bsums,
                                             unsigned* __restrict__ cursor, int n) {
  int t = threadIdx.x;
  int base = blockIdx.x * 1024 + t * 4;
  unsigned add = bsums[blockIdx.x];
#pragma unroll
  for (int j = 0; j < 4; ++j) {
    int idx = base + j;
    if (idx < n) {
      unsigned r = arr[idx] + add;
      arr[idx] = r;
      cursor[idx] = r;
    }
  }
}

// payload = src index in kvpack space | slot<<20
__global__ void scatter_kernel(const int* __restrict__ src, const int* __restrict__ dst, int E,
                               unsigned* __restrict__ cursor, unsigned* __restrict__ eidx,
                               int dstbase, int srcbase, unsigned slot) {
  int i = blockIdx.x * blockDim.x + threadIdx.x;
  int stride = gridDim.x * blockDim.x;
  for (; i < E; i += stride) {
    unsigned pos = atomicAdd(&cursor[dstbase + dst[i]], 1u);
    eidx[pos] = (unsigned)(srcbase + src[i]) | (slot << 20);
  }
}

// ---------------- gather: softmax-weighted aggregation per dst node ----------------
// kvpack rows: 256B contiguous = [k fp16 x64 | v fp16 x64] -> 2 cache lines/edge.

template <int NREL>
__global__ __launch_bounds__(256) void gather_kernel(
    int N, int nodebase,
    const unsigned* __restrict__ row_start, const unsigned* __restrict__ row_end,
    const unsigned* __restrict__ eidx,
    const __half* __restrict__ kvpack,
    const float* __restrict__ qtbase, int qtstride, int qt1off,
    const float* __restrict__ Av0, const float* __restrict__ Av1,
    const float* __restrict__ prel0, const float* __restrict__ prel1,
    float* __restrict__ agg)
{
  int lane = threadIdx.x & 63;
  int h = lane >> 5, f = lane & 31;
  float av0[32], av1[32];
#pragma unroll
  for (int dd = 0; dd < 32; ++dd) av0[dd] = Av0[h * 1024 + dd * 32 + f];
  if (NREL == 2) {
#pragma unroll
    for (int dd = 0; dd < 32; ++dd) av1[dd] = Av1[h * 1024 + dd * 32 + f];
  }
  const float isd = 0.17677669529663687f;
  float pr0 = prel0[h] * isd;
  float pr1 = (NREL == 2) ? prel1[h] * isd : 0.f;

  int wid = (int)((blockIdx.x * blockDim.x + threadIdx.x) >> 6);
  int nw = (int)((gridDim.x * blockDim.x) >> 6);
  for (int n = wid; n < N; n += nw) {
    float qt0v = qtbase[(size_t)n * qtstride + lane];
    float qt1v = (NREL == 2) ? qtbase[(size_t)n * qtstride + qt1off + lane] : 0.f;
    unsigned i0 = row_start[nodebase + n];
    unsigned i1 = row_end[nodebase + n];
    float vs0 = 0.f, vs1 = 0.f, ss = 0.f;
    unsigned i = i0;
    for (; i + 2 <= i1; i += 2) {
      unsigned p1 = eidx[i], p2 = eidx[i + 1];
      unsigned s1i = p1 & 0xFFFFFu, s2i = p2 & 0xFFFFFu;
      bool r1 = (NREL == 2) && (p1 >> 20);
      bool r2 = (NREL == 2) && (p2 >> 20);
      const __half* kv1 = kvpack + (size_t)s1i * 128;
      const __half* kv2 = kvpack + (size_t)s2i * 128;
      float k1 = __half2float(kv1[lane]);
      float v1 = __half2float(kv1[64 + lane]);
      float k2 = __half2float(kv2[lane]);
      float v2 = __half2float(kv2[64 + lane]);
      float sa = k1 * (r1 ? qt1v : qt0v);
      float sb = k2 * (r2 ? qt1v : qt0v);
#pragma unroll
      for (int off = 16; off > 0; off >>= 1) {
        sa += __shfl_xor(sa, off, 32);
        sb += __shfl_xor(sb, off, 32);
      }
      float w1 = expf(sa * (r1 ? pr1 : pr0));
      float w2 = expf(sb * (r2 ? pr1 : pr0));
      ss += w1 + w2;
      if (NREL == 2) {
        float wv1 = w1 * v1, wv2 = w2 * v2;
        vs0 += (r1 ? 0.f : wv1) + (r2 ? 0.f : wv2);
        vs1 += (r1 ? wv1 : 0.f) + (r2 ? wv2 : 0.f);
      } else {
        vs0 = fmaf(w1, v1, vs0);
        vs0 = fmaf(w2, v2, vs0);
      }
    }
    if (i < i1) {
      unsigned p1 = eidx[i];
      unsigned s1i = p1 & 0xFFFFFu;
      bool r1 = (NREL == 2) && (p1 >> 20);
      const __half* kv1 = kvpack + (size_t)s1i * 128;
      float k1 = __half2float(kv1[lane]);
      float v1 = __half2float(kv1[64 + lane]);
      float sa = k1 * (r1 ? qt1v : qt0v);
#pragma unroll
      for (int off = 16; off > 0; off >>= 1) sa += __shfl_xor(sa, off, 32);
      float w1 = expf(sa * (r1 ? pr1 : pr0));
      ss += w1;
      if (NREL == 2) {
        float wv1 = w1 * v1;
        vs0 += r1 ? 0.f : wv1;
        vs1 += r1 ? wv1 : 0.f;
      } else {
        vs0 = fmaf(w1, v1, vs0);
      }
    }
    // A_v transform: 4 parallel partial chains
    float o0 = 0.f, o1 = 0.f, o2 = 0.f, o3 = 0.f;
#pragma unroll
    for (int dd = 0; dd < 8; ++dd) {
      o0 = fmaf(av0[dd], __shfl(vs0, dd, 32), o0);
      o1 = fmaf(av0[dd + 8], __shfl(vs0, dd + 8, 32), o1);
      o2 = fmaf(av0[dd + 16], __shfl(vs0, dd + 16, 32), o2);
      o3 = fmaf(av0[dd + 24], __shfl(vs0, dd + 24, 32), o3);
    }
    if (NREL == 2) {
#pragma unroll
      for (int dd = 0; dd < 8; ++dd) {
        o0 = fmaf(av1[dd], __shfl(vs1, dd, 32), o0);
        o1 = fmaf(av1[dd + 8], __shfl(vs1, dd + 8, 32), o1);
        o2 = fmaf(av1[dd + 16], __shfl(vs1, dd + 16, 32), o2);
        o3 = fmaf(av1[dd + 24], __shfl(vs1, dd + 24, 32), o3);
      }
    }
    float o = (o0 + o1) + (o2 + o3);
    float val = (ss > 0.f) ? o / ss : 0.f;
    val = 0.5f * val * (1.f + erff(val * 0.70710678118654752f));
    agg[((size_t)(nodebase + n)) * 64 + lane] = val;
  }
}

// ---------------- final predictions ----------------

__global__ void pred_kernel(const int* __restrict__ qi, const int* __restrict__ ai, int Np,
                            const float* __restrict__ zq, const float* __restrict__ za,
                            float* __restrict__ outp) {
  int i = blockIdx.x * blockDim.x + threadIdx.x;
  if (i >= Np) return;
  const float4* a = (const float4*)(zq + (size_t)qi[i] * 64);
  const float4* b = (const float4*)(za + (size_t)ai[i] * 64);
  float ssum = 0.f;
#pragma unroll
  for (int j = 0; j < 16; ++j) {
    float4 x = a[j], y = b[j];
    ssum += x.x * y.x + x.y * y.y + x.z * y.z + x.w * y.w;
  }
  outp[i] = ssum;
}

// ---------------- host launch ----------------

extern "C" void kernel_launch(void* const* d_in, const int* in_sizes, int n_in,
                              void* d_out, int out_size, void* d_ws, size_t ws_size,
                              hipStream_t stream) {
  const float* xq = (const float*)d_in[0];
  const float* xa = (const float*)d_in[1];
  const float* xe = (const float*)d_in[2];
  const int* e_e2q = (const int*)d_in[3];
  const int* e_e2e = (const int*)d_in[4];
  const int* e_e2a = (const int*)d_in[5];
  const int* e_q2a = (const int*)d_in[6];
  const int* pos_idx = (const int*)d_in[7];
  const int* neg_idx = (const int*)d_in[8];
  const float* W_in = (const float*)d_in[9];
  const float* b_in = (const float*)d_in[10];
  const float* bn_gamma = (const float*)d_in[11];
  const float* bn_beta = (const float*)d_in[12];
  const float* W_kqv = (const float*)d_in[13];
  const float* b_kqv = (const float*)d_in[14];
  const float* A_k = (const float*)d_in[15];
  const float* A_v = (const float*)d_in[16];
  const float* p_rel = (const float*)d_in[17];
  const float* W_out = (const float*)d_in[18];
  const float* b_out = (const float*)d_in[19];
  const float* skip = (const float*)d_in[20];
  float* out = (float*)d_out;

  float* ws = (float*)d_ws;
  size_t off = 0;
  float* y_all = ws;           off += (size_t)NT_TOTAL * 64;
  __half* kvpack = (__half*)(ws + off); off += (size_t)(NQ + NE) * 64;  // 128 halves/row
  float* qt_qe = ws + off;     off += (size_t)(NQ + NE) * 64;
  float* kqv_a = ws + off;     off += (size_t)NA * 128;
  float* agg_all = ws + off;   off += (size_t)NT_TOTAL * 64;
  float* stats = ws + off;     off += 384;
  float* scale = ws + off;     off += 192;
  float* shift = ws + off;     off += 192;
  float* bias2 = ws + off;     off += 576;
  float* Wq = ws + off;        off += 64 * 192;
  float* We = ws + off;        off += 64 * 192;
  float* Wa = ws + off;        off += 64 * 128;
  float* bias_big = ws + off;  off += 512;
  float* bstats = ws + off;    off += (size_t)(NBQ + NBA + NBE) * 128;
  unsigned* row_start = (unsigned*)(ws + off); off += NT_TOTAL;
  unsigned* cursor = (unsigned*)(ws + off);    off += NT_TOTAL;
  unsigned* bsums = (unsigned*)(ws + off);     off += 1024;
  unsigned* eidx = (unsigned*)(ws + off);      off += E_TOTAL;

  const int Ns[3] = {NQ, NA, NE};
  const float* xs[3] = {xq, xa, xe};
  float* ybase[3] = {y_all, y_all + (size_t)NQ * 64, y_all + (size_t)(NQ + NA) * 64};
  float* aggbase[3] = {agg_all, agg_all + (size_t)NQ * 64, agg_all + (size_t)(NQ + NA) * 64};
  float* zq_out = out + (N_POS + N_NEG);
  float* zbase[3] = {zq_out, zq_out + (size_t)NQ * 64, zq_out + (size_t)(NQ + NA) * 64};
  const int bb[3] = {0, NBQ, NBQ + NBA};

  fill_kernel<<<dim3(128), dim3(256), 0, stream>>>((float*)row_start, 0.f, NT_TOTAL);

  // ---- in-proj + relu -> y, with fused per-block BN stats ----
  for (int t = 0; t < 3; ++t) {
    gemm_fp32<256, 64, 8, 8, 128, 1><<<dim3(CDIV(Ns[t], 256)), dim3(256), 0, stream>>>(
        xs[t], F_IN, nullptr, W_in + (size_t)t * F_IN * 64, 64, b_in + t * 64,
        ybase[t], 64, Ns[t], nullptr, 0, nullptr, nullptr, nullptr, 0,
        bstats + (size_t)bb[t] * 128, nullptr, nullptr);
  }
  stats_reduce<<<dim3(384), dim3(256), 0, stream>>>(bstats, stats);
  bn_finalize<<<dim3(1), dim3(192), 0, stream>>>(stats, bn_gamma, bn_beta, scale, shift);
  kqv_bias2<<<dim3(3), dim3(192), 0, stream>>>(b_kqv, W_kqv, shift, bias2);
  wprep<<<dim3(512), dim3(64), 0, stream>>>(W_kqv, bias2, A_k, Wq, We, Wa, bias_big);

  // ---- kqv projections (BN + A_k folded; q/e write fp16 kv-pack + fp32 qt) ----
  gemm_fp32<128, 192, 8, 12, 64, 3><<<dim3(CDIV(NQ, 128)), dim3(256), 0, stream>>>(
      ybase[0], 64, scale, Wq, 192, bias_big, nullptr, 0, NQ,
      nullptr, 0, nullptr, nullptr, nullptr, 0, nullptr, kvpack, qt_qe);
  gemm_fp32<128, 192, 8, 12, 64, 3><<<dim3(CDIV(NE, 128)), dim3(256), 0, stream>>>(
      ybase[2], 64, scale + 128, We, 192, bias_big + 192, nullptr, 0, NE,
      nullptr, 0, nullptr, nullptr, nullptr, 0, nullptr,
      kvpack + (size_t)NQ * 128, qt_qe + (size_t)NQ * 64);
  gemm_fp32<128, 128, 8, 8, 64, 0><<<dim3(CDIV(NA, 128)), dim3(256), 0, stream>>>(
      ybase[1], 64, scale + 64, Wa, 128, bias_big + 384, kqv_a, 128, NA,
      nullptr, 0, nullptr, nullptr, nullptr, 0, nullptr, nullptr, nullptr);

  // ---- CSR build ----
  struct Rel { const int* ei; int E; int srcbase; int dstbase; unsigned slot; };
  Rel rels[4] = {{e_e2q, E_E2Q, SRC_E, BASE_Q, 0u},
                 {e_e2e, E_E2E, SRC_E, BASE_E, 0u},
                 {e_e2a, E_E2A, SRC_E, BASE_A, 0u},
                 {e_q2a, E_Q2A, SRC_Q, BASE_A, 1u}};
  for (int r = 0; r < 4; ++r) {
    int blocks = CDIV(rels[r].E, 256); if (blocks > 2048) blocks = 2048;
    hist_kernel<<<dim3(blocks), dim3(256), 0, stream>>>(rels[r].ei + rels[r].E, rels[r].E,
                                                        row_start, rels[r].dstbase);
  }
  scan1<<<dim3(NBLK_SCAN), dim3(256), 0, stream>>>(row_start, NT_TOTAL, bsums);
  scan2<<<dim3(1), dim3(256), 0, stream>>>(bsums, NBLK_SCAN);
  scan3<<<dim3(NBLK_SCAN), dim3(256), 0, stream>>>(row_start, bsums, cursor, NT_TOTAL);
  for (int r = 0; r < 4; ++r) {
    int blocks = CDIV(rels[r].E, 256); if (blocks > 2048) blocks = 2048;
    scatter_kernel<<<dim3(blocks), dim3(256), 0, stream>>>(
        rels[r].ei, rels[r].ei + rels[r].E, rels[r].E, cursor, eidx,
        rels[r].dstbase, rels[r].srcbase, rels[r].slot);
  }

  // ---- gathers ----
  gather_kernel<1><<<dim3(CDIV(NQ, 4)), dim3(256), 0, stream>>>(
      NQ, BASE_Q, row_start, cursor, eidx, kvpack,
      qt_qe, 64, 0, A_v, A_v, p_rel, p_rel, agg_all);
  gather_kernel<1><<<dim3(4096), dim3(256), 0, stream>>>(
      NE, BASE_E, row_start, cursor, eidx, kvpack,
      qt_qe + (size_t)NQ * 64, 64, 0, A_v + 1 * 2048, A_v + 1 * 2048,
      p_rel + 2, p_rel + 2, agg_all);
  gather_kernel<2><<<dim3(CDIV(NA, 4)), dim3(256), 0, stream>>>(
      NA, BASE_A, row_start, cursor, eidx, kvpack,
      kqv_a, 128, 64, A_v + 2 * 2048, A_v + 3 * 2048, p_rel + 4, p_rel + 6, agg_all);

  // ---- out projection + skip blend ----
  for (int t = 0; t < 3; ++t) {
    gemm_fp32<256, 64, 8, 8, 64, 2><<<dim3(CDIV(Ns[t], 256)), dim3(256), 0, stream>>>(
        aggbase[t], 64, nullptr, W_out + (size_t)t * 64 * 64, 64, b_out + t * 64,
        zbase[t], 64, Ns[t], ybase[t], 64, scale + t * 64, shift + t * 64, skip, t,
        nullptr, nullptr, nullptr);
  }

  // ---- predictions ----
  pred_kernel<<<dim3(CDIV(N_POS, 256)), dim3(256), 0, stream>>>(
      pos_idx, pos_idx + N_POS, N_POS, zbase[0], zbase[1], out);
  pred_kernel<<<dim3(CDIV(N_NEG, 256)), dim3(256), 0, stream>>>(
      neg_idx, neg_idx + N_NEG, N_NEG, zbase[0], zbase[1], out + N_POS);
}

// Round 8
// 1083.676 us; speedup vs baseline: 1.7848x; 1.2795x over previous
//
#include <hip/hip_runtime.h>
#include <hip/hip_bf16.h>
#include <hip/hip_fp16.h>
#include <math.h>

#define NQ 8192
#define NA 32768
#define NE 500000
#define F_IN 128
#define E_E2Q 131072
#define E_E2E 800000
#define E_E2A 262144
#define E_Q2A 32768
#define N_POS 8192
#define N_NEG 24576

#define NT_TOTAL (NQ + NA + NE)                      // 540960
#define E_TOTAL (E_E2Q + E_E2E + E_E2A + E_Q2A)      // 1225984
#define NBLK_SCAN ((NT_TOTAL + 1023) / 1024)         // 529
#define CDIV(a, b) (((a) + (b) - 1) / (b))

// dst node index space: [question: 0) [answer: NQ) [entity: NQ+NA)
#define BASE_Q 0
#define BASE_A NQ
#define BASE_E (NQ + NA)
// src (kvpack) index space: [question: 0) [entity: NQ)
#define SRC_Q 0
#define SRC_E NQ

// in-proj block counts (BM=128) for bstats layout
#define NBQ 64      // CDIV(NQ,128)
#define NBA 256     // CDIV(NA,128)
#define NBE 3907    // CDIV(NE,128)

typedef _Float16 half8_t __attribute__((ext_vector_type(8)));
typedef _Float16 half4_t __attribute__((ext_vector_type(4)));
typedef float f32x4_t __attribute__((ext_vector_type(4)));

// ---------------- utility ----------------

__global__ void fill_kernel(float* __restrict__ p, float v, size_t n) {
  size_t i = (size_t)blockIdx.x * blockDim.x + threadIdx.x;
  size_t stride = (size_t)gridDim.x * blockDim.x;
  for (; i < n; i += stride) p[i] = v;
}

// ---------------- MFMA fp16 GEMM (BM=128, 4 waves, full-K in LDS) ----------------
// MODE 0: in-proj:  A=fp32[M][K] cvt, out y fp16[M][64] relu'd + bstats
// MODE 1: kqv q/e:  A=fp16[M][64], N=192 -> pack fp16 [k|v] + qt fp32
// MODE 2: kqv a:    A=fp16[M][64], N=128 -> Cf fp32 [M][128]
// MODE 3: out-proj: A=fp32[M][64] cvt, skip-blend vs fp16 residual -> Cf fp32
// WT: [N][K+8] fp16 pre-transposed, padded. Fragment layout (16x16x32):
//   A: lane row=l&15, k=8*(l>>4)+j ; B: lane col=l&15, same k ; D: col=l&15, row=4*(l>>4)+reg

template <int BN, int KTOT, int MODE>
__global__ __launch_bounds__(256) void gemm_mfma(
    const float* __restrict__ Af, const _Float16* __restrict__ Ah,
    const _Float16* __restrict__ WT, const float* __restrict__ bias, int M,
    float* __restrict__ Cf,
    _Float16* __restrict__ y_out, float* __restrict__ bstats,
    _Float16* __restrict__ pack_out, float* __restrict__ qt_out,
    const _Float16* __restrict__ resh, const float* __restrict__ rsc,
    const float* __restrict__ rsh, const float* __restrict__ skip_ptr, int skip_idx)
{
  constexpr int KP = KTOT + 8;
  __shared__ _Float16 As[128 * KP];
  __shared__ _Float16 Bs[BN * KP];
  __shared__ float s1[64], s2[64];
  int tid = threadIdx.x;
  int row0 = blockIdx.x * 128;
  if (MODE == 0 && tid < 64) { s1[tid] = 0.f; s2[tid] = 0.f; }

  // ---- stage A ----
  if (MODE == 0 || MODE == 3) {
    constexpr int CH = KTOT / 4;
    for (int idx = tid; idx < 128 * CH; idx += 256) {
      int row = idx / CH, c = idx % CH;
      int gr = row0 + row;
      float4 a4 = make_float4(0.f, 0.f, 0.f, 0.f);
      if (gr < M) a4 = *(const float4*)&Af[(size_t)gr * KTOT + c * 4];
      half4_t h4 = {(_Float16)a4.x, (_Float16)a4.y, (_Float16)a4.z, (_Float16)a4.w};
      *(half4_t*)&As[row * KP + c * 4] = h4;
    }
  } else {
    constexpr int CH = KTOT / 8;
    for (int idx = tid; idx < 128 * CH; idx += 256) {
      int row = idx / CH, c = idx % CH;
      int gr = row0 + row;
      half8_t a8 = {};
      if (gr < M) a8 = *(const half8_t*)&Ah[(size_t)gr * KTOT + c * 8];
      *(half8_t*)&As[row * KP + c * 8] = a8;
    }
  }
  // ---- stage B (flat copy, WT already padded) ----
  for (int idx = tid; idx < BN * KP / 8; idx += 256)
    *(half8_t*)&Bs[idx * 8] = *(const half8_t*)&WT[(size_t)idx * 8];
  __syncthreads();

  int w = tid >> 6, l = tid & 63;
  int lr = l & 15, lg = l >> 4;
  constexpr int NCT = BN / 16;
  constexpr int NKS = KTOT / 32;
  f32x4_t acc[2][NCT] = {};
#pragma unroll
  for (int ks = 0; ks < NKS; ++ks) {
    half8_t a0 = *(const half8_t*)&As[(w * 32 + lr) * KP + ks * 32 + lg * 8];
    half8_t a1 = *(const half8_t*)&As[(w * 32 + 16 + lr) * KP + ks * 32 + lg * 8];
#pragma unroll
    for (int ct = 0; ct < NCT; ++ct) {
      half8_t b = *(const half8_t*)&Bs[(ct * 16 + lr) * KP + ks * 32 + lg * 8];
      acc[0][ct] = __builtin_amdgcn_mfma_f32_16x16x32_f16(a0, b, acc[0][ct], 0, 0, 0);
      acc[1][ct] = __builtin_amdgcn_mfma_f32_16x16x32_f16(a1, b, acc[1][ct], 0, 0, 0);
    }
  }

  // ---- epilogue ----
  float g = 1.f, gb = 0.f;
  if (MODE == 3) { g = 1.f / (1.f + expf(-skip_ptr[skip_idx])); gb = 1.f - g; }
#pragma unroll
  for (int rt = 0; rt < 2; ++rt) {
    int rbase = row0 + w * 32 + rt * 16 + lg * 4;
#pragma unroll
    for (int ct = 0; ct < NCT; ++ct) {
      int col = ct * 16 + lr;
      float bval = bias[col];
      float p1 = 0.f, p2 = 0.f;
#pragma unroll
      for (int j = 0; j < 4; ++j) {
        int row = rbase + j;
        if (row >= M) continue;
        float val = acc[rt][ct][j] + bval;
        if (MODE == 0) {
          val = fmaxf(val, 0.f);
          y_out[(size_t)row * 64 + col] = (_Float16)val;
          p1 += val; p2 += val * val;
        } else if (MODE == 1) {
          if (col < 64) pack_out[(size_t)row * 128 + col] = (_Float16)val;
          else if (col < 128) qt_out[(size_t)row * 64 + (col - 64)] = val;
          else pack_out[(size_t)row * 128 + (col - 64)] = (_Float16)val;
        } else if (MODE == 2) {
          Cf[(size_t)row * 128 + col] = val;
        } else {
          float rv = (float)resh[(size_t)row * 64 + col];
          Cf[(size_t)row * 64 + col] = g * val + gb * (rsc[col] * rv + rsh[col]);
        }
      }
      if (MODE == 0) { atomicAdd(&s1[col], p1); atomicAdd(&s2[col], p2); }
    }
  }
  if (MODE == 0) {
    __syncthreads();
    if (tid < 64) {
      bstats[(size_t)blockIdx.x * 128 + tid] = s1[tid];
      bstats[(size_t)blockIdx.x * 128 + 64 + tid] = s2[tid];
    }
  }
}

// ---------------- BN: reduce per-block stats (1 block per type×column) ----------------

__global__ __launch_bounds__(256) void stats_reduce(const float* __restrict__ bstats,
                                                    float* __restrict__ stats) {
  __shared__ float sh[256];
  int t = blockIdx.x >> 7;        // 0=q 1=a 2=e
  int c = blockIdx.x & 127;       // 0..127
  int nb = (t == 0) ? NBQ : (t == 1) ? NBA : NBE;
  int base = (t == 0) ? 0 : (t == 1) ? NBQ : (NBQ + NBA);
  float s = 0.f;
  for (int i = threadIdx.x; i < nb; i += 256)
    s += bstats[(size_t)(base + i) * 128 + c];
  sh[threadIdx.x] = s;
  __syncthreads();
  for (int off2 = 128; off2 > 0; off2 >>= 1) {
    if (threadIdx.x < off2) sh[threadIdx.x] += sh[threadIdx.x + off2];
    __syncthreads();
  }
  if (threadIdx.x == 0) stats[t * 128 + c] = sh[0];
}

__global__ void bn_finalize(const float* __restrict__ stats,
                            const float* __restrict__ gamma, const float* __restrict__ beta,
                            float* __restrict__ scale, float* __restrict__ shift) {
  int t = threadIdx.x;
  if (t >= 192) return;
  int ty = t >> 6, c = t & 63;
  float invN = (ty == 0) ? (1.f / NQ) : (ty == 1) ? (1.f / NA) : (1.f / NE);
  float mu = stats[ty * 128 + c] * invN;
  float var = stats[ty * 128 + 64 + c] * invN - mu * mu;
  float rs = rsqrtf(var + 1e-5f);
  float gm = gamma[ty * 64 + c];
  scale[t] = gm * rs;
  shift[t] = beta[ty * 64 + c] - gm * mu * rs;
}

// bias2[t][n] = b_kqv[t][n] + sum_k shift[t][k] * W_kqv[t][k][n]
__global__ void kqv_bias2(const float* __restrict__ b_kqv, const float* __restrict__ W_kqv,
                          const float* __restrict__ shift, float* __restrict__ bias2) {
  int t = blockIdx.x, n = threadIdx.x;
  float s = b_kqv[t * 192 + n];
  for (int k = 0; k < 64; ++k)
    s += shift[t * 64 + k] * W_kqv[(size_t)t * 64 * 192 + k * 192 + n];
  bias2[t * 192 + n] = s;
}

// ---------------- weight prep ----------------
// kqv weights: transposed fp16, padded [N][72]; A_k fold on q-cols, BN scale folded.
// WqT[192][72] (question), WeT[192][72] (entity), WaT[128][72] (answer qt rel2|rel3)
// bias_big[512] = [q:192 | e:192 | a:128]

__global__ void wprep_kqv(const float* __restrict__ W_kqv, const float* __restrict__ bias2,
                          const float* __restrict__ A_k, const float* __restrict__ scale,
                          _Float16* __restrict__ WqT, _Float16* __restrict__ WeT,
                          _Float16* __restrict__ WaT, float* __restrict__ bias_big) {
  int j = blockIdx.x;   // 0..511
  int c = threadIdx.x;  // 0..63 (k index)
  int t, jj, bofs;
  _Float16* W;
  if (j < 192)      { t = 0; jj = j;       W = WqT; bofs = 0; }
  else if (j < 384) { t = 2; jj = j - 192; W = WeT; bofs = 192; }
  else              { t = 1; jj = j - 384; W = WaT; bofs = 384; }
  const float* Wt = W_kqv + (size_t)t * 64 * 192;
  const float* b2 = bias2 + t * 192;
  bool isqt = false;
  int rel = 0, h = 0, d = 0;
  if (t == 1) { isqt = true; rel = (jj < 64) ? 2 : 3; h = (jj & 63) >> 5; d = jj & 31; }
  else if (jj >= 64 && jj < 128) {
    isqt = true; rel = (t == 0) ? 0 : 1; h = (jj - 64) >> 5; d = jj & 31;
  }
  float wv, bv;
  if (isqt) {
    const float* Ar = A_k + ((size_t)rel * 2048 + h * 1024 + d * 32);
    float s = 0.f, sb = 0.f;
    for (int ff = 0; ff < 32; ++ff) {
      float a = Ar[ff];
      s = fmaf(a, Wt[(size_t)c * 192 + 64 + h * 32 + ff], s);
      sb = fmaf(a, b2[64 + h * 32 + ff], sb);
    }
    wv = s; bv = sb;
  } else {
    wv = Wt[(size_t)c * 192 + jj];
    bv = b2[jj];
  }
  wv *= scale[t * 64 + c];                    // fold BN scale (input-dim side)
  W[(size_t)jj * 72 + c] = (_Float16)wv;      // transposed
  if (c < 8) W[(size_t)jj * 72 + 64 + c] = (_Float16)0.f;  // pad
  if (c == 0) bias_big[bofs + jj] = bv;
}

// WinT[t][64][136] fp16 = W_in[t][k][n] transposed+padded
__global__ void wprep_in(const float* __restrict__ W_in, _Float16* __restrict__ WinT) {
  int t = blockIdx.x >> 6, n = blockIdx.x & 63, k = threadIdx.x;  // k 0..135
  float v = (k < 128) ? W_in[(size_t)t * 128 * 64 + (size_t)k * 64 + n] : 0.f;
  WinT[((size_t)t * 64 + n) * 136 + k] = (_Float16)v;
}

// WoutT[t][64][72] fp16 = W_out[t][k][n] transposed+padded
__global__ void wprep_out(const float* __restrict__ W_out, _Float16* __restrict__ WoutT) {
  int t = blockIdx.x >> 6, n = blockIdx.x & 63, k = threadIdx.x;  // k 0..71
  float v = (k < 64) ? W_out[(size_t)t * 64 * 64 + (size_t)k * 64 + n] : 0.f;
  WoutT[((size_t)t * 64 + n) * 72 + k] = (_Float16)v;
}

// ---------------- CSR build ----------------

__global__ void hist_kernel(const int* __restrict__ dst, int E,
                            unsigned* __restrict__ cnt, int base) {
  int i = blockIdx.x * blockDim.x + threadIdx.x;
  int stride = gridDim.x * blockDim.x;
  for (; i < E; i += stride) atomicAdd(&cnt[base + dst[i]], 1u);
}

__global__ __launch_bounds__(256) void scan1(unsigned* __restrict__ arr, int n,
                                             unsigned* __restrict__ bsums) {
  __shared__ unsigned sh[256];
  int t = threadIdx.x;
  int base = blockIdx.x * 1024 + t * 4;
  unsigned v[4];
  unsigned s = 0;
#pragma unroll
  for (int j = 0; j < 4; ++j) {
    v[j] = (base + j < n) ? arr[base + j] : 0u;
    s += v[j];
  }
  sh[t] = s;
  __syncthreads();
  for (int off = 1; off < 256; off <<= 1) {
    unsigned x = (t >= off) ? sh[t - off] : 0u;
    __syncthreads();
    sh[t] += x;
    __syncthreads();
  }
  unsigned run = sh[t] - s;
#pragma unroll
  for (int j = 0; j < 4; ++j) {
    if (base + j < n) arr[base + j] = run;
    run += v[j];
  }
  if (t == 255) bsums[blockIdx.x] = sh[255];
}

__global__ __launch_bounds__(256) void scan2(unsigned* __restrict__ bsums, int nb) {
  __shared__ unsigned sh[256];
  __shared__ unsigned carry;
  int t = threadIdx.x;
  if (t == 0) carry = 0;
  __syncthreads();
  for (int chunk = 0; chunk < nb; chunk += 256) {
    int i = chunk + t;
    unsigned v = (i < nb) ? bsums[i] : 0u;
    sh[t] = v;
    __syncthreads();
    for (int off = 1; off < 256; off <<= 1) {
      unsigned x = (t >= off) ? sh[t - off] : 0u;
      __syncthreads();
      sh[t] += x;
      __syncthreads();
    }
    unsigned inc = sh[t];
    unsigned c = carry;
    __syncthreads();
    if (i < nb) bsums[i] = c + inc - v;
    if (t == 255) carry = c + sh[255];
    __syncthreads();
  }
}

__global__ __launch_bounds__(256) void scan3(unsigned* __restrict__ arr,
                                             const unsigned* __restrict__ bsums,
                                             unsigned* __restrict__ cursor, int n) {
  int t = threadIdx.x;
  int base = blockIdx.x * 1024 + t * 4;
  unsigned add = bsums[blockIdx.x];
#pragma unroll
  for (int j = 0; j < 4; ++j) {
    int idx = base + j;
    if (idx < n) {
      unsigned r = arr[idx] + add;
      arr[idx] = r;
      cursor[idx] = r;
    }
  }
}

// payload = src index in kvpack space | slot<<20
__global__ void scatter_kernel(const int* __restrict__ src, const int* __restrict__ dst, int E,
                               unsigned* __restrict__ cursor, unsigned* __restrict__ eidx,
                               int dstbase, int srcbase, unsigned slot) {
  int i = blockIdx.x * blockDim.x + threadIdx.x;
  int stride = gridDim.x * blockDim.x;
  for (; i < E; i += stride) {
    unsigned pos = atomicAdd(&cursor[dstbase + dst[i]], 1u);
    eidx[pos] = (unsigned)(srcbase + src[i]) | (slot << 20);
  }
}

// ---------------- gather: softmax-weighted aggregation per dst node ----------------

template <int NREL>
__global__ __launch_bounds__(256) void gather_kernel(
    int N, int nodebase,
    const unsigned* __restrict__ row_start, const unsigned* __restrict__ row_end,
    const unsigned* __restrict__ eidx,
    const __half* __restrict__ kvpack,
    const float* __restrict__ qtbase, int qtstride, int qt1off,
    const float* __restrict__ Av0, const float* __restrict__ Av1,
    const float* __restrict__ prel0, const float* __restrict__ prel1,
    float* __restrict__ agg)
{
  int lane = threadIdx.x & 63;
  int h = lane >> 5, f = lane & 31;
  float av0[32], av1[32];
#pragma unroll
  for (int dd = 0; dd < 32; ++dd) av0[dd] = Av0[h * 1024 + dd * 32 + f];
  if (NREL == 2) {
#pragma unroll
    for (int dd = 0; dd < 32; ++dd) av1[dd] = Av1[h * 1024 + dd * 32 + f];
  }
  const float isd = 0.17677669529663687f;
  float pr0 = prel0[h] * isd;
  float pr1 = (NREL == 2) ? prel1[h] * isd : 0.f;

  int wid = (int)((blockIdx.x * blockDim.x + threadIdx.x) >> 6);
  int nw = (int)((gridDim.x * blockDim.x) >> 6);
  for (int n = wid; n < N; n += nw) {
    float qt0v = qtbase[(size_t)n * qtstride + lane];
    float qt1v = (NREL == 2) ? qtbase[(size_t)n * qtstride + qt1off + lane] : 0.f;
    unsigned i0 = row_start[nodebase + n];
    unsigned i1 = row_end[nodebase + n];
    float vs0 = 0.f, vs1 = 0.f, ss = 0.f;
    unsigned i = i0;
    for (; i + 2 <= i1; i += 2) {
      unsigned p1 = eidx[i], p2 = eidx[i + 1];
      unsigned s1i = p1 & 0xFFFFFu, s2i = p2 & 0xFFFFFu;
      bool r1 = (NREL == 2) && (p1 >> 20);
      bool r2 = (NREL == 2) && (p2 >> 20);
      const __half* kv1 = kvpack + (size_t)s1i * 128;
      const __half* kv2 = kvpack + (size_t)s2i * 128;
      float k1 = __half2float(kv1[lane]);
      float v1 = __half2float(kv1[64 + lane]);
      float k2 = __half2float(kv2[lane]);
      float v2 = __half2float(kv2[64 + lane]);
      float sa = k1 * (r1 ? qt1v : qt0v);
      float sb = k2 * (r2 ? qt1v : qt0v);
#pragma unroll
      for (int off = 16; off > 0; off >>= 1) {
        sa += __shfl_xor(sa, off, 32);
        sb += __shfl_xor(sb, off, 32);
      }
      float w1 = expf(sa * (r1 ? pr1 : pr0));
      float w2 = expf(sb * (r2 ? pr1 : pr0));
      ss += w1 + w2;
      if (NREL == 2) {
        float wv1 = w1 * v1, wv2 = w2 * v2;
        vs0 += (r1 ? 0.f : wv1) + (r2 ? 0.f : wv2);
        vs1 += (r1 ? wv1 : 0.f) + (r2 ? wv2 : 0.f);
      } else {
        vs0 = fmaf(w1, v1, vs0);
        vs0 = fmaf(w2, v2, vs0);
      }
    }
    if (i < i1) {
      unsigned p1 = eidx[i];
      unsigned s1i = p1 & 0xFFFFFu;
      bool r1 = (NREL == 2) && (p1 >> 20);
      const __half* kv1 = kvpack + (size_t)s1i * 128;
      float k1 = __half2float(kv1[lane]);
      float v1 = __half2float(kv1[64 + lane]);
      float sa = k1 * (r1 ? qt1v : qt0v);
#pragma unroll
      for (int off = 16; off > 0; off >>= 1) sa += __shfl_xor(sa, off, 32);
      float w1 = expf(sa * (r1 ? pr1 : pr0));
      ss += w1;
      if (NREL == 2) {
        float wv1 = w1 * v1;
        vs0 += r1 ? 0.f : wv1;
        vs1 += r1 ? wv1 : 0.f;
      } else {
        vs0 = fmaf(w1, v1, vs0);
      }
    }
    float o0 = 0.f, o1 = 0.f, o2 = 0.f, o3 = 0.f;
#pragma unroll
    for (int dd = 0; dd < 8; ++dd) {
      o0 = fmaf(av0[dd], __shfl(vs0, dd, 32), o0);
      o1 = fmaf(av0[dd + 8], __shfl(vs0, dd + 8, 32), o1);
      o2 = fmaf(av0[dd + 16], __shfl(vs0, dd + 16, 32), o2);
      o3 = fmaf(av0[dd + 24], __shfl(vs0, dd + 24, 32), o3);
    }
    if (NREL == 2) {
#pragma unroll
      for (int dd = 0; dd < 8; ++dd) {
        o0 = fmaf(av1[dd], __shfl(vs1, dd, 32), o0);
        o1 = fmaf(av1[dd + 8], __shfl(vs1, dd + 8, 32), o1);
        o2 = fmaf(av1[dd + 16], __shfl(vs1, dd + 16, 32), o2);
        o3 = fmaf(av1[dd + 24], __shfl(vs1, dd + 24, 32), o3);
      }
    }
    float o = (o0 + o1) + (o2 + o3);
    float val = (ss > 0.f) ? o / ss : 0.f;
    val = 0.5f * val * (1.f + erff(val * 0.70710678118654752f));
    agg[((size_t)(nodebase + n)) * 64 + lane] = val;
  }
}

// ---------------- final predictions ----------------

__global__ void pred_kernel(const int* __restrict__ qi, const int* __restrict__ ai, int Np,
                            const float* __restrict__ zq, const float* __restrict__ za,
                            float* __restrict__ outp) {
  int i = blockIdx.x * blockDim.x + threadIdx.x;
  if (i >= Np) return;
  const float4* a = (const float4*)(zq + (size_t)qi[i] * 64);
  const float4* b = (const float4*)(za + (size_t)ai[i] * 64);
  float ssum = 0.f;
#pragma unroll
  for (int j = 0; j < 16; ++j) {
    float4 x = a[j], y = b[j];
    ssum += x.x * y.x + x.y * y.y + x.z * y.z + x.w * y.w;
  }
  outp[i] = ssum;
}

// ---------------- host launch ----------------

extern "C" void kernel_launch(void* const* d_in, const int* in_sizes, int n_in,
                              void* d_out, int out_size, void* d_ws, size_t ws_size,
                              hipStream_t stream) {
  const float* xq = (const float*)d_in[0];
  const float* xa = (const float*)d_in[1];
  const float* xe = (const float*)d_in[2];
  const int* e_e2q = (const int*)d_in[3];
  const int* e_e2e = (const int*)d_in[4];
  const int* e_e2a = (const int*)d_in[5];
  const int* e_q2a = (const int*)d_in[6];
  const int* pos_idx = (const int*)d_in[7];
  const int* neg_idx = (const int*)d_in[8];
  const float* W_in = (const float*)d_in[9];
  const float* b_in = (const float*)d_in[10];
  const float* bn_gamma = (const float*)d_in[11];
  const float* bn_beta = (const float*)d_in[12];
  const float* W_kqv = (const float*)d_in[13];
  const float* b_kqv = (const float*)d_in[14];
  const float* A_k = (const float*)d_in[15];
  const float* A_v = (const float*)d_in[16];
  const float* p_rel = (const float*)d_in[17];
  const float* W_out = (const float*)d_in[18];
  const float* b_out = (const float*)d_in[19];
  const float* skip = (const float*)d_in[20];
  float* out = (float*)d_out;

  float* ws = (float*)d_ws;
  size_t off = 0;
  _Float16* y_h = (_Float16*)(ws + off);    off += (size_t)NT_TOTAL * 32;      // fp16 [NT][64]
  _Float16* kvpack = (_Float16*)(ws + off); off += (size_t)(NQ + NE) * 64;     // fp16 [..][128]
  float* qt_qe = ws + off;                  off += (size_t)(NQ + NE) * 64;
  float* kqv_a = ws + off;                  off += (size_t)NA * 128;
  float* agg_all = ws + off;                off += (size_t)NT_TOTAL * 64;
  float* stats = ws + off;                  off += 384;
  float* scale = ws + off;                  off += 192;
  float* shift = ws + off;                  off += 192;
  float* bias2 = ws + off;                  off += 576;
  float* bias_big = ws + off;               off += 512;
  _Float16* WqT = (_Float16*)(ws + off);    off += 192 * 72 / 2;   // 6912
  _Float16* WeT = (_Float16*)(ws + off);    off += 192 * 72 / 2;
  _Float16* WaT = (_Float16*)(ws + off);    off += 128 * 72 / 2;   // 4608
  _Float16* WinT = (_Float16*)(ws + off);   off += 3 * 64 * 136 / 2;  // 13056
  _Float16* WoutT = (_Float16*)(ws + off);  off += 3 * 64 * 72 / 2;   // 6912
  float* bstats = ws + off;                 off += (size_t)(NBQ + NBA + NBE) * 128;
  unsigned* row_start = (unsigned*)(ws + off); off += NT_TOTAL;
  unsigned* cursor = (unsigned*)(ws + off);    off += NT_TOTAL;
  unsigned* bsums = (unsigned*)(ws + off);     off += 1024;
  unsigned* eidx = (unsigned*)(ws + off);      off += E_TOTAL;

  const int Ns[3] = {NQ, NA, NE};
  const float* xs[3] = {xq, xa, xe};
  _Float16* yhb[3] = {y_h, y_h + (size_t)NQ * 64, y_h + (size_t)(NQ + NA) * 64};
  float* aggbase[3] = {agg_all, agg_all + (size_t)NQ * 64, agg_all + (size_t)(NQ + NA) * 64};
  float* zq_out = out + (N_POS + N_NEG);
  float* zbase[3] = {zq_out, zq_out + (size_t)NQ * 64, zq_out + (size_t)(NQ + NA) * 64};
  const int bb[3] = {0, NBQ, NBQ + NBA};

  fill_kernel<<<dim3(128), dim3(256), 0, stream>>>((float*)row_start, 0.f, NT_TOTAL);
  wprep_in<<<dim3(192), dim3(136), 0, stream>>>(W_in, WinT);
  wprep_out<<<dim3(192), dim3(72), 0, stream>>>(W_out, WoutT);

  // ---- in-proj (MFMA, fp32->fp16 staged) + relu -> y fp16, fused bstats ----
  for (int t = 0; t < 3; ++t) {
    gemm_mfma<64, 128, 0><<<dim3(CDIV(Ns[t], 128)), dim3(256), 0, stream>>>(
        xs[t], nullptr, WinT + (size_t)t * 64 * 136, b_in + t * 64, Ns[t],
        nullptr, yhb[t], bstats + (size_t)bb[t] * 128, nullptr, nullptr,
        nullptr, nullptr, nullptr, nullptr, 0);
  }
  stats_reduce<<<dim3(384), dim3(256), 0, stream>>>(bstats, stats);
  bn_finalize<<<dim3(1), dim3(192), 0, stream>>>(stats, bn_gamma, bn_beta, scale, shift);
  kqv_bias2<<<dim3(3), dim3(192), 0, stream>>>(b_kqv, W_kqv, shift, bias2);
  wprep_kqv<<<dim3(512), dim3(64), 0, stream>>>(W_kqv, bias2, A_k, scale, WqT, WeT, WaT,
                                                bias_big);

  // ---- kqv projections (MFMA; BN scale folded into weights) ----
  gemm_mfma<192, 64, 1><<<dim3(CDIV(NQ, 128)), dim3(256), 0, stream>>>(
      nullptr, yhb[0], WqT, bias_big, NQ,
      nullptr, nullptr, nullptr, kvpack, qt_qe,
      nullptr, nullptr, nullptr, nullptr, 0);
  gemm_mfma<192, 64, 1><<<dim3(CDIV(NE, 128)), dim3(256), 0, stream>>>(
      nullptr, yhb[2], WeT, bias_big + 192, NE,
      nullptr, nullptr, nullptr, kvpack + (size_t)NQ * 128, qt_qe + (size_t)NQ * 64,
      nullptr, nullptr, nullptr, nullptr, 0);
  gemm_mfma<128, 64, 2><<<dim3(CDIV(NA, 128)), dim3(256), 0, stream>>>(
      nullptr, yhb[1], WaT, bias_big + 384, NA,
      kqv_a, nullptr, nullptr, nullptr, nullptr,
      nullptr, nullptr, nullptr, nullptr, 0);

  // ---- CSR build ----
  struct Rel { const int* ei; int E; int srcbase; int dstbase; unsigned slot; };
  Rel rels[4] = {{e_e2q, E_E2Q, SRC_E, BASE_Q, 0u},
                 {e_e2e, E_E2E, SRC_E, BASE_E, 0u},
                 {e_e2a, E_E2A, SRC_E, BASE_A, 0u},
                 {e_q2a, E_Q2A, SRC_Q, BASE_A, 1u}};
  for (int r = 0; r < 4; ++r) {
    int blocks = CDIV(rels[r].E, 256); if (blocks > 2048) blocks = 2048;
    hist_kernel<<<dim3(blocks), dim3(256), 0, stream>>>(rels[r].ei + rels[r].E, rels[r].E,
                                                        row_start, rels[r].dstbase);
  }
  scan1<<<dim3(NBLK_SCAN), dim3(256), 0, stream>>>(row_start, NT_TOTAL, bsums);
  scan2<<<dim3(1), dim3(256), 0, stream>>>(bsums, NBLK_SCAN);
  scan3<<<dim3(NBLK_SCAN), dim3(256), 0, stream>>>(row_start, bsums, cursor, NT_TOTAL);
  for (int r = 0; r < 4; ++r) {
    int blocks = CDIV(rels[r].E, 256); if (blocks > 2048) blocks = 2048;
    scatter_kernel<<<dim3(blocks), dim3(256), 0, stream>>>(
        rels[r].ei, rels[r].ei + rels[r].E, rels[r].E, cursor, eidx,
        rels[r].dstbase, rels[r].srcbase, rels[r].slot);
  }

  // ---- gathers ----
  gather_kernel<1><<<dim3(CDIV(NQ, 4)), dim3(256), 0, stream>>>(
      NQ, BASE_Q, row_start, cursor, eidx, (const __half*)kvpack,
      qt_qe, 64, 0, A_v, A_v, p_rel, p_rel, agg_all);
  gather_kernel<1><<<dim3(4096), dim3(256), 0, stream>>>(
      NE, BASE_E, row_start, cursor, eidx, (const __half*)kvpack,
      qt_qe + (size_t)NQ * 64, 64, 0, A_v + 1 * 2048, A_v + 1 * 2048,
      p_rel + 2, p_rel + 2, agg_all);
  gather_kernel<2><<<dim3(CDIV(NA, 4)), dim3(256), 0, stream>>>(
      NA, BASE_A, row_start, cursor, eidx, (const __half*)kvpack,
      kqv_a, 128, 64, A_v + 2 * 2048, A_v + 3 * 2048, p_rel + 4, p_rel + 6, agg_all);

  // ---- out projection (MFMA) + skip blend ----
  for (int t = 0; t < 3; ++t) {
    gemm_mfma<64, 64, 3><<<dim3(CDIV(Ns[t], 128)), dim3(256), 0, stream>>>(
        aggbase[t], nullptr, WoutT + (size_t)t * 64 * 72, b_out + t * 64, Ns[t],
        zbase[t], nullptr, nullptr, nullptr, nullptr,
        yhb[t], scale + t * 64, shift + t * 64, skip, t);
  }

  // ---- predictions ----
  pred_kernel<<<dim3(CDIV(N_POS, 256)), dim3(256), 0, stream>>>(
      pos_idx, pos_idx + N_POS, N_POS, zbase[0], zbase[1], out);
  pred_kernel<<<dim3(CDIV(N_NEG, 256)), dim3(256), 0, stream>>>(
      neg_idx, neg_idx + N_NEG, N_NEG, zbase[0], zbase[1], out + N_POS);
}

// Round 9
// 1037.009 us; speedup vs baseline: 1.8651x; 1.0450x over previous
//
#include <hip/hip_runtime.h>
#include <hip/hip_bf16.h>
#include <hip/hip_fp16.h>
#include <math.h>

#define NQ 8192
#define NA 32768
#define NE 500000
#define F_IN 128
#define E_E2Q 131072
#define E_E2E 800000
#define E_E2A 262144
#define E_Q2A 32768
#define N_POS 8192
#define N_NEG 24576

#define NT_TOTAL (NQ + NA + NE)                      // 540960
#define E_TOTAL (E_E2Q + E_E2E + E_E2A + E_Q2A)      // 1225984
#define NBLK_SCAN ((NT_TOTAL + 1023) / 1024)         // 529
#define CDIV(a, b) (((a) + (b) - 1) / (b))

// dst node index space: [question: 0) [answer: NQ) [entity: NQ+NA)
#define BASE_Q 0
#define BASE_A NQ
#define BASE_E (NQ + NA)
// src index space: [question: 0) [entity: NQ)
#define SRC_Q 0
#define SRC_E NQ

// in-proj block counts (BM=128) for bstats layout
#define NBQ 64      // CDIV(NQ,128)
#define NBA 256     // CDIV(NA,128)
#define NBE 3907    // CDIV(NE,128)

typedef _Float16 half8_t __attribute__((ext_vector_type(8)));
typedef _Float16 half4_t __attribute__((ext_vector_type(4)));
typedef float f32x4_t __attribute__((ext_vector_type(4)));

// ---------------- utility ----------------

__global__ void fill_kernel(float* __restrict__ p, float v, size_t n) {
  size_t i = (size_t)blockIdx.x * blockDim.x + threadIdx.x;
  size_t stride = (size_t)gridDim.x * blockDim.x;
  for (; i < n; i += stride) p[i] = v;
}

// ---------------- MFMA fp16 GEMM (BM=128, 4 waves, full-K in LDS) ----------------
// MODE 0: in-proj: A=fp32[M][128] cvt, relu -> y fp16[M][64] + per-block bstats
// MODE 1: multi-out: A=fp16[M][64], outs o0..o4 fp16 (64 cols each, stride 64)
// MODE 3: out-proj: A=fp16[M][64] (agg), skip-blend vs fp16 residual -> fp32 C

template <int BN, int KTOT, int MODE>
__global__ __launch_bounds__(256) void gemm_mfma(
    const float* __restrict__ Af, const _Float16* __restrict__ Ah,
    const _Float16* __restrict__ WT, const float* __restrict__ bias, int M,
    float* __restrict__ Cf,
    _Float16* __restrict__ o0, _Float16* __restrict__ o1, _Float16* __restrict__ o2,
    _Float16* __restrict__ o3, _Float16* __restrict__ o4,
    float* __restrict__ bstats,
    const _Float16* __restrict__ resh, const float* __restrict__ rsc,
    const float* __restrict__ rsh, const float* __restrict__ skip_ptr, int skip_idx)
{
  constexpr int KP = KTOT + 8;
  __shared__ _Float16 As[128 * KP];
  __shared__ _Float16 Bs[BN * KP];
  __shared__ float s1[64], s2[64];
  int tid = threadIdx.x;
  int row0 = blockIdx.x * 128;
  if (MODE == 0 && tid < 64) { s1[tid] = 0.f; s2[tid] = 0.f; }

  // ---- stage A ----
  if (MODE == 0) {
    constexpr int CH = KTOT / 4;
    for (int idx = tid; idx < 128 * CH; idx += 256) {
      int row = idx / CH, c = idx % CH;
      int gr = row0 + row;
      float4 a4 = make_float4(0.f, 0.f, 0.f, 0.f);
      if (gr < M) a4 = *(const float4*)&Af[(size_t)gr * KTOT + c * 4];
      half4_t h4 = {(_Float16)a4.x, (_Float16)a4.y, (_Float16)a4.z, (_Float16)a4.w};
      *(half4_t*)&As[row * KP + c * 4] = h4;
    }
  } else {
    constexpr int CH = KTOT / 8;
    for (int idx = tid; idx < 128 * CH; idx += 256) {
      int row = idx / CH, c = idx % CH;
      int gr = row0 + row;
      half8_t a8 = {};
      if (gr < M) a8 = *(const half8_t*)&Ah[(size_t)gr * KTOT + c * 8];
      *(half8_t*)&As[row * KP + c * 8] = a8;
    }
  }
  // ---- stage B (flat copy, WT already padded) ----
  for (int idx = tid; idx < BN * KP / 8; idx += 256)
    *(half8_t*)&Bs[idx * 8] = *(const half8_t*)&WT[(size_t)idx * 8];
  __syncthreads();

  int w = tid >> 6, l = tid & 63;
  int lr = l & 15, lg = l >> 4;
  constexpr int NCT = BN / 16;
  constexpr int NKS = KTOT / 32;
  f32x4_t acc[2][NCT] = {};
#pragma unroll
  for (int ks = 0; ks < NKS; ++ks) {
    half8_t a0 = *(const half8_t*)&As[(w * 32 + lr) * KP + ks * 32 + lg * 8];
    half8_t a1 = *(const half8_t*)&As[(w * 32 + 16 + lr) * KP + ks * 32 + lg * 8];
#pragma unroll
    for (int ct = 0; ct < NCT; ++ct) {
      half8_t b = *(const half8_t*)&Bs[(ct * 16 + lr) * KP + ks * 32 + lg * 8];
      acc[0][ct] = __builtin_amdgcn_mfma_f32_16x16x32_f16(a0, b, acc[0][ct], 0, 0, 0);
      acc[1][ct] = __builtin_amdgcn_mfma_f32_16x16x32_f16(a1, b, acc[1][ct], 0, 0, 0);
    }
  }

  // ---- epilogue ----
  float g = 1.f, gb = 0.f;
  if (MODE == 3) { g = 1.f / (1.f + expf(-skip_ptr[skip_idx])); gb = 1.f - g; }
#pragma unroll
  for (int rt = 0; rt < 2; ++rt) {
    int rbase = row0 + w * 32 + rt * 16 + lg * 4;
#pragma unroll
    for (int ct = 0; ct < NCT; ++ct) {
      int col = ct * 16 + lr;
      float bval = bias[col];
      _Float16* ob = nullptr;
      if (MODE == 1) {
        constexpr int dummy = 0; (void)dummy;
        switch (ct >> 2) {
          case 0: ob = o0; break;
          case 1: ob = o1; break;
          case 2: ob = o2; break;
          case 3: ob = o3; break;
          default: ob = o4; break;
        }
      }
      float p1 = 0.f, p2 = 0.f;
#pragma unroll
      for (int j = 0; j < 4; ++j) {
        int row = rbase + j;
        if (row >= M) continue;
        float val = acc[rt][ct][j] + bval;
        if (MODE == 0) {
          val = fmaxf(val, 0.f);
          o0[(size_t)row * 64 + col] = (_Float16)val;
          p1 += val; p2 += val * val;
        } else if (MODE == 1) {
          ob[(size_t)row * 64 + (col & 63)] = (_Float16)val;
        } else {
          float rv = (float)resh[(size_t)row * 64 + col];
          Cf[(size_t)row * 64 + col] = g * val + gb * (rsc[col] * rv + rsh[col]);
        }
      }
      if (MODE == 0) { atomicAdd(&s1[col], p1); atomicAdd(&s2[col], p2); }
    }
  }
  if (MODE == 0) {
    __syncthreads();
    if (tid < 64) {
      bstats[(size_t)blockIdx.x * 128 + tid] = s1[tid];
      bstats[(size_t)blockIdx.x * 128 + 64 + tid] = s2[tid];
    }
  }
}

// ---------------- BN: reduce per-block stats (1 block per type×column) ----------------

__global__ __launch_bounds__(256) void stats_reduce(const float* __restrict__ bstats,
                                                    float* __restrict__ stats) {
  __shared__ float sh[256];
  int t = blockIdx.x >> 7;        // 0=q 1=a 2=e
  int c = blockIdx.x & 127;       // 0..127
  int nb = (t == 0) ? NBQ : (t == 1) ? NBA : NBE;
  int base = (t == 0) ? 0 : (t == 1) ? NBQ : (NBQ + NBA);
  float s = 0.f;
  for (int i = threadIdx.x; i < nb; i += 256)
    s += bstats[(size_t)(base + i) * 128 + c];
  sh[threadIdx.x] = s;
  __syncthreads();
  for (int off2 = 128; off2 > 0; off2 >>= 1) {
    if (threadIdx.x < off2) sh[threadIdx.x] += sh[threadIdx.x + off2];
    __syncthreads();
  }
  if (threadIdx.x == 0) stats[t * 128 + c] = sh[0];
}

__global__ void bn_finalize(const float* __restrict__ stats,
                            const float* __restrict__ gamma, const float* __restrict__ beta,
                            float* __restrict__ scale, float* __restrict__ shift) {
  int t = threadIdx.x;
  if (t >= 192) return;
  int ty = t >> 6, c = t & 63;
  float invN = (ty == 0) ? (1.f / NQ) : (ty == 1) ? (1.f / NA) : (1.f / NE);
  float mu = stats[ty * 128 + c] * invN;
  float var = stats[ty * 128 + 64 + c] * invN - mu * mu;
  float rs = rsqrtf(var + 1e-5f);
  float gm = gamma[ty * 64 + c];
  scale[t] = gm * rs;
  shift[t] = beta[ty * 64 + c] - gm * mu * rs;
}

// bias2[t][n] = b_kqv[t][n] + sum_k shift[t][k] * W_kqv[t][k][n]
__global__ void kqv_bias2(const float* __restrict__ b_kqv, const float* __restrict__ W_kqv,
                          const float* __restrict__ shift, float* __restrict__ bias2) {
  int t = blockIdx.x, n = threadIdx.x;
  float s = b_kqv[t * 192 + n];
  for (int k = 0; k < 64; ++k)
    s += shift[t * 64 + k] * W_kqv[(size_t)t * 64 * 192 + k * 192 + n];
  bias2[t * 192 + n] = s;
}

// ---------------- weight prep ----------------
// WqT[192][72]: question = [k | qt(rel0,A_k) | v'(rel3,A_v)]
// WeT[320][72]: entity   = [k | qt(rel1,A_k) | v'(rel0) | v'(rel1) | v'(rel2)]
// WaT[128][72]: answer   = [qt(rel2) | qt(rel3)]
// bias_big[640] = [q:192 | e:320 | a:128].  BN scale folded on input dim.
// qt fold: out d, contract f:  W'[c][d] = Σf A_k[r,h,d,f] W[c][64+h*32+f]
// v' fold: out f, contract d:  W'[c][f] = Σd A_v[r,h,d,f] W[c][128+h*32+d]

__global__ void wprep_kqv(const float* __restrict__ W_kqv, const float* __restrict__ bias2,
                          const float* __restrict__ A_k, const float* __restrict__ A_v,
                          const float* __restrict__ scale,
                          _Float16* __restrict__ WqT, _Float16* __restrict__ WeT,
                          _Float16* __restrict__ WaT, float* __restrict__ bias_big) {
  int j = blockIdx.x;   // 0..639
  int c = threadIdx.x;  // 0..63 (input k index)
  int t, jj, bofs;
  _Float16* W;
  if (j < 192)      { t = 0; jj = j;       W = WqT; bofs = 0; }
  else if (j < 512) { t = 2; jj = j - 192; W = WeT; bofs = 192; }
  else              { t = 1; jj = j - 512; W = WaT; bofs = 512; }
  const float* Wt = W_kqv + (size_t)t * 64 * 192;
  const float* b2 = bias2 + t * 192;
  int mode = 0, rel = 0, sub = 0;   // 0 plain-k, 1 qt(A_k), 2 v'(A_v)
  if (t == 1) { mode = 1; rel = (jj < 64) ? 2 : 3; sub = jj & 63; }
  else if (jj >= 64 && jj < 128) { mode = 1; rel = (t == 0) ? 0 : 1; sub = jj - 64; }
  else if (jj >= 128) {
    mode = 2; sub = (jj - 128) & 63;
    rel = (t == 0) ? 3 : ((jj - 128) >> 6);   // entity: 0,1,2 ; question: 3
  }
  int h = sub >> 5, x = sub & 31;
  float wv, bv;
  if (mode == 0) {
    wv = Wt[(size_t)c * 192 + jj];
    bv = b2[jj];
  } else if (mode == 1) {
    const float* Ar = A_k + ((size_t)rel * 2048 + h * 1024 + x * 32);
    float s = 0.f, sb = 0.f;
    for (int f = 0; f < 32; ++f) {
      float a = Ar[f];
      s = fmaf(a, Wt[(size_t)c * 192 + 64 + h * 32 + f], s);
      sb = fmaf(a, b2[64 + h * 32 + f], sb);
    }
    wv = s; bv = sb;
  } else {
    const float* Ar = A_v + ((size_t)rel * 2048 + h * 1024 + x);
    float s = 0.f, sb = 0.f;
    for (int d = 0; d < 32; ++d) {
      float a = Ar[d * 32];
      s = fmaf(a, Wt[(size_t)c * 192 + 128 + h * 32 + d], s);
      sb = fmaf(a, b2[128 + h * 32 + d], sb);
    }
    wv = s; bv = sb;
  }
  wv *= scale[t * 64 + c];
  W[(size_t)jj * 72 + c] = (_Float16)wv;
  if (c < 8) W[(size_t)jj * 72 + 64 + c] = (_Float16)0.f;
  if (c == 0) bias_big[bofs + jj] = bv;
}

// WinT[t][64][136] fp16 = W_in[t][k][n] transposed+padded
__global__ void wprep_in(const float* __restrict__ W_in, _Float16* __restrict__ WinT) {
  int t = blockIdx.x >> 6, n = blockIdx.x & 63, k = threadIdx.x;  // k 0..135
  float v = (k < 128) ? W_in[(size_t)t * 128 * 64 + (size_t)k * 64 + n] : 0.f;
  WinT[((size_t)t * 64 + n) * 136 + k] = (_Float16)v;
}

// WoutT[t][64][72] fp16 = W_out[t][k][n] transposed+padded
__global__ void wprep_out(const float* __restrict__ W_out, _Float16* __restrict__ WoutT) {
  int t = blockIdx.x >> 6, n = blockIdx.x & 63, k = threadIdx.x;  // k 0..71
  float v = (k < 64) ? W_out[(size_t)t * 64 * 64 + (size_t)k * 64 + n] : 0.f;
  WoutT[((size_t)t * 64 + n) * 72 + k] = (_Float16)v;
}

// ---------------- CSR build ----------------

__global__ void hist_kernel(const int* __restrict__ dst, int E,
                            unsigned* __restrict__ cnt, int base) {
  int i = blockIdx.x * blockDim.x + threadIdx.x;
  int stride = gridDim.x * blockDim.x;
  for (; i < E; i += stride) atomicAdd(&cnt[base + dst[i]], 1u);
}

__global__ __launch_bounds__(256) void scan1(unsigned* __restrict__ arr, int n,
                                             unsigned* __restrict__ bsums) {
  __shared__ unsigned sh[256];
  int t = threadIdx.x;
  int base = blockIdx.x * 1024 + t * 4;
  unsigned v[4];
  unsigned s = 0;
#pragma unroll
  for (int j = 0; j < 4; ++j) {
    v[j] = (base + j < n) ? arr[base + j] : 0u;
    s += v[j];
  }
  sh[t] = s;
  __syncthreads();
  for (int off = 1; off < 256; off <<= 1) {
    unsigned x = (t >= off) ? sh[t - off] : 0u;
    __syncthreads();
    sh[t] += x;
    __syncthreads();
  }
  unsigned run = sh[t] - s;
#pragma unroll
  for (int j = 0; j < 4; ++j) {
    if (base + j < n) arr[base + j] = run;
    run += v[j];
  }
  if (t == 255) bsums[blockIdx.x] = sh[255];
}

__global__ __launch_bounds__(256) void scan2(unsigned* __restrict__ bsums, int nb) {
  __shared__ unsigned sh[256];
  __shared__ unsigned carry;
  int t = threadIdx.x;
  if (t == 0) carry = 0;
  __syncthreads();
  for (int chunk = 0; chunk < nb; chunk += 256) {
    int i = chunk + t;
    unsigned v = (i < nb) ? bsums[i] : 0u;
    sh[t] = v;
    __syncthreads();
    for (int off = 1; off < 256; off <<= 1) {
      unsigned x = (t >= off) ? sh[t - off] : 0u;
      __syncthreads();
      sh[t] += x;
      __syncthreads();
    }
    unsigned inc = sh[t];
    unsigned c = carry;
    __syncthreads();
    if (i < nb) bsums[i] = c + inc - v;
    if (t == 255) carry = c + sh[255];
    __syncthreads();
  }
}

__global__ __launch_bounds__(256) void scan3(unsigned* __restrict__ arr,
                                             const unsigned* __restrict__ bsums,
                                             unsigned* __restrict__ cursor, int n) {
  int t = threadIdx.x;
  int base = blockIdx.x * 1024 + t * 4;
  unsigned add = bsums[blockIdx.x];
#pragma unroll
  for (int j = 0; j < 4; ++j) {
    int idx = base + j;
    if (idx < n) {
      unsigned r = arr[idx] + add;
      arr[idx] = r;
      cursor[idx] = r;
    }
  }
}

// payload = src index in unified src space | slot<<20
__global__ void scatter_kernel(const int* __restrict__ src, const int* __restrict__ dst, int E,
                               unsigned* __restrict__ cursor, unsigned* __restrict__ eidx,
                               int dstbase, int srcbase, unsigned slot) {
  int i = blockIdx.x * blockDim.x + threadIdx.x;
  int stride = gridDim.x * blockDim.x;
  for (; i < E; i += stride) {
    unsigned pos = atomicAdd(&cursor[dstbase + dst[i]], 1u);
    eidx[pos] = (unsigned)(srcbase + src[i]) | (slot << 20);
  }
}

// ---------------- gather: softmax-weighted aggregation per dst node ----------------
// v' pre-transformed at source -> no A_v epilogue. All fp16 operands.
// vpA/vpB are pre-offset so direct indexing by unified src id works.

template <int NREL>
__global__ __launch_bounds__(256) void gather_kernel(
    int N, int nodebase,
    const unsigned* __restrict__ row_start, const unsigned* __restrict__ row_end,
    const unsigned* __restrict__ eidx,
    const _Float16* __restrict__ kp,
    const _Float16* __restrict__ vpA, const _Float16* __restrict__ vpB,
    const _Float16* __restrict__ qtA, const _Float16* __restrict__ qtB,
    const float* __restrict__ prelA, const float* __restrict__ prelB,
    _Float16* __restrict__ agg)
{
  int lane = threadIdx.x & 63;
  int h = lane >> 5;
  const float isd = 0.17677669529663687f;
  float pr0 = prelA[h] * isd;
  float pr1 = (NREL == 2) ? prelB[h] * isd : 0.f;

  int wid = (int)((blockIdx.x * blockDim.x + threadIdx.x) >> 6);
  int nw = (int)((gridDim.x * blockDim.x) >> 6);

  int n = wid;
  unsigned pi0 = 0, pi1 = 0;
  float pqt0 = 0.f, pqt1 = 0.f;
  if (n < N) {
    pi0 = row_start[nodebase + n];
    pi1 = row_end[nodebase + n];
    pqt0 = (float)qtA[(size_t)n * 64 + lane];
    if (NREL == 2) pqt1 = (float)qtB[(size_t)n * 64 + lane];
  }
  while (n < N) {
    unsigned ci0 = pi0, ci1 = pi1;
    float cqt0 = pqt0, cqt1 = pqt1;
    int nn = n + nw;
    if (nn < N) {  // prefetch next node (overlaps edge processing below)
      pi0 = row_start[nodebase + nn];
      pi1 = row_end[nodebase + nn];
      pqt0 = (float)qtA[(size_t)nn * 64 + lane];
      if (NREL == 2) pqt1 = (float)qtB[(size_t)nn * 64 + lane];
    }
    float vs = 0.f, ss = 0.f;
    unsigned i = ci0;
    for (; i + 2 <= ci1; i += 2) {
      unsigned p1 = eidx[i], p2 = eidx[i + 1];
      unsigned s1i = p1 & 0xFFFFFu, s2i = p2 & 0xFFFFFu;
      bool r1 = (NREL == 2) && (p1 >> 20);
      bool r2 = (NREL == 2) && (p2 >> 20);
      float k1 = (float)kp[(size_t)s1i * 64 + lane];
      float v1 = (float)(r1 ? vpB : vpA)[(size_t)s1i * 64 + lane];
      float k2 = (float)kp[(size_t)s2i * 64 + lane];
      float v2 = (float)(r2 ? vpB : vpA)[(size_t)s2i * 64 + lane];
      float sa = k1 * (r1 ? cqt1 : cqt0);
      float sb = k2 * (r2 ? cqt1 : cqt0);
#pragma unroll
      for (int off = 16; off > 0; off >>= 1) {
        sa += __shfl_xor(sa, off, 32);
        sb += __shfl_xor(sb, off, 32);
      }
      float w1 = expf(sa * (r1 ? pr1 : pr0));
      float w2 = expf(sb * (r2 ? pr1 : pr0));
      ss += w1 + w2;
      vs = fmaf(w1, v1, vs);
      vs = fmaf(w2, v2, vs);
    }
    if (i < ci1) {
      unsigned p1 = eidx[i];
      unsigned s1i = p1 & 0xFFFFFu;
      bool r1 = (NREL == 2) && (p1 >> 20);
      float k1 = (float)kp[(size_t)s1i * 64 + lane];
      float v1 = (float)(r1 ? vpB : vpA)[(size_t)s1i * 64 + lane];
      float sa = k1 * (r1 ? cqt1 : cqt0);
#pragma unroll
      for (int off = 16; off > 0; off >>= 1) sa += __shfl_xor(sa, off, 32);
      float w1 = expf(sa * (r1 ? pr1 : pr0));
      ss += w1;
      vs = fmaf(w1, v1, vs);
    }
    float val = (ss > 0.f) ? vs / ss : 0.f;
    val = 0.5f * val * (1.f + erff(val * 0.70710678118654752f));
    agg[((size_t)(nodebase + n)) * 64 + lane] = (_Float16)val;
    n = nn;
  }
}

// ---------------- final predictions ----------------

__global__ void pred_kernel(const int* __restrict__ qi, const int* __restrict__ ai, int Np,
                            const float* __restrict__ zq, const float* __restrict__ za,
                            float* __restrict__ outp) {
  int i = blockIdx.x * blockDim.x + threadIdx.x;
  if (i >= Np) return;
  const float4* a = (const float4*)(zq + (size_t)qi[i] * 64);
  const float4* b = (const float4*)(za + (size_t)ai[i] * 64);
  float ssum = 0.f;
#pragma unroll
  for (int j = 0; j < 16; ++j) {
    float4 x = a[j], y = b[j];
    ssum += x.x * y.x + x.y * y.y + x.z * y.z + x.w * y.w;
  }
  outp[i] = ssum;
}

// ---------------- host launch ----------------

extern "C" void kernel_launch(void* const* d_in, const int* in_sizes, int n_in,
                              void* d_out, int out_size, void* d_ws, size_t ws_size,
                              hipStream_t stream) {
  const float* xq = (const float*)d_in[0];
  const float* xa = (const float*)d_in[1];
  const float* xe = (const float*)d_in[2];
  const int* e_e2q = (const int*)d_in[3];
  const int* e_e2e = (const int*)d_in[4];
  const int* e_e2a = (const int*)d_in[5];
  const int* e_q2a = (const int*)d_in[6];
  const int* pos_idx = (const int*)d_in[7];
  const int* neg_idx = (const int*)d_in[8];
  const float* W_in = (const float*)d_in[9];
  const float* b_in = (const float*)d_in[10];
  const float* bn_gamma = (const float*)d_in[11];
  const float* bn_beta = (const float*)d_in[12];
  const float* W_kqv = (const float*)d_in[13];
  const float* b_kqv = (const float*)d_in[14];
  const float* A_k = (const float*)d_in[15];
  const float* A_v = (const float*)d_in[16];
  const float* p_rel = (const float*)d_in[17];
  const float* W_out = (const float*)d_in[18];
  const float* b_out = (const float*)d_in[19];
  const float* skip = (const float*)d_in[20];
  float* out = (float*)d_out;

  float* ws = (float*)d_ws;
  size_t off = 0;
  _Float16* y_h = (_Float16*)(ws + off);    off += (size_t)NT_TOTAL * 32;
  _Float16* kpack = (_Float16*)(ws + off);  off += (size_t)(NQ + NE) * 32;   // [src][64]
  _Float16* qth = (_Float16*)(ws + off);    off += (size_t)(NQ + NE) * 32;   // q:rel0 / e:rel1
  _Float16* qta0 = (_Float16*)(ws + off);   off += (size_t)NA * 32;          // rel2
  _Float16* qta1 = (_Float16*)(ws + off);   off += (size_t)NA * 32;          // rel3
  _Float16* vp0 = (_Float16*)(ws + off);    off += (size_t)NE * 32;          // v' rel0 (entity)
  _Float16* vp1 = (_Float16*)(ws + off);    off += (size_t)NE * 32;          // v' rel1
  _Float16* vp2 = (_Float16*)(ws + off);    off += (size_t)NE * 32;          // v' rel2
  _Float16* vp3 = (_Float16*)(ws + off);    off += (size_t)NQ * 32;          // v' rel3 (question)
  _Float16* agg_h = (_Float16*)(ws + off);  off += (size_t)NT_TOTAL * 32;
  float* stats = ws + off;                  off += 384;
  float* scale = ws + off;                  off += 192;
  float* shift = ws + off;                  off += 192;
  float* bias2 = ws + off;                  off += 576;
  float* bias_big = ws + off;               off += 640;
  _Float16* WqT = (_Float16*)(ws + off);    off += 192 * 72 / 2;
  _Float16* WeT = (_Float16*)(ws + off);    off += 320 * 72 / 2;
  _Float16* WaT = (_Float16*)(ws + off);    off += 128 * 72 / 2;
  _Float16* WinT = (_Float16*)(ws + off);   off += 3 * 64 * 136 / 2;
  _Float16* WoutT = (_Float16*)(ws + off);  off += 3 * 64 * 72 / 2;
  float* bstats = ws + off;                 off += (size_t)(NBQ + NBA + NBE) * 128;
  unsigned* row_start = (unsigned*)(ws + off); off += NT_TOTAL;
  unsigned* cursor = (unsigned*)(ws + off);    off += NT_TOTAL;
  unsigned* bsums = (unsigned*)(ws + off);     off += 1024;
  unsigned* eidx = (unsigned*)(ws + off);      off += E_TOTAL;

  const int Ns[3] = {NQ, NA, NE};
  const float* xs[3] = {xq, xa, xe};
  _Float16* yhb[3] = {y_h, y_h + (size_t)NQ * 64, y_h + (size_t)(NQ + NA) * 64};
  _Float16* aggb[3] = {agg_h, agg_h + (size_t)NQ * 64, agg_h + (size_t)(NQ + NA) * 64};
  float* zq_out = out + (N_POS + N_NEG);
  float* zbase[3] = {zq_out, zq_out + (size_t)NQ * 64, zq_out + (size_t)(NQ + NA) * 64};
  const int bb[3] = {0, NBQ, NBQ + NBA};

  fill_kernel<<<dim3(128), dim3(256), 0, stream>>>((float*)row_start, 0.f, NT_TOTAL);
  wprep_in<<<dim3(192), dim3(136), 0, stream>>>(W_in, WinT);
  wprep_out<<<dim3(192), dim3(72), 0, stream>>>(W_out, WoutT);

  // ---- in-proj (MFMA) + relu -> y fp16, fused bstats ----
  for (int t = 0; t < 3; ++t) {
    gemm_mfma<64, 128, 0><<<dim3(CDIV(Ns[t], 128)), dim3(256), 0, stream>>>(
        xs[t], nullptr, WinT + (size_t)t * 64 * 136, b_in + t * 64, Ns[t],
        nullptr, yhb[t], nullptr, nullptr, nullptr, nullptr,
        bstats + (size_t)bb[t] * 128, nullptr, nullptr, nullptr, nullptr, 0);
  }
  stats_reduce<<<dim3(384), dim3(256), 0, stream>>>(bstats, stats);
  bn_finalize<<<dim3(1), dim3(192), 0, stream>>>(stats, bn_gamma, bn_beta, scale, shift);
  kqv_bias2<<<dim3(3), dim3(192), 0, stream>>>(b_kqv, W_kqv, shift, bias2);
  wprep_kqv<<<dim3(640), dim3(64), 0, stream>>>(W_kqv, bias2, A_k, A_v, scale,
                                                WqT, WeT, WaT, bias_big);

  // ---- kqv projections (BN scale + A_k + A_v folded into weights) ----
  gemm_mfma<192, 64, 1><<<dim3(CDIV(NQ, 128)), dim3(256), 0, stream>>>(
      nullptr, yhb[0], WqT, bias_big, NQ, nullptr,
      kpack, qth, vp3, nullptr, nullptr,
      nullptr, nullptr, nullptr, nullptr, nullptr, 0);
  gemm_mfma<320, 64, 1><<<dim3(CDIV(NE, 128)), dim3(256), 0, stream>>>(
      nullptr, yhb[2], WeT, bias_big + 192, NE, nullptr,
      kpack + (size_t)NQ * 64, qth + (size_t)NQ * 64, vp0, vp1, vp2,
      nullptr, nullptr, nullptr, nullptr, nullptr, 0);
  gemm_mfma<128, 64, 1><<<dim3(CDIV(NA, 128)), dim3(256), 0, stream>>>(
      nullptr, yhb[1], WaT, bias_big + 512, NA, nullptr,
      qta0, qta1, nullptr, nullptr, nullptr,
      nullptr, nullptr, nullptr, nullptr, nullptr, 0);

  // ---- CSR build ----
  struct Rel { const int* ei; int E; int srcbase; int dstbase; unsigned slot; };
  Rel rels[4] = {{e_e2q, E_E2Q, SRC_E, BASE_Q, 0u},
                 {e_e2e, E_E2E, SRC_E, BASE_E, 0u},
                 {e_e2a, E_E2A, SRC_E, BASE_A, 0u},
                 {e_q2a, E_Q2A, SRC_Q, BASE_A, 1u}};
  for (int r = 0; r < 4; ++r) {
    int blocks = CDIV(rels[r].E, 256); if (blocks > 2048) blocks = 2048;
    hist_kernel<<<dim3(blocks), dim3(256), 0, stream>>>(rels[r].ei + rels[r].E, rels[r].E,
                                                        row_start, rels[r].dstbase);
  }
  scan1<<<dim3(NBLK_SCAN), dim3(256), 0, stream>>>(row_start, NT_TOTAL, bsums);
  scan2<<<dim3(1), dim3(256), 0, stream>>>(bsums, NBLK_SCAN);
  scan3<<<dim3(NBLK_SCAN), dim3(256), 0, stream>>>(row_start, bsums, cursor, NT_TOTAL);
  for (int r = 0; r < 4; ++r) {
    int blocks = CDIV(rels[r].E, 256); if (blocks > 2048) blocks = 2048;
    scatter_kernel<<<dim3(blocks), dim3(256), 0, stream>>>(
        rels[r].ei, rels[r].ei + rels[r].E, rels[r].E, cursor, eidx,
        rels[r].dstbase, rels[r].srcbase, rels[r].slot);
  }

  // ---- gathers (v' pre-transformed; fp16 everywhere; node prefetch) ----
  gather_kernel<1><<<dim3(CDIV(NQ, 4)), dim3(256), 0, stream>>>(
      NQ, BASE_Q, row_start, cursor, eidx, kpack,
      vp0 - (size_t)SRC_E * 64, nullptr,
      qth, nullptr, p_rel + 0, p_rel + 0, agg_h);
  gather_kernel<1><<<dim3(4096), dim3(256), 0, stream>>>(
      NE, BASE_E, row_start, cursor, eidx, kpack,
      vp1 - (size_t)SRC_E * 64, nullptr,
      qth + (size_t)NQ * 64, nullptr, p_rel + 2, p_rel + 2, agg_h);
  gather_kernel<2><<<dim3(CDIV(NA, 4)), dim3(256), 0, stream>>>(
      NA, BASE_A, row_start, cursor, eidx, kpack,
      vp2 - (size_t)SRC_E * 64, vp3,
      qta0, qta1, p_rel + 4, p_rel + 6, agg_h);

  // ---- out projection (MFMA, fp16 A) + skip blend -> fp32 z ----
  for (int t = 0; t < 3; ++t) {
    gemm_mfma<64, 64, 3><<<dim3(CDIV(Ns[t], 128)), dim3(256), 0, stream>>>(
        nullptr, aggb[t], WoutT + (size_t)t * 64 * 72, b_out + t * 64, Ns[t],
        zbase[t], nullptr, nullptr, nullptr, nullptr, nullptr,
        nullptr, yhb[t], scale + t * 64, shift + t * 64, skip, t);
  }

  // ---- predictions ----
  pred_kernel<<<dim3(CDIV(N_POS, 256)), dim3(256), 0, stream>>>(
      pos_idx, pos_idx + N_POS, N_POS, zbase[0], zbase[1], out);
  pred_kernel<<<dim3(CDIV(N_NEG, 256)), dim3(256), 0, stream>>>(
      neg_idx, neg_idx + N_NEG, N_NEG, zbase[0], zbase[1], out + N_POS);
}

// Round 10
// 874.830 us; speedup vs baseline: 2.2109x; 1.1854x over previous
//
#include <hip/hip_runtime.h>
#include <hip/hip_bf16.h>
#include <hip/hip_fp16.h>
#include <math.h>

#define NQ 8192
#define NA 32768
#define NE 500000
#define F_IN 128
#define E_E2Q 131072
#define E_E2E 800000
#define E_E2A 262144
#define E_Q2A 32768
#define N_POS 8192
#define N_NEG 24576

#define NT_TOTAL (NQ + NA + NE)                      // 540960
#define E_TOTAL (E_E2Q + E_E2E + E_E2A + E_Q2A)      // 1225984
#define NBLK_SCAN ((NT_TOTAL + 1023) / 1024)         // 529
#define CDIV(a, b) (((a) + (b) - 1) / (b))

// dst node index space: [question: 0) [answer: NQ) [entity: NQ+NA)
#define BASE_Q 0
#define BASE_A NQ
#define BASE_E (NQ + NA)

// in-proj block counts (BM=128) for bstats layout
#define NBQ 64      // CDIV(NQ,128)
#define NBA 256     // CDIV(NA,128)
#define NBE 3907    // CDIV(NE,128)

typedef _Float16 half8_t __attribute__((ext_vector_type(8)));
typedef _Float16 half4_t __attribute__((ext_vector_type(4)));
typedef float f32x4_t __attribute__((ext_vector_type(4)));

// ---------------- utility ----------------

__global__ void fill_kernel(float* __restrict__ p, float v, size_t n) {
  size_t i = (size_t)blockIdx.x * blockDim.x + threadIdx.x;
  size_t stride = (size_t)gridDim.x * blockDim.x;
  for (; i < n; i += stride) p[i] = v;
}

// ---------------- MFMA fp16 GEMM ----------------
// BM rows/block, BM*2 threads (BM/32 waves, 32 rows each). grid.y tiles columns by BNT.
// MODE 0: in-proj: A=fp32 cvt, relu -> oh fp16 (LDO) + per-block bstats
// MODE 1: kqv:     A=fp16, -> oh fp16 (LDO), single buffer
// MODE 3: out-proj:A=fp16 (agg), skip-blend vs fp16 residual -> Cf fp32 (LD 64)

template <int BM, int BNT, int KTOT, int MODE>
__global__ __launch_bounds__(BM * 2) void gemm_mfma(
    const float* __restrict__ Af, const _Float16* __restrict__ Ah,
    const _Float16* __restrict__ WT, const float* __restrict__ bias, int M,
    _Float16* __restrict__ oh, int LDO,
    float* __restrict__ Cf,
    float* __restrict__ bstats,
    const _Float16* __restrict__ resh, const float* __restrict__ rsc,
    const float* __restrict__ rsh, const float* __restrict__ skip_ptr, int skip_idx)
{
  constexpr int KP = KTOT + 8;
  constexpr int NTHR = BM * 2;
  __shared__ _Float16 As[BM * KP];
  __shared__ _Float16 Bs[BNT * KP];
  __shared__ float s1[64], s2[64];
  int tid = threadIdx.x;
  int row0 = blockIdx.x * BM;
  int colbase = blockIdx.y * BNT;
  if (MODE == 0 && tid < 64) { s1[tid] = 0.f; s2[tid] = 0.f; }

  // ---- stage A ----
  if (MODE == 0) {
    constexpr int CH = KTOT / 4;
    for (int idx = tid; idx < BM * CH; idx += NTHR) {
      int row = idx / CH, c = idx % CH;
      int gr = row0 + row;
      float4 a4 = make_float4(0.f, 0.f, 0.f, 0.f);
      if (gr < M) a4 = *(const float4*)&Af[(size_t)gr * KTOT + c * 4];
      half4_t h4 = {(_Float16)a4.x, (_Float16)a4.y, (_Float16)a4.z, (_Float16)a4.w};
      *(half4_t*)&As[row * KP + c * 4] = h4;
    }
  } else {
    constexpr int CH = KTOT / 8;
    for (int idx = tid; idx < BM * CH; idx += NTHR) {
      int row = idx / CH, c = idx % CH;
      int gr = row0 + row;
      half8_t a8 = {};
      if (gr < M) a8 = *(const half8_t*)&Ah[(size_t)gr * KTOT + c * 8];
      *(half8_t*)&As[row * KP + c * 8] = a8;
    }
  }
  // ---- stage B (flat copy of BNT padded rows from WT + colbase*KP) ----
  {
    const _Float16* wsrc = WT + (size_t)colbase * KP;
    for (int idx = tid; idx < BNT * KP / 8; idx += NTHR)
      *(half8_t*)&Bs[idx * 8] = *(const half8_t*)&wsrc[(size_t)idx * 8];
  }
  __syncthreads();

  int w = tid >> 6, l = tid & 63;
  int lr = l & 15, lg = l >> 4;
  constexpr int NCT = BNT / 16;
  constexpr int NKS = KTOT / 32;
  f32x4_t acc[2][NCT] = {};
#pragma unroll
  for (int ks = 0; ks < NKS; ++ks) {
    half8_t a0 = *(const half8_t*)&As[(w * 32 + lr) * KP + ks * 32 + lg * 8];
    half8_t a1 = *(const half8_t*)&As[(w * 32 + 16 + lr) * KP + ks * 32 + lg * 8];
#pragma unroll
    for (int ct = 0; ct < NCT; ++ct) {
      half8_t b = *(const half8_t*)&Bs[(ct * 16 + lr) * KP + ks * 32 + lg * 8];
      acc[0][ct] = __builtin_amdgcn_mfma_f32_16x16x32_f16(a0, b, acc[0][ct], 0, 0, 0);
      acc[1][ct] = __builtin_amdgcn_mfma_f32_16x16x32_f16(a1, b, acc[1][ct], 0, 0, 0);
    }
  }

  // ---- epilogue ----
  float g = 1.f, gb = 0.f;
  if (MODE == 3) { g = 1.f / (1.f + expf(-skip_ptr[skip_idx])); gb = 1.f - g; }
#pragma unroll
  for (int rt = 0; rt < 2; ++rt) {
    int rbase = row0 + w * 32 + rt * 16 + lg * 4;
#pragma unroll
    for (int ct = 0; ct < NCT; ++ct) {
      int col = colbase + ct * 16 + lr;
      float bval = bias[col];
      float p1 = 0.f, p2 = 0.f;
#pragma unroll
      for (int j = 0; j < 4; ++j) {
        int row = rbase + j;
        if (row >= M) continue;
        float val = acc[rt][ct][j] + bval;
        if (MODE == 0) {
          val = fmaxf(val, 0.f);
          oh[(size_t)row * LDO + col] = (_Float16)val;
          p1 += val; p2 += val * val;
        } else if (MODE == 1) {
          oh[(size_t)row * LDO + col] = (_Float16)val;
        } else {
          float rv = (float)resh[(size_t)row * 64 + col];
          Cf[(size_t)row * 64 + col] = g * val + gb * (rsc[col] * rv + rsh[col]);
        }
      }
      if (MODE == 0) { atomicAdd(&s1[col], p1); atomicAdd(&s2[col], p2); }
    }
  }
  if (MODE == 0) {
    __syncthreads();
    if (tid < 64) {
      bstats[(size_t)blockIdx.x * 128 + tid] = s1[tid];
      bstats[(size_t)blockIdx.x * 128 + 64 + tid] = s2[tid];
    }
  }
}

// ---------------- BN: reduce per-block stats (1 block per type×column) ----------------

__global__ __launch_bounds__(256) void stats_reduce(const float* __restrict__ bstats,
                                                    float* __restrict__ stats) {
  __shared__ float sh[256];
  int t = blockIdx.x >> 7;        // 0=q 1=a 2=e
  int c = blockIdx.x & 127;       // 0..127
  int nb = (t == 0) ? NBQ : (t == 1) ? NBA : NBE;
  int base = (t == 0) ? 0 : (t == 1) ? NBQ : (NBQ + NBA);
  float s = 0.f;
  for (int i = threadIdx.x; i < nb; i += 256)
    s += bstats[(size_t)(base + i) * 128 + c];
  sh[threadIdx.x] = s;
  __syncthreads();
  for (int off2 = 128; off2 > 0; off2 >>= 1) {
    if (threadIdx.x < off2) sh[threadIdx.x] += sh[threadIdx.x + off2];
    __syncthreads();
  }
  if (threadIdx.x == 0) stats[t * 128 + c] = sh[0];
}

__global__ void bn_finalize(const float* __restrict__ stats,
                            const float* __restrict__ gamma, const float* __restrict__ beta,
                            float* __restrict__ scale, float* __restrict__ shift) {
  int t = threadIdx.x;
  if (t >= 192) return;
  int ty = t >> 6, c = t & 63;
  float invN = (ty == 0) ? (1.f / NQ) : (ty == 1) ? (1.f / NA) : (1.f / NE);
  float mu = stats[ty * 128 + c] * invN;
  float var = stats[ty * 128 + 64 + c] * invN - mu * mu;
  float rs = rsqrtf(var + 1e-5f);
  float gm = gamma[ty * 64 + c];
  scale[t] = gm * rs;
  shift[t] = beta[ty * 64 + c] - gm * mu * rs;
}

// bias2[t][n] = b_kqv[t][n] + sum_k shift[t][k] * W_kqv[t][k][n]
__global__ void kqv_bias2(const float* __restrict__ b_kqv, const float* __restrict__ W_kqv,
                          const float* __restrict__ shift, float* __restrict__ bias2) {
  int t = blockIdx.x, n = threadIdx.x;
  float s = b_kqv[t * 192 + n];
  for (int k = 0; k < 64; ++k)
    s += shift[t * 64 + k] * W_kqv[(size_t)t * 64 * 192 + k * 192 + n];
  bias2[t * 192 + n] = s;
}

// ---------------- weight prep ----------------
// WqT[192][72]: question = [k | qt(rel0,A_k) | v'(rel3,A_v)]
// WeT[320][72]: entity   = [k | qt(rel1,A_k) | v'(rel0) | v'(rel1) | v'(rel2)]
// WaT[128][72]: answer   = [qt(rel2) | qt(rel3)]
// bias_big[640] = [q:192 | e:320 | a:128].  BN scale folded on input dim.

__global__ void wprep_kqv(const float* __restrict__ W_kqv, const float* __restrict__ bias2,
                          const float* __restrict__ A_k, const float* __restrict__ A_v,
                          const float* __restrict__ scale,
                          _Float16* __restrict__ WqT, _Float16* __restrict__ WeT,
                          _Float16* __restrict__ WaT, float* __restrict__ bias_big) {
  int j = blockIdx.x;   // 0..639
  int c = threadIdx.x;  // 0..63 (input k index)
  int t, jj, bofs;
  _Float16* W;
  if (j < 192)      { t = 0; jj = j;       W = WqT; bofs = 0; }
  else if (j < 512) { t = 2; jj = j - 192; W = WeT; bofs = 192; }
  else              { t = 1; jj = j - 512; W = WaT; bofs = 512; }
  const float* Wt = W_kqv + (size_t)t * 64 * 192;
  const float* b2 = bias2 + t * 192;
  int mode = 0, rel = 0, sub = 0;   // 0 plain-k, 1 qt(A_k), 2 v'(A_v)
  if (t == 1) { mode = 1; rel = (jj < 64) ? 2 : 3; sub = jj & 63; }
  else if (jj >= 64 && jj < 128) { mode = 1; rel = (t == 0) ? 0 : 1; sub = jj - 64; }
  else if (jj >= 128) {
    mode = 2; sub = (jj - 128) & 63;
    rel = (t == 0) ? 3 : ((jj - 128) >> 6);   // entity: 0,1,2 ; question: 3
  }
  int h = sub >> 5, x = sub & 31;
  float wv, bv;
  if (mode == 0) {
    wv = Wt[(size_t)c * 192 + jj];
    bv = b2[jj];
  } else if (mode == 1) {
    const float* Ar = A_k + ((size_t)rel * 2048 + h * 1024 + x * 32);
    float s = 0.f, sb = 0.f;
    for (int f = 0; f < 32; ++f) {
      float a = Ar[f];
      s = fmaf(a, Wt[(size_t)c * 192 + 64 + h * 32 + f], s);
      sb = fmaf(a, b2[64 + h * 32 + f], sb);
    }
    wv = s; bv = sb;
  } else {
    const float* Ar = A_v + ((size_t)rel * 2048 + h * 1024 + x);
    float s = 0.f, sb = 0.f;
    for (int d = 0; d < 32; ++d) {
      float a = Ar[d * 32];
      s = fmaf(a, Wt[(size_t)c * 192 + 128 + h * 32 + d], s);
      sb = fmaf(a, b2[128 + h * 32 + d], sb);
    }
    wv = s; bv = sb;
  }
  wv *= scale[t * 64 + c];
  W[(size_t)jj * 72 + c] = (_Float16)wv;
  if (c < 8) W[(size_t)jj * 72 + 64 + c] = (_Float16)0.f;
  if (c == 0) bias_big[bofs + jj] = bv;
}

// WinT[t][64][136] fp16 = W_in[t][k][n] transposed+padded
__global__ void wprep_in(const float* __restrict__ W_in, _Float16* __restrict__ WinT) {
  int t = blockIdx.x >> 6, n = blockIdx.x & 63, k = threadIdx.x;  // k 0..135
  float v = (k < 128) ? W_in[(size_t)t * 128 * 64 + (size_t)k * 64 + n] : 0.f;
  WinT[((size_t)t * 64 + n) * 136 + k] = (_Float16)v;
}

// WoutT[t][64][72] fp16 = W_out[t][k][n] transposed+padded
__global__ void wprep_out(const float* __restrict__ W_out, _Float16* __restrict__ WoutT) {
  int t = blockIdx.x >> 6, n = blockIdx.x & 63, k = threadIdx.x;  // k 0..71
  float v = (k < 64) ? W_out[(size_t)t * 64 * 64 + (size_t)k * 64 + n] : 0.f;
  WoutT[((size_t)t * 64 + n) * 72 + k] = (_Float16)v;
}

// ---------------- CSR build ----------------

__global__ void hist_kernel(const int* __restrict__ dst, int E,
                            unsigned* __restrict__ cnt, int base) {
  int i = blockIdx.x * blockDim.x + threadIdx.x;
  int stride = gridDim.x * blockDim.x;
  for (; i < E; i += stride) atomicAdd(&cnt[base + dst[i]], 1u);
}

__global__ __launch_bounds__(256) void scan1(unsigned* __restrict__ arr, int n,
                                             unsigned* __restrict__ bsums) {
  __shared__ unsigned sh[256];
  int t = threadIdx.x;
  int base = blockIdx.x * 1024 + t * 4;
  unsigned v[4];
  unsigned s = 0;
#pragma unroll
  for (int j = 0; j < 4; ++j) {
    v[j] = (base + j < n) ? arr[base + j] : 0u;
    s += v[j];
  }
  sh[t] = s;
  __syncthreads();
  for (int off = 1; off < 256; off <<= 1) {
    unsigned x = (t >= off) ? sh[t - off] : 0u;
    __syncthreads();
    sh[t] += x;
    __syncthreads();
  }
  unsigned run = sh[t] - s;
#pragma unroll
  for (int j = 0; j < 4; ++j) {
    if (base + j < n) arr[base + j] = run;
    run += v[j];
  }
  if (t == 255) bsums[blockIdx.x] = sh[255];
}

__global__ __launch_bounds__(256) void scan2(unsigned* __restrict__ bsums, int nb) {
  __shared__ unsigned sh[256];
  __shared__ unsigned carry;
  int t = threadIdx.x;
  if (t == 0) carry = 0;
  __syncthreads();
  for (int chunk = 0; chunk < nb; chunk += 256) {
    int i = chunk + t;
    unsigned v = (i < nb) ? bsums[i] : 0u;
    sh[t] = v;
    __syncthreads();
    for (int off = 1; off < 256; off <<= 1) {
      unsigned x = (t >= off) ? sh[t - off] : 0u;
      __syncthreads();
      sh[t] += x;
      __syncthreads();
    }
    unsigned inc = sh[t];
    unsigned c = carry;
    __syncthreads();
    if (i < nb) bsums[i] = c + inc - v;
    if (t == 255) carry = c + sh[255];
    __syncthreads();
  }
}

__global__ __launch_bounds__(256) void scan3(unsigned* __restrict__ arr,
                                             const unsigned* __restrict__ bsums,
                                             unsigned* __restrict__ cursor, int n) {
  int t = threadIdx.x;
  int base = blockIdx.x * 1024 + t * 4;
  unsigned add = bsums[blockIdx.x];
#pragma unroll
  for (int j = 0; j < 4; ++j) {
    int idx = base + j;
    if (idx < n) {
      unsigned r = arr[idx] + add;
      arr[idx] = r;
      cursor[idx] = r;
    }
  }
}

// payload = LOCAL src index | slot<<20
__global__ void scatter_kernel(const int* __restrict__ src, const int* __restrict__ dst, int E,
                               unsigned* __restrict__ cursor, unsigned* __restrict__ eidx,
                               int dstbase, unsigned slot) {
  int i = blockIdx.x * blockDim.x + threadIdx.x;
  int stride = gridDim.x * blockDim.x;
  for (; i < E; i += stride) {
    unsigned pos = atomicAdd(&cursor[dstbase + dst[i]], 1u);
    eidx[pos] = (unsigned)src[i] | (slot << 20);
  }
}

// ---------------- gather: softmax-weighted aggregation per dst node ----------------
// kqv rows hold [k | qt | v'...]; per-relation base/stride/val-offset. All fp16.

template <int NREL>
__global__ __launch_bounds__(256) void gather_kernel(
    int N, int nodebase,
    const unsigned* __restrict__ row_start, const unsigned* __restrict__ row_end,
    const unsigned* __restrict__ eidx,
    const _Float16* __restrict__ baseA, int ldA, int vofA,
    const _Float16* __restrict__ baseB, int ldB, int vofB,
    const _Float16* __restrict__ qtA, int ldqA,
    const _Float16* __restrict__ qtB, int ldqB,
    const float* __restrict__ prelA, const float* __restrict__ prelB,
    _Float16* __restrict__ agg)
{
  int lane = threadIdx.x & 63;
  int h = lane >> 5;
  const float isd = 0.17677669529663687f;
  float pr0 = prelA[h] * isd;
  float pr1 = (NREL == 2) ? prelB[h] * isd : 0.f;

  int wid = (int)((blockIdx.x * blockDim.x + threadIdx.x) >> 6);
  int nw = (int)((gridDim.x * blockDim.x) >> 6);

  int n = wid;
  unsigned pi0 = 0, pi1 = 0;
  float pqt0 = 0.f, pqt1 = 0.f;
  if (n < N) {
    pi0 = row_start[nodebase + n];
    pi1 = row_end[nodebase + n];
    pqt0 = (float)qtA[(size_t)n * ldqA + lane];
    if (NREL == 2) pqt1 = (float)qtB[(size_t)n * ldqB + lane];
  }
  while (n < N) {
    unsigned ci0 = pi0, ci1 = pi1;
    float cqt0 = pqt0, cqt1 = pqt1;
    int nn = n + nw;
    if (nn < N) {  // prefetch next node
      pi0 = row_start[nodebase + nn];
      pi1 = row_end[nodebase + nn];
      pqt0 = (float)qtA[(size_t)nn * ldqA + lane];
      if (NREL == 2) pqt1 = (float)qtB[(size_t)nn * ldqB + lane];
    }
    float vs = 0.f, ss = 0.f;
    unsigned i = ci0;
    for (; i + 2 <= ci1; i += 2) {
      unsigned p1 = eidx[i], p2 = eidx[i + 1];
      unsigned s1i = p1 & 0xFFFFFu, s2i = p2 & 0xFFFFFu;
      bool r1 = (NREL == 2) && (p1 >> 20);
      bool r2 = (NREL == 2) && (p2 >> 20);
      const _Float16* b1 = r1 ? baseB + (size_t)s1i * ldB : baseA + (size_t)s1i * ldA;
      const _Float16* b2 = r2 ? baseB + (size_t)s2i * ldB : baseA + (size_t)s2i * ldA;
      float k1 = (float)b1[lane];
      float v1 = (float)b1[(r1 ? vofB : vofA) + lane];
      float k2 = (float)b2[lane];
      float v2 = (float)b2[(r2 ? vofB : vofA) + lane];
      float sa = k1 * (r1 ? cqt1 : cqt0);
      float sb = k2 * (r2 ? cqt1 : cqt0);
#pragma unroll
      for (int off = 16; off > 0; off >>= 1) {
        sa += __shfl_xor(sa, off, 32);
        sb += __shfl_xor(sb, off, 32);
      }
      float w1 = expf(sa * (r1 ? pr1 : pr0));
      float w2 = expf(sb * (r2 ? pr1 : pr0));
      ss += w1 + w2;
      vs = fmaf(w1, v1, vs);
      vs = fmaf(w2, v2, vs);
    }
    if (i < ci1) {
      unsigned p1 = eidx[i];
      unsigned s1i = p1 & 0xFFFFFu;
      bool r1 = (NREL == 2) && (p1 >> 20);
      const _Float16* b1 = r1 ? baseB + (size_t)s1i * ldB : baseA + (size_t)s1i * ldA;
      float k1 = (float)b1[lane];
      float v1 = (float)b1[(r1 ? vofB : vofA) + lane];
      float sa = k1 * (r1 ? cqt1 : cqt0);
#pragma unroll
      for (int off = 16; off > 0; off >>= 1) sa += __shfl_xor(sa, off, 32);
      float w1 = expf(sa * (r1 ? pr1 : pr0));
      ss += w1;
      vs = fmaf(w1, v1, vs);
    }
    float val = (ss > 0.f) ? vs / ss : 0.f;
    val = 0.5f * val * (1.f + erff(val * 0.70710678118654752f));
    agg[((size_t)(nodebase + n)) * 64 + lane] = (_Float16)val;
    n = nn;
  }
}

// ---------------- final predictions ----------------

__global__ void pred_kernel(const int* __restrict__ qi, const int* __restrict__ ai, int Np,
                            const float* __restrict__ zq, const float* __restrict__ za,
                            float* __restrict__ outp) {
  int i = blockIdx.x * blockDim.x + threadIdx.x;
  if (i >= Np) return;
  const float4* a = (const float4*)(zq + (size_t)qi[i] * 64);
  const float4* b = (const float4*)(za + (size_t)ai[i] * 64);
  float ssum = 0.f;
#pragma unroll
  for (int j = 0; j < 16; ++j) {
    float4 x = a[j], y = b[j];
    ssum += x.x * y.x + x.y * y.y + x.z * y.z + x.w * y.w;
  }
  outp[i] = ssum;
}

// ---------------- host launch ----------------

extern "C" void kernel_launch(void* const* d_in, const int* in_sizes, int n_in,
                              void* d_out, int out_size, void* d_ws, size_t ws_size,
                              hipStream_t stream) {
  const float* xq = (const float*)d_in[0];
  const float* xa = (const float*)d_in[1];
  const float* xe = (const float*)d_in[2];
  const int* e_e2q = (const int*)d_in[3];
  const int* e_e2e = (const int*)d_in[4];
  const int* e_e2a = (const int*)d_in[5];
  const int* e_q2a = (const int*)d_in[6];
  const int* pos_idx = (const int*)d_in[7];
  const int* neg_idx = (const int*)d_in[8];
  const float* W_in = (const float*)d_in[9];
  const float* b_in = (const float*)d_in[10];
  const float* bn_gamma = (const float*)d_in[11];
  const float* bn_beta = (const float*)d_in[12];
  const float* W_kqv = (const float*)d_in[13];
  const float* b_kqv = (const float*)d_in[14];
  const float* A_k = (const float*)d_in[15];
  const float* A_v = (const float*)d_in[16];
  const float* p_rel = (const float*)d_in[17];
  const float* W_out = (const float*)d_in[18];
  const float* b_out = (const float*)d_in[19];
  const float* skip = (const float*)d_in[20];
  float* out = (float*)d_out;

  float* ws = (float*)d_ws;
  size_t off = 0;
  _Float16* y_h = (_Float16*)(ws + off);    off += (size_t)NT_TOTAL * 32;
  _Float16* kqvQ = (_Float16*)(ws + off);   off += (size_t)NQ * 96;    // [NQ][192]
  _Float16* kqvE = (_Float16*)(ws + off);   off += (size_t)NE * 160;   // [NE][320]
  _Float16* kqvA = (_Float16*)(ws + off);   off += (size_t)NA * 64;    // [NA][128]
  _Float16* agg_h = (_Float16*)(ws + off);  off += (size_t)NT_TOTAL * 32;
  float* stats = ws + off;                  off += 384;
  float* scale = ws + off;                  off += 192;
  float* shift = ws + off;                  off += 192;
  float* bias2 = ws + off;                  off += 576;
  float* bias_big = ws + off;               off += 640;
  _Float16* WqT = (_Float16*)(ws + off);    off += 192 * 72 / 2;
  _Float16* WeT = (_Float16*)(ws + off);    off += 320 * 72 / 2;
  _Float16* WaT = (_Float16*)(ws + off);    off += 128 * 72 / 2;
  _Float16* WinT = (_Float16*)(ws + off);   off += 3 * 64 * 136 / 2;
  _Float16* WoutT = (_Float16*)(ws + off);  off += 3 * 64 * 72 / 2;
  float* bstats = ws + off;                 off += (size_t)(NBQ + NBA + NBE) * 128;
  unsigned* row_start = (unsigned*)(ws + off); off += NT_TOTAL;
  unsigned* cursor = (unsigned*)(ws + off);    off += NT_TOTAL;
  unsigned* bsums = (unsigned*)(ws + off);     off += 1024;
  unsigned* eidx = (unsigned*)(ws + off);      off += E_TOTAL;

  const int Ns[3] = {NQ, NA, NE};
  const float* xs[3] = {xq, xa, xe};
  _Float16* yhb[3] = {y_h, y_h + (size_t)NQ * 64, y_h + (size_t)(NQ + NA) * 64};
  _Float16* aggb[3] = {agg_h, agg_h + (size_t)NQ * 64, agg_h + (size_t)(NQ + NA) * 64};
  float* zq_out = out + (N_POS + N_NEG);
  float* zbase[3] = {zq_out, zq_out + (size_t)NQ * 64, zq_out + (size_t)(NQ + NA) * 64};
  const int bb[3] = {0, NBQ, NBQ + NBA};

  fill_kernel<<<dim3(128), dim3(256), 0, stream>>>((float*)row_start, 0.f, NT_TOTAL);
  wprep_in<<<dim3(192), dim3(136), 0, stream>>>(W_in, WinT);
  wprep_out<<<dim3(192), dim3(72), 0, stream>>>(W_out, WoutT);

  // ---- in-proj (MFMA) + relu -> y fp16, fused bstats ----
  for (int t = 0; t < 3; ++t) {
    gemm_mfma<128, 64, 128, 0><<<dim3(CDIV(Ns[t], 128)), dim3(256), 0, stream>>>(
        xs[t], nullptr, WinT + (size_t)t * 64 * 136, b_in + t * 64, Ns[t],
        yhb[t], 64, nullptr, bstats + (size_t)bb[t] * 128,
        nullptr, nullptr, nullptr, nullptr, 0);
  }
  stats_reduce<<<dim3(384), dim3(256), 0, stream>>>(bstats, stats);
  bn_finalize<<<dim3(1), dim3(192), 0, stream>>>(stats, bn_gamma, bn_beta, scale, shift);
  kqv_bias2<<<dim3(3), dim3(192), 0, stream>>>(b_kqv, W_kqv, shift, bias2);
  wprep_kqv<<<dim3(640), dim3(64), 0, stream>>>(W_kqv, bias2, A_k, A_v, scale,
                                                WqT, WeT, WaT, bias_big);

  // ---- kqv projections (8-wave blocks; entity split into 2 col-tiles) ----
  gemm_mfma<256, 192, 64, 1><<<dim3(CDIV(NQ, 256)), dim3(512), 0, stream>>>(
      nullptr, yhb[0], WqT, bias_big, NQ,
      kqvQ, 192, nullptr, nullptr, nullptr, nullptr, nullptr, nullptr, 0);
  gemm_mfma<256, 160, 64, 1><<<dim3(CDIV(NE, 256), 2), dim3(512), 0, stream>>>(
      nullptr, yhb[2], WeT, bias_big + 192, NE,
      kqvE, 320, nullptr, nullptr, nullptr, nullptr, nullptr, nullptr, 0);
  gemm_mfma<256, 128, 64, 1><<<dim3(CDIV(NA, 256)), dim3(512), 0, stream>>>(
      nullptr, yhb[1], WaT, bias_big + 512, NA,
      kqvA, 128, nullptr, nullptr, nullptr, nullptr, nullptr, nullptr, 0);

  // ---- CSR build ----
  struct Rel { const int* ei; int E; int dstbase; unsigned slot; };
  Rel rels[4] = {{e_e2q, E_E2Q, BASE_Q, 0u},
                 {e_e2e, E_E2E, BASE_E, 0u},
                 {e_e2a, E_E2A, BASE_A, 0u},
                 {e_q2a, E_Q2A, BASE_A, 1u}};
  for (int r = 0; r < 4; ++r) {
    int blocks = CDIV(rels[r].E, 256); if (blocks > 2048) blocks = 2048;
    hist_kernel<<<dim3(blocks), dim3(256), 0, stream>>>(rels[r].ei + rels[r].E, rels[r].E,
                                                        row_start, rels[r].dstbase);
  }
  scan1<<<dim3(NBLK_SCAN), dim3(256), 0, stream>>>(row_start, NT_TOTAL, bsums);
  scan2<<<dim3(1), dim3(256), 0, stream>>>(bsums, NBLK_SCAN);
  scan3<<<dim3(NBLK_SCAN), dim3(256), 0, stream>>>(row_start, bsums, cursor, NT_TOTAL);
  for (int r = 0; r < 4; ++r) {
    int blocks = CDIV(rels[r].E, 256); if (blocks > 2048) blocks = 2048;
    scatter_kernel<<<dim3(blocks), dim3(256), 0, stream>>>(
        rels[r].ei, rels[r].ei + rels[r].E, rels[r].E, cursor, eidx,
        rels[r].dstbase, rels[r].slot);
  }

  // ---- gathers ----
  // e2q: src=entity rows of kqvE, v'(rel0)@128; qt = kqvQ[..]+64
  gather_kernel<1><<<dim3(CDIV(NQ, 4)), dim3(256), 0, stream>>>(
      NQ, BASE_Q, row_start, cursor, eidx,
      kqvE, 320, 128, nullptr, 0, 0,
      kqvQ + 64, 192, nullptr, 0, p_rel + 0, p_rel + 0, agg_h);
  // e2e: v'(rel1)@192; qt = kqvE[..]+64
  gather_kernel<1><<<dim3(4096), dim3(256), 0, stream>>>(
      NE, BASE_E, row_start, cursor, eidx,
      kqvE, 320, 192, nullptr, 0, 0,
      kqvE + 64, 320, nullptr, 0, p_rel + 2, p_rel + 2, agg_h);
  // answers: relA=e2a (entity, v'@256), relB=q2a (question, v'@128); qt2@0, qt3@64
  gather_kernel<2><<<dim3(CDIV(NA, 4)), dim3(256), 0, stream>>>(
      NA, BASE_A, row_start, cursor, eidx,
      kqvE, 320, 256, kqvQ, 192, 128,
      kqvA, 128, kqvA + 64, 128, p_rel + 4, p_rel + 6, agg_h);

  // ---- out projection (MFMA, fp16 A) + skip blend -> fp32 z ----
  for (int t = 0; t < 3; ++t) {
    gemm_mfma<256, 64, 64, 3><<<dim3(CDIV(Ns[t], 256)), dim3(512), 0, stream>>>(
        nullptr, aggb[t], WoutT + (size_t)t * 64 * 72, b_out + t * 64, Ns[t],
        nullptr, 0, zbase[t], nullptr,
        yhb[t], scale + t * 64, shift + t * 64, skip, t);
  }

  // ---- predictions ----
  pred_kernel<<<dim3(CDIV(N_POS, 256)), dim3(256), 0, stream>>>(
      pos_idx, pos_idx + N_POS, N_POS, zbase[0], zbase[1], out);
  pred_kernel<<<dim3(CDIV(N_NEG, 256)), dim3(256), 0, stream>>>(
      neg_idx, neg_idx + N_NEG, N_NEG, zbase[0], zbase[1], out + N_POS);
}

// Round 11
// 865.862 us; speedup vs baseline: 2.2338x; 1.0104x over previous
//
#include <hip/hip_runtime.h>
#include <hip/hip_bf16.h>
#include <hip/hip_fp16.h>
#include <math.h>

#define NQ 8192
#define NA 32768
#define NE 500000
#define F_IN 128
#define E_E2Q 131072
#define E_E2E 800000
#define E_E2A 262144
#define E_Q2A 32768
#define N_POS 8192
#define N_NEG 24576

#define NT_TOTAL (NQ + NA + NE)                      // 540960
#define E_TOTAL (E_E2Q + E_E2E + E_E2A + E_Q2A)      // 1225984
#define NBLK_SCAN ((NT_TOTAL + 1023) / 1024)         // 529
#define CDIV(a, b) (((a) + (b) - 1) / (b))

// dst node index space: [question: 0) [answer: NQ) [entity: NQ+NA)
#define BASE_Q 0
#define BASE_A NQ
#define BASE_E (NQ + NA)

// in-proj block counts (BM=128) for bstats layout
#define NBQ 64      // CDIV(NQ,128)
#define NBA 256     // CDIV(NA,128)
#define NBE 3907    // CDIV(NE,128)

typedef _Float16 half8_t __attribute__((ext_vector_type(8)));
typedef _Float16 half4_t __attribute__((ext_vector_type(4)));
typedef float f32x4_t __attribute__((ext_vector_type(4)));

// ---------------- utility ----------------

__global__ void fill_kernel(float* __restrict__ p, float v, size_t n) {
  size_t i = (size_t)blockIdx.x * blockDim.x + threadIdx.x;
  size_t stride = (size_t)gridDim.x * blockDim.x;
  for (; i < n; i += stride) p[i] = v;
}

// ---------------- direct-A MFMA GEMM (no A-LDS; 4 waves x 32 rows = BM 128) ----------------
// A fragments loaded straight from global in MFMA lane layout (lane lr=row, lg=k-chunk).
// MODE 0: in-proj: A=fp32[M][K] cvt -> relu -> oh fp16 + per-block bstats
// MODE 3: out-proj: A=fp16 agg, skip-blend vs fp16 residual -> Cf fp32

template <int BNT, int KTOT, int MODE>
__global__ __launch_bounds__(256) void gemm_direct(
    const float* __restrict__ Af, const _Float16* __restrict__ Ah,
    const _Float16* __restrict__ WT, const float* __restrict__ bias, int M,
    _Float16* __restrict__ oh, int LDO,
    float* __restrict__ Cf,
    float* __restrict__ bstats,
    const _Float16* __restrict__ resh, const float* __restrict__ rsc,
    const float* __restrict__ rsh, const float* __restrict__ skip_ptr, int skip_idx)
{
  constexpr int KP = KTOT + 8;
  __shared__ _Float16 Bs[BNT * KP];
  __shared__ float s1[64], s2[64];
  int tid = threadIdx.x;
  int row0 = blockIdx.x * 128;
  if (MODE == 0 && tid < 64) { s1[tid] = 0.f; s2[tid] = 0.f; }

  // stage B (weights) to LDS
  for (int idx = tid; idx < BNT * KP / 8; idx += 256)
    *(half8_t*)&Bs[idx * 8] = *(const half8_t*)&WT[(size_t)idx * 8];

  int w = tid >> 6, l = tid & 63;
  int lr = l & 15, lg = l >> 4;
  constexpr int NKS = KTOT / 32;
  // direct A-fragment loads (registers)
  half8_t afrag[2][NKS];
#pragma unroll
  for (int rt = 0; rt < 2; ++rt) {
    int gr = row0 + w * 32 + rt * 16 + lr;
    bool ok = gr < M;
#pragma unroll
    for (int ks = 0; ks < NKS; ++ks) {
      if (MODE == 0) {
        float4 x0 = make_float4(0.f, 0.f, 0.f, 0.f), x1 = x0;
        if (ok) {
          x0 = *(const float4*)&Af[(size_t)gr * KTOT + ks * 32 + lg * 8];
          x1 = *(const float4*)&Af[(size_t)gr * KTOT + ks * 32 + lg * 8 + 4];
        }
        half8_t h8 = {(_Float16)x0.x, (_Float16)x0.y, (_Float16)x0.z, (_Float16)x0.w,
                      (_Float16)x1.x, (_Float16)x1.y, (_Float16)x1.z, (_Float16)x1.w};
        afrag[rt][ks] = h8;
      } else {
        half8_t h8 = {};
        if (ok) h8 = *(const half8_t*)&Ah[(size_t)gr * KTOT + ks * 32 + lg * 8];
        afrag[rt][ks] = h8;
      }
    }
  }
  __syncthreads();

  constexpr int NCT = BNT / 16;
  f32x4_t acc[2][NCT] = {};
#pragma unroll
  for (int ks = 0; ks < NKS; ++ks) {
#pragma unroll
    for (int ct = 0; ct < NCT; ++ct) {
      half8_t b = *(const half8_t*)&Bs[(ct * 16 + lr) * KP + ks * 32 + lg * 8];
      acc[0][ct] = __builtin_amdgcn_mfma_f32_16x16x32_f16(afrag[0][ks], b, acc[0][ct], 0, 0, 0);
      acc[1][ct] = __builtin_amdgcn_mfma_f32_16x16x32_f16(afrag[1][ks], b, acc[1][ct], 0, 0, 0);
    }
  }

  // epilogue
  float g = 1.f, gb = 0.f;
  if (MODE == 3) { g = 1.f / (1.f + expf(-skip_ptr[skip_idx])); gb = 1.f - g; }
#pragma unroll
  for (int rt = 0; rt < 2; ++rt) {
    int rbase = row0 + w * 32 + rt * 16 + lg * 4;
#pragma unroll
    for (int ct = 0; ct < NCT; ++ct) {
      int col = ct * 16 + lr;
      float bval = bias[col];
      float p1 = 0.f, p2 = 0.f;
#pragma unroll
      for (int j = 0; j < 4; ++j) {
        int row = rbase + j;
        if (row >= M) continue;
        float val = acc[rt][ct][j] + bval;
        if (MODE == 0) {
          val = fmaxf(val, 0.f);
          oh[(size_t)row * LDO + col] = (_Float16)val;
          p1 += val; p2 += val * val;
        } else {
          float rv = (float)resh[(size_t)row * 64 + col];
          Cf[(size_t)row * 64 + col] = g * val + gb * (rsc[col] * rv + rsh[col]);
        }
      }
      if (MODE == 0) { atomicAdd(&s1[col], p1); atomicAdd(&s2[col], p2); }
    }
  }
  if (MODE == 0) {
    __syncthreads();
    if (tid < 64) {
      bstats[(size_t)blockIdx.x * 128 + tid] = s1[tid];
      bstats[(size_t)blockIdx.x * 128 + 64 + tid] = s2[tid];
    }
  }
}

// ---------------- staged MFMA GEMM (kqv, 8 waves, col-tiled) ----------------
// MODE 1 only: A=fp16[M][64] -> oh fp16 (LDO)

template <int BM, int BNT, int KTOT>
__global__ __launch_bounds__(BM * 2) void gemm_mfma(
    const _Float16* __restrict__ Ah,
    const _Float16* __restrict__ WT, const float* __restrict__ bias, int M,
    _Float16* __restrict__ oh, int LDO)
{
  constexpr int KP = KTOT + 8;
  constexpr int NTHR = BM * 2;
  __shared__ _Float16 As[BM * KP];
  __shared__ _Float16 Bs[BNT * KP];
  int tid = threadIdx.x;
  int row0 = blockIdx.x * BM;
  int colbase = blockIdx.y * BNT;

  {
    constexpr int CH = KTOT / 8;
    for (int idx = tid; idx < BM * CH; idx += NTHR) {
      int row = idx / CH, c = idx % CH;
      int gr = row0 + row;
      half8_t a8 = {};
      if (gr < M) a8 = *(const half8_t*)&Ah[(size_t)gr * KTOT + c * 8];
      *(half8_t*)&As[row * KP + c * 8] = a8;
    }
  }
  {
    const _Float16* wsrc = WT + (size_t)colbase * KP;
    for (int idx = tid; idx < BNT * KP / 8; idx += NTHR)
      *(half8_t*)&Bs[idx * 8] = *(const half8_t*)&wsrc[(size_t)idx * 8];
  }
  __syncthreads();

  int w = tid >> 6, l = tid & 63;
  int lr = l & 15, lg = l >> 4;
  constexpr int NCT = BNT / 16;
  constexpr int NKS = KTOT / 32;
  f32x4_t acc[2][NCT] = {};
#pragma unroll
  for (int ks = 0; ks < NKS; ++ks) {
    half8_t a0 = *(const half8_t*)&As[(w * 32 + lr) * KP + ks * 32 + lg * 8];
    half8_t a1 = *(const half8_t*)&As[(w * 32 + 16 + lr) * KP + ks * 32 + lg * 8];
#pragma unroll
    for (int ct = 0; ct < NCT; ++ct) {
      half8_t b = *(const half8_t*)&Bs[(ct * 16 + lr) * KP + ks * 32 + lg * 8];
      acc[0][ct] = __builtin_amdgcn_mfma_f32_16x16x32_f16(a0, b, acc[0][ct], 0, 0, 0);
      acc[1][ct] = __builtin_amdgcn_mfma_f32_16x16x32_f16(a1, b, acc[1][ct], 0, 0, 0);
    }
  }
#pragma unroll
  for (int rt = 0; rt < 2; ++rt) {
    int rbase = row0 + w * 32 + rt * 16 + lg * 4;
#pragma unroll
    for (int ct = 0; ct < NCT; ++ct) {
      int col = colbase + ct * 16 + lr;
      float bval = bias[col];
#pragma unroll
      for (int j = 0; j < 4; ++j) {
        int row = rbase + j;
        if (row >= M) continue;
        oh[(size_t)row * LDO + col] = (_Float16)(acc[rt][ct][j] + bval);
      }
    }
  }
}

// ---------------- BN: reduce per-block stats ----------------

__global__ __launch_bounds__(256) void stats_reduce(const float* __restrict__ bstats,
                                                    float* __restrict__ stats) {
  __shared__ float sh[256];
  int t = blockIdx.x >> 7;
  int c = blockIdx.x & 127;
  int nb = (t == 0) ? NBQ : (t == 1) ? NBA : NBE;
  int base = (t == 0) ? 0 : (t == 1) ? NBQ : (NBQ + NBA);
  float s = 0.f;
  for (int i = threadIdx.x; i < nb; i += 256)
    s += bstats[(size_t)(base + i) * 128 + c];
  sh[threadIdx.x] = s;
  __syncthreads();
  for (int off2 = 128; off2 > 0; off2 >>= 1) {
    if (threadIdx.x < off2) sh[threadIdx.x] += sh[threadIdx.x + off2];
    __syncthreads();
  }
  if (threadIdx.x == 0) stats[t * 128 + c] = sh[0];
}

__global__ void bn_finalize(const float* __restrict__ stats,
                            const float* __restrict__ gamma, const float* __restrict__ beta,
                            float* __restrict__ scale, float* __restrict__ shift) {
  int t = threadIdx.x;
  if (t >= 192) return;
  int ty = t >> 6, c = t & 63;
  float invN = (ty == 0) ? (1.f / NQ) : (ty == 1) ? (1.f / NA) : (1.f / NE);
  float mu = stats[ty * 128 + c] * invN;
  float var = stats[ty * 128 + 64 + c] * invN - mu * mu;
  float rs = rsqrtf(var + 1e-5f);
  float gm = gamma[ty * 64 + c];
  scale[t] = gm * rs;
  shift[t] = beta[ty * 64 + c] - gm * mu * rs;
}

__global__ void kqv_bias2(const float* __restrict__ b_kqv, const float* __restrict__ W_kqv,
                          const float* __restrict__ shift, float* __restrict__ bias2) {
  int t = blockIdx.x, n = threadIdx.x;
  float s = b_kqv[t * 192 + n];
  for (int k = 0; k < 64; ++k)
    s += shift[t * 64 + k] * W_kqv[(size_t)t * 64 * 192 + k * 192 + n];
  bias2[t * 192 + n] = s;
}

// ---------------- weight prep ----------------
// WqT[192][72]: question = [k | qt(rel0,A_k) | v'(rel3,A_v)]
// WeT[320][72]: entity   = [k | qt(rel1,A_k) | v'(rel0) | v'(rel1) | v'(rel2)]
// WaT[128][72]: answer   = [qt(rel2) | qt(rel3)]
// bias_big[640] = [q:192 | e:320 | a:128].  BN scale folded on input dim.

__global__ void wprep_kqv(const float* __restrict__ W_kqv, const float* __restrict__ bias2,
                          const float* __restrict__ A_k, const float* __restrict__ A_v,
                          const float* __restrict__ scale,
                          _Float16* __restrict__ WqT, _Float16* __restrict__ WeT,
                          _Float16* __restrict__ WaT, float* __restrict__ bias_big) {
  int j = blockIdx.x;   // 0..639
  int c = threadIdx.x;  // 0..63
  int t, jj, bofs;
  _Float16* W;
  if (j < 192)      { t = 0; jj = j;       W = WqT; bofs = 0; }
  else if (j < 512) { t = 2; jj = j - 192; W = WeT; bofs = 192; }
  else              { t = 1; jj = j - 512; W = WaT; bofs = 512; }
  const float* Wt = W_kqv + (size_t)t * 64 * 192;
  const float* b2 = bias2 + t * 192;
  int mode = 0, rel = 0, sub = 0;
  if (t == 1) { mode = 1; rel = (jj < 64) ? 2 : 3; sub = jj & 63; }
  else if (jj >= 64 && jj < 128) { mode = 1; rel = (t == 0) ? 0 : 1; sub = jj - 64; }
  else if (jj >= 128) {
    mode = 2; sub = (jj - 128) & 63;
    rel = (t == 0) ? 3 : ((jj - 128) >> 6);
  }
  int h = sub >> 5, x = sub & 31;
  float wv, bv;
  if (mode == 0) {
    wv = Wt[(size_t)c * 192 + jj];
    bv = b2[jj];
  } else if (mode == 1) {
    const float* Ar = A_k + ((size_t)rel * 2048 + h * 1024 + x * 32);
    float s = 0.f, sb = 0.f;
    for (int f = 0; f < 32; ++f) {
      float a = Ar[f];
      s = fmaf(a, Wt[(size_t)c * 192 + 64 + h * 32 + f], s);
      sb = fmaf(a, b2[64 + h * 32 + f], sb);
    }
    wv = s; bv = sb;
  } else {
    const float* Ar = A_v + ((size_t)rel * 2048 + h * 1024 + x);
    float s = 0.f, sb = 0.f;
    for (int d = 0; d < 32; ++d) {
      float a = Ar[d * 32];
      s = fmaf(a, Wt[(size_t)c * 192 + 128 + h * 32 + d], s);
      sb = fmaf(a, b2[128 + h * 32 + d], sb);
    }
    wv = s; bv = sb;
  }
  wv *= scale[t * 64 + c];
  W[(size_t)jj * 72 + c] = (_Float16)wv;
  if (c < 8) W[(size_t)jj * 72 + 64 + c] = (_Float16)0.f;
  if (c == 0) bias_big[bofs + jj] = bv;
}

__global__ void wprep_in(const float* __restrict__ W_in, _Float16* __restrict__ WinT) {
  int t = blockIdx.x >> 6, n = blockIdx.x & 63, k = threadIdx.x;  // k 0..135
  float v = (k < 128) ? W_in[(size_t)t * 128 * 64 + (size_t)k * 64 + n] : 0.f;
  WinT[((size_t)t * 64 + n) * 136 + k] = (_Float16)v;
}

__global__ void wprep_out(const float* __restrict__ W_out, _Float16* __restrict__ WoutT) {
  int t = blockIdx.x >> 6, n = blockIdx.x & 63, k = threadIdx.x;  // k 0..71
  float v = (k < 64) ? W_out[(size_t)t * 64 * 64 + (size_t)k * 64 + n] : 0.f;
  WoutT[((size_t)t * 64 + n) * 72 + k] = (_Float16)v;
}

// ---------------- CSR build ----------------

__global__ void hist_kernel(const int* __restrict__ dst, int E,
                            unsigned* __restrict__ cnt, int base) {
  int i = blockIdx.x * blockDim.x + threadIdx.x;
  int stride = gridDim.x * blockDim.x;
  for (; i < E; i += stride) atomicAdd(&cnt[base + dst[i]], 1u);
}

__global__ __launch_bounds__(256) void scan1(unsigned* __restrict__ arr, int n,
                                             unsigned* __restrict__ bsums) {
  __shared__ unsigned sh[256];
  int t = threadIdx.x;
  int base = blockIdx.x * 1024 + t * 4;
  unsigned v[4];
  unsigned s = 0;
#pragma unroll
  for (int j = 0; j < 4; ++j) {
    v[j] = (base + j < n) ? arr[base + j] : 0u;
    s += v[j];
  }
  sh[t] = s;
  __syncthreads();
  for (int off = 1; off < 256; off <<= 1) {
    unsigned x = (t >= off) ? sh[t - off] : 0u;
    __syncthreads();
    sh[t] += x;
    __syncthreads();
  }
  unsigned run = sh[t] - s;
#pragma unroll
  for (int j = 0; j < 4; ++j) {
    if (base + j < n) arr[base + j] = run;
    run += v[j];
  }
  if (t == 255) bsums[blockIdx.x] = sh[255];
}

__global__ __launch_bounds__(256) void scan2(unsigned* __restrict__ bsums, int nb) {
  __shared__ unsigned sh[256];
  __shared__ unsigned carry;
  int t = threadIdx.x;
  if (t == 0) carry = 0;
  __syncthreads();
  for (int chunk = 0; chunk < nb; chunk += 256) {
    int i = chunk + t;
    unsigned v = (i < nb) ? bsums[i] : 0u;
    sh[t] = v;
    __syncthreads();
    for (int off = 1; off < 256; off <<= 1) {
      unsigned x = (t >= off) ? sh[t - off] : 0u;
      __syncthreads();
      sh[t] += x;
      __syncthreads();
    }
    unsigned inc = sh[t];
    unsigned c = carry;
    __syncthreads();
    if (i < nb) bsums[i] = c + inc - v;
    if (t == 255) carry = c + sh[255];
    __syncthreads();
  }
}

__global__ __launch_bounds__(256) void scan3(unsigned* __restrict__ arr,
                                             const unsigned* __restrict__ bsums,
                                             unsigned* __restrict__ cursor, int n) {
  int t = threadIdx.x;
  int base = blockIdx.x * 1024 + t * 4;
  unsigned add = bsums[blockIdx.x];
#pragma unroll
  for (int j = 0; j < 4; ++j) {
    int idx = base + j;
    if (idx < n) {
      unsigned r = arr[idx] + add;
      arr[idx] = r;
      cursor[idx] = r;
    }
  }
}

// payload = LOCAL src index | slot<<20
__global__ void scatter_kernel(const int* __restrict__ src, const int* __restrict__ dst, int E,
                               unsigned* __restrict__ cursor, unsigned* __restrict__ eidx,
                               int dstbase, unsigned slot) {
  int i = blockIdx.x * blockDim.x + threadIdx.x;
  int stride = gridDim.x * blockDim.x;
  for (; i < E; i += stride) {
    unsigned pos = atomicAdd(&cursor[dstbase + dst[i]], 1u);
    eidx[pos] = (unsigned)src[i] | (slot << 20);
  }
}

// ---------------- gather: softmax-weighted aggregation per dst node ----------------

template <int NREL>
__global__ __launch_bounds__(256) void gather_kernel(
    int N, int nodebase,
    const unsigned* __restrict__ row_start, const unsigned* __restrict__ row_end,
    const unsigned* __restrict__ eidx,
    const _Float16* __restrict__ baseA, int ldA, int vofA,
    const _Float16* __restrict__ baseB, int ldB, int vofB,
    const _Float16* __restrict__ qtA, int ldqA,
    const _Float16* __restrict__ qtB, int ldqB,
    const float* __restrict__ prelA, const float* __restrict__ prelB,
    _Float16* __restrict__ agg)
{
  int lane = threadIdx.x & 63;
  int h = lane >> 5;
  const float isd = 0.17677669529663687f;
  float pr0 = prelA[h] * isd;
  float pr1 = (NREL == 2) ? prelB[h] * isd : 0.f;

  int wid = (int)((blockIdx.x * blockDim.x + threadIdx.x) >> 6);
  int nw = (int)((gridDim.x * blockDim.x) >> 6);

  int n = wid;
  unsigned pi0 = 0, pi1 = 0;
  float pqt0 = 0.f, pqt1 = 0.f;
  if (n < N) {
    pi0 = row_start[nodebase + n];
    pi1 = row_end[nodebase + n];
    pqt0 = (float)qtA[(size_t)n * ldqA + lane];
    if (NREL == 2) pqt1 = (float)qtB[(size_t)n * ldqB + lane];
  }
  while (n < N) {
    unsigned ci0 = pi0, ci1 = pi1;
    float cqt0 = pqt0, cqt1 = pqt1;
    int nn = n + nw;
    if (nn < N) {
      pi0 = row_start[nodebase + nn];
      pi1 = row_end[nodebase + nn];
      pqt0 = (float)qtA[(size_t)nn * ldqA + lane];
      if (NREL == 2) pqt1 = (float)qtB[(size_t)nn * ldqB + lane];
    }
    float vs = 0.f, ss = 0.f;
    unsigned i = ci0;
    for (; i + 2 <= ci1; i += 2) {
      unsigned p1 = eidx[i], p2 = eidx[i + 1];
      unsigned s1i = p1 & 0xFFFFFu, s2i = p2 & 0xFFFFFu;
      bool r1 = (NREL == 2) && (p1 >> 20);
      bool r2 = (NREL == 2) && (p2 >> 20);
      const _Float16* b1 = r1 ? baseB + (size_t)s1i * ldB : baseA + (size_t)s1i * ldA;
      const _Float16* b2 = r2 ? baseB + (size_t)s2i * ldB : baseA + (size_t)s2i * ldA;
      float k1 = (float)b1[lane];
      float v1 = (float)b1[(r1 ? vofB : vofA) + lane];
      float k2 = (float)b2[lane];
      float v2 = (float)b2[(r2 ? vofB : vofA) + lane];
      float sa = k1 * (r1 ? cqt1 : cqt0);
      float sb = k2 * (r2 ? cqt1 : cqt0);
#pragma unroll
      for (int off = 16; off > 0; off >>= 1) {
        sa += __shfl_xor(sa, off, 32);
        sb += __shfl_xor(sb, off, 32);
      }
      float w1 = expf(sa * (r1 ? pr1 : pr0));
      float w2 = expf(sb * (r2 ? pr1 : pr0));
      ss += w1 + w2;
      vs = fmaf(w1, v1, vs);
      vs = fmaf(w2, v2, vs);
    }
    if (i < ci1) {
      unsigned p1 = eidx[i];
      unsigned s1i = p1 & 0xFFFFFu;
      bool r1 = (NREL == 2) && (p1 >> 20);
      const _Float16* b1 = r1 ? baseB + (size_t)s1i * ldB : baseA + (size_t)s1i * ldA;
      float k1 = (float)b1[lane];
      float v1 = (float)b1[(r1 ? vofB : vofA) + lane];
      float sa = k1 * (r1 ? cqt1 : cqt0);
#pragma unroll
      for (int off = 16; off > 0; off >>= 1) sa += __shfl_xor(sa, off, 32);
      float w1 = expf(sa * (r1 ? pr1 : pr0));
      ss += w1;
      vs = fmaf(w1, v1, vs);
    }
    float val = (ss > 0.f) ? vs / ss : 0.f;
    val = 0.5f * val * (1.f + erff(val * 0.70710678118654752f));
    agg[((size_t)(nodebase + n)) * 64 + lane] = (_Float16)val;
    n = nn;
  }
}

// ---------------- final predictions ----------------

__global__ void pred_kernel(const int* __restrict__ qi, const int* __restrict__ ai, int Np,
                            const float* __restrict__ zq, const float* __restrict__ za,
                            float* __restrict__ outp) {
  int i = blockIdx.x * blockDim.x + threadIdx.x;
  if (i >= Np) return;
  const float4* a = (const float4*)(zq + (size_t)qi[i] * 64);
  const float4* b = (const float4*)(za + (size_t)ai[i] * 64);
  float ssum = 0.f;
#pragma unroll
  for (int j = 0; j < 16; ++j) {
    float4 x = a[j], y = b[j];
    ssum += x.x * y.x + x.y * y.y + x.z * y.z + x.w * y.w;
  }
  outp[i] = ssum;
}

// ---------------- host launch ----------------

extern "C" void kernel_launch(void* const* d_in, const int* in_sizes, int n_in,
                              void* d_out, int out_size, void* d_ws, size_t ws_size,
                              hipStream_t stream) {
  const float* xq = (const float*)d_in[0];
  const float* xa = (const float*)d_in[1];
  const float* xe = (const float*)d_in[2];
  const int* e_e2q = (const int*)d_in[3];
  const int* e_e2e = (const int*)d_in[4];
  const int* e_e2a = (const int*)d_in[5];
  const int* e_q2a = (const int*)d_in[6];
  const int* pos_idx = (const int*)d_in[7];
  const int* neg_idx = (const int*)d_in[8];
  const float* W_in = (const float*)d_in[9];
  const float* b_in = (const float*)d_in[10];
  const float* bn_gamma = (const float*)d_in[11];
  const float* bn_beta = (const float*)d_in[12];
  const float* W_kqv = (const float*)d_in[13];
  const float* b_kqv = (const float*)d_in[14];
  const float* A_k = (const float*)d_in[15];
  const float* A_v = (const float*)d_in[16];
  const float* p_rel = (const float*)d_in[17];
  const float* W_out = (const float*)d_in[18];
  const float* b_out = (const float*)d_in[19];
  const float* skip = (const float*)d_in[20];
  float* out = (float*)d_out;

  float* ws = (float*)d_ws;
  size_t off = 0;
  _Float16* y_h = (_Float16*)(ws + off);    off += (size_t)NT_TOTAL * 32;
  _Float16* kqvQ = (_Float16*)(ws + off);   off += (size_t)NQ * 96;    // [NQ][192]
  _Float16* kqvE = (_Float16*)(ws + off);   off += (size_t)NE * 160;   // [NE][320]
  _Float16* kqvA = (_Float16*)(ws + off);   off += (size_t)NA * 64;    // [NA][128]
  _Float16* agg_h = (_Float16*)(ws + off);  off += (size_t)NT_TOTAL * 32;
  float* stats = ws + off;                  off += 384;
  float* scale = ws + off;                  off += 192;
  float* shift = ws + off;                  off += 192;
  float* bias2 = ws + off;                  off += 576;
  float* bias_big = ws + off;               off += 640;
  _Float16* WqT = (_Float16*)(ws + off);    off += 192 * 72 / 2;
  _Float16* WeT = (_Float16*)(ws + off);    off += 320 * 72 / 2;
  _Float16* WaT = (_Float16*)(ws + off);    off += 128 * 72 / 2;
  _Float16* WinT = (_Float16*)(ws + off);   off += 3 * 64 * 136 / 2;
  _Float16* WoutT = (_Float16*)(ws + off);  off += 3 * 64 * 72 / 2;
  float* bstats = ws + off;                 off += (size_t)(NBQ + NBA + NBE) * 128;
  unsigned* row_start = (unsigned*)(ws + off); off += NT_TOTAL;
  unsigned* cursor = (unsigned*)(ws + off);    off += NT_TOTAL;
  unsigned* bsums = (unsigned*)(ws + off);     off += 1024;
  unsigned* eidx = (unsigned*)(ws + off);      off += E_TOTAL;

  const int Ns[3] = {NQ, NA, NE};
  const float* xs[3] = {xq, xa, xe};
  _Float16* yhb[3] = {y_h, y_h + (size_t)NQ * 64, y_h + (size_t)(NQ + NA) * 64};
  _Float16* aggb[3] = {agg_h, agg_h + (size_t)NQ * 64, agg_h + (size_t)(NQ + NA) * 64};
  float* zq_out = out + (N_POS + N_NEG);
  float* zbase[3] = {zq_out, zq_out + (size_t)NQ * 64, zq_out + (size_t)(NQ + NA) * 64};
  const int bb[3] = {0, NBQ, NBQ + NBA};

  fill_kernel<<<dim3(128), dim3(256), 0, stream>>>((float*)row_start, 0.f, NT_TOTAL);
  wprep_in<<<dim3(192), dim3(136), 0, stream>>>(W_in, WinT);
  wprep_out<<<dim3(192), dim3(72), 0, stream>>>(W_out, WoutT);

  // ---- in-proj (direct-A MFMA) + relu -> y fp16, fused bstats ----
  for (int t = 0; t < 3; ++t) {
    gemm_direct<64, 128, 0><<<dim3(CDIV(Ns[t], 128)), dim3(256), 0, stream>>>(
        xs[t], nullptr, WinT + (size_t)t * 64 * 136, b_in + t * 64, Ns[t],
        yhb[t], 64, nullptr, bstats + (size_t)bb[t] * 128,
        nullptr, nullptr, nullptr, nullptr, 0);
  }
  stats_reduce<<<dim3(384), dim3(256), 0, stream>>>(bstats, stats);
  bn_finalize<<<dim3(1), dim3(192), 0, stream>>>(stats, bn_gamma, bn_beta, scale, shift);
  kqv_bias2<<<dim3(3), dim3(192), 0, stream>>>(b_kqv, W_kqv, shift, bias2);
  wprep_kqv<<<dim3(640), dim3(64), 0, stream>>>(W_kqv, bias2, A_k, A_v, scale,
                                                WqT, WeT, WaT, bias_big);

  // ---- kqv projections (staged 8-wave; entity split into 2 col-tiles) ----
  gemm_mfma<256, 192, 64><<<dim3(CDIV(NQ, 256)), dim3(512), 0, stream>>>(
      yhb[0], WqT, bias_big, NQ, kqvQ, 192);
  gemm_mfma<256, 160, 64><<<dim3(CDIV(NE, 256), 2), dim3(512), 0, stream>>>(
      yhb[2], WeT, bias_big + 192, NE, kqvE, 320);
  gemm_mfma<256, 128, 64><<<dim3(CDIV(NA, 256)), dim3(512), 0, stream>>>(
      yhb[1], WaT, bias_big + 512, NA, kqvA, 128);

  // ---- CSR build ----
  struct Rel { const int* ei; int E; int dstbase; unsigned slot; };
  Rel rels[4] = {{e_e2q, E_E2Q, BASE_Q, 0u},
                 {e_e2e, E_E2E, BASE_E, 0u},
                 {e_e2a, E_E2A, BASE_A, 0u},
                 {e_q2a, E_Q2A, BASE_A, 1u}};
  for (int r = 0; r < 4; ++r) {
    int blocks = CDIV(rels[r].E, 256); if (blocks > 2048) blocks = 2048;
    hist_kernel<<<dim3(blocks), dim3(256), 0, stream>>>(rels[r].ei + rels[r].E, rels[r].E,
                                                        row_start, rels[r].dstbase);
  }
  scan1<<<dim3(NBLK_SCAN), dim3(256), 0, stream>>>(row_start, NT_TOTAL, bsums);
  scan2<<<dim3(1), dim3(256), 0, stream>>>(bsums, NBLK_SCAN);
  scan3<<<dim3(NBLK_SCAN), dim3(256), 0, stream>>>(row_start, bsums, cursor, NT_TOTAL);
  for (int r = 0; r < 4; ++r) {
    int blocks = CDIV(rels[r].E, 256); if (blocks > 2048) blocks = 2048;
    scatter_kernel<<<dim3(blocks), dim3(256), 0, stream>>>(
        rels[r].ei, rels[r].ei + rels[r].E, rels[r].E, cursor, eidx,
        rels[r].dstbase, rels[r].slot);
  }

  // ---- gathers ----
  gather_kernel<1><<<dim3(CDIV(NQ, 4)), dim3(256), 0, stream>>>(
      NQ, BASE_Q, row_start, cursor, eidx,
      kqvE, 320, 128, nullptr, 0, 0,
      kqvQ + 64, 192, nullptr, 0, p_rel + 0, p_rel + 0, agg_h);
  gather_kernel<1><<<dim3(4096), dim3(256), 0, stream>>>(
      NE, BASE_E, row_start, cursor, eidx,
      kqvE, 320, 192, nullptr, 0, 0,
      kqvE + 64, 320, nullptr, 0, p_rel + 2, p_rel + 2, agg_h);
  gather_kernel<2><<<dim3(CDIV(NA, 4)), dim3(256), 0, stream>>>(
      NA, BASE_A, row_start, cursor, eidx,
      kqvE, 320, 256, kqvQ, 192, 128,
      kqvA, 128, kqvA + 64, 128, p_rel + 4, p_rel + 6, agg_h);

  // ---- out projection (direct-A MFMA) + skip blend -> fp32 z ----
  for (int t = 0; t < 3; ++t) {
    gemm_direct<64, 64, 3><<<dim3(CDIV(Ns[t], 128)), dim3(256), 0, stream>>>(
        nullptr, aggb[t], WoutT + (size_t)t * 64 * 72, b_out + t * 64, Ns[t],
        nullptr, 0, zbase[t], nullptr,
        yhb[t], scale + t * 64, shift + t * 64, skip, t);
  }

  // ---- predictions ----
  pred_kernel<<<dim3(CDIV(N_POS, 256)), dim3(256), 0, stream>>>(
      pos_idx, pos_idx + N_POS, N_POS, zbase[0], zbase[1], out);
  pred_kernel<<<dim3(CDIV(N_NEG, 256)), dim3(256), 0, stream>>>(
      neg_idx, neg_idx + N_NEG, N_NEG, zbase[0], zbase[1], out + N_POS);
}

// Round 12
// 826.509 us; speedup vs baseline: 2.3402x; 1.0476x over previous
//
#include <hip/hip_runtime.h>
#include <hip/hip_bf16.h>
#include <hip/hip_fp16.h>
#include <math.h>

#define NQ 8192
#define NA 32768
#define NE 500000
#define F_IN 128
#define E_E2Q 131072
#define E_E2E 800000
#define E_E2A 262144
#define E_Q2A 32768
#define N_POS 8192
#define N_NEG 24576

#define NT_TOTAL (NQ + NA + NE)                      // 540960
#define E_TOTAL (E_E2Q + E_E2E + E_E2A + E_Q2A)      // 1225984
#define NBLK_SCAN ((NT_TOTAL + 1023) / 1024)         // 529
#define CDIV(a, b) (((a) + (b) - 1) / (b))

// dst node index space: [question: 0) [answer: NQ) [entity: NQ+NA)
#define BASE_Q 0
#define BASE_A NQ
#define BASE_E (NQ + NA)

// in-proj grids (1 block per bstats row)
#define GIN_Q 64     // = tiles(8192/128)
#define GIN_A 256    // = tiles(32768/128)
#define GIN_E 512    // < tiles(3907), grid-stride
#define SMEM_INPROJ (65536 + 17408 + 512)

typedef _Float16 half8_t __attribute__((ext_vector_type(8)));
typedef _Float16 half4_t __attribute__((ext_vector_type(4)));
typedef float f32x4_t __attribute__((ext_vector_type(4)));

__device__ inline void load_lds16(const void* g, void* l) {
  __builtin_amdgcn_global_load_lds((const __attribute__((address_space(1))) void*)g,
                                   (__attribute__((address_space(3))) void*)l, 16, 0, 0);
}

// ---------------- utility ----------------

__global__ void fill_kernel(float* __restrict__ p, float v, size_t n) {
  size_t i = (size_t)blockIdx.x * blockDim.x + threadIdx.x;
  size_t stride = (size_t)gridDim.x * blockDim.x;
  for (; i < n; i += stride) p[i] = v;
}

// ---------------- in-proj: LDS-staged fp32 A (global_load_lds), MFMA, fused bstats ----------------
// Block = 4 waves, grid-strides over 128-row tiles. Per tile: stage 64KB fp32 x-tile to LDS
// (64 wave-ops of 16B/lane -> 64KB in flight, VGPR-free), then MFMA vs fp16 W in LDS.

__global__ __launch_bounds__(256) void gemm_inproj(
    const float* __restrict__ Af, const _Float16* __restrict__ WT,
    const float* __restrict__ bias, int M, int ntiles,
    _Float16* __restrict__ oh, float* __restrict__ bstats)
{
  extern __shared__ char smem[];
  float* As32 = (float*)smem;                       // 128 x 128 fp32 = 64KB
  _Float16* Bs = (_Float16*)(smem + 65536);         // 64 x 136 fp16 = 17408B
  float* s1 = (float*)(smem + 65536 + 17408);       // 64
  float* s2 = s1 + 64;                              // 64

  int tid = threadIdx.x;
  int w = tid >> 6, l = tid & 63;
  int lr = l & 15, lg = l >> 4;

  // stage weights once
  for (int idx = tid; idx < 64 * 136 / 8; idx += 256)
    *(half8_t*)&Bs[idx * 8] = *(const half8_t*)&WT[(size_t)idx * 8];
  if (tid < 64) { s1[tid] = 0.f; s2[tid] = 0.f; }

  float ps1[4] = {}, ps2[4] = {};
  float bval[4];
#pragma unroll
  for (int ct = 0; ct < 4; ++ct) bval[ct] = bias[ct * 16 + lr];

  for (int tile = blockIdx.x; tile < ntiles; tile += gridDim.x) {
    // ---- stage A tile: 16 rounds x (4 waves x 1KB) ----
    const char* srcbase = (const char*)Af + (size_t)tile * 128 * 512;
    int rowlim = M - tile * 128;  // rows valid in this tile
#pragma unroll
    for (int r = 0; r < 16; ++r) {
      int unit = r * 4 + w;                         // wave-uniform 0..63
      char* ldst = (char*)As32 + unit * 1024;
      int p = unit * 1024 + l * 16;
      int row = p >> 9;
      const char* src = (row < rowlim) ? srcbase + (size_t)row * 512 + (p & 511)
                                       : srcbase;   // clamped, in-bounds
      load_lds16(src, ldst);
    }
    __syncthreads();  // drains vmcnt -> staged tile visible

    // ---- MFMA ----
    f32x4_t acc[2][4] = {};
#pragma unroll
    for (int ks = 0; ks < 4; ++ks) {
      half8_t a0, a1;
      {
        const float4* pa = (const float4*)((const char*)As32 +
                            (w * 32 + lr) * 512 + ks * 128 + lg * 32);
        float4 x0 = pa[0], x1 = pa[1];
        a0 = half8_t{(_Float16)x0.x, (_Float16)x0.y, (_Float16)x0.z, (_Float16)x0.w,
                     (_Float16)x1.x, (_Float16)x1.y, (_Float16)x1.z, (_Float16)x1.w};
      }
      {
        const float4* pa = (const float4*)((const char*)As32 +
                            (w * 32 + 16 + lr) * 512 + ks * 128 + lg * 32);
        float4 x0 = pa[0], x1 = pa[1];
        a1 = half8_t{(_Float16)x0.x, (_Float16)x0.y, (_Float16)x0.z, (_Float16)x0.w,
                     (_Float16)x1.x, (_Float16)x1.y, (_Float16)x1.z, (_Float16)x1.w};
      }
#pragma unroll
      for (int ct = 0; ct < 4; ++ct) {
        half8_t b = *(const half8_t*)&Bs[(ct * 16 + lr) * 136 + ks * 32 + lg * 8];
        acc[0][ct] = __builtin_amdgcn_mfma_f32_16x16x32_f16(a0, b, acc[0][ct], 0, 0, 0);
        acc[1][ct] = __builtin_amdgcn_mfma_f32_16x16x32_f16(a1, b, acc[1][ct], 0, 0, 0);
      }
    }

    // ---- epilogue: relu -> fp16 store + reg bstats ----
#pragma unroll
    for (int rt = 0; rt < 2; ++rt) {
      int rbase = tile * 128 + w * 32 + rt * 16 + lg * 4;
#pragma unroll
      for (int ct = 0; ct < 4; ++ct) {
        int col = ct * 16 + lr;
#pragma unroll
        for (int j = 0; j < 4; ++j) {
          int row = rbase + j;
          if (row >= M) continue;
          float val = fmaxf(acc[rt][ct][j] + bval[ct], 0.f);
          oh[(size_t)row * 64 + col] = (_Float16)val;
          ps1[ct] += val;
          ps2[ct] += val * val;
        }
      }
    }
    __syncthreads();  // all waves done reading As32 before next stage
  }

  // ---- block bstats reduce ----
#pragma unroll
  for (int ct = 0; ct < 4; ++ct) {
    atomicAdd(&s1[ct * 16 + lr], ps1[ct]);
    atomicAdd(&s2[ct * 16 + lr], ps2[ct]);
  }
  __syncthreads();
  if (tid < 64) {
    bstats[(size_t)blockIdx.x * 128 + tid] = s1[tid];
    bstats[(size_t)blockIdx.x * 128 + 64 + tid] = s2[tid];
  }
}

// ---------------- direct-A MFMA GEMM (out-proj, MODE 3) ----------------

template <int BNT, int KTOT, int MODE>
__global__ __launch_bounds__(256) void gemm_direct(
    const float* __restrict__ Af, const _Float16* __restrict__ Ah,
    const _Float16* __restrict__ WT, const float* __restrict__ bias, int M,
    _Float16* __restrict__ oh, int LDO,
    float* __restrict__ Cf,
    float* __restrict__ bstats,
    const _Float16* __restrict__ resh, const float* __restrict__ rsc,
    const float* __restrict__ rsh, const float* __restrict__ skip_ptr, int skip_idx)
{
  constexpr int KP = KTOT + 8;
  __shared__ _Float16 Bs[BNT * KP];
  int tid = threadIdx.x;
  int row0 = blockIdx.x * 128;

  for (int idx = tid; idx < BNT * KP / 8; idx += 256)
    *(half8_t*)&Bs[idx * 8] = *(const half8_t*)&WT[(size_t)idx * 8];

  int w = tid >> 6, l = tid & 63;
  int lr = l & 15, lg = l >> 4;
  constexpr int NKS = KTOT / 32;
  half8_t afrag[2][NKS];
#pragma unroll
  for (int rt = 0; rt < 2; ++rt) {
    int gr = row0 + w * 32 + rt * 16 + lr;
    bool ok = gr < M;
#pragma unroll
    for (int ks = 0; ks < NKS; ++ks) {
      half8_t h8 = {};
      if (ok) h8 = *(const half8_t*)&Ah[(size_t)gr * KTOT + ks * 32 + lg * 8];
      afrag[rt][ks] = h8;
    }
  }
  __syncthreads();

  constexpr int NCT = BNT / 16;
  f32x4_t acc[2][NCT] = {};
#pragma unroll
  for (int ks = 0; ks < NKS; ++ks) {
#pragma unroll
    for (int ct = 0; ct < NCT; ++ct) {
      half8_t b = *(const half8_t*)&Bs[(ct * 16 + lr) * KP + ks * 32 + lg * 8];
      acc[0][ct] = __builtin_amdgcn_mfma_f32_16x16x32_f16(afrag[0][ks], b, acc[0][ct], 0, 0, 0);
      acc[1][ct] = __builtin_amdgcn_mfma_f32_16x16x32_f16(afrag[1][ks], b, acc[1][ct], 0, 0, 0);
    }
  }

  float g = 1.f / (1.f + __expf(-skip_ptr[skip_idx]));
  float gb = 1.f - g;
#pragma unroll
  for (int rt = 0; rt < 2; ++rt) {
    int rbase = row0 + w * 32 + rt * 16 + lg * 4;
#pragma unroll
    for (int ct = 0; ct < NCT; ++ct) {
      int col = ct * 16 + lr;
      float bval = bias[col];
#pragma unroll
      for (int j = 0; j < 4; ++j) {
        int row = rbase + j;
        if (row >= M) continue;
        float val = acc[rt][ct][j] + bval;
        float rv = (float)resh[(size_t)row * 64 + col];
        Cf[(size_t)row * 64 + col] = g * val + gb * (rsc[col] * rv + rsh[col]);
      }
    }
  }
}

// ---------------- staged MFMA GEMM (kqv, 8 waves, col-tiled) ----------------

template <int BM, int BNT, int KTOT>
__global__ __launch_bounds__(BM * 2) void gemm_mfma(
    const _Float16* __restrict__ Ah,
    const _Float16* __restrict__ WT, const float* __restrict__ bias, int M,
    _Float16* __restrict__ oh, int LDO)
{
  constexpr int KP = KTOT + 8;
  constexpr int NTHR = BM * 2;
  __shared__ _Float16 As[BM * KP];
  __shared__ _Float16 Bs[BNT * KP];
  int tid = threadIdx.x;
  int row0 = blockIdx.x * BM;
  int colbase = blockIdx.y * BNT;

  {
    constexpr int CH = KTOT / 8;
    for (int idx = tid; idx < BM * CH; idx += NTHR) {
      int row = idx / CH, c = idx % CH;
      int gr = row0 + row;
      half8_t a8 = {};
      if (gr < M) a8 = *(const half8_t*)&Ah[(size_t)gr * KTOT + c * 8];
      *(half8_t*)&As[row * KP + c * 8] = a8;
    }
  }
  {
    const _Float16* wsrc = WT + (size_t)colbase * KP;
    for (int idx = tid; idx < BNT * KP / 8; idx += NTHR)
      *(half8_t*)&Bs[idx * 8] = *(const half8_t*)&wsrc[(size_t)idx * 8];
  }
  __syncthreads();

  int w = tid >> 6, l = tid & 63;
  int lr = l & 15, lg = l >> 4;
  constexpr int NCT = BNT / 16;
  constexpr int NKS = KTOT / 32;
  f32x4_t acc[2][NCT] = {};
#pragma unroll
  for (int ks = 0; ks < NKS; ++ks) {
    half8_t a0 = *(const half8_t*)&As[(w * 32 + lr) * KP + ks * 32 + lg * 8];
    half8_t a1 = *(const half8_t*)&As[(w * 32 + 16 + lr) * KP + ks * 32 + lg * 8];
#pragma unroll
    for (int ct = 0; ct < NCT; ++ct) {
      half8_t b = *(const half8_t*)&Bs[(ct * 16 + lr) * KP + ks * 32 + lg * 8];
      acc[0][ct] = __builtin_amdgcn_mfma_f32_16x16x32_f16(a0, b, acc[0][ct], 0, 0, 0);
      acc[1][ct] = __builtin_amdgcn_mfma_f32_16x16x32_f16(a1, b, acc[1][ct], 0, 0, 0);
    }
  }
#pragma unroll
  for (int rt = 0; rt < 2; ++rt) {
    int rbase = row0 + w * 32 + rt * 16 + lg * 4;
#pragma unroll
    for (int ct = 0; ct < NCT; ++ct) {
      int col = colbase + ct * 16 + lr;
      float bval = bias[col];
#pragma unroll
      for (int j = 0; j < 4; ++j) {
        int row = rbase + j;
        if (row >= M) continue;
        oh[(size_t)row * LDO + col] = (_Float16)(acc[rt][ct][j] + bval);
      }
    }
  }
}

// ---------------- BN: reduce per-block stats ----------------

__global__ __launch_bounds__(256) void stats_reduce(const float* __restrict__ bstats,
                                                    float* __restrict__ stats) {
  __shared__ float sh[256];
  int t = blockIdx.x >> 7;
  int c = blockIdx.x & 127;
  int nb = (t == 0) ? GIN_Q : (t == 1) ? GIN_A : GIN_E;
  int base = (t == 0) ? 0 : (t == 1) ? GIN_Q : (GIN_Q + GIN_A);
  float s = 0.f;
  for (int i = threadIdx.x; i < nb; i += 256)
    s += bstats[(size_t)(base + i) * 128 + c];
  sh[threadIdx.x] = s;
  __syncthreads();
  for (int off2 = 128; off2 > 0; off2 >>= 1) {
    if (threadIdx.x < off2) sh[threadIdx.x] += sh[threadIdx.x + off2];
    __syncthreads();
  }
  if (threadIdx.x == 0) stats[t * 128 + c] = sh[0];
}

__global__ void bn_finalize(const float* __restrict__ stats,
                            const float* __restrict__ gamma, const float* __restrict__ beta,
                            float* __restrict__ scale, float* __restrict__ shift) {
  int t = threadIdx.x;
  if (t >= 192) return;
  int ty = t >> 6, c = t & 63;
  float invN = (ty == 0) ? (1.f / NQ) : (ty == 1) ? (1.f / NA) : (1.f / NE);
  float mu = stats[ty * 128 + c] * invN;
  float var = stats[ty * 128 + 64 + c] * invN - mu * mu;
  float rs = rsqrtf(var + 1e-5f);
  float gm = gamma[ty * 64 + c];
  scale[t] = gm * rs;
  shift[t] = beta[ty * 64 + c] - gm * mu * rs;
}

__global__ void kqv_bias2(const float* __restrict__ b_kqv, const float* __restrict__ W_kqv,
                          const float* __restrict__ shift, float* __restrict__ bias2) {
  int t = blockIdx.x, n = threadIdx.x;
  float s = b_kqv[t * 192 + n];
  for (int k = 0; k < 64; ++k)
    s += shift[t * 64 + k] * W_kqv[(size_t)t * 64 * 192 + k * 192 + n];
  bias2[t * 192 + n] = s;
}

// ---------------- weight prep ----------------
// WqT[192][72]: question = [k | qt(rel0,A_k) | v'(rel3,A_v)]
// WeT[320][72]: entity   = [k | qt(rel1,A_k) | v'(rel0) | v'(rel1) | v'(rel2)]
// WaT[128][72]: answer   = [qt(rel2) | qt(rel3)]
// bias_big[640] = [q:192 | e:320 | a:128].  BN scale folded on input dim.

__global__ void wprep_kqv(const float* __restrict__ W_kqv, const float* __restrict__ bias2,
                          const float* __restrict__ A_k, const float* __restrict__ A_v,
                          const float* __restrict__ scale,
                          _Float16* __restrict__ WqT, _Float16* __restrict__ WeT,
                          _Float16* __restrict__ WaT, float* __restrict__ bias_big) {
  int j = blockIdx.x;   // 0..639
  int c = threadIdx.x;  // 0..63
  int t, jj, bofs;
  _Float16* W;
  if (j < 192)      { t = 0; jj = j;       W = WqT; bofs = 0; }
  else if (j < 512) { t = 2; jj = j - 192; W = WeT; bofs = 192; }
  else              { t = 1; jj = j - 512; W = WaT; bofs = 512; }
  const float* Wt = W_kqv + (size_t)t * 64 * 192;
  const float* b2 = bias2 + t * 192;
  int mode = 0, rel = 0, sub = 0;
  if (t == 1) { mode = 1; rel = (jj < 64) ? 2 : 3; sub = jj & 63; }
  else if (jj >= 64 && jj < 128) { mode = 1; rel = (t == 0) ? 0 : 1; sub = jj - 64; }
  else if (jj >= 128) {
    mode = 2; sub = (jj - 128) & 63;
    rel = (t == 0) ? 3 : ((jj - 128) >> 6);
  }
  int h = sub >> 5, x = sub & 31;
  float wv, bv;
  if (mode == 0) {
    wv = Wt[(size_t)c * 192 + jj];
    bv = b2[jj];
  } else if (mode == 1) {
    const float* Ar = A_k + ((size_t)rel * 2048 + h * 1024 + x * 32);
    float s = 0.f, sb = 0.f;
    for (int f = 0; f < 32; ++f) {
      float a = Ar[f];
      s = fmaf(a, Wt[(size_t)c * 192 + 64 + h * 32 + f], s);
      sb = fmaf(a, b2[64 + h * 32 + f], sb);
    }
    wv = s; bv = sb;
  } else {
    const float* Ar = A_v + ((size_t)rel * 2048 + h * 1024 + x);
    float s = 0.f, sb = 0.f;
    for (int d = 0; d < 32; ++d) {
      float a = Ar[d * 32];
      s = fmaf(a, Wt[(size_t)c * 192 + 128 + h * 32 + d], s);
      sb = fmaf(a, b2[128 + h * 32 + d], sb);
    }
    wv = s; bv = sb;
  }
  wv *= scale[t * 64 + c];
  W[(size_t)jj * 72 + c] = (_Float16)wv;
  if (c < 8) W[(size_t)jj * 72 + 64 + c] = (_Float16)0.f;
  if (c == 0) bias_big[bofs + jj] = bv;
}

__global__ void wprep_in(const float* __restrict__ W_in, _Float16* __restrict__ WinT) {
  int t = blockIdx.x >> 6, n = blockIdx.x & 63, k = threadIdx.x;  // k 0..135
  float v = (k < 128) ? W_in[(size_t)t * 128 * 64 + (size_t)k * 64 + n] : 0.f;
  WinT[((size_t)t * 64 + n) * 136 + k] = (_Float16)v;
}

__global__ void wprep_out(const float* __restrict__ W_out, _Float16* __restrict__ WoutT) {
  int t = blockIdx.x >> 6, n = blockIdx.x & 63, k = threadIdx.x;  // k 0..71
  float v = (k < 64) ? W_out[(size_t)t * 64 * 64 + (size_t)k * 64 + n] : 0.f;
  WoutT[((size_t)t * 64 + n) * 72 + k] = (_Float16)v;
}

// ---------------- CSR build ----------------

__global__ void hist_kernel(const int* __restrict__ dst, int E,
                            unsigned* __restrict__ cnt, int base) {
  int i = blockIdx.x * blockDim.x + threadIdx.x;
  int stride = gridDim.x * blockDim.x;
  for (; i < E; i += stride) atomicAdd(&cnt[base + dst[i]], 1u);
}

__global__ __launch_bounds__(256) void scan1(unsigned* __restrict__ arr, int n,
                                             unsigned* __restrict__ bsums) {
  __shared__ unsigned sh[256];
  int t = threadIdx.x;
  int base = blockIdx.x * 1024 + t * 4;
  unsigned v[4];
  unsigned s = 0;
#pragma unroll
  for (int j = 0; j < 4; ++j) {
    v[j] = (base + j < n) ? arr[base + j] : 0u;
    s += v[j];
  }
  sh[t] = s;
  __syncthreads();
  for (int off = 1; off < 256; off <<= 1) {
    unsigned x = (t >= off) ? sh[t - off] : 0u;
    __syncthreads();
    sh[t] += x;
    __syncthreads();
  }
  unsigned run = sh[t] - s;
#pragma unroll
  for (int j = 0; j < 4; ++j) {
    if (base + j < n) arr[base + j] = run;
    run += v[j];
  }
  if (t == 255) bsums[blockIdx.x] = sh[255];
}

__global__ __launch_bounds__(256) void scan2(unsigned* __restrict__ bsums, int nb) {
  __shared__ unsigned sh[256];
  __shared__ unsigned carry;
  int t = threadIdx.x;
  if (t == 0) carry = 0;
  __syncthreads();
  for (int chunk = 0; chunk < nb; chunk += 256) {
    int i = chunk + t;
    unsigned v = (i < nb) ? bsums[i] : 0u;
    sh[t] = v;
    __syncthreads();
    for (int off = 1; off < 256; off <<= 1) {
      unsigned x = (t >= off) ? sh[t - off] : 0u;
      __syncthreads();
      sh[t] += x;
      __syncthreads();
    }
    unsigned inc = sh[t];
    unsigned c = carry;
    __syncthreads();
    if (i < nb) bsums[i] = c + inc - v;
    if (t == 255) carry = c + sh[255];
    __syncthreads();
  }
}

__global__ __launch_bounds__(256) void scan3(unsigned* __restrict__ arr,
                                             const unsigned* __restrict__ bsums,
                                             unsigned* __restrict__ cursor, int n) {
  int t = threadIdx.x;
  int base = blockIdx.x * 1024 + t * 4;
  unsigned add = bsums[blockIdx.x];
#pragma unroll
  for (int j = 0; j < 4; ++j) {
    int idx = base + j;
    if (idx < n) {
      unsigned r = arr[idx] + add;
      arr[idx] = r;
      cursor[idx] = r;
    }
  }
}

// payload = LOCAL src index | slot<<20
__global__ void scatter_kernel(const int* __restrict__ src, const int* __restrict__ dst, int E,
                               unsigned* __restrict__ cursor, unsigned* __restrict__ eidx,
                               int dstbase, unsigned slot) {
  int i = blockIdx.x * blockDim.x + threadIdx.x;
  int stride = gridDim.x * blockDim.x;
  for (; i < E; i += stride) {
    unsigned pos = atomicAdd(&cursor[dstbase + dst[i]], 1u);
    eidx[pos] = (unsigned)src[i] | (slot << 20);
  }
}

// ---------------- gather: softmax-weighted aggregation per dst node ----------------

template <int NREL>
__global__ __launch_bounds__(256) void gather_kernel(
    int N, int nodebase,
    const unsigned* __restrict__ row_start, const unsigned* __restrict__ row_end,
    const unsigned* __restrict__ eidx,
    const _Float16* __restrict__ baseA, int ldA, int vofA,
    const _Float16* __restrict__ baseB, int ldB, int vofB,
    const _Float16* __restrict__ qtA, int ldqA,
    const _Float16* __restrict__ qtB, int ldqB,
    const float* __restrict__ prelA, const float* __restrict__ prelB,
    _Float16* __restrict__ agg)
{
  int lane = threadIdx.x & 63;
  int h = lane >> 5;
  const float isd = 0.17677669529663687f;
  float pr0 = prelA[h] * isd;
  float pr1 = (NREL == 2) ? prelB[h] * isd : 0.f;

  int wid = (int)((blockIdx.x * blockDim.x + threadIdx.x) >> 6);
  int nw = (int)((gridDim.x * blockDim.x) >> 6);

  int n = wid;
  unsigned pi0 = 0, pi1 = 0;
  float pqt0 = 0.f, pqt1 = 0.f;
  if (n < N) {
    pi0 = row_start[nodebase + n];
    pi1 = row_end[nodebase + n];
    pqt0 = (float)qtA[(size_t)n * ldqA + lane];
    if (NREL == 2) pqt1 = (float)qtB[(size_t)n * ldqB + lane];
  }
  while (n < N) {
    unsigned ci0 = pi0, ci1 = pi1;
    float cqt0 = pqt0, cqt1 = pqt1;
    int nn = n + nw;
    if (nn < N) {
      pi0 = row_start[nodebase + nn];
      pi1 = row_end[nodebase + nn];
      pqt0 = (float)qtA[(size_t)nn * ldqA + lane];
      if (NREL == 2) pqt1 = (float)qtB[(size_t)nn * ldqB + lane];
    }
    float vs = 0.f, ss = 0.f;
    unsigned i = ci0;
    for (; i + 2 <= ci1; i += 2) {
      unsigned p1 = eidx[i], p2 = eidx[i + 1];
      unsigned s1i = p1 & 0xFFFFFu, s2i = p2 & 0xFFFFFu;
      bool r1 = (NREL == 2) && (p1 >> 20);
      bool r2 = (NREL == 2) && (p2 >> 20);
      const _Float16* b1 = r1 ? baseB + (size_t)s1i * ldB : baseA + (size_t)s1i * ldA;
      const _Float16* b2 = r2 ? baseB + (size_t)s2i * ldB : baseA + (size_t)s2i * ldA;
      float k1 = (float)b1[lane];
      float v1 = (float)b1[(r1 ? vofB : vofA) + lane];
      float k2 = (float)b2[lane];
      float v2 = (float)b2[(r2 ? vofB : vofA) + lane];
      float sa = k1 * (r1 ? cqt1 : cqt0);
      float sb = k2 * (r2 ? cqt1 : cqt0);
#pragma unroll
      for (int off = 16; off > 0; off >>= 1) {
        sa += __shfl_xor(sa, off, 32);
        sb += __shfl_xor(sb, off, 32);
      }
      float w1 = __expf(sa * (r1 ? pr1 : pr0));
      float w2 = __expf(sb * (r2 ? pr1 : pr0));
      ss += w1 + w2;
      vs = fmaf(w1, v1, vs);
      vs = fmaf(w2, v2, vs);
    }
    if (i < ci1) {
      unsigned p1 = eidx[i];
      unsigned s1i = p1 & 0xFFFFFu;
      bool r1 = (NREL == 2) && (p1 >> 20);
      const _Float16* b1 = r1 ? baseB + (size_t)s1i * ldB : baseA + (size_t)s1i * ldA;
      float k1 = (float)b1[lane];
      float v1 = (float)b1[(r1 ? vofB : vofA) + lane];
      float sa = k1 * (r1 ? cqt1 : cqt0);
#pragma unroll
      for (int off = 16; off > 0; off >>= 1) sa += __shfl_xor(sa, off, 32);
      float w1 = __expf(sa * (r1 ? pr1 : pr0));
      ss += w1;
      vs = fmaf(w1, v1, vs);
    }
    float val = (ss > 0.f) ? vs / ss : 0.f;
    val = 0.5f * val * (1.f + erff(val * 0.70710678118654752f));
    agg[((size_t)(nodebase + n)) * 64 + lane] = (_Float16)val;
    n = nn;
  }
}

// ---------------- final predictions ----------------

__global__ void pred_kernel(const int* __restrict__ qi, const int* __restrict__ ai, int Np,
                            const float* __restrict__ zq, const float* __restrict__ za,
                            float* __restrict__ outp) {
  int i = blockIdx.x * blockDim.x + threadIdx.x;
  if (i >= Np) return;
  const float4* a = (const float4*)(zq + (size_t)qi[i] * 64);
  const float4* b = (const float4*)(za + (size_t)ai[i] * 64);
  float ssum = 0.f;
#pragma unroll
  for (int j = 0; j < 16; ++j) {
    float4 x = a[j], y = b[j];
    ssum += x.x * y.x + x.y * y.y + x.z * y.z + x.w * y.w;
  }
  outp[i] = ssum;
}

// ---------------- host launch ----------------

extern "C" void kernel_launch(void* const* d_in, const int* in_sizes, int n_in,
                              void* d_out, int out_size, void* d_ws, size_t ws_size,
                              hipStream_t stream) {
  const float* xq = (const float*)d_in[0];
  const float* xa = (const float*)d_in[1];
  const float* xe = (const float*)d_in[2];
  const int* e_e2q = (const int*)d_in[3];
  const int* e_e2e = (const int*)d_in[4];
  const int* e_e2a = (const int*)d_in[5];
  const int* e_q2a = (const int*)d_in[6];
  const int* pos_idx = (const int*)d_in[7];
  const int* neg_idx = (const int*)d_in[8];
  const float* W_in = (const float*)d_in[9];
  const float* b_in = (const float*)d_in[10];
  const float* bn_gamma = (const float*)d_in[11];
  const float* bn_beta = (const float*)d_in[12];
  const float* W_kqv = (const float*)d_in[13];
  const float* b_kqv = (const float*)d_in[14];
  const float* A_k = (const float*)d_in[15];
  const float* A_v = (const float*)d_in[16];
  const float* p_rel = (const float*)d_in[17];
  const float* W_out = (const float*)d_in[18];
  const float* b_out = (const float*)d_in[19];
  const float* skip = (const float*)d_in[20];
  float* out = (float*)d_out;

  float* ws = (float*)d_ws;
  size_t off = 0;
  _Float16* y_h = (_Float16*)(ws + off);    off += (size_t)NT_TOTAL * 32;
  _Float16* kqvQ = (_Float16*)(ws + off);   off += (size_t)NQ * 96;    // [NQ][192]
  _Float16* kqvE = (_Float16*)(ws + off);   off += (size_t)NE * 160;   // [NE][320]
  _Float16* kqvA = (_Float16*)(ws + off);   off += (size_t)NA * 64;    // [NA][128]
  _Float16* agg_h = (_Float16*)(ws + off);  off += (size_t)NT_TOTAL * 32;
  float* stats = ws + off;                  off += 384;
  float* scale = ws + off;                  off += 192;
  float* shift = ws + off;                  off += 192;
  float* bias2 = ws + off;                  off += 576;
  float* bias_big = ws + off;               off += 640;
  _Float16* WqT = (_Float16*)(ws + off);    off += 192 * 72 / 2;
  _Float16* WeT = (_Float16*)(ws + off);    off += 320 * 72 / 2;
  _Float16* WaT = (_Float16*)(ws + off);    off += 128 * 72 / 2;
  _Float16* WinT = (_Float16*)(ws + off);   off += 3 * 64 * 136 / 2;
  _Float16* WoutT = (_Float16*)(ws + off);  off += 3 * 64 * 72 / 2;
  float* bstats = ws + off;                 off += (size_t)(GIN_Q + GIN_A + GIN_E) * 128;
  unsigned* row_start = (unsigned*)(ws + off); off += NT_TOTAL;
  unsigned* cursor = (unsigned*)(ws + off);    off += NT_TOTAL;
  unsigned* bsums = (unsigned*)(ws + off);     off += 1024;
  unsigned* eidx = (unsigned*)(ws + off);      off += E_TOTAL;

  const int Ns[3] = {NQ, NA, NE};
  const float* xs[3] = {xq, xa, xe};
  const int gin[3] = {GIN_Q, GIN_A, GIN_E};
  const int bb[3] = {0, GIN_Q, GIN_Q + GIN_A};
  _Float16* yhb[3] = {y_h, y_h + (size_t)NQ * 64, y_h + (size_t)(NQ + NA) * 64};
  _Float16* aggb[3] = {agg_h, agg_h + (size_t)NQ * 64, agg_h + (size_t)(NQ + NA) * 64};
  float* zq_out = out + (N_POS + N_NEG);
  float* zbase[3] = {zq_out, zq_out + (size_t)NQ * 64, zq_out + (size_t)(NQ + NA) * 64};

  fill_kernel<<<dim3(128), dim3(256), 0, stream>>>((float*)row_start, 0.f, NT_TOTAL);
  wprep_in<<<dim3(192), dim3(136), 0, stream>>>(W_in, WinT);
  wprep_out<<<dim3(192), dim3(72), 0, stream>>>(W_out, WoutT);

  // ---- in-proj (LDS-staged MFMA) + relu -> y fp16, fused bstats ----
  for (int t = 0; t < 3; ++t) {
    gemm_inproj<<<dim3(gin[t]), dim3(256), SMEM_INPROJ, stream>>>(
        xs[t], WinT + (size_t)t * 64 * 136, b_in + t * 64, Ns[t], CDIV(Ns[t], 128),
        yhb[t], bstats + (size_t)bb[t] * 128);
  }
  stats_reduce<<<dim3(384), dim3(256), 0, stream>>>(bstats, stats);
  bn_finalize<<<dim3(1), dim3(192), 0, stream>>>(stats, bn_gamma, bn_beta, scale, shift);
  kqv_bias2<<<dim3(3), dim3(192), 0, stream>>>(b_kqv, W_kqv, shift, bias2);
  wprep_kqv<<<dim3(640), dim3(64), 0, stream>>>(W_kqv, bias2, A_k, A_v, scale,
                                                WqT, WeT, WaT, bias_big);

  // ---- kqv projections (staged 8-wave; entity split into 2 col-tiles) ----
  gemm_mfma<256, 192, 64><<<dim3(CDIV(NQ, 256)), dim3(512), 0, stream>>>(
      yhb[0], WqT, bias_big, NQ, kqvQ, 192);
  gemm_mfma<256, 160, 64><<<dim3(CDIV(NE, 256), 2), dim3(512), 0, stream>>>(
      yhb[2], WeT, bias_big + 192, NE, kqvE, 320);
  gemm_mfma<256, 128, 64><<<dim3(CDIV(NA, 256)), dim3(512), 0, stream>>>(
      yhb[1], WaT, bias_big + 512, NA, kqvA, 128);

  // ---- CSR build ----
  struct Rel { const int* ei; int E; int dstbase; unsigned slot; };
  Rel rels[4] = {{e_e2q, E_E2Q, BASE_Q, 0u},
                 {e_e2e, E_E2E, BASE_E, 0u},
                 {e_e2a, E_E2A, BASE_A, 0u},
                 {e_q2a, E_Q2A, BASE_A, 1u}};
  for (int r = 0; r < 4; ++r) {
    int blocks = CDIV(rels[r].E, 256); if (blocks > 2048) blocks = 2048;
    hist_kernel<<<dim3(blocks), dim3(256), 0, stream>>>(rels[r].ei + rels[r].E, rels[r].E,
                                                        row_start, rels[r].dstbase);
  }
  scan1<<<dim3(NBLK_SCAN), dim3(256), 0, stream>>>(row_start, NT_TOTAL, bsums);
  scan2<<<dim3(1), dim3(256), 0, stream>>>(bsums, NBLK_SCAN);
  scan3<<<dim3(NBLK_SCAN), dim3(256), 0, stream>>>(row_start, bsums, cursor, NT_TOTAL);
  for (int r = 0; r < 4; ++r) {
    int blocks = CDIV(rels[r].E, 256); if (blocks > 2048) blocks = 2048;
    scatter_kernel<<<dim3(blocks), dim3(256), 0, stream>>>(
        rels[r].ei, rels[r].ei + rels[r].E, rels[r].E, cursor, eidx,
        rels[r].dstbase, rels[r].slot);
  }

  // ---- gathers ----
  gather_kernel<1><<<dim3(CDIV(NQ, 4)), dim3(256), 0, stream>>>(
      NQ, BASE_Q, row_start, cursor, eidx,
      kqvE, 320, 128, nullptr, 0, 0,
      kqvQ + 64, 192, nullptr, 0, p_rel + 0, p_rel + 0, agg_h);
  gather_kernel<1><<<dim3(4096), dim3(256), 0, stream>>>(
      NE, BASE_E, row_start, cursor, eidx,
      kqvE, 320, 192, nullptr, 0, 0,
      kqvE + 64, 320, nullptr, 0, p_rel + 2, p_rel + 2, agg_h);
  gather_kernel<2><<<dim3(CDIV(NA, 4)), dim3(256), 0, stream>>>(
      NA, BASE_A, row_start, cursor, eidx,
      kqvE, 320, 256, kqvQ, 192, 128,
      kqvA, 128, kqvA + 64, 128, p_rel + 4, p_rel + 6, agg_h);

  // ---- out projection (direct-A MFMA) + skip blend -> fp32 z ----
  for (int t = 0; t < 3; ++t) {
    gemm_direct<64, 64, 3><<<dim3(CDIV(Ns[t], 128)), dim3(256), 0, stream>>>(
        nullptr, aggb[t], WoutT + (size_t)t * 64 * 72, b_out + t * 64, Ns[t],
        nullptr, 0, zbase[t], nullptr,
        yhb[t], scale + t * 64, shift + t * 64, skip, t);
  }

  // ---- predictions ----
  pred_kernel<<<dim3(CDIV(N_POS, 256)), dim3(256), 0, stream>>>(
      pos_idx, pos_idx + N_POS, N_POS, zbase[0], zbase[1], out);
  pred_kernel<<<dim3(CDIV(N_NEG, 256)), dim3(256), 0, stream>>>(
      neg_idx, neg_idx + N_NEG, N_NEG, zbase[0], zbase[1], out + N_POS);
}

// Round 13
// 789.022 us; speedup vs baseline: 2.4513x; 1.0475x over previous
//
#include <hip/hip_runtime.h>
#include <hip/hip_bf16.h>
#include <hip/hip_fp16.h>
#include <math.h>

#define NQ 8192
#define NA 32768
#define NE 500000
#define F_IN 128
#define E_E2Q 131072
#define E_E2E 800000
#define E_E2A 262144
#define E_Q2A 32768
#define N_POS 8192
#define N_NEG 24576

#define NT_TOTAL (NQ + NA + NE)                      // 540960
#define E_TOTAL (E_E2Q + E_E2E + E_E2A + E_Q2A)      // 1225984
#define NBLK_SCAN ((NT_TOTAL + 1023) / 1024)         // 529
#define CDIV(a, b) (((a) + (b) - 1) / (b))

// dst node index space: [question: 0) [answer: NQ) [entity: NQ+NA)
#define BASE_Q 0
#define BASE_A NQ
#define BASE_E (NQ + NA)

// in-proj grids (64-row tiles; 1 block per bstats row)
#define GIN_Q 128    // = tiles(8192/64)
#define GIN_A 512    // = tiles(32768/64)
#define GIN_E 768    // < tiles(7813), grid-stride; 3 blocks/CU
#define SMEM_INPROJ (32768 + 17408 + 512)

typedef _Float16 half8_t __attribute__((ext_vector_type(8)));
typedef _Float16 half4_t __attribute__((ext_vector_type(4)));
typedef float f32x4_t __attribute__((ext_vector_type(4)));

__device__ inline void load_lds16(const void* g, void* l) {
  __builtin_amdgcn_global_load_lds((const __attribute__((address_space(1))) void*)g,
                                   (__attribute__((address_space(3))) void*)l, 16, 0, 0);
}

__device__ inline float fast_gelu(float v) {
  // tanh-approx GELU: v * sigmoid(1.5957691*(v + 0.044715 v^3)); |err| < ~1e-3
  float u = 1.5957691216057308f * fmaf(0.044715f * v * v, v, v);
  return v / (1.f + __expf(-u));
}

// ---------------- utility ----------------

__global__ void fill_kernel(float* __restrict__ p, float v, size_t n) {
  size_t i = (size_t)blockIdx.x * blockDim.x + threadIdx.x;
  size_t stride = (size_t)gridDim.x * blockDim.x;
  for (; i < n; i += stride) p[i] = v;
}

// ---------------- in-proj: LDS-staged fp32 A (global_load_lds), MFMA, fused bstats ----------------
// 64-row tiles (32KB As) -> 50.7KB LDS -> 3 blocks/CU for cross-block stage/compute overlap.
// Each of 4 waves computes one 16-row strip.

__global__ __launch_bounds__(256) void gemm_inproj(
    const float* __restrict__ Af, const _Float16* __restrict__ WT,
    const float* __restrict__ bias, int M, int ntiles,
    _Float16* __restrict__ oh, float* __restrict__ bstats)
{
  extern __shared__ char smem[];
  float* As32 = (float*)smem;                       // 64 x 128 fp32 = 32KB
  _Float16* Bs = (_Float16*)(smem + 32768);         // 64 x 136 fp16 = 17408B
  float* s1 = (float*)(smem + 32768 + 17408);       // 64
  float* s2 = s1 + 64;                              // 64

  int tid = threadIdx.x;
  int w = tid >> 6, l = tid & 63;
  int lr = l & 15, lg = l >> 4;

  // stage weights once
  for (int idx = tid; idx < 64 * 136 / 8; idx += 256)
    *(half8_t*)&Bs[idx * 8] = *(const half8_t*)&WT[(size_t)idx * 8];
  if (tid < 64) { s1[tid] = 0.f; s2[tid] = 0.f; }

  float ps1[4] = {}, ps2[4] = {};
  float bval[4];
#pragma unroll
  for (int ct = 0; ct < 4; ++ct) bval[ct] = bias[ct * 16 + lr];

  for (int tile = blockIdx.x; tile < ntiles; tile += gridDim.x) {
    // ---- stage A tile: 8 rounds x (4 waves x 1KB) = 32KB ----
    const char* srcbase = (const char*)Af + (size_t)tile * 64 * 512;
    int rowlim = M - tile * 64;
#pragma unroll
    for (int r = 0; r < 8; ++r) {
      int unit = r * 4 + w;                         // wave-uniform 0..31
      char* ldst = (char*)As32 + unit * 1024;
      int p = unit * 1024 + l * 16;
      int row = p >> 9;
      const char* src = (row < rowlim) ? srcbase + (size_t)row * 512 + (p & 511)
                                       : srcbase;   // clamped, in-bounds
      load_lds16(src, ldst);
    }
    __syncthreads();  // drains vmcnt -> staged tile visible

    // ---- MFMA: wave w handles rows [w*16, w*16+16) ----
    f32x4_t acc[4] = {};
#pragma unroll
    for (int ks = 0; ks < 4; ++ks) {
      const float4* pa = (const float4*)((const char*)As32 +
                          (w * 16 + lr) * 512 + ks * 128 + lg * 32);
      float4 x0 = pa[0], x1 = pa[1];
      half8_t a0 = {(_Float16)x0.x, (_Float16)x0.y, (_Float16)x0.z, (_Float16)x0.w,
                    (_Float16)x1.x, (_Float16)x1.y, (_Float16)x1.z, (_Float16)x1.w};
#pragma unroll
      for (int ct = 0; ct < 4; ++ct) {
        half8_t b = *(const half8_t*)&Bs[(ct * 16 + lr) * 136 + ks * 32 + lg * 8];
        acc[ct] = __builtin_amdgcn_mfma_f32_16x16x32_f16(a0, b, acc[ct], 0, 0, 0);
      }
    }

    // ---- epilogue: relu -> fp16 store + reg bstats ----
    int rbase = tile * 64 + w * 16 + lg * 4;
#pragma unroll
    for (int ct = 0; ct < 4; ++ct) {
      int col = ct * 16 + lr;
#pragma unroll
      for (int j = 0; j < 4; ++j) {
        int row = rbase + j;
        if (row >= M) continue;
        float val = fmaxf(acc[ct][j] + bval[ct], 0.f);
        oh[(size_t)row * 64 + col] = (_Float16)val;
        ps1[ct] += val;
        ps2[ct] += val * val;
      }
    }
    __syncthreads();  // all waves done reading As32 before next stage
  }

  // ---- block bstats reduce ----
#pragma unroll
  for (int ct = 0; ct < 4; ++ct) {
    atomicAdd(&s1[ct * 16 + lr], ps1[ct]);
    atomicAdd(&s2[ct * 16 + lr], ps2[ct]);
  }
  __syncthreads();
  if (tid < 64) {
    bstats[(size_t)blockIdx.x * 128 + tid] = s1[tid];
    bstats[(size_t)blockIdx.x * 128 + 64 + tid] = s2[tid];
  }
}

// ---------------- direct-A MFMA GEMM (out-proj, MODE 3) ----------------

template <int BNT, int KTOT, int MODE>
__global__ __launch_bounds__(256) void gemm_direct(
    const float* __restrict__ Af, const _Float16* __restrict__ Ah,
    const _Float16* __restrict__ WT, const float* __restrict__ bias, int M,
    _Float16* __restrict__ oh, int LDO,
    float* __restrict__ Cf,
    float* __restrict__ bstats,
    const _Float16* __restrict__ resh, const float* __restrict__ rsc,
    const float* __restrict__ rsh, const float* __restrict__ skip_ptr, int skip_idx)
{
  constexpr int KP = KTOT + 8;
  __shared__ _Float16 Bs[BNT * KP];
  int tid = threadIdx.x;
  int row0 = blockIdx.x * 128;

  for (int idx = tid; idx < BNT * KP / 8; idx += 256)
    *(half8_t*)&Bs[idx * 8] = *(const half8_t*)&WT[(size_t)idx * 8];

  int w = tid >> 6, l = tid & 63;
  int lr = l & 15, lg = l >> 4;
  constexpr int NKS = KTOT / 32;
  half8_t afrag[2][NKS];
#pragma unroll
  for (int rt = 0; rt < 2; ++rt) {
    int gr = row0 + w * 32 + rt * 16 + lr;
    bool ok = gr < M;
#pragma unroll
    for (int ks = 0; ks < NKS; ++ks) {
      half8_t h8 = {};
      if (ok) h8 = *(const half8_t*)&Ah[(size_t)gr * KTOT + ks * 32 + lg * 8];
      afrag[rt][ks] = h8;
    }
  }
  __syncthreads();

  constexpr int NCT = BNT / 16;
  f32x4_t acc[2][NCT] = {};
#pragma unroll
  for (int ks = 0; ks < NKS; ++ks) {
#pragma unroll
    for (int ct = 0; ct < NCT; ++ct) {
      half8_t b = *(const half8_t*)&Bs[(ct * 16 + lr) * KP + ks * 32 + lg * 8];
      acc[0][ct] = __builtin_amdgcn_mfma_f32_16x16x32_f16(afrag[0][ks], b, acc[0][ct], 0, 0, 0);
      acc[1][ct] = __builtin_amdgcn_mfma_f32_16x16x32_f16(afrag[1][ks], b, acc[1][ct], 0, 0, 0);
    }
  }

  float g = 1.f / (1.f + __expf(-skip_ptr[skip_idx]));
  float gb = 1.f - g;
#pragma unroll
  for (int rt = 0; rt < 2; ++rt) {
    int rbase = row0 + w * 32 + rt * 16 + lg * 4;
#pragma unroll
    for (int ct = 0; ct < NCT; ++ct) {
      int col = ct * 16 + lr;
      float bval = bias[col];
#pragma unroll
      for (int j = 0; j < 4; ++j) {
        int row = rbase + j;
        if (row >= M) continue;
        float val = acc[rt][ct][j] + bval;
        float rv = (float)resh[(size_t)row * 64 + col];
        Cf[(size_t)row * 64 + col] = g * val + gb * (rsc[col] * rv + rsh[col]);
      }
    }
  }
}

// ---------------- staged MFMA GEMM (kqv, 8 waves, col-tiled) ----------------

template <int BM, int BNT, int KTOT>
__global__ __launch_bounds__(BM * 2) void gemm_mfma(
    const _Float16* __restrict__ Ah,
    const _Float16* __restrict__ WT, const float* __restrict__ bias, int M,
    _Float16* __restrict__ oh, int LDO)
{
  constexpr int KP = KTOT + 8;
  constexpr int NTHR = BM * 2;
  __shared__ _Float16 As[BM * KP];
  __shared__ _Float16 Bs[BNT * KP];
  int tid = threadIdx.x;
  int row0 = blockIdx.x * BM;
  int colbase = blockIdx.y * BNT;

  {
    constexpr int CH = KTOT / 8;
    for (int idx = tid; idx < BM * CH; idx += NTHR) {
      int row = idx / CH, c = idx % CH;
      int gr = row0 + row;
      half8_t a8 = {};
      if (gr < M) a8 = *(const half8_t*)&Ah[(size_t)gr * KTOT + c * 8];
      *(half8_t*)&As[row * KP + c * 8] = a8;
    }
  }
  {
    const _Float16* wsrc = WT + (size_t)colbase * KP;
    for (int idx = tid; idx < BNT * KP / 8; idx += NTHR)
      *(half8_t*)&Bs[idx * 8] = *(const half8_t*)&wsrc[(size_t)idx * 8];
  }
  __syncthreads();

  int w = tid >> 6, l = tid & 63;
  int lr = l & 15, lg = l >> 4;
  constexpr int NCT = BNT / 16;
  constexpr int NKS = KTOT / 32;
  f32x4_t acc[2][NCT] = {};
#pragma unroll
  for (int ks = 0; ks < NKS; ++ks) {
    half8_t a0 = *(const half8_t*)&As[(w * 32 + lr) * KP + ks * 32 + lg * 8];
    half8_t a1 = *(const half8_t*)&As[(w * 32 + 16 + lr) * KP + ks * 32 + lg * 8];
#pragma unroll
    for (int ct = 0; ct < NCT; ++ct) {
      half8_t b = *(const half8_t*)&Bs[(ct * 16 + lr) * KP + ks * 32 + lg * 8];
      acc[0][ct] = __builtin_amdgcn_mfma_f32_16x16x32_f16(a0, b, acc[0][ct], 0, 0, 0);
      acc[1][ct] = __builtin_amdgcn_mfma_f32_16x16x32_f16(a1, b, acc[1][ct], 0, 0, 0);
    }
  }
#pragma unroll
  for (int rt = 0; rt < 2; ++rt) {
    int rbase = row0 + w * 32 + rt * 16 + lg * 4;
#pragma unroll
    for (int ct = 0; ct < NCT; ++ct) {
      int col = colbase + ct * 16 + lr;
      float bval = bias[col];
#pragma unroll
      for (int j = 0; j < 4; ++j) {
        int row = rbase + j;
        if (row >= M) continue;
        oh[(size_t)row * LDO + col] = (_Float16)(acc[rt][ct][j] + bval);
      }
    }
  }
}

// ---------------- BN: reduce per-block stats ----------------

__global__ __launch_bounds__(256) void stats_reduce(const float* __restrict__ bstats,
                                                    float* __restrict__ stats) {
  __shared__ float sh[256];
  int t = blockIdx.x >> 7;
  int c = blockIdx.x & 127;
  int nb = (t == 0) ? GIN_Q : (t == 1) ? GIN_A : GIN_E;
  int base = (t == 0) ? 0 : (t == 1) ? GIN_Q : (GIN_Q + GIN_A);
  float s = 0.f;
  for (int i = threadIdx.x; i < nb; i += 256)
    s += bstats[(size_t)(base + i) * 128 + c];
  sh[threadIdx.x] = s;
  __syncthreads();
  for (int off2 = 128; off2 > 0; off2 >>= 1) {
    if (threadIdx.x < off2) sh[threadIdx.x] += sh[threadIdx.x + off2];
    __syncthreads();
  }
  if (threadIdx.x == 0) stats[t * 128 + c] = sh[0];
}

__global__ void bn_finalize(const float* __restrict__ stats,
                            const float* __restrict__ gamma, const float* __restrict__ beta,
                            float* __restrict__ scale, float* __restrict__ shift) {
  int t = threadIdx.x;
  if (t >= 192) return;
  int ty = t >> 6, c = t & 63;
  float invN = (ty == 0) ? (1.f / NQ) : (ty == 1) ? (1.f / NA) : (1.f / NE);
  float mu = stats[ty * 128 + c] * invN;
  float var = stats[ty * 128 + 64 + c] * invN - mu * mu;
  float rs = rsqrtf(var + 1e-5f);
  float gm = gamma[ty * 64 + c];
  scale[t] = gm * rs;
  shift[t] = beta[ty * 64 + c] - gm * mu * rs;
}

__global__ void kqv_bias2(const float* __restrict__ b_kqv, const float* __restrict__ W_kqv,
                          const float* __restrict__ shift, float* __restrict__ bias2) {
  int t = blockIdx.x, n = threadIdx.x;
  float s = b_kqv[t * 192 + n];
  for (int k = 0; k < 64; ++k)
    s += shift[t * 64 + k] * W_kqv[(size_t)t * 64 * 192 + k * 192 + n];
  bias2[t * 192 + n] = s;
}

// ---------------- weight prep ----------------
// WqT[192][72]: question = [k | qt(rel0,A_k) | v'(rel3,A_v)]
// WeT[320][72]: entity   = [k | qt(rel1,A_k) | v'(rel0) | v'(rel1) | v'(rel2)]
// WaT[128][72]: answer   = [qt(rel2) | qt(rel3)]
// bias_big[640] = [q:192 | e:320 | a:128].  BN scale folded on input dim.

__global__ void wprep_kqv(const float* __restrict__ W_kqv, const float* __restrict__ bias2,
                          const float* __restrict__ A_k, const float* __restrict__ A_v,
                          const float* __restrict__ scale,
                          _Float16* __restrict__ WqT, _Float16* __restrict__ WeT,
                          _Float16* __restrict__ WaT, float* __restrict__ bias_big) {
  int j = blockIdx.x;   // 0..639
  int c = threadIdx.x;  // 0..63
  int t, jj, bofs;
  _Float16* W;
  if (j < 192)      { t = 0; jj = j;       W = WqT; bofs = 0; }
  else if (j < 512) { t = 2; jj = j - 192; W = WeT; bofs = 192; }
  else              { t = 1; jj = j - 512; W = WaT; bofs = 512; }
  const float* Wt = W_kqv + (size_t)t * 64 * 192;
  const float* b2 = bias2 + t * 192;
  int mode = 0, rel = 0, sub = 0;
  if (t == 1) { mode = 1; rel = (jj < 64) ? 2 : 3; sub = jj & 63; }
  else if (jj >= 64 && jj < 128) { mode = 1; rel = (t == 0) ? 0 : 1; sub = jj - 64; }
  else if (jj >= 128) {
    mode = 2; sub = (jj - 128) & 63;
    rel = (t == 0) ? 3 : ((jj - 128) >> 6);
  }
  int h = sub >> 5, x = sub & 31;
  float wv, bv;
  if (mode == 0) {
    wv = Wt[(size_t)c * 192 + jj];
    bv = b2[jj];
  } else if (mode == 1) {
    const float* Ar = A_k + ((size_t)rel * 2048 + h * 1024 + x * 32);
    float s = 0.f, sb = 0.f;
    for (int f = 0; f < 32; ++f) {
      float a = Ar[f];
      s = fmaf(a, Wt[(size_t)c * 192 + 64 + h * 32 + f], s);
      sb = fmaf(a, b2[64 + h * 32 + f], sb);
    }
    wv = s; bv = sb;
  } else {
    const float* Ar = A_v + ((size_t)rel * 2048 + h * 1024 + x);
    float s = 0.f, sb = 0.f;
    for (int d = 0; d < 32; ++d) {
      float a = Ar[d * 32];
      s = fmaf(a, Wt[(size_t)c * 192 + 128 + h * 32 + d], s);
      sb = fmaf(a, b2[128 + h * 32 + d], sb);
    }
    wv = s; bv = sb;
  }
  wv *= scale[t * 64 + c];
  W[(size_t)jj * 72 + c] = (_Float16)wv;
  if (c < 8) W[(size_t)jj * 72 + 64 + c] = (_Float16)0.f;
  if (c == 0) bias_big[bofs + jj] = bv;
}

__global__ void wprep_in(const float* __restrict__ W_in, _Float16* __restrict__ WinT) {
  int t = blockIdx.x >> 6, n = blockIdx.x & 63, k = threadIdx.x;  // k 0..135
  float v = (k < 128) ? W_in[(size_t)t * 128 * 64 + (size_t)k * 64 + n] : 0.f;
  WinT[((size_t)t * 64 + n) * 136 + k] = (_Float16)v;
}

__global__ void wprep_out(const float* __restrict__ W_out, _Float16* __restrict__ WoutT) {
  int t = blockIdx.x >> 6, n = blockIdx.x & 63, k = threadIdx.x;  // k 0..71
  float v = (k < 64) ? W_out[(size_t)t * 64 * 64 + (size_t)k * 64 + n] : 0.f;
  WoutT[((size_t)t * 64 + n) * 72 + k] = (_Float16)v;
}

// ---------------- CSR build ----------------

__global__ void hist_kernel(const int* __restrict__ dst, int E,
                            unsigned* __restrict__ cnt, int base) {
  int i = blockIdx.x * blockDim.x + threadIdx.x;
  int stride = gridDim.x * blockDim.x;
  for (; i < E; i += stride) atomicAdd(&cnt[base + dst[i]], 1u);
}

__global__ __launch_bounds__(256) void scan1(unsigned* __restrict__ arr, int n,
                                             unsigned* __restrict__ bsums) {
  __shared__ unsigned sh[256];
  int t = threadIdx.x;
  int base = blockIdx.x * 1024 + t * 4;
  unsigned v[4];
  unsigned s = 0;
#pragma unroll
  for (int j = 0; j < 4; ++j) {
    v[j] = (base + j < n) ? arr[base + j] : 0u;
    s += v[j];
  }
  sh[t] = s;
  __syncthreads();
  for (int off = 1; off < 256; off <<= 1) {
    unsigned x = (t >= off) ? sh[t - off] : 0u;
    __syncthreads();
    sh[t] += x;
    __syncthreads();
  }
  unsigned run = sh[t] - s;
#pragma unroll
  for (int j = 0; j < 4; ++j) {
    if (base + j < n) arr[base + j] = run;
    run += v[j];
  }
  if (t == 255) bsums[blockIdx.x] = sh[255];
}

__global__ __launch_bounds__(256) void scan2(unsigned* __restrict__ bsums, int nb) {
  __shared__ unsigned sh[256];
  __shared__ unsigned carry;
  int t = threadIdx.x;
  if (t == 0) carry = 0;
  __syncthreads();
  for (int chunk = 0; chunk < nb; chunk += 256) {
    int i = chunk + t;
    unsigned v = (i < nb) ? bsums[i] : 0u;
    sh[t] = v;
    __syncthreads();
    for (int off = 1; off < 256; off <<= 1) {
      unsigned x = (t >= off) ? sh[t - off] : 0u;
      __syncthreads();
      sh[t] += x;
      __syncthreads();
    }
    unsigned inc = sh[t];
    unsigned c = carry;
    __syncthreads();
    if (i < nb) bsums[i] = c + inc - v;
    if (t == 255) carry = c + sh[255];
    __syncthreads();
  }
}

__global__ __launch_bounds__(256) void scan3(unsigned* __restrict__ arr,
                                             const unsigned* __restrict__ bsums,
                                             unsigned* __restrict__ cursor, int n) {
  int t = threadIdx.x;
  int base = blockIdx.x * 1024 + t * 4;
  unsigned add = bsums[blockIdx.x];
#pragma unroll
  for (int j = 0; j < 4; ++j) {
    int idx = base + j;
    if (idx < n) {
      unsigned r = arr[idx] + add;
      arr[idx] = r;
      cursor[idx] = r;
    }
  }
}

// payload = LOCAL src index | slot<<20
__global__ void scatter_kernel(const int* __restrict__ src, const int* __restrict__ dst, int E,
                               unsigned* __restrict__ cursor, unsigned* __restrict__ eidx,
                               int dstbase, unsigned slot) {
  int i = blockIdx.x * blockDim.x + threadIdx.x;
  int stride = gridDim.x * blockDim.x;
  for (; i < E; i += stride) {
    unsigned pos = atomicAdd(&cursor[dstbase + dst[i]], 1u);
    eidx[pos] = (unsigned)src[i] | (slot << 20);
  }
}

// ---------------- gather: softmax-weighted aggregation per dst node ----------------

template <int NREL>
__global__ __launch_bounds__(256) void gather_kernel(
    int N, int nodebase,
    const unsigned* __restrict__ row_start, const unsigned* __restrict__ row_end,
    const unsigned* __restrict__ eidx,
    const _Float16* __restrict__ baseA, int ldA, int vofA,
    const _Float16* __restrict__ baseB, int ldB, int vofB,
    const _Float16* __restrict__ qtA, int ldqA,
    const _Float16* __restrict__ qtB, int ldqB,
    const float* __restrict__ prelA, const float* __restrict__ prelB,
    _Float16* __restrict__ agg)
{
  int lane = threadIdx.x & 63;
  int h = lane >> 5;
  const float isd = 0.17677669529663687f;
  float pr0 = prelA[h] * isd;
  float pr1 = (NREL == 2) ? prelB[h] * isd : 0.f;

  int wid = (int)((blockIdx.x * blockDim.x + threadIdx.x) >> 6);
  int nw = (int)((gridDim.x * blockDim.x) >> 6);

  int n = wid;
  unsigned pi0 = 0, pi1 = 0;
  float pqt0 = 0.f, pqt1 = 0.f;
  if (n < N) {
    pi0 = row_start[nodebase + n];
    pi1 = row_end[nodebase + n];
    pqt0 = (float)qtA[(size_t)n * ldqA + lane];
    if (NREL == 2) pqt1 = (float)qtB[(size_t)n * ldqB + lane];
  }
  while (n < N) {
    unsigned ci0 = pi0, ci1 = pi1;
    float cqt0 = pqt0, cqt1 = pqt1;
    int nn = n + nw;
    if (nn < N) {
      pi0 = row_start[nodebase + nn];
      pi1 = row_end[nodebase + nn];
      pqt0 = (float)qtA[(size_t)nn * ldqA + lane];
      if (NREL == 2) pqt1 = (float)qtB[(size_t)nn * ldqB + lane];
    }
    float vs = 0.f, ss = 0.f;
    unsigned i = ci0;
    for (; i + 2 <= ci1; i += 2) {
      unsigned p1 = eidx[i], p2 = eidx[i + 1];
      unsigned s1i = p1 & 0xFFFFFu, s2i = p2 & 0xFFFFFu;
      bool r1 = (NREL == 2) && (p1 >> 20);
      bool r2 = (NREL == 2) && (p2 >> 20);
      const _Float16* b1 = r1 ? baseB + (size_t)s1i * ldB : baseA + (size_t)s1i * ldA;
      const _Float16* b2 = r2 ? baseB + (size_t)s2i * ldB : baseA + (size_t)s2i * ldA;
      float k1 = (float)b1[lane];
      float v1 = (float)b1[(r1 ? vofB : vofA) + lane];
      float k2 = (float)b2[lane];
      float v2 = (float)b2[(r2 ? vofB : vofA) + lane];
      float sa = k1 * (r1 ? cqt1 : cqt0);
      float sb = k2 * (r2 ? cqt1 : cqt0);
#pragma unroll
      for (int off = 16; off > 0; off >>= 1) {
        sa += __shfl_xor(sa, off, 32);
        sb += __shfl_xor(sb, off, 32);
      }
      float w1 = __expf(sa * (r1 ? pr1 : pr0));
      float w2 = __expf(sb * (r2 ? pr1 : pr0));
      ss += w1 + w2;
      vs = fmaf(w1, v1, vs);
      vs = fmaf(w2, v2, vs);
    }
    if (i < ci1) {
      unsigned p1 = eidx[i];
      unsigned s1i = p1 & 0xFFFFFu;
      bool r1 = (NREL == 2) && (p1 >> 20);
      const _Float16* b1 = r1 ? baseB + (size_t)s1i * ldB : baseA + (size_t)s1i * ldA;
      float k1 = (float)b1[lane];
      float v1 = (float)b1[(r1 ? vofB : vofA) + lane];
      float sa = k1 * (r1 ? cqt1 : cqt0);
#pragma unroll
      for (int off = 16; off > 0; off >>= 1) sa += __shfl_xor(sa, off, 32);
      float w1 = __expf(sa * (r1 ? pr1 : pr0));
      ss += w1;
      vs = fmaf(w1, v1, vs);
    }
    float val = (ss > 0.f) ? vs / ss : 0.f;
    val = fast_gelu(val);
    agg[((size_t)(nodebase + n)) * 64 + lane] = (_Float16)val;
    n = nn;
  }
}

// ---------------- final predictions ----------------

__global__ void pred_kernel(const int* __restrict__ qi, const int* __restrict__ ai, int Np,
                            const float* __restrict__ zq, const float* __restrict__ za,
                            float* __restrict__ outp) {
  int i = blockIdx.x * blockDim.x + threadIdx.x;
  if (i >= Np) return;
  const float4* a = (const float4*)(zq + (size_t)qi[i] * 64);
  const float4* b = (const float4*)(za + (size_t)ai[i] * 64);
  float ssum = 0.f;
#pragma unroll
  for (int j = 0; j < 16; ++j) {
    float4 x = a[j], y = b[j];
    ssum += x.x * y.x + x.y * y.y + x.z * y.z + x.w * y.w;
  }
  outp[i] = ssum;
}

// ---------------- host launch ----------------

extern "C" void kernel_launch(void* const* d_in, const int* in_sizes, int n_in,
                              void* d_out, int out_size, void* d_ws, size_t ws_size,
                              hipStream_t stream) {
  const float* xq = (const float*)d_in[0];
  const float* xa = (const float*)d_in[1];
  const float* xe = (const float*)d_in[2];
  const int* e_e2q = (const int*)d_in[3];
  const int* e_e2e = (const int*)d_in[4];
  const int* e_e2a = (const int*)d_in[5];
  const int* e_q2a = (const int*)d_in[6];
  const int* pos_idx = (const int*)d_in[7];
  const int* neg_idx = (const int*)d_in[8];
  const float* W_in = (const float*)d_in[9];
  const float* b_in = (const float*)d_in[10];
  const float* bn_gamma = (const float*)d_in[11];
  const float* bn_beta = (const float*)d_in[12];
  const float* W_kqv = (const float*)d_in[13];
  const float* b_kqv = (const float*)d_in[14];
  const float* A_k = (const float*)d_in[15];
  const float* A_v = (const float*)d_in[16];
  const float* p_rel = (const float*)d_in[17];
  const float* W_out = (const float*)d_in[18];
  const float* b_out = (const float*)d_in[19];
  const float* skip = (const float*)d_in[20];
  float* out = (float*)d_out;

  float* ws = (float*)d_ws;
  size_t off = 0;
  _Float16* y_h = (_Float16*)(ws + off);    off += (size_t)NT_TOTAL * 32;
  _Float16* kqvQ = (_Float16*)(ws + off);   off += (size_t)NQ * 96;    // [NQ][192]
  _Float16* kqvE = (_Float16*)(ws + off);   off += (size_t)NE * 160;   // [NE][320]
  _Float16* kqvA = (_Float16*)(ws + off);   off += (size_t)NA * 64;    // [NA][128]
  _Float16* agg_h = (_Float16*)(ws + off);  off += (size_t)NT_TOTAL * 32;
  float* stats = ws + off;                  off += 384;
  float* scale = ws + off;                  off += 192;
  float* shift = ws + off;                  off += 192;
  float* bias2 = ws + off;                  off += 576;
  float* bias_big = ws + off;               off += 640;
  _Float16* WqT = (_Float16*)(ws + off);    off += 192 * 72 / 2;
  _Float16* WeT = (_Float16*)(ws + off);    off += 320 * 72 / 2;
  _Float16* WaT = (_Float16*)(ws + off);    off += 128 * 72 / 2;
  _Float16* WinT = (_Float16*)(ws + off);   off += 3 * 64 * 136 / 2;
  _Float16* WoutT = (_Float16*)(ws + off);  off += 3 * 64 * 72 / 2;
  float* bstats = ws + off;                 off += (size_t)(GIN_Q + GIN_A + GIN_E) * 128;
  unsigned* row_start = (unsigned*)(ws + off); off += NT_TOTAL;
  unsigned* cursor = (unsigned*)(ws + off);    off += NT_TOTAL;
  unsigned* bsums = (unsigned*)(ws + off);     off += 1024;
  unsigned* eidx = (unsigned*)(ws + off);      off += E_TOTAL;

  const int Ns[3] = {NQ, NA, NE};
  const float* xs[3] = {xq, xa, xe};
  const int gin[3] = {GIN_Q, GIN_A, GIN_E};
  const int bb[3] = {0, GIN_Q, GIN_Q + GIN_A};
  _Float16* yhb[3] = {y_h, y_h + (size_t)NQ * 64, y_h + (size_t)(NQ + NA) * 64};
  _Float16* aggb[3] = {agg_h, agg_h + (size_t)NQ * 64, agg_h + (size_t)(NQ + NA) * 64};
  float* zq_out = out + (N_POS + N_NEG);
  float* zbase[3] = {zq_out, zq_out + (size_t)NQ * 64, zq_out + (size_t)(NQ + NA) * 64};

  fill_kernel<<<dim3(128), dim3(256), 0, stream>>>((float*)row_start, 0.f, NT_TOTAL);
  wprep_in<<<dim3(192), dim3(136), 0, stream>>>(W_in, WinT);
  wprep_out<<<dim3(192), dim3(72), 0, stream>>>(W_out, WoutT);

  // ---- in-proj (LDS-staged MFMA, 3 blocks/CU) + relu -> y fp16, fused bstats ----
  for (int t = 0; t < 3; ++t) {
    gemm_inproj<<<dim3(gin[t]), dim3(256), SMEM_INPROJ, stream>>>(
        xs[t], WinT + (size_t)t * 64 * 136, b_in + t * 64, Ns[t], CDIV(Ns[t], 64),
        yhb[t], bstats + (size_t)bb[t] * 128);
  }
  stats_reduce<<<dim3(384), dim3(256), 0, stream>>>(bstats, stats);
  bn_finalize<<<dim3(1), dim3(192), 0, stream>>>(stats, bn_gamma, bn_beta, scale, shift);
  kqv_bias2<<<dim3(3), dim3(192), 0, stream>>>(b_kqv, W_kqv, shift, bias2);
  wprep_kqv<<<dim3(640), dim3(64), 0, stream>>>(W_kqv, bias2, A_k, A_v, scale,
                                                WqT, WeT, WaT, bias_big);

  // ---- kqv projections (staged 8-wave; entity split into 2 col-tiles) ----
  gemm_mfma<256, 192, 64><<<dim3(CDIV(NQ, 256)), dim3(512), 0, stream>>>(
      yhb[0], WqT, bias_big, NQ, kqvQ, 192);
  gemm_mfma<256, 160, 64><<<dim3(CDIV(NE, 256), 2), dim3(512), 0, stream>>>(
      yhb[2], WeT, bias_big + 192, NE, kqvE, 320);
  gemm_mfma<256, 128, 64><<<dim3(CDIV(NA, 256)), dim3(512), 0, stream>>>(
      yhb[1], WaT, bias_big + 512, NA, kqvA, 128);

  // ---- CSR build ----
  struct Rel { const int* ei; int E; int dstbase; unsigned slot; };
  Rel rels[4] = {{e_e2q, E_E2Q, BASE_Q, 0u},
                 {e_e2e, E_E2E, BASE_E, 0u},
                 {e_e2a, E_E2A, BASE_A, 0u},
                 {e_q2a, E_Q2A, BASE_A, 1u}};
  for (int r = 0; r < 4; ++r) {
    int blocks = CDIV(rels[r].E, 256); if (blocks > 2048) blocks = 2048;
    hist_kernel<<<dim3(blocks), dim3(256), 0, stream>>>(rels[r].ei + rels[r].E, rels[r].E,
                                                        row_start, rels[r].dstbase);
  }
  scan1<<<dim3(NBLK_SCAN), dim3(256), 0, stream>>>(row_start, NT_TOTAL, bsums);
  scan2<<<dim3(1), dim3(256), 0, stream>>>(bsums, NBLK_SCAN);
  scan3<<<dim3(NBLK_SCAN), dim3(256), 0, stream>>>(row_start, bsums, cursor, NT_TOTAL);
  for (int r = 0; r < 4; ++r) {
    int blocks = CDIV(rels[r].E, 256); if (blocks > 2048) blocks = 2048;
    scatter_kernel<<<dim3(blocks), dim3(256), 0, stream>>>(
        rels[r].ei, rels[r].ei + rels[r].E, rels[r].E, cursor, eidx,
        rels[r].dstbase, rels[r].slot);
  }

  // ---- gathers ----
  gather_kernel<1><<<dim3(CDIV(NQ, 4)), dim3(256), 0, stream>>>(
      NQ, BASE_Q, row_start, cursor, eidx,
      kqvE, 320, 128, nullptr, 0, 0,
      kqvQ + 64, 192, nullptr, 0, p_rel + 0, p_rel + 0, agg_h);
  gather_kernel<1><<<dim3(4096), dim3(256), 0, stream>>>(
      NE, BASE_E, row_start, cursor, eidx,
      kqvE, 320, 192, nullptr, 0, 0,
      kqvE + 64, 320, nullptr, 0, p_rel + 2, p_rel + 2, agg_h);
  gather_kernel<2><<<dim3(CDIV(NA, 4)), dim3(256), 0, stream>>>(
      NA, BASE_A, row_start, cursor, eidx,
      kqvE, 320, 256, kqvQ, 192, 128,
      kqvA, 128, kqvA + 64, 128, p_rel + 4, p_rel + 6, agg_h);

  // ---- out projection (direct-A MFMA) + skip blend -> fp32 z ----
  for (int t = 0; t < 3; ++t) {
    gemm_direct<64, 64, 3><<<dim3(CDIV(Ns[t], 128)), dim3(256), 0, stream>>>(
        nullptr, aggb[t], WoutT + (size_t)t * 64 * 72, b_out + t * 64, Ns[t],
        nullptr, 0, zbase[t], nullptr,
        yhb[t], scale + t * 64, shift + t * 64, skip, t);
  }

  // ---- predictions ----
  pred_kernel<<<dim3(CDIV(N_POS, 256)), dim3(256), 0, stream>>>(
      pos_idx, pos_idx + N_POS, N_POS, zbase[0], zbase[1], out);
  pred_kernel<<<dim3(CDIV(N_NEG, 256)), dim3(256), 0, stream>>>(
      neg_idx, neg_idx + N_NEG, N_NEG, zbase[0], zbase[1], out + N_POS);
}

// Round 14
// 773.937 us; speedup vs baseline: 2.4991x; 1.0195x over previous
//
#include <hip/hip_runtime.h>
#include <hip/hip_bf16.h>
#include <hip/hip_fp16.h>
#include <math.h>

#define NQ 8192
#define NA 32768
#define NE 500000
#define F_IN 128
#define E_E2Q 131072
#define E_E2E 800000
#define E_E2A 262144
#define E_Q2A 32768
#define N_POS 8192
#define N_NEG 24576

#define NT_TOTAL (NQ + NA + NE)                      // 540960
#define E_TOTAL (E_E2Q + E_E2E + E_E2A + E_Q2A)      // 1225984
#define NBLK_SCAN ((NT_TOTAL + 1023) / 1024)         // 529
#define CDIV(a, b) (((a) + (b) - 1) / (b))

// dst node index space: [question: 0) [answer: NQ) [entity: NQ+NA)
#define BASE_Q 0
#define BASE_A NQ
#define BASE_E (NQ + NA)

// in-proj grids (64-row tiles; 1 block per bstats row)
#define GIN_Q 128    // = tiles(8192/64)
#define GIN_A 512    // = tiles(32768/64)
#define GIN_E 768    // < tiles(7813), grid-stride; 3 blocks/CU
#define SMEM_INPROJ (32768 + 17408 + 512)

typedef _Float16 half8_t __attribute__((ext_vector_type(8)));
typedef _Float16 half4_t __attribute__((ext_vector_type(4)));
typedef float f32x4_t __attribute__((ext_vector_type(4)));

__device__ inline void load_lds16(const void* g, void* l) {
  __builtin_amdgcn_global_load_lds((const __attribute__((address_space(1))) void*)g,
                                   (__attribute__((address_space(3))) void*)l, 16, 0, 0);
}

__device__ inline float fast_gelu(float v) {
  // tanh-approx GELU: v * sigmoid(1.5957691*(v + 0.044715 v^3)); |err| < ~1e-3
  float u = 1.5957691216057308f * fmaf(0.044715f * v * v, v, v);
  return v / (1.f + __expf(-u));
}

// ---------------- utility ----------------

__global__ void fill_kernel(float* __restrict__ p, float v, size_t n) {
  size_t i = (size_t)blockIdx.x * blockDim.x + threadIdx.x;
  size_t stride = (size_t)gridDim.x * blockDim.x;
  for (; i < n; i += stride) p[i] = v;
}

// ---------------- in-proj: LDS-staged fp32 A (global_load_lds), MFMA, fused bstats ----------------

__global__ __launch_bounds__(256) void gemm_inproj(
    const float* __restrict__ Af, const _Float16* __restrict__ WT,
    const float* __restrict__ bias, int M, int ntiles,
    _Float16* __restrict__ oh, float* __restrict__ bstats)
{
  extern __shared__ char smem[];
  float* As32 = (float*)smem;                       // 64 x 128 fp32 = 32KB
  _Float16* Bs = (_Float16*)(smem + 32768);         // 64 x 136 fp16 = 17408B
  float* s1 = (float*)(smem + 32768 + 17408);       // 64
  float* s2 = s1 + 64;                              // 64

  int tid = threadIdx.x;
  int w = tid >> 6, l = tid & 63;
  int lr = l & 15, lg = l >> 4;

  for (int idx = tid; idx < 64 * 136 / 8; idx += 256)
    *(half8_t*)&Bs[idx * 8] = *(const half8_t*)&WT[(size_t)idx * 8];
  if (tid < 64) { s1[tid] = 0.f; s2[tid] = 0.f; }

  float ps1[4] = {}, ps2[4] = {};
  float bval[4];
#pragma unroll
  for (int ct = 0; ct < 4; ++ct) bval[ct] = bias[ct * 16 + lr];

  for (int tile = blockIdx.x; tile < ntiles; tile += gridDim.x) {
    const char* srcbase = (const char*)Af + (size_t)tile * 64 * 512;
    int rowlim = M - tile * 64;
#pragma unroll
    for (int r = 0; r < 8; ++r) {
      int unit = r * 4 + w;
      char* ldst = (char*)As32 + unit * 1024;
      int p = unit * 1024 + l * 16;
      int row = p >> 9;
      const char* src = (row < rowlim) ? srcbase + (size_t)row * 512 + (p & 511)
                                       : srcbase;
      load_lds16(src, ldst);
    }
    __syncthreads();

    f32x4_t acc[4] = {};
#pragma unroll
    for (int ks = 0; ks < 4; ++ks) {
      const float4* pa = (const float4*)((const char*)As32 +
                          (w * 16 + lr) * 512 + ks * 128 + lg * 32);
      float4 x0 = pa[0], x1 = pa[1];
      half8_t a0 = {(_Float16)x0.x, (_Float16)x0.y, (_Float16)x0.z, (_Float16)x0.w,
                    (_Float16)x1.x, (_Float16)x1.y, (_Float16)x1.z, (_Float16)x1.w};
#pragma unroll
      for (int ct = 0; ct < 4; ++ct) {
        half8_t b = *(const half8_t*)&Bs[(ct * 16 + lr) * 136 + ks * 32 + lg * 8];
        acc[ct] = __builtin_amdgcn_mfma_f32_16x16x32_f16(a0, b, acc[ct], 0, 0, 0);
      }
    }

    int rbase = tile * 64 + w * 16 + lg * 4;
#pragma unroll
    for (int ct = 0; ct < 4; ++ct) {
      int col = ct * 16 + lr;
#pragma unroll
      for (int j = 0; j < 4; ++j) {
        int row = rbase + j;
        if (row >= M) continue;
        float val = fmaxf(acc[ct][j] + bval[ct], 0.f);
        oh[(size_t)row * 64 + col] = (_Float16)val;
        ps1[ct] += val;
        ps2[ct] += val * val;
      }
    }
    __syncthreads();
  }

#pragma unroll
  for (int ct = 0; ct < 4; ++ct) {
    atomicAdd(&s1[ct * 16 + lr], ps1[ct]);
    atomicAdd(&s2[ct * 16 + lr], ps2[ct]);
  }
  __syncthreads();
  if (tid < 64) {
    bstats[(size_t)blockIdx.x * 128 + tid] = s1[tid];
    bstats[(size_t)blockIdx.x * 128 + 64 + tid] = s2[tid];
  }
}

// ---------------- direct-A MFMA GEMM (out-proj, MODE 3) ----------------

template <int BNT, int KTOT, int MODE>
__global__ __launch_bounds__(256) void gemm_direct(
    const float* __restrict__ Af, const _Float16* __restrict__ Ah,
    const _Float16* __restrict__ WT, const float* __restrict__ bias, int M,
    _Float16* __restrict__ oh, int LDO,
    float* __restrict__ Cf,
    float* __restrict__ bstats,
    const _Float16* __restrict__ resh, const float* __restrict__ rsc,
    const float* __restrict__ rsh, const float* __restrict__ skip_ptr, int skip_idx)
{
  constexpr int KP = KTOT + 8;
  __shared__ _Float16 Bs[BNT * KP];
  int tid = threadIdx.x;
  int row0 = blockIdx.x * 128;

  for (int idx = tid; idx < BNT * KP / 8; idx += 256)
    *(half8_t*)&Bs[idx * 8] = *(const half8_t*)&WT[(size_t)idx * 8];

  int w = tid >> 6, l = tid & 63;
  int lr = l & 15, lg = l >> 4;
  constexpr int NKS = KTOT / 32;
  half8_t afrag[2][NKS];
#pragma unroll
  for (int rt = 0; rt < 2; ++rt) {
    int gr = row0 + w * 32 + rt * 16 + lr;
    bool ok = gr < M;
#pragma unroll
    for (int ks = 0; ks < NKS; ++ks) {
      half8_t h8 = {};
      if (ok) h8 = *(const half8_t*)&Ah[(size_t)gr * KTOT + ks * 32 + lg * 8];
      afrag[rt][ks] = h8;
    }
  }
  __syncthreads();

  constexpr int NCT = BNT / 16;
  f32x4_t acc[2][NCT] = {};
#pragma unroll
  for (int ks = 0; ks < NKS; ++ks) {
#pragma unroll
    for (int ct = 0; ct < NCT; ++ct) {
      half8_t b = *(const half8_t*)&Bs[(ct * 16 + lr) * KP + ks * 32 + lg * 8];
      acc[0][ct] = __builtin_amdgcn_mfma_f32_16x16x32_f16(afrag[0][ks], b, acc[0][ct], 0, 0, 0);
      acc[1][ct] = __builtin_amdgcn_mfma_f32_16x16x32_f16(afrag[1][ks], b, acc[1][ct], 0, 0, 0);
    }
  }

  float g = 1.f / (1.f + __expf(-skip_ptr[skip_idx]));
  float gb = 1.f - g;
#pragma unroll
  for (int rt = 0; rt < 2; ++rt) {
    int rbase = row0 + w * 32 + rt * 16 + lg * 4;
#pragma unroll
    for (int ct = 0; ct < NCT; ++ct) {
      int col = ct * 16 + lr;
      float bval = bias[col];
#pragma unroll
      for (int j = 0; j < 4; ++j) {
        int row = rbase + j;
        if (row >= M) continue;
        float val = acc[rt][ct][j] + bval;
        float rv = (float)resh[(size_t)row * 64 + col];
        Cf[(size_t)row * 64 + col] = g * val + gb * (rsc[col] * rv + rsh[col]);
      }
    }
  }
}

// ---------------- staged MFMA GEMM (kqv, 8 waves, col-tiled) ----------------

template <int BM, int BNT, int KTOT>
__global__ __launch_bounds__(BM * 2) void gemm_mfma(
    const _Float16* __restrict__ Ah,
    const _Float16* __restrict__ WT, const float* __restrict__ bias, int M,
    _Float16* __restrict__ oh, int LDO)
{
  constexpr int KP = KTOT + 8;
  constexpr int NTHR = BM * 2;
  __shared__ _Float16 As[BM * KP];
  __shared__ _Float16 Bs[BNT * KP];
  int tid = threadIdx.x;
  int row0 = blockIdx.x * BM;
  int colbase = blockIdx.y * BNT;

  {
    constexpr int CH = KTOT / 8;
    for (int idx = tid; idx < BM * CH; idx += NTHR) {
      int row = idx / CH, c = idx % CH;
      int gr = row0 + row;
      half8_t a8 = {};
      if (gr < M) a8 = *(const half8_t*)&Ah[(size_t)gr * KTOT + c * 8];
      *(half8_t*)&As[row * KP + c * 8] = a8;
    }
  }
  {
    const _Float16* wsrc = WT + (size_t)colbase * KP;
    for (int idx = tid; idx < BNT * KP / 8; idx += NTHR)
      *(half8_t*)&Bs[idx * 8] = *(const half8_t*)&wsrc[(size_t)idx * 8];
  }
  __syncthreads();

  int w = tid >> 6, l = tid & 63;
  int lr = l & 15, lg = l >> 4;
  constexpr int NCT = BNT / 16;
  constexpr int NKS = KTOT / 32;
  f32x4_t acc[2][NCT] = {};
#pragma unroll
  for (int ks = 0; ks < NKS; ++ks) {
    half8_t a0 = *(const half8_t*)&As[(w * 32 + lr) * KP + ks * 32 + lg * 8];
    half8_t a1 = *(const half8_t*)&As[(w * 32 + 16 + lr) * KP + ks * 32 + lg * 8];
#pragma unroll
    for (int ct = 0; ct < NCT; ++ct) {
      half8_t b = *(const half8_t*)&Bs[(ct * 16 + lr) * KP + ks * 32 + lg * 8];
      acc[0][ct] = __builtin_amdgcn_mfma_f32_16x16x32_f16(a0, b, acc[0][ct], 0, 0, 0);
      acc[1][ct] = __builtin_amdgcn_mfma_f32_16x16x32_f16(a1, b, acc[1][ct], 0, 0, 0);
    }
  }
#pragma unroll
  for (int rt = 0; rt < 2; ++rt) {
    int rbase = row0 + w * 32 + rt * 16 + lg * 4;
#pragma unroll
    for (int ct = 0; ct < NCT; ++ct) {
      int col = colbase + ct * 16 + lr;
      float bval = bias[col];
#pragma unroll
      for (int j = 0; j < 4; ++j) {
        int row = rbase + j;
        if (row >= M) continue;
        oh[(size_t)row * LDO + col] = (_Float16)(acc[rt][ct][j] + bval);
      }
    }
  }
}

// ---------------- BN: reduce per-block stats ----------------

__global__ __launch_bounds__(256) void stats_reduce(const float* __restrict__ bstats,
                                                    float* __restrict__ stats) {
  __shared__ float sh[256];
  int t = blockIdx.x >> 7;
  int c = blockIdx.x & 127;
  int nb = (t == 0) ? GIN_Q : (t == 1) ? GIN_A : GIN_E;
  int base = (t == 0) ? 0 : (t == 1) ? GIN_Q : (GIN_Q + GIN_A);
  float s = 0.f;
  for (int i = threadIdx.x; i < nb; i += 256)
    s += bstats[(size_t)(base + i) * 128 + c];
  sh[threadIdx.x] = s;
  __syncthreads();
  for (int off2 = 128; off2 > 0; off2 >>= 1) {
    if (threadIdx.x < off2) sh[threadIdx.x] += sh[threadIdx.x + off2];
    __syncthreads();
  }
  if (threadIdx.x == 0) stats[t * 128 + c] = sh[0];
}

__global__ void bn_finalize(const float* __restrict__ stats,
                            const float* __restrict__ gamma, const float* __restrict__ beta,
                            float* __restrict__ scale, float* __restrict__ shift) {
  int t = threadIdx.x;
  if (t >= 192) return;
  int ty = t >> 6, c = t & 63;
  float invN = (ty == 0) ? (1.f / NQ) : (ty == 1) ? (1.f / NA) : (1.f / NE);
  float mu = stats[ty * 128 + c] * invN;
  float var = stats[ty * 128 + 64 + c] * invN - mu * mu;
  float rs = rsqrtf(var + 1e-5f);
  float gm = gamma[ty * 64 + c];
  scale[t] = gm * rs;
  shift[t] = beta[ty * 64 + c] - gm * mu * rs;
}

__global__ void kqv_bias2(const float* __restrict__ b_kqv, const float* __restrict__ W_kqv,
                          const float* __restrict__ shift, float* __restrict__ bias2) {
  int t = blockIdx.x, n = threadIdx.x;
  float s = b_kqv[t * 192 + n];
  for (int k = 0; k < 64; ++k)
    s += shift[t * 64 + k] * W_kqv[(size_t)t * 64 * 192 + k * 192 + n];
  bias2[t * 192 + n] = s;
}

// ---------------- weight prep ----------------

__global__ void wprep_kqv(const float* __restrict__ W_kqv, const float* __restrict__ bias2,
                          const float* __restrict__ A_k, const float* __restrict__ A_v,
                          const float* __restrict__ scale,
                          _Float16* __restrict__ WqT, _Float16* __restrict__ WeT,
                          _Float16* __restrict__ WaT, float* __restrict__ bias_big) {
  int j = blockIdx.x;   // 0..639
  int c = threadIdx.x;  // 0..63
  int t, jj, bofs;
  _Float16* W;
  if (j < 192)      { t = 0; jj = j;       W = WqT; bofs = 0; }
  else if (j < 512) { t = 2; jj = j - 192; W = WeT; bofs = 192; }
  else              { t = 1; jj = j - 512; W = WaT; bofs = 512; }
  const float* Wt = W_kqv + (size_t)t * 64 * 192;
  const float* b2 = bias2 + t * 192;
  int mode = 0, rel = 0, sub = 0;
  if (t == 1) { mode = 1; rel = (jj < 64) ? 2 : 3; sub = jj & 63; }
  else if (jj >= 64 && jj < 128) { mode = 1; rel = (t == 0) ? 0 : 1; sub = jj - 64; }
  else if (jj >= 128) {
    mode = 2; sub = (jj - 128) & 63;
    rel = (t == 0) ? 3 : ((jj - 128) >> 6);
  }
  int h = sub >> 5, x = sub & 31;
  float wv, bv;
  if (mode == 0) {
    wv = Wt[(size_t)c * 192 + jj];
    bv = b2[jj];
  } else if (mode == 1) {
    const float* Ar = A_k + ((size_t)rel * 2048 + h * 1024 + x * 32);
    float s = 0.f, sb = 0.f;
    for (int f = 0; f < 32; ++f) {
      float a = Ar[f];
      s = fmaf(a, Wt[(size_t)c * 192 + 64 + h * 32 + f], s);
      sb = fmaf(a, b2[64 + h * 32 + f], sb);
    }
    wv = s; bv = sb;
  } else {
    const float* Ar = A_v + ((size_t)rel * 2048 + h * 1024 + x);
    float s = 0.f, sb = 0.f;
    for (int d = 0; d < 32; ++d) {
      float a = Ar[d * 32];
      s = fmaf(a, Wt[(size_t)c * 192 + 128 + h * 32 + d], s);
      sb = fmaf(a, b2[128 + h * 32 + d], sb);
    }
    wv = s; bv = sb;
  }
  wv *= scale[t * 64 + c];
  W[(size_t)jj * 72 + c] = (_Float16)wv;
  if (c < 8) W[(size_t)jj * 72 + 64 + c] = (_Float16)0.f;
  if (c == 0) bias_big[bofs + jj] = bv;
}

__global__ void wprep_in(const float* __restrict__ W_in, _Float16* __restrict__ WinT) {
  int t = blockIdx.x >> 6, n = blockIdx.x & 63, k = threadIdx.x;  // k 0..135
  float v = (k < 128) ? W_in[(size_t)t * 128 * 64 + (size_t)k * 64 + n] : 0.f;
  WinT[((size_t)t * 64 + n) * 136 + k] = (_Float16)v;
}

__global__ void wprep_out(const float* __restrict__ W_out, _Float16* __restrict__ WoutT) {
  int t = blockIdx.x >> 6, n = blockIdx.x & 63, k = threadIdx.x;  // k 0..71
  float v = (k < 64) ? W_out[(size_t)t * 64 * 64 + (size_t)k * 64 + n] : 0.f;
  WoutT[((size_t)t * 64 + n) * 72 + k] = (_Float16)v;
}

// ---------------- CSR build ----------------

__global__ void hist_kernel(const int* __restrict__ dst, int E,
                            unsigned* __restrict__ cnt, int base) {
  int i = blockIdx.x * blockDim.x + threadIdx.x;
  int stride = gridDim.x * blockDim.x;
  for (; i < E; i += stride) atomicAdd(&cnt[base + dst[i]], 1u);
}

__global__ __launch_bounds__(256) void scan1(unsigned* __restrict__ arr, int n,
                                             unsigned* __restrict__ bsums) {
  __shared__ unsigned sh[256];
  int t = threadIdx.x;
  int base = blockIdx.x * 1024 + t * 4;
  unsigned v[4];
  unsigned s = 0;
#pragma unroll
  for (int j = 0; j < 4; ++j) {
    v[j] = (base + j < n) ? arr[base + j] : 0u;
    s += v[j];
  }
  sh[t] = s;
  __syncthreads();
  for (int off = 1; off < 256; off <<= 1) {
    unsigned x = (t >= off) ? sh[t - off] : 0u;
    __syncthreads();
    sh[t] += x;
    __syncthreads();
  }
  unsigned run = sh[t] - s;
#pragma unroll
  for (int j = 0; j < 4; ++j) {
    if (base + j < n) arr[base + j] = run;
    run += v[j];
  }
  if (t == 255) bsums[blockIdx.x] = sh[255];
}

__global__ __launch_bounds__(256) void scan2(unsigned* __restrict__ bsums, int nb) {
  __shared__ unsigned sh[256];
  __shared__ unsigned carry;
  int t = threadIdx.x;
  if (t == 0) carry = 0;
  __syncthreads();
  for (int chunk = 0; chunk < nb; chunk += 256) {
    int i = chunk + t;
    unsigned v = (i < nb) ? bsums[i] : 0u;
    sh[t] = v;
    __syncthreads();
    for (int off = 1; off < 256; off <<= 1) {
      unsigned x = (t >= off) ? sh[t - off] : 0u;
      __syncthreads();
      sh[t] += x;
      __syncthreads();
    }
    unsigned inc = sh[t];
    unsigned c = carry;
    __syncthreads();
    if (i < nb) bsums[i] = c + inc - v;
    if (t == 255) carry = c + sh[255];
    __syncthreads();
  }
}

__global__ __launch_bounds__(256) void scan3(unsigned* __restrict__ arr,
                                             const unsigned* __restrict__ bsums,
                                             unsigned* __restrict__ cursor, int n) {
  int t = threadIdx.x;
  int base = blockIdx.x * 1024 + t * 4;
  unsigned add = bsums[blockIdx.x];
#pragma unroll
  for (int j = 0; j < 4; ++j) {
    int idx = base + j;
    if (idx < n) {
      unsigned r = arr[idx] + add;
      arr[idx] = r;
      cursor[idx] = r;
    }
  }
}

// payload = LOCAL src index | slot<<20
__global__ void scatter_kernel(const int* __restrict__ src, const int* __restrict__ dst, int E,
                               unsigned* __restrict__ cursor, unsigned* __restrict__ eidx,
                               int dstbase, unsigned slot) {
  int i = blockIdx.x * blockDim.x + threadIdx.x;
  int stride = gridDim.x * blockDim.x;
  for (; i < E; i += stride) {
    unsigned pos = atomicAdd(&cursor[dstbase + dst[i]], 1u);
    eidx[pos] = (unsigned)src[i] | (slot << 20);
  }
}

// ---------------- gather: softmax-weighted aggregation per dst node ----------------
// Distance-2 node pipeline: bounds/qt prefetched 2 ahead, first-2 edge payloads 1 ahead.
// eidx is padded by 8 entries so speculative payload loads stay in-bounds.

template <int NREL>
__global__ __launch_bounds__(256) void gather_kernel(
    int N, int nodebase,
    const unsigned* __restrict__ row_start, const unsigned* __restrict__ row_end,
    const unsigned* __restrict__ eidx,
    const _Float16* __restrict__ baseA, int ldA, int vofA,
    const _Float16* __restrict__ baseB, int ldB, int vofB,
    const _Float16* __restrict__ qtA, int ldqA,
    const _Float16* __restrict__ qtB, int ldqB,
    const float* __restrict__ prelA, const float* __restrict__ prelB,
    _Float16* __restrict__ agg)
{
  int lane = threadIdx.x & 63;
  int h = lane >> 5;
  const float isd = 0.17677669529663687f;
  float pr0 = prelA[h] * isd;
  float pr1 = (NREL == 2) ? prelB[h] * isd : 0.f;

  int wid = (int)((blockIdx.x * blockDim.x + threadIdx.x) >> 6);
  int nw = (int)((gridDim.x * blockDim.x) >> 6);

  // pipeline state: node n0 (current, fully prefetched incl. first 2 payloads),
  // node n1 (bounds+qt prefetched)
  int n0 = wid;
  unsigned b0s = 0, b0e = 0, e00 = 0, e01 = 0;
  float q00 = 0.f, q01 = 0.f;
  if (n0 < N) {
    b0s = row_start[nodebase + n0];
    b0e = row_end[nodebase + n0];
    q00 = (float)qtA[(size_t)n0 * ldqA + lane];
    if (NREL == 2) q01 = (float)qtB[(size_t)n0 * ldqB + lane];
    e00 = eidx[b0s];
    e01 = eidx[b0s + 1];
  }
  int n1 = n0 + nw;
  unsigned b1s = 0, b1e = 0;
  float q10 = 0.f, q11 = 0.f;
  if (n0 < N && n1 < N) {
    b1s = row_start[nodebase + n1];
    b1e = row_end[nodebase + n1];
    q10 = (float)qtA[(size_t)n1 * ldqA + lane];
    if (NREL == 2) q11 = (float)qtB[(size_t)n1 * ldqB + lane];
  }

  while (n0 < N) {
    // prefetch payloads for n1 (bounds already in regs)
    unsigned e10 = 0, e11 = 0;
    if (n1 < N) {
      e10 = eidx[b1s];
      e11 = eidx[b1s + 1];
    }
    // prefetch bounds+qt for n2
    int n2 = n1 + nw;
    unsigned b2s = 0, b2e = 0;
    float q20 = 0.f, q21 = 0.f;
    if (n2 < N) {
      b2s = row_start[nodebase + n2];
      b2e = row_end[nodebase + n2];
      q20 = (float)qtA[(size_t)n2 * ldqA + lane];
      if (NREL == 2) q21 = (float)qtB[(size_t)n2 * ldqB + lane];
    }

    // ---- process node n0 ----
    float vs = 0.f, ss = 0.f;
    unsigned i = b0s;

    auto do_pair = [&](unsigned p1, unsigned p2) {
      unsigned s1i = p1 & 0xFFFFFu, s2i = p2 & 0xFFFFFu;
      bool r1 = (NREL == 2) && (p1 >> 20);
      bool r2 = (NREL == 2) && (p2 >> 20);
      const _Float16* b1 = r1 ? baseB + (size_t)s1i * ldB : baseA + (size_t)s1i * ldA;
      const _Float16* b2 = r2 ? baseB + (size_t)s2i * ldB : baseA + (size_t)s2i * ldA;
      float k1 = (float)b1[lane];
      float v1 = (float)b1[(r1 ? vofB : vofA) + lane];
      float k2 = (float)b2[lane];
      float v2 = (float)b2[(r2 ? vofB : vofA) + lane];
      float sa = k1 * (r1 ? q01 : q00);
      float sb = k2 * (r2 ? q01 : q00);
#pragma unroll
      for (int off = 16; off > 0; off >>= 1) {
        sa += __shfl_xor(sa, off, 32);
        sb += __shfl_xor(sb, off, 32);
      }
      float w1 = __expf(sa * (r1 ? pr1 : pr0));
      float w2 = __expf(sb * (r2 ? pr1 : pr0));
      ss += w1 + w2;
      vs = fmaf(w1, v1, vs);
      vs = fmaf(w2, v2, vs);
    };
    auto do_single = [&](unsigned p1) {
      unsigned s1i = p1 & 0xFFFFFu;
      bool r1 = (NREL == 2) && (p1 >> 20);
      const _Float16* b1 = r1 ? baseB + (size_t)s1i * ldB : baseA + (size_t)s1i * ldA;
      float k1 = (float)b1[lane];
      float v1 = (float)b1[(r1 ? vofB : vofA) + lane];
      float sa = k1 * (r1 ? q01 : q00);
#pragma unroll
      for (int off = 16; off > 0; off >>= 1) sa += __shfl_xor(sa, off, 32);
      float w1 = __expf(sa * (r1 ? pr1 : pr0));
      ss += w1;
      vs = fmaf(w1, v1, vs);
    };

    if (i + 2 <= b0e) { do_pair(e00, e01); i += 2; }
    else if (i < b0e) { do_single(e00); i = b0e; }
    for (; i + 2 <= b0e; i += 2) do_pair(eidx[i], eidx[i + 1]);
    if (i < b0e) do_single(eidx[i]);

    float val = (ss > 0.f) ? vs / ss : 0.f;
    val = fast_gelu(val);
    agg[((size_t)(nodebase + n0)) * 64 + lane] = (_Float16)val;

    // rotate pipeline
    n0 = n1; b0s = b1s; b0e = b1e; q00 = q10; q01 = q11; e00 = e10; e01 = e11;
    n1 = n2; b1s = b2s; b1e = b2e; q10 = q20; q11 = q21;
  }
}

// ---------------- final predictions ----------------

__global__ void pred_kernel(const int* __restrict__ qi, const int* __restrict__ ai, int Np,
                            const float* __restrict__ zq, const float* __restrict__ za,
                            float* __restrict__ outp) {
  int i = blockIdx.x * blockDim.x + threadIdx.x;
  if (i >= Np) return;
  const float4* a = (const float4*)(zq + (size_t)qi[i] * 64);
  const float4* b = (const float4*)(za + (size_t)ai[i] * 64);
  float ssum = 0.f;
#pragma unroll
  for (int j = 0; j < 16; ++j) {
    float4 x = a[j], y = b[j];
    ssum += x.x * y.x + x.y * y.y + x.z * y.z + x.w * y.w;
  }
  outp[i] = ssum;
}

// ---------------- host launch ----------------

extern "C" void kernel_launch(void* const* d_in, const int* in_sizes, int n_in,
                              void* d_out, int out_size, void* d_ws, size_t ws_size,
                              hipStream_t stream) {
  const float* xq = (const float*)d_in[0];
  const float* xa = (const float*)d_in[1];
  const float* xe = (const float*)d_in[2];
  const int* e_e2q = (const int*)d_in[3];
  const int* e_e2e = (const int*)d_in[4];
  const int* e_e2a = (const int*)d_in[5];
  const int* e_q2a = (const int*)d_in[6];
  const int* pos_idx = (const int*)d_in[7];
  const int* neg_idx = (const int*)d_in[8];
  const float* W_in = (const float*)d_in[9];
  const float* b_in = (const float*)d_in[10];
  const float* bn_gamma = (const float*)d_in[11];
  const float* bn_beta = (const float*)d_in[12];
  const float* W_kqv = (const float*)d_in[13];
  const float* b_kqv = (const float*)d_in[14];
  const float* A_k = (const float*)d_in[15];
  const float* A_v = (const float*)d_in[16];
  const float* p_rel = (const float*)d_in[17];
  const float* W_out = (const float*)d_in[18];
  const float* b_out = (const float*)d_in[19];
  const float* skip = (const float*)d_in[20];
  float* out = (float*)d_out;

  float* ws = (float*)d_ws;
  size_t off = 0;
  _Float16* y_h = (_Float16*)(ws + off);    off += (size_t)NT_TOTAL * 32;
  _Float16* kqvQ = (_Float16*)(ws + off);   off += (size_t)NQ * 96;    // [NQ][192]
  _Float16* kqvE = (_Float16*)(ws + off);   off += (size_t)NE * 160;   // [NE][320]
  _Float16* kqvA = (_Float16*)(ws + off);   off += (size_t)NA * 64;    // [NA][128]
  _Float16* agg_h = (_Float16*)(ws + off);  off += (size_t)NT_TOTAL * 32;
  float* stats = ws + off;                  off += 384;
  float* scale = ws + off;                  off += 192;
  float* shift = ws + off;                  off += 192;
  float* bias2 = ws + off;                  off += 576;
  float* bias_big = ws + off;               off += 640;
  _Float16* WqT = (_Float16*)(ws + off);    off += 192 * 72 / 2;
  _Float16* WeT = (_Float16*)(ws + off);    off += 320 * 72 / 2;
  _Float16* WaT = (_Float16*)(ws + off);    off += 128 * 72 / 2;
  _Float16* WinT = (_Float16*)(ws + off);   off += 3 * 64 * 136 / 2;
  _Float16* WoutT = (_Float16*)(ws + off);  off += 3 * 64 * 72 / 2;
  float* bstats = ws + off;                 off += (size_t)(GIN_Q + GIN_A + GIN_E) * 128;
  unsigned* row_start = (unsigned*)(ws + off); off += NT_TOTAL;
  unsigned* cursor = (unsigned*)(ws + off);    off += NT_TOTAL;
  unsigned* bsums = (unsigned*)(ws + off);     off += 1024;
  unsigned* eidx = (unsigned*)(ws + off);      off += E_TOTAL + 8;  // +8 pad for spec loads

  const int Ns[3] = {NQ, NA, NE};
  const float* xs[3] = {xq, xa, xe};
  const int gin[3] = {GIN_Q, GIN_A, GIN_E};
  const int bb[3] = {0, GIN_Q, GIN_Q + GIN_A};
  _Float16* yhb[3] = {y_h, y_h + (size_t)NQ * 64, y_h + (size_t)(NQ + NA) * 64};
  _Float16* aggb[3] = {agg_h, agg_h + (size_t)NQ * 64, agg_h + (size_t)(NQ + NA) * 64};
  float* zq_out = out + (N_POS + N_NEG);
  float* zbase[3] = {zq_out, zq_out + (size_t)NQ * 64, zq_out + (size_t)(NQ + NA) * 64};

  fill_kernel<<<dim3(128), dim3(256), 0, stream>>>((float*)row_start, 0.f, NT_TOTAL);
  wprep_in<<<dim3(192), dim3(136), 0, stream>>>(W_in, WinT);
  wprep_out<<<dim3(192), dim3(72), 0, stream>>>(W_out, WoutT);

  // ---- in-proj (LDS-staged MFMA, 3 blocks/CU) + relu -> y fp16, fused bstats ----
  for (int t = 0; t < 3; ++t) {
    gemm_inproj<<<dim3(gin[t]), dim3(256), SMEM_INPROJ, stream>>>(
        xs[t], WinT + (size_t)t * 64 * 136, b_in + t * 64, Ns[t], CDIV(Ns[t], 64),
        yhb[t], bstats + (size_t)bb[t] * 128);
  }
  stats_reduce<<<dim3(384), dim3(256), 0, stream>>>(bstats, stats);
  bn_finalize<<<dim3(1), dim3(192), 0, stream>>>(stats, bn_gamma, bn_beta, scale, shift);
  kqv_bias2<<<dim3(3), dim3(192), 0, stream>>>(b_kqv, W_kqv, shift, bias2);
  wprep_kqv<<<dim3(640), dim3(64), 0, stream>>>(W_kqv, bias2, A_k, A_v, scale,
                                                WqT, WeT, WaT, bias_big);

  // ---- kqv projections (staged 8-wave; entity split into 2 col-tiles) ----
  gemm_mfma<256, 192, 64><<<dim3(CDIV(NQ, 256)), dim3(512), 0, stream>>>(
      yhb[0], WqT, bias_big, NQ, kqvQ, 192);
  gemm_mfma<256, 160, 64><<<dim3(CDIV(NE, 256), 2), dim3(512), 0, stream>>>(
      yhb[2], WeT, bias_big + 192, NE, kqvE, 320);
  gemm_mfma<256, 128, 64><<<dim3(CDIV(NA, 256)), dim3(512), 0, stream>>>(
      yhb[1], WaT, bias_big + 512, NA, kqvA, 128);

  // ---- CSR build ----
  struct Rel { const int* ei; int E; int dstbase; unsigned slot; };
  Rel rels[4] = {{e_e2q, E_E2Q, BASE_Q, 0u},
                 {e_e2e, E_E2E, BASE_E, 0u},
                 {e_e2a, E_E2A, BASE_A, 0u},
                 {e_q2a, E_Q2A, BASE_A, 1u}};
  for (int r = 0; r < 4; ++r) {
    int blocks = CDIV(rels[r].E, 256); if (blocks > 2048) blocks = 2048;
    hist_kernel<<<dim3(blocks), dim3(256), 0, stream>>>(rels[r].ei + rels[r].E, rels[r].E,
                                                        row_start, rels[r].dstbase);
  }
  scan1<<<dim3(NBLK_SCAN), dim3(256), 0, stream>>>(row_start, NT_TOTAL, bsums);
  scan2<<<dim3(1), dim3(256), 0, stream>>>(bsums, NBLK_SCAN);
  scan3<<<dim3(NBLK_SCAN), dim3(256), 0, stream>>>(row_start, bsums, cursor, NT_TOTAL);
  for (int r = 0; r < 4; ++r) {
    int blocks = CDIV(rels[r].E, 256); if (blocks > 2048) blocks = 2048;
    scatter_kernel<<<dim3(blocks), dim3(256), 0, stream>>>(
        rels[r].ei, rels[r].ei + rels[r].E, rels[r].E, cursor, eidx,
        rels[r].dstbase, rels[r].slot);
  }

  // ---- gathers ----
  gather_kernel<1><<<dim3(CDIV(NQ, 4)), dim3(256), 0, stream>>>(
      NQ, BASE_Q, row_start, cursor, eidx,
      kqvE, 320, 128, nullptr, 0, 0,
      kqvQ + 64, 192, nullptr, 0, p_rel + 0, p_rel + 0, agg_h);
  gather_kernel<1><<<dim3(4096), dim3(256), 0, stream>>>(
      NE, BASE_E, row_start, cursor, eidx,
      kqvE, 320, 192, nullptr, 0, 0,
      kqvE + 64, 320, nullptr, 0, p_rel + 2, p_rel + 2, agg_h);
  gather_kernel<2><<<dim3(CDIV(NA, 4)), dim3(256), 0, stream>>>(
      NA, BASE_A, row_start, cursor, eidx,
      kqvE, 320, 256, kqvQ, 192, 128,
      kqvA, 128, kqvA + 64, 128, p_rel + 4, p_rel + 6, agg_h);

  // ---- out projection (direct-A MFMA) + skip blend -> fp32 z ----
  for (int t = 0; t < 3; ++t) {
    gemm_direct<64, 64, 3><<<dim3(CDIV(Ns[t], 128)), dim3(256), 0, stream>>>(
        nullptr, aggb[t], WoutT + (size_t)t * 64 * 72, b_out + t * 64, Ns[t],
        nullptr, 0, zbase[t], nullptr,
        yhb[t], scale + t * 64, shift + t * 64, skip, t);
  }

  // ---- predictions ----
  pred_kernel<<<dim3(CDIV(N_POS, 256)), dim3(256), 0, stream>>>(
      pos_idx, pos_idx + N_POS, N_POS, zbase[0], zbase[1], out);
  pred_kernel<<<dim3(CDIV(N_NEG, 256)), dim3(256), 0, stream>>>(
      neg_idx, neg_idx + N_NEG, N_NEG, zbase[0], zbase[1], out + N_POS);
}

// Round 15
// 747.544 us; speedup vs baseline: 2.5874x; 1.0353x over previous
//
#include <hip/hip_runtime.h>
#include <hip/hip_bf16.h>
#include <hip/hip_fp16.h>
#include <math.h>

#define NQ 8192
#define NA 32768
#define NE 500000
#define F_IN 128
#define E_E2Q 131072
#define E_E2E 800000
#define E_E2A 262144
#define E_Q2A 32768
#define N_POS 8192
#define N_NEG 24576

#define NT_TOTAL (NQ + NA + NE)                      // 540960
#define E_TOTAL (E_E2Q + E_E2E + E_E2A + E_Q2A)      // 1225984
#define NBLK_SCAN ((NT_TOTAL + 1023) / 1024)         // 529
#define CDIV(a, b) (((a) + (b) - 1) / (b))

// dst node index space: [question: 0) [answer: NQ) [entity: NQ+NA)
#define BASE_Q 0
#define BASE_A NQ
#define BASE_E (NQ + NA)

// in-proj grids (64-row tiles; 1 block per bstats row)
#define GIN_Q 128
#define GIN_A 512
#define GIN_E 768
#define SMEM_INPROJ (32768 + 17408 + 512)

typedef _Float16 half8_t __attribute__((ext_vector_type(8)));
typedef _Float16 half4_t __attribute__((ext_vector_type(4)));
typedef _Float16 half2_t __attribute__((ext_vector_type(2)));
typedef float f32x4_t __attribute__((ext_vector_type(4)));

__device__ inline void load_lds16(const void* g, void* l) {
  __builtin_amdgcn_global_load_lds((const __attribute__((address_space(1))) void*)g,
                                   (__attribute__((address_space(3))) void*)l, 16, 0, 0);
}

__device__ inline float fast_gelu(float v) {
  float u = 1.5957691216057308f * fmaf(0.044715f * v * v, v, v);
  return v / (1.f + __expf(-u));
}

// ---------------- utility ----------------

__global__ void fill_kernel(float* __restrict__ p, float v, size_t n) {
  size_t i = (size_t)blockIdx.x * blockDim.x + threadIdx.x;
  size_t stride = (size_t)gridDim.x * blockDim.x;
  for (; i < n; i += stride) p[i] = v;
}

// ---------------- in-proj: LDS-staged fp32 A (global_load_lds), MFMA, fused bstats ----------------

__global__ __launch_bounds__(256) void gemm_inproj(
    const float* __restrict__ Af, const _Float16* __restrict__ WT,
    const float* __restrict__ bias, int M, int ntiles,
    _Float16* __restrict__ oh, float* __restrict__ bstats)
{
  extern __shared__ char smem[];
  float* As32 = (float*)smem;                       // 64 x 128 fp32 = 32KB
  _Float16* Bs = (_Float16*)(smem + 32768);         // 64 x 136 fp16
  float* s1 = (float*)(smem + 32768 + 17408);
  float* s2 = s1 + 64;

  int tid = threadIdx.x;
  int w = tid >> 6, l = tid & 63;
  int lr = l & 15, lg = l >> 4;

  for (int idx = tid; idx < 64 * 136 / 8; idx += 256)
    *(half8_t*)&Bs[idx * 8] = *(const half8_t*)&WT[(size_t)idx * 8];
  if (tid < 64) { s1[tid] = 0.f; s2[tid] = 0.f; }

  float ps1[4] = {}, ps2[4] = {};
  float bval[4];
#pragma unroll
  for (int ct = 0; ct < 4; ++ct) bval[ct] = bias[ct * 16 + lr];

  for (int tile = blockIdx.x; tile < ntiles; tile += gridDim.x) {
    const char* srcbase = (const char*)Af + (size_t)tile * 64 * 512;
    int rowlim = M - tile * 64;
#pragma unroll
    for (int r = 0; r < 8; ++r) {
      int unit = r * 4 + w;
      char* ldst = (char*)As32 + unit * 1024;
      int p = unit * 1024 + l * 16;
      int row = p >> 9;
      const char* src = (row < rowlim) ? srcbase + (size_t)row * 512 + (p & 511)
                                       : srcbase;
      load_lds16(src, ldst);
    }
    __syncthreads();

    f32x4_t acc[4] = {};
#pragma unroll
    for (int ks = 0; ks < 4; ++ks) {
      const float4* pa = (const float4*)((const char*)As32 +
                          (w * 16 + lr) * 512 + ks * 128 + lg * 32);
      float4 x0 = pa[0], x1 = pa[1];
      half8_t a0 = {(_Float16)x0.x, (_Float16)x0.y, (_Float16)x0.z, (_Float16)x0.w,
                    (_Float16)x1.x, (_Float16)x1.y, (_Float16)x1.z, (_Float16)x1.w};
#pragma unroll
      for (int ct = 0; ct < 4; ++ct) {
        half8_t b = *(const half8_t*)&Bs[(ct * 16 + lr) * 136 + ks * 32 + lg * 8];
        acc[ct] = __builtin_amdgcn_mfma_f32_16x16x32_f16(a0, b, acc[ct], 0, 0, 0);
      }
    }

    int rbase = tile * 64 + w * 16 + lg * 4;
#pragma unroll
    for (int ct = 0; ct < 4; ++ct) {
      int col = ct * 16 + lr;
#pragma unroll
      for (int j = 0; j < 4; ++j) {
        int row = rbase + j;
        if (row >= M) continue;
        float val = fmaxf(acc[ct][j] + bval[ct], 0.f);
        oh[(size_t)row * 64 + col] = (_Float16)val;
        ps1[ct] += val;
        ps2[ct] += val * val;
      }
    }
    __syncthreads();
  }

#pragma unroll
  for (int ct = 0; ct < 4; ++ct) {
    atomicAdd(&s1[ct * 16 + lr], ps1[ct]);
    atomicAdd(&s2[ct * 16 + lr], ps2[ct]);
  }
  __syncthreads();
  if (tid < 64) {
    bstats[(size_t)blockIdx.x * 128 + tid] = s1[tid];
    bstats[(size_t)blockIdx.x * 128 + 64 + tid] = s2[tid];
  }
}

// ---------------- direct-A MFMA GEMM (out-proj, MODE 3) ----------------

template <int BNT, int KTOT, int MODE>
__global__ __launch_bounds__(256) void gemm_direct(
    const float* __restrict__ Af, const _Float16* __restrict__ Ah,
    const _Float16* __restrict__ WT, const float* __restrict__ bias, int M,
    _Float16* __restrict__ oh, int LDO,
    float* __restrict__ Cf,
    float* __restrict__ bstats,
    const _Float16* __restrict__ resh, const float* __restrict__ rsc,
    const float* __restrict__ rsh, const float* __restrict__ skip_ptr, int skip_idx)
{
  constexpr int KP = KTOT + 8;
  __shared__ _Float16 Bs[BNT * KP];
  int tid = threadIdx.x;
  int row0 = blockIdx.x * 128;

  for (int idx = tid; idx < BNT * KP / 8; idx += 256)
    *(half8_t*)&Bs[idx * 8] = *(const half8_t*)&WT[(size_t)idx * 8];

  int w = tid >> 6, l = tid & 63;
  int lr = l & 15, lg = l >> 4;
  constexpr int NKS = KTOT / 32;
  half8_t afrag[2][NKS];
#pragma unroll
  for (int rt = 0; rt < 2; ++rt) {
    int gr = row0 + w * 32 + rt * 16 + lr;
    bool ok = gr < M;
#pragma unroll
    for (int ks = 0; ks < NKS; ++ks) {
      half8_t h8 = {};
      if (ok) h8 = *(const half8_t*)&Ah[(size_t)gr * KTOT + ks * 32 + lg * 8];
      afrag[rt][ks] = h8;
    }
  }
  __syncthreads();

  constexpr int NCT = BNT / 16;
  f32x4_t acc[2][NCT] = {};
#pragma unroll
  for (int ks = 0; ks < NKS; ++ks) {
#pragma unroll
    for (int ct = 0; ct < NCT; ++ct) {
      half8_t b = *(const half8_t*)&Bs[(ct * 16 + lr) * KP + ks * 32 + lg * 8];
      acc[0][ct] = __builtin_amdgcn_mfma_f32_16x16x32_f16(afrag[0][ks], b, acc[0][ct], 0, 0, 0);
      acc[1][ct] = __builtin_amdgcn_mfma_f32_16x16x32_f16(afrag[1][ks], b, acc[1][ct], 0, 0, 0);
    }
  }

  float g = 1.f / (1.f + __expf(-skip_ptr[skip_idx]));
  float gb = 1.f - g;
#pragma unroll
  for (int rt = 0; rt < 2; ++rt) {
    int rbase = row0 + w * 32 + rt * 16 + lg * 4;
#pragma unroll
    for (int ct = 0; ct < NCT; ++ct) {
      int col = ct * 16 + lr;
      float bval = bias[col];
#pragma unroll
      for (int j = 0; j < 4; ++j) {
        int row = rbase + j;
        if (row >= M) continue;
        float val = acc[rt][ct][j] + bval;
        float rv = (float)resh[(size_t)row * 64 + col];
        Cf[(size_t)row * 64 + col] = g * val + gb * (rsc[col] * rv + rsh[col]);
      }
    }
  }
}

// ---------------- staged MFMA GEMM (kqv, 8 waves, col-tiled) ----------------

template <int BM, int BNT, int KTOT>
__global__ __launch_bounds__(BM * 2) void gemm_mfma(
    const _Float16* __restrict__ Ah,
    const _Float16* __restrict__ WT, const float* __restrict__ bias, int M,
    _Float16* __restrict__ oh, int LDO)
{
  constexpr int KP = KTOT + 8;
  constexpr int NTHR = BM * 2;
  __shared__ _Float16 As[BM * KP];
  __shared__ _Float16 Bs[BNT * KP];
  int tid = threadIdx.x;
  int row0 = blockIdx.x * BM;
  int colbase = blockIdx.y * BNT;

  {
    constexpr int CH = KTOT / 8;
    for (int idx = tid; idx < BM * CH; idx += NTHR) {
      int row = idx / CH, c = idx % CH;
      int gr = row0 + row;
      half8_t a8 = {};
      if (gr < M) a8 = *(const half8_t*)&Ah[(size_t)gr * KTOT + c * 8];
      *(half8_t*)&As[row * KP + c * 8] = a8;
    }
  }
  {
    const _Float16* wsrc = WT + (size_t)colbase * KP;
    for (int idx = tid; idx < BNT * KP / 8; idx += NTHR)
      *(half8_t*)&Bs[idx * 8] = *(const half8_t*)&wsrc[(size_t)idx * 8];
  }
  __syncthreads();

  int w = tid >> 6, l = tid & 63;
  int lr = l & 15, lg = l >> 4;
  constexpr int NCT = BNT / 16;
  constexpr int NKS = KTOT / 32;
  f32x4_t acc[2][NCT] = {};
#pragma unroll
  for (int ks = 0; ks < NKS; ++ks) {
    half8_t a0 = *(const half8_t*)&As[(w * 32 + lr) * KP + ks * 32 + lg * 8];
    half8_t a1 = *(const half8_t*)&As[(w * 32 + 16 + lr) * KP + ks * 32 + lg * 8];
#pragma unroll
    for (int ct = 0; ct < NCT; ++ct) {
      half8_t b = *(const half8_t*)&Bs[(ct * 16 + lr) * KP + ks * 32 + lg * 8];
      acc[0][ct] = __builtin_amdgcn_mfma_f32_16x16x32_f16(a0, b, acc[0][ct], 0, 0, 0);
      acc[1][ct] = __builtin_amdgcn_mfma_f32_16x16x32_f16(a1, b, acc[1][ct], 0, 0, 0);
    }
  }
#pragma unroll
  for (int rt = 0; rt < 2; ++rt) {
    int rbase = row0 + w * 32 + rt * 16 + lg * 4;
#pragma unroll
    for (int ct = 0; ct < NCT; ++ct) {
      int col = colbase + ct * 16 + lr;
      float bval = bias[col];
#pragma unroll
      for (int j = 0; j < 4; ++j) {
        int row = rbase + j;
        if (row >= M) continue;
        oh[(size_t)row * LDO + col] = (_Float16)(acc[rt][ct][j] + bval);
      }
    }
  }
}

// ---------------- BN: reduce per-block stats ----------------

__global__ __launch_bounds__(256) void stats_reduce(const float* __restrict__ bstats,
                                                    float* __restrict__ stats) {
  __shared__ float sh[256];
  int t = blockIdx.x >> 7;
  int c = blockIdx.x & 127;
  int nb = (t == 0) ? GIN_Q : (t == 1) ? GIN_A : GIN_E;
  int base = (t == 0) ? 0 : (t == 1) ? GIN_Q : (GIN_Q + GIN_A);
  float s = 0.f;
  for (int i = threadIdx.x; i < nb; i += 256)
    s += bstats[(size_t)(base + i) * 128 + c];
  sh[threadIdx.x] = s;
  __syncthreads();
  for (int off2 = 128; off2 > 0; off2 >>= 1) {
    if (threadIdx.x < off2) sh[threadIdx.x] += sh[threadIdx.x + off2];
    __syncthreads();
  }
  if (threadIdx.x == 0) stats[t * 128 + c] = sh[0];
}

__global__ void bn_finalize(const float* __restrict__ stats,
                            const float* __restrict__ gamma, const float* __restrict__ beta,
                            float* __restrict__ scale, float* __restrict__ shift) {
  int t = threadIdx.x;
  if (t >= 192) return;
  int ty = t >> 6, c = t & 63;
  float invN = (ty == 0) ? (1.f / NQ) : (ty == 1) ? (1.f / NA) : (1.f / NE);
  float mu = stats[ty * 128 + c] * invN;
  float var = stats[ty * 128 + 64 + c] * invN - mu * mu;
  float rs = rsqrtf(var + 1e-5f);
  float gm = gamma[ty * 64 + c];
  scale[t] = gm * rs;
  shift[t] = beta[ty * 64 + c] - gm * mu * rs;
}

__global__ void kqv_bias2(const float* __restrict__ b_kqv, const float* __restrict__ W_kqv,
                          const float* __restrict__ shift, float* __restrict__ bias2) {
  int t = blockIdx.x, n = threadIdx.x;
  float s = b_kqv[t * 192 + n];
  for (int k = 0; k < 64; ++k)
    s += shift[t * 64 + k] * W_kqv[(size_t)t * 64 * 192 + k * 192 + n];
  bias2[t * 192 + n] = s;
}

// ---------------- weight prep ----------------

__global__ void wprep_kqv(const float* __restrict__ W_kqv, const float* __restrict__ bias2,
                          const float* __restrict__ A_k, const float* __restrict__ A_v,
                          const float* __restrict__ scale,
                          _Float16* __restrict__ WqT, _Float16* __restrict__ WeT,
                          _Float16* __restrict__ WaT, float* __restrict__ bias_big) {
  int j = blockIdx.x;   // 0..639
  int c = threadIdx.x;  // 0..63
  int t, jj, bofs;
  _Float16* W;
  if (j < 192)      { t = 0; jj = j;       W = WqT; bofs = 0; }
  else if (j < 512) { t = 2; jj = j - 192; W = WeT; bofs = 192; }
  else              { t = 1; jj = j - 512; W = WaT; bofs = 512; }
  const float* Wt = W_kqv + (size_t)t * 64 * 192;
  const float* b2 = bias2 + t * 192;
  int mode = 0, rel = 0, sub = 0;
  if (t == 1) { mode = 1; rel = (jj < 64) ? 2 : 3; sub = jj & 63; }
  else if (jj >= 64 && jj < 128) { mode = 1; rel = (t == 0) ? 0 : 1; sub = jj - 64; }
  else if (jj >= 128) {
    mode = 2; sub = (jj - 128) & 63;
    rel = (t == 0) ? 3 : ((jj - 128) >> 6);
  }
  int h = sub >> 5, x = sub & 31;
  float wv, bv;
  if (mode == 0) {
    wv = Wt[(size_t)c * 192 + jj];
    bv = b2[jj];
  } else if (mode == 1) {
    const float* Ar = A_k + ((size_t)rel * 2048 + h * 1024 + x * 32);
    float s = 0.f, sb = 0.f;
    for (int f = 0; f < 32; ++f) {
      float a = Ar[f];
      s = fmaf(a, Wt[(size_t)c * 192 + 64 + h * 32 + f], s);
      sb = fmaf(a, b2[64 + h * 32 + f], sb);
    }
    wv = s; bv = sb;
  } else {
    const float* Ar = A_v + ((size_t)rel * 2048 + h * 1024 + x);
    float s = 0.f, sb = 0.f;
    for (int d = 0; d < 32; ++d) {
      float a = Ar[d * 32];
      s = fmaf(a, Wt[(size_t)c * 192 + 128 + h * 32 + d], s);
      sb = fmaf(a, b2[128 + h * 32 + d], sb);
    }
    wv = s; bv = sb;
  }
  wv *= scale[t * 64 + c];
  W[(size_t)jj * 72 + c] = (_Float16)wv;
  if (c < 8) W[(size_t)jj * 72 + 64 + c] = (_Float16)0.f;
  if (c == 0) bias_big[bofs + jj] = bv;
}

__global__ void wprep_in(const float* __restrict__ W_in, _Float16* __restrict__ WinT) {
  int t = blockIdx.x >> 6, n = blockIdx.x & 63, k = threadIdx.x;  // k 0..135
  float v = (k < 128) ? W_in[(size_t)t * 128 * 64 + (size_t)k * 64 + n] : 0.f;
  WinT[((size_t)t * 64 + n) * 136 + k] = (_Float16)v;
}

__global__ void wprep_out(const float* __restrict__ W_out, _Float16* __restrict__ WoutT) {
  int t = blockIdx.x >> 6, n = blockIdx.x & 63, k = threadIdx.x;  // k 0..71
  float v = (k < 64) ? W_out[(size_t)t * 64 * 64 + (size_t)k * 64 + n] : 0.f;
  WoutT[((size_t)t * 64 + n) * 72 + k] = (_Float16)v;
}

// ---------------- CSR build ----------------

__global__ void hist_kernel(const int* __restrict__ dst, int E,
                            unsigned* __restrict__ cnt, int base) {
  int i = blockIdx.x * blockDim.x + threadIdx.x;
  int stride = gridDim.x * blockDim.x;
  for (; i < E; i += stride) atomicAdd(&cnt[base + dst[i]], 1u);
}

__global__ __launch_bounds__(256) void scan1(unsigned* __restrict__ arr, int n,
                                             unsigned* __restrict__ bsums) {
  __shared__ unsigned sh[256];
  int t = threadIdx.x;
  int base = blockIdx.x * 1024 + t * 4;
  unsigned v[4];
  unsigned s = 0;
#pragma unroll
  for (int j = 0; j < 4; ++j) {
    v[j] = (base + j < n) ? arr[base + j] : 0u;
    s += v[j];
  }
  sh[t] = s;
  __syncthreads();
  for (int off = 1; off < 256; off <<= 1) {
    unsigned x = (t >= off) ? sh[t - off] : 0u;
    __syncthreads();
    sh[t] += x;
    __syncthreads();
  }
  unsigned run = sh[t] - s;
#pragma unroll
  for (int j = 0; j < 4; ++j) {
    if (base + j < n) arr[base + j] = run;
    run += v[j];
  }
  if (t == 255) bsums[blockIdx.x] = sh[255];
}

__global__ __launch_bounds__(256) void scan2(unsigned* __restrict__ bsums, int nb) {
  __shared__ unsigned sh[256];
  __shared__ unsigned carry;
  int t = threadIdx.x;
  if (t == 0) carry = 0;
  __syncthreads();
  for (int chunk = 0; chunk < nb; chunk += 256) {
    int i = chunk + t;
    unsigned v = (i < nb) ? bsums[i] : 0u;
    sh[t] = v;
    __syncthreads();
    for (int off = 1; off < 256; off <<= 1) {
      unsigned x = (t >= off) ? sh[t - off] : 0u;
      __syncthreads();
      sh[t] += x;
      __syncthreads();
    }
    unsigned inc = sh[t];
    unsigned c = carry;
    __syncthreads();
    if (i < nb) bsums[i] = c + inc - v;
    if (t == 255) carry = c + sh[255];
    __syncthreads();
  }
}

__global__ __launch_bounds__(256) void scan3(unsigned* __restrict__ arr,
                                             const unsigned* __restrict__ bsums,
                                             unsigned* __restrict__ cursor, int n) {
  int t = threadIdx.x;
  int base = blockIdx.x * 1024 + t * 4;
  unsigned add = bsums[blockIdx.x];
#pragma unroll
  for (int j = 0; j < 4; ++j) {
    int idx = base + j;
    if (idx < n) {
      unsigned r = arr[idx] + add;
      arr[idx] = r;
      cursor[idx] = r;
    }
  }
}

// payload = src elem-offset (src*ld) | slot<<31
__global__ void scatter_kernel(const int* __restrict__ src, const int* __restrict__ dst, int E,
                               unsigned* __restrict__ cursor, unsigned* __restrict__ eidx,
                               int dstbase, int srcld, unsigned slot) {
  int i = blockIdx.x * blockDim.x + threadIdx.x;
  int stride = gridDim.x * blockDim.x;
  for (; i < E; i += stride) {
    unsigned pos = atomicAdd(&cursor[dstbase + dst[i]], 1u);
    eidx[pos] = (unsigned)(src[i] * srcld) | (slot << 31);
  }
}

// ---------------- gather: softmax-weighted aggregation per dst node ----------------
// Payloads are pre-multiplied element offsets; score via packed v_dot2 (4-step reduce).
// Distance-2 node pipeline; eidx padded by 8 for speculative payload-word loads
// (garbage payloads are never dereferenced).

template <int NREL>
__global__ __launch_bounds__(256) void gather_kernel(
    int N, int nodebase,
    const unsigned* __restrict__ row_start, const unsigned* __restrict__ row_end,
    const unsigned* __restrict__ eidx,
    const _Float16* __restrict__ baseA, int vofA,
    const _Float16* __restrict__ baseB, int vofB,
    const _Float16* __restrict__ qtA, int ldqA,
    const _Float16* __restrict__ qtB, int ldqB,
    const float* __restrict__ prelA, const float* __restrict__ prelB,
    _Float16* __restrict__ agg)
{
  int lane = threadIdx.x & 63;
  int h = lane >> 5, f = lane & 31;
  int idx2 = h * 32 + 2 * (f & 15);     // packed half2 index for k/q dot
  const float isd = 0.17677669529663687f;
  float pr0 = prelA[h] * isd;
  float pr1 = (NREL == 2) ? prelB[h] * isd : 0.f;

  int wid = (int)((blockIdx.x * blockDim.x + threadIdx.x) >> 6);
  int nw = (int)((gridDim.x * blockDim.x) >> 6);

  int n0 = wid;
  unsigned b0s = 0, b0e = 0, e00 = 0, e01 = 0;
  half2_t q00p = {}, q01p = {};
  if (n0 < N) {
    b0s = row_start[nodebase + n0];
    b0e = row_end[nodebase + n0];
    q00p = *(const half2_t*)&qtA[(size_t)n0 * ldqA + idx2];
    if (NREL == 2) q01p = *(const half2_t*)&qtB[(size_t)n0 * ldqB + idx2];
    e00 = eidx[b0s];
    e01 = eidx[b0s + 1];
  }
  int n1 = n0 + nw;
  unsigned b1s = 0, b1e = 0;
  half2_t q10p = {}, q11p = {};
  if (n0 < N && n1 < N) {
    b1s = row_start[nodebase + n1];
    b1e = row_end[nodebase + n1];
    q10p = *(const half2_t*)&qtA[(size_t)n1 * ldqA + idx2];
    if (NREL == 2) q11p = *(const half2_t*)&qtB[(size_t)n1 * ldqB + idx2];
  }

  while (n0 < N) {
    unsigned e10 = 0, e11 = 0;
    if (n1 < N) {
      e10 = eidx[b1s];
      e11 = eidx[b1s + 1];
    }
    int n2 = n1 + nw;
    unsigned b2s = 0, b2e = 0;
    half2_t q20p = {}, q21p = {};
    if (n2 < N) {
      b2s = row_start[nodebase + n2];
      b2e = row_end[nodebase + n2];
      q20p = *(const half2_t*)&qtA[(size_t)n2 * ldqA + idx2];
      if (NREL == 2) q21p = *(const half2_t*)&qtB[(size_t)n2 * ldqB + idx2];
    }

    float vs = 0.f, ss = 0.f;
    unsigned i = b0s;

    auto do_pair = [&](unsigned p1, unsigned p2) {
      unsigned o1 = p1 & 0x7FFFFFFFu, o2 = p2 & 0x7FFFFFFFu;
      bool r1 = (NREL == 2) && (p1 >> 31);
      bool r2 = (NREL == 2) && (p2 >> 31);
      const _Float16* b1 = (r1 ? baseB : baseA) + o1;
      const _Float16* b2 = (r2 ? baseB : baseA) + o2;
      half2_t k21 = *(const half2_t*)&b1[idx2];
      float v1 = (float)b1[(r1 ? vofB : vofA) + lane];
      half2_t k22 = *(const half2_t*)&b2[idx2];
      float v2 = (float)b2[(r2 ? vofB : vofA) + lane];
      float sa = __builtin_amdgcn_fdot2(k21, r1 ? q01p : q00p, 0.f, false);
      float sb = __builtin_amdgcn_fdot2(k22, r2 ? q01p : q00p, 0.f, false);
#pragma unroll
      for (int off = 1; off <= 8; off <<= 1) {
        sa += __shfl_xor(sa, off, 32);
        sb += __shfl_xor(sb, off, 32);
      }
      float w1 = __expf(sa * (r1 ? pr1 : pr0));
      float w2 = __expf(sb * (r2 ? pr1 : pr0));
      ss += w1 + w2;
      vs = fmaf(w1, v1, vs);
      vs = fmaf(w2, v2, vs);
    };
    auto do_single = [&](unsigned p1) {
      unsigned o1 = p1 & 0x7FFFFFFFu;
      bool r1 = (NREL == 2) && (p1 >> 31);
      const _Float16* b1 = (r1 ? baseB : baseA) + o1;
      half2_t k21 = *(const half2_t*)&b1[idx2];
      float v1 = (float)b1[(r1 ? vofB : vofA) + lane];
      float sa = __builtin_amdgcn_fdot2(k21, r1 ? q01p : q00p, 0.f, false);
#pragma unroll
      for (int off = 1; off <= 8; off <<= 1) sa += __shfl_xor(sa, off, 32);
      float w1 = __expf(sa * (r1 ? pr1 : pr0));
      ss += w1;
      vs = fmaf(w1, v1, vs);
    };

    if (i + 2 <= b0e) { do_pair(e00, e01); i += 2; }
    else if (i < b0e) { do_single(e00); i = b0e; }
    for (; i + 2 <= b0e; i += 2) do_pair(eidx[i], eidx[i + 1]);
    if (i < b0e) do_single(eidx[i]);

    float val = (ss > 0.f) ? vs / ss : 0.f;
    val = fast_gelu(val);
    agg[((size_t)(nodebase + n0)) * 64 + lane] = (_Float16)val;

    n0 = n1; b0s = b1s; b0e = b1e; q00p = q10p; q01p = q11p; e00 = e10; e01 = e11;
    n1 = n2; b1s = b2s; b1e = b2e; q10p = q20p; q11p = q21p;
  }
}

// ---------------- final predictions ----------------

__global__ void pred_kernel(const int* __restrict__ qi, const int* __restrict__ ai, int Np,
                            const float* __restrict__ zq, const float* __restrict__ za,
                            float* __restrict__ outp) {
  int i = blockIdx.x * blockDim.x + threadIdx.x;
  if (i >= Np) return;
  const float4* a = (const float4*)(zq + (size_t)qi[i] * 64);
  const float4* b = (const float4*)(za + (size_t)ai[i] * 64);
  float ssum = 0.f;
#pragma unroll
  for (int j = 0; j < 16; ++j) {
    float4 x = a[j], y = b[j];
    ssum += x.x * y.x + x.y * y.y + x.z * y.z + x.w * y.w;
  }
  outp[i] = ssum;
}

// ---------------- host launch ----------------

extern "C" void kernel_launch(void* const* d_in, const int* in_sizes, int n_in,
                              void* d_out, int out_size, void* d_ws, size_t ws_size,
                              hipStream_t stream) {
  const float* xq = (const float*)d_in[0];
  const float* xa = (const float*)d_in[1];
  const float* xe = (const float*)d_in[2];
  const int* e_e2q = (const int*)d_in[3];
  const int* e_e2e = (const int*)d_in[4];
  const int* e_e2a = (const int*)d_in[5];
  const int* e_q2a = (const int*)d_in[6];
  const int* pos_idx = (const int*)d_in[7];
  const int* neg_idx = (const int*)d_in[8];
  const float* W_in = (const float*)d_in[9];
  const float* b_in = (const float*)d_in[10];
  const float* bn_gamma = (const float*)d_in[11];
  const float* bn_beta = (const float*)d_in[12];
  const float* W_kqv = (const float*)d_in[13];
  const float* b_kqv = (const float*)d_in[14];
  const float* A_k = (const float*)d_in[15];
  const float* A_v = (const float*)d_in[16];
  const float* p_rel = (const float*)d_in[17];
  const float* W_out = (const float*)d_in[18];
  const float* b_out = (const float*)d_in[19];
  const float* skip = (const float*)d_in[20];
  float* out = (float*)d_out;

  float* ws = (float*)d_ws;
  size_t off = 0;
  _Float16* y_h = (_Float16*)(ws + off);    off += (size_t)NT_TOTAL * 32;
  _Float16* kqvQ = (_Float16*)(ws + off);   off += (size_t)NQ * 96;    // [NQ][192]
  _Float16* kqvE = (_Float16*)(ws + off);   off += (size_t)NE * 160;   // [NE][320]
  _Float16* kqvA = (_Float16*)(ws + off);   off += (size_t)NA * 64;    // [NA][128]
  _Float16* agg_h = (_Float16*)(ws + off);  off += (size_t)NT_TOTAL * 32;
  float* stats = ws + off;                  off += 384;
  float* scale = ws + off;                  off += 192;
  float* shift = ws + off;                  off += 192;
  float* bias2 = ws + off;                  off += 576;
  float* bias_big = ws + off;               off += 640;
  _Float16* WqT = (_Float16*)(ws + off);    off += 192 * 72 / 2;
  _Float16* WeT = (_Float16*)(ws + off);    off += 320 * 72 / 2;
  _Float16* WaT = (_Float16*)(ws + off);    off += 128 * 72 / 2;
  _Float16* WinT = (_Float16*)(ws + off);   off += 3 * 64 * 136 / 2;
  _Float16* WoutT = (_Float16*)(ws + off);  off += 3 * 64 * 72 / 2;
  float* bstats = ws + off;                 off += (size_t)(GIN_Q + GIN_A + GIN_E) * 128;
  unsigned* row_start = (unsigned*)(ws + off); off += NT_TOTAL;
  unsigned* cursor = (unsigned*)(ws + off);    off += NT_TOTAL;
  unsigned* bsums = (unsigned*)(ws + off);     off += 1024;
  unsigned* eidx = (unsigned*)(ws + off);      off += E_TOTAL + 8;  // +8 pad

  const int Ns[3] = {NQ, NA, NE};
  const float* xs[3] = {xq, xa, xe};
  const int gin[3] = {GIN_Q, GIN_A, GIN_E};
  const int bb[3] = {0, GIN_Q, GIN_Q + GIN_A};
  _Float16* yhb[3] = {y_h, y_h + (size_t)NQ * 64, y_h + (size_t)(NQ + NA) * 64};
  _Float16* aggb[3] = {agg_h, agg_h + (size_t)NQ * 64, agg_h + (size_t)(NQ + NA) * 64};
  float* zq_out = out + (N_POS + N_NEG);
  float* zbase[3] = {zq_out, zq_out + (size_t)NQ * 64, zq_out + (size_t)(NQ + NA) * 64};

  fill_kernel<<<dim3(128), dim3(256), 0, stream>>>((float*)row_start, 0.f, NT_TOTAL);
  wprep_in<<<dim3(192), dim3(136), 0, stream>>>(W_in, WinT);
  wprep_out<<<dim3(192), dim3(72), 0, stream>>>(W_out, WoutT);

  // ---- in-proj (LDS-staged MFMA, 3 blocks/CU) + relu -> y fp16, fused bstats ----
  for (int t = 0; t < 3; ++t) {
    gemm_inproj<<<dim3(gin[t]), dim3(256), SMEM_INPROJ, stream>>>(
        xs[t], WinT + (size_t)t * 64 * 136, b_in + t * 64, Ns[t], CDIV(Ns[t], 64),
        yhb[t], bstats + (size_t)bb[t] * 128);
  }
  stats_reduce<<<dim3(384), dim3(256), 0, stream>>>(bstats, stats);
  bn_finalize<<<dim3(1), dim3(192), 0, stream>>>(stats, bn_gamma, bn_beta, scale, shift);
  kqv_bias2<<<dim3(3), dim3(192), 0, stream>>>(b_kqv, W_kqv, shift, bias2);
  wprep_kqv<<<dim3(640), dim3(64), 0, stream>>>(W_kqv, bias2, A_k, A_v, scale,
                                                WqT, WeT, WaT, bias_big);

  // ---- kqv projections (staged 8-wave; entity split into 2 col-tiles) ----
  gemm_mfma<256, 192, 64><<<dim3(CDIV(NQ, 256)), dim3(512), 0, stream>>>(
      yhb[0], WqT, bias_big, NQ, kqvQ, 192);
  gemm_mfma<256, 160, 64><<<dim3(CDIV(NE, 256), 2), dim3(512), 0, stream>>>(
      yhb[2], WeT, bias_big + 192, NE, kqvE, 320);
  gemm_mfma<256, 128, 64><<<dim3(CDIV(NA, 256)), dim3(512), 0, stream>>>(
      yhb[1], WaT, bias_big + 512, NA, kqvA, 128);

  // ---- CSR build ----
  struct Rel { const int* ei; int E; int dstbase; int srcld; unsigned slot; };
  Rel rels[4] = {{e_e2q, E_E2Q, BASE_Q, 320, 0u},
                 {e_e2e, E_E2E, BASE_E, 320, 0u},
                 {e_e2a, E_E2A, BASE_A, 320, 0u},
                 {e_q2a, E_Q2A, BASE_A, 192, 1u}};
  for (int r = 0; r < 4; ++r) {
    int blocks = CDIV(rels[r].E, 256); if (blocks > 2048) blocks = 2048;
    hist_kernel<<<dim3(blocks), dim3(256), 0, stream>>>(rels[r].ei + rels[r].E, rels[r].E,
                                                        row_start, rels[r].dstbase);
  }
  scan1<<<dim3(NBLK_SCAN), dim3(256), 0, stream>>>(row_start, NT_TOTAL, bsums);
  scan2<<<dim3(1), dim3(256), 0, stream>>>(bsums, NBLK_SCAN);
  scan3<<<dim3(NBLK_SCAN), dim3(256), 0, stream>>>(row_start, bsums, cursor, NT_TOTAL);
  for (int r = 0; r < 4; ++r) {
    int blocks = CDIV(rels[r].E, 256); if (blocks > 2048) blocks = 2048;
    scatter_kernel<<<dim3(blocks), dim3(256), 0, stream>>>(
        rels[r].ei, rels[r].ei + rels[r].E, rels[r].E, cursor, eidx,
        rels[r].dstbase, rels[r].srcld, rels[r].slot);
  }

  // ---- gathers (offset payloads + dot2 score) ----
  gather_kernel<1><<<dim3(CDIV(NQ, 4)), dim3(256), 0, stream>>>(
      NQ, BASE_Q, row_start, cursor, eidx,
      kqvE, 128, nullptr, 0,
      kqvQ + 64, 192, nullptr, 0, p_rel + 0, p_rel + 0, agg_h);
  gather_kernel<1><<<dim3(4096), dim3(256), 0, stream>>>(
      NE, BASE_E, row_start, cursor, eidx,
      kqvE, 192, nullptr, 0,
      kqvE + 64, 320, nullptr, 0, p_rel + 2, p_rel + 2, agg_h);
  gather_kernel<2><<<dim3(CDIV(NA, 4)), dim3(256), 0, stream>>>(
      NA, BASE_A, row_start, cursor, eidx,
      kqvE, 256, kqvQ, 128,
      kqvA, 128, kqvA + 64, 128, p_rel + 4, p_rel + 6, agg_h);

  // ---- out projection (direct-A MFMA) + skip blend -> fp32 z ----
  for (int t = 0; t < 3; ++t) {
    gemm_direct<64, 64, 3><<<dim3(CDIV(Ns[t], 128)), dim3(256), 0, stream>>>(
        nullptr, aggb[t], WoutT + (size_t)t * 64 * 72, b_out + t * 64, Ns[t],
        nullptr, 0, zbase[t], nullptr,
        yhb[t], scale + t * 64, shift + t * 64, skip, t);
  }

  // ---- predictions ----
  pred_kernel<<<dim3(CDIV(N_POS, 256)), dim3(256), 0, stream>>>(
      pos_idx, pos_idx + N_POS, N_POS, zbase[0], zbase[1], out);
  pred_kernel<<<dim3(CDIV(N_NEG, 256)), dim3(256), 0, stream>>>(
      neg_idx, neg_idx + N_NEG, N_NEG, zbase[0], zbase[1], out + N_POS);
}

// Round 16
// 738.456 us; speedup vs baseline: 2.6192x; 1.0123x over previous
//
#include <hip/hip_runtime.h>
#include <hip/hip_bf16.h>
#include <hip/hip_fp16.h>
#include <math.h>

#define NQ 8192
#define NA 32768
#define NE 500000
#define F_IN 128
#define E_E2Q 131072
#define E_E2E 800000
#define E_E2A 262144
#define E_Q2A 32768
#define N_POS 8192
#define N_NEG 24576

#define NT_TOTAL (NQ + NA + NE)                      // 540960
#define E_TOTAL (E_E2Q + E_E2E + E_E2A + E_Q2A)      // 1225984
#define NBLK_SCAN ((NT_TOTAL + 1023) / 1024)         // 529
#define CDIV(a, b) (((a) + (b) - 1) / (b))

// dst node index space: [question: 0) [answer: NQ) [entity: NQ+NA)
#define BASE_Q 0
#define BASE_A NQ
#define BASE_E (NQ + NA)

// in-proj grids (64-row tiles; 1 block per bstats row)
#define GIN_Q 128
#define GIN_A 512
#define GIN_E 768
#define SMEM_INPROJ (32768 + 17408 + 512)

typedef _Float16 half8_t __attribute__((ext_vector_type(8)));
typedef _Float16 half4_t __attribute__((ext_vector_type(4)));
typedef _Float16 half2_t __attribute__((ext_vector_type(2)));
typedef float f32x4_t __attribute__((ext_vector_type(4)));

__device__ inline void load_lds16(const void* g, void* l) {
  __builtin_amdgcn_global_load_lds((const __attribute__((address_space(1))) void*)g,
                                   (__attribute__((address_space(3))) void*)l, 16, 0, 0);
}

__device__ inline float fast_gelu(float v) {
  float u = 1.5957691216057308f * fmaf(0.044715f * v * v, v, v);
  return v / (1.f + __expf(-u));
}

// ---------------- utility ----------------

__global__ void fill_kernel(float* __restrict__ p, float v, size_t n) {
  size_t i = (size_t)blockIdx.x * blockDim.x + threadIdx.x;
  size_t stride = (size_t)gridDim.x * blockDim.x;
  for (; i < n; i += stride) p[i] = v;
}

// ---------------- in-proj: LDS-staged fp32 A (global_load_lds), MFMA, fused bstats ----------------

__global__ __launch_bounds__(256) void gemm_inproj(
    const float* __restrict__ Af, const _Float16* __restrict__ WT,
    const float* __restrict__ bias, int M, int ntiles,
    _Float16* __restrict__ oh, float* __restrict__ bstats)
{
  extern __shared__ char smem[];
  float* As32 = (float*)smem;                       // 64 x 128 fp32 = 32KB
  _Float16* Bs = (_Float16*)(smem + 32768);         // 64 x 136 fp16
  float* s1 = (float*)(smem + 32768 + 17408);
  float* s2 = s1 + 64;

  int tid = threadIdx.x;
  int w = tid >> 6, l = tid & 63;
  int lr = l & 15, lg = l >> 4;

  for (int idx = tid; idx < 64 * 136 / 8; idx += 256)
    *(half8_t*)&Bs[idx * 8] = *(const half8_t*)&WT[(size_t)idx * 8];
  if (tid < 64) { s1[tid] = 0.f; s2[tid] = 0.f; }

  float ps1[4] = {}, ps2[4] = {};
  float bval[4];
#pragma unroll
  for (int ct = 0; ct < 4; ++ct) bval[ct] = bias[ct * 16 + lr];

  for (int tile = blockIdx.x; tile < ntiles; tile += gridDim.x) {
    const char* srcbase = (const char*)Af + (size_t)tile * 64 * 512;
    int rowlim = M - tile * 64;
#pragma unroll
    for (int r = 0; r < 8; ++r) {
      int unit = r * 4 + w;
      char* ldst = (char*)As32 + unit * 1024;
      int p = unit * 1024 + l * 16;
      int row = p >> 9;
      const char* src = (row < rowlim) ? srcbase + (size_t)row * 512 + (p & 511)
                                       : srcbase;
      load_lds16(src, ldst);
    }
    __syncthreads();

    f32x4_t acc[4] = {};
#pragma unroll
    for (int ks = 0; ks < 4; ++ks) {
      const float4* pa = (const float4*)((const char*)As32 +
                          (w * 16 + lr) * 512 + ks * 128 + lg * 32);
      float4 x0 = pa[0], x1 = pa[1];
      half8_t a0 = {(_Float16)x0.x, (_Float16)x0.y, (_Float16)x0.z, (_Float16)x0.w,
                    (_Float16)x1.x, (_Float16)x1.y, (_Float16)x1.z, (_Float16)x1.w};
#pragma unroll
      for (int ct = 0; ct < 4; ++ct) {
        half8_t b = *(const half8_t*)&Bs[(ct * 16 + lr) * 136 + ks * 32 + lg * 8];
        acc[ct] = __builtin_amdgcn_mfma_f32_16x16x32_f16(a0, b, acc[ct], 0, 0, 0);
      }
    }

    int rbase = tile * 64 + w * 16 + lg * 4;
#pragma unroll
    for (int ct = 0; ct < 4; ++ct) {
      int col = ct * 16 + lr;
#pragma unroll
      for (int j = 0; j < 4; ++j) {
        int row = rbase + j;
        if (row >= M) continue;
        float val = fmaxf(acc[ct][j] + bval[ct], 0.f);
        oh[(size_t)row * 64 + col] = (_Float16)val;
        ps1[ct] += val;
        ps2[ct] += val * val;
      }
    }
    __syncthreads();
  }

#pragma unroll
  for (int ct = 0; ct < 4; ++ct) {
    atomicAdd(&s1[ct * 16 + lr], ps1[ct]);
    atomicAdd(&s2[ct * 16 + lr], ps2[ct]);
  }
  __syncthreads();
  if (tid < 64) {
    bstats[(size_t)blockIdx.x * 128 + tid] = s1[tid];
    bstats[(size_t)blockIdx.x * 128 + 64 + tid] = s2[tid];
  }
}

// ---------------- direct-A MFMA GEMM (out-proj, MODE 3) ----------------

template <int BNT, int KTOT, int MODE>
__global__ __launch_bounds__(256) void gemm_direct(
    const float* __restrict__ Af, const _Float16* __restrict__ Ah,
    const _Float16* __restrict__ WT, const float* __restrict__ bias, int M,
    _Float16* __restrict__ oh, int LDO,
    float* __restrict__ Cf,
    float* __restrict__ bstats,
    const _Float16* __restrict__ resh, const float* __restrict__ rsc,
    const float* __restrict__ rsh, const float* __restrict__ skip_ptr, int skip_idx)
{
  constexpr int KP = KTOT + 8;
  __shared__ _Float16 Bs[BNT * KP];
  int tid = threadIdx.x;
  int w = tid >> 6, l = tid & 63;
  int lr = l & 15, lg = l >> 4;
  int row0 = blockIdx.x * 128;

  for (int idx = tid; idx < BNT * KP / 8; idx += 256)
    *(half8_t*)&Bs[idx * 8] = *(const half8_t*)&WT[(size_t)idx * 8];

  constexpr int NKS = KTOT / 32;
  half8_t afrag[2][NKS];
#pragma unroll
  for (int rt = 0; rt < 2; ++rt) {
    int gr = row0 + w * 32 + rt * 16 + lr;
    bool ok = gr < M;
#pragma unroll
    for (int ks = 0; ks < NKS; ++ks) {
      half8_t h8 = {};
      if (ok) h8 = *(const half8_t*)&Ah[(size_t)gr * KTOT + ks * 32 + lg * 8];
      afrag[rt][ks] = h8;
    }
  }
  __syncthreads();

  constexpr int NCT = BNT / 16;
  f32x4_t acc[2][NCT] = {};
#pragma unroll
  for (int ks = 0; ks < NKS; ++ks) {
#pragma unroll
    for (int ct = 0; ct < NCT; ++ct) {
      half8_t b = *(const half8_t*)&Bs[(ct * 16 + lr) * KP + ks * 32 + lg * 8];
      acc[0][ct] = __builtin_amdgcn_mfma_f32_16x16x32_f16(afrag[0][ks], b, acc[0][ct], 0, 0, 0);
      acc[1][ct] = __builtin_amdgcn_mfma_f32_16x16x32_f16(afrag[1][ks], b, acc[1][ct], 0, 0, 0);
    }
  }

  float g = 1.f / (1.f + __expf(-skip_ptr[skip_idx]));
  float gb = 1.f - g;
#pragma unroll
  for (int rt = 0; rt < 2; ++rt) {
    int rbase = row0 + w * 32 + rt * 16 + lg * 4;
#pragma unroll
    for (int ct = 0; ct < NCT; ++ct) {
      int col = ct * 16 + lr;
      float bval = bias[col];
#pragma unroll
      for (int j = 0; j < 4; ++j) {
        int row = rbase + j;
        if (row >= M) continue;
        float val = acc[rt][ct][j] + bval;
        float rv = (float)resh[(size_t)row * 64 + col];
        Cf[(size_t)row * 64 + col] = g * val + gb * (rsc[col] * rv + rsh[col]);
      }
    }
  }
}

// ---------------- staged MFMA GEMM (kqv, 8 waves, col-tiled, LDS-transposed stores) ----------------

template <int BM, int BNT, int KTOT>
__global__ __launch_bounds__(BM * 2) void gemm_mfma(
    const _Float16* __restrict__ Ah,
    const _Float16* __restrict__ WT, const float* __restrict__ bias, int M,
    _Float16* __restrict__ oh, int LDO)
{
  constexpr int KP = KTOT + 8;
  constexpr int NTHR = BM * 2;
  constexpr int TP = BNT + 8;
  constexpr int SZ_AB = (BM * KP + BNT * KP) * 2;
  constexpr int SZ_T = 128 * TP * 2;
  constexpr int SZ = SZ_AB > SZ_T ? SZ_AB : SZ_T;
  __shared__ __align__(16) char smem[SZ];
  _Float16* As = (_Float16*)smem;
  _Float16* Bs = As + BM * KP;
  _Float16* Ts = (_Float16*)smem;   // overlays As/Bs after compute
  int tid = threadIdx.x;
  int row0 = blockIdx.x * BM;
  int colbase = blockIdx.y * BNT;

  {
    constexpr int CH = KTOT / 8;
    for (int idx = tid; idx < BM * CH; idx += NTHR) {
      int row = idx / CH, c = idx % CH;
      int gr = row0 + row;
      half8_t a8 = {};
      if (gr < M) a8 = *(const half8_t*)&Ah[(size_t)gr * KTOT + c * 8];
      *(half8_t*)&As[row * KP + c * 8] = a8;
    }
  }
  {
    const _Float16* wsrc = WT + (size_t)colbase * KP;
    for (int idx = tid; idx < BNT * KP / 8; idx += NTHR)
      *(half8_t*)&Bs[idx * 8] = *(const half8_t*)&wsrc[(size_t)idx * 8];
  }
  __syncthreads();

  int w = tid >> 6, l = tid & 63;
  int lr = l & 15, lg = l >> 4;
  constexpr int NCT = BNT / 16;
  constexpr int NKS = KTOT / 32;
  f32x4_t acc[2][NCT] = {};
#pragma unroll
  for (int ks = 0; ks < NKS; ++ks) {
    half8_t a0 = *(const half8_t*)&As[(w * 32 + lr) * KP + ks * 32 + lg * 8];
    half8_t a1 = *(const half8_t*)&As[(w * 32 + 16 + lr) * KP + ks * 32 + lg * 8];
#pragma unroll
    for (int ct = 0; ct < NCT; ++ct) {
      half8_t b = *(const half8_t*)&Bs[(ct * 16 + lr) * KP + ks * 32 + lg * 8];
      acc[0][ct] = __builtin_amdgcn_mfma_f32_16x16x32_f16(a0, b, acc[0][ct], 0, 0, 0);
      acc[1][ct] = __builtin_amdgcn_mfma_f32_16x16x32_f16(a1, b, acc[1][ct], 0, 0, 0);
    }
  }

  // bias per ct (col = ct*16+lr)
  float bval[NCT];
#pragma unroll
  for (int ct = 0; ct < NCT; ++ct) bval[ct] = bias[colbase + ct * 16 + lr];

  // two passes: stage 128 rows (one rt) into LDS, then wide coalesced stores
#pragma unroll
  for (int rt = 0; rt < 2; ++rt) {
    __syncthreads();   // As/Bs (or previous Ts) no longer needed
    int r2base = w * 16 + lg * 4;  // local row in Ts
#pragma unroll
    for (int ct = 0; ct < NCT; ++ct) {
      int colL = ct * 16 + lr;
#pragma unroll
      for (int j = 0; j < 4; ++j)
        Ts[(r2base + j) * TP + colL] = (_Float16)(acc[rt][ct][j] + bval[ct]);
    }
    __syncthreads();
    constexpr int C8 = BNT / 8;
    for (int idx = tid; idx < 128 * C8; idx += NTHR) {
      int r2 = idx / C8, c8 = (idx % C8) * 8;
      int gr = row0 + (r2 >> 4) * 32 + rt * 16 + (r2 & 15);
      if (gr < M)
        *(half8_t*)&oh[(size_t)gr * LDO + colbase + c8] = *(const half8_t*)&Ts[r2 * TP + c8];
    }
  }
}

// ---------------- BN: reduce per-block stats ----------------

__global__ __launch_bounds__(256) void stats_reduce(const float* __restrict__ bstats,
                                                    float* __restrict__ stats) {
  __shared__ float sh[256];
  int t = blockIdx.x >> 7;
  int c = blockIdx.x & 127;
  int nb = (t == 0) ? GIN_Q : (t == 1) ? GIN_A : GIN_E;
  int base = (t == 0) ? 0 : (t == 1) ? GIN_Q : (GIN_Q + GIN_A);
  float s = 0.f;
  for (int i = threadIdx.x; i < nb; i += 256)
    s += bstats[(size_t)(base + i) * 128 + c];
  sh[threadIdx.x] = s;
  __syncthreads();
  for (int off2 = 128; off2 > 0; off2 >>= 1) {
    if (threadIdx.x < off2) sh[threadIdx.x] += sh[threadIdx.x + off2];
    __syncthreads();
  }
  if (threadIdx.x == 0) stats[t * 128 + c] = sh[0];
}

__global__ void bn_finalize(const float* __restrict__ stats,
                            const float* __restrict__ gamma, const float* __restrict__ beta,
                            float* __restrict__ scale, float* __restrict__ shift) {
  int t = threadIdx.x;
  if (t >= 192) return;
  int ty = t >> 6, c = t & 63;
  float invN = (ty == 0) ? (1.f / NQ) : (ty == 1) ? (1.f / NA) : (1.f / NE);
  float mu = stats[ty * 128 + c] * invN;
  float var = stats[ty * 128 + 64 + c] * invN - mu * mu;
  float rs = rsqrtf(var + 1e-5f);
  float gm = gamma[ty * 64 + c];
  scale[t] = gm * rs;
  shift[t] = beta[ty * 64 + c] - gm * mu * rs;
}

__global__ void kqv_bias2(const float* __restrict__ b_kqv, const float* __restrict__ W_kqv,
                          const float* __restrict__ shift, float* __restrict__ bias2) {
  int t = blockIdx.x, n = threadIdx.x;
  float s = b_kqv[t * 192 + n];
  for (int k = 0; k < 64; ++k)
    s += shift[t * 64 + k] * W_kqv[(size_t)t * 64 * 192 + k * 192 + n];
  bias2[t * 192 + n] = s;
}

// ---------------- weight prep ----------------

__global__ void wprep_kqv(const float* __restrict__ W_kqv, const float* __restrict__ bias2,
                          const float* __restrict__ A_k, const float* __restrict__ A_v,
                          const float* __restrict__ scale,
                          _Float16* __restrict__ WqT, _Float16* __restrict__ WeT,
                          _Float16* __restrict__ WaT, float* __restrict__ bias_big) {
  int j = blockIdx.x;   // 0..639
  int c = threadIdx.x;  // 0..63
  int t, jj, bofs;
  _Float16* W;
  if (j < 192)      { t = 0; jj = j;       W = WqT; bofs = 0; }
  else if (j < 512) { t = 2; jj = j - 192; W = WeT; bofs = 192; }
  else              { t = 1; jj = j - 512; W = WaT; bofs = 512; }
  const float* Wt = W_kqv + (size_t)t * 64 * 192;
  const float* b2 = bias2 + t * 192;
  int mode = 0, rel = 0, sub = 0;
  if (t == 1) { mode = 1; rel = (jj < 64) ? 2 : 3; sub = jj & 63; }
  else if (jj >= 64 && jj < 128) { mode = 1; rel = (t == 0) ? 0 : 1; sub = jj - 64; }
  else if (jj >= 128) {
    mode = 2; sub = (jj - 128) & 63;
    rel = (t == 0) ? 3 : ((jj - 128) >> 6);
  }
  int h = sub >> 5, x = sub & 31;
  float wv, bv;
  if (mode == 0) {
    wv = Wt[(size_t)c * 192 + jj];
    bv = b2[jj];
  } else if (mode == 1) {
    const float* Ar = A_k + ((size_t)rel * 2048 + h * 1024 + x * 32);
    float s = 0.f, sb = 0.f;
    for (int f = 0; f < 32; ++f) {
      float a = Ar[f];
      s = fmaf(a, Wt[(size_t)c * 192 + 64 + h * 32 + f], s);
      sb = fmaf(a, b2[64 + h * 32 + f], sb);
    }
    wv = s; bv = sb;
  } else {
    const float* Ar = A_v + ((size_t)rel * 2048 + h * 1024 + x);
    float s = 0.f, sb = 0.f;
    for (int d = 0; d < 32; ++d) {
      float a = Ar[d * 32];
      s = fmaf(a, Wt[(size_t)c * 192 + 128 + h * 32 + d], s);
      sb = fmaf(a, b2[128 + h * 32 + d], sb);
    }
    wv = s; bv = sb;
  }
  wv *= scale[t * 64 + c];
  W[(size_t)jj * 72 + c] = (_Float16)wv;
  if (c < 8) W[(size_t)jj * 72 + 64 + c] = (_Float16)0.f;
  if (c == 0) bias_big[bofs + jj] = bv;
}

__global__ void wprep_in(const float* __restrict__ W_in, _Float16* __restrict__ WinT) {
  int t = blockIdx.x >> 6, n = blockIdx.x & 63, k = threadIdx.x;  // k 0..135
  float v = (k < 128) ? W_in[(size_t)t * 128 * 64 + (size_t)k * 64 + n] : 0.f;
  WinT[((size_t)t * 64 + n) * 136 + k] = (_Float16)v;
}

__global__ void wprep_out(const float* __restrict__ W_out, _Float16* __restrict__ WoutT) {
  int t = blockIdx.x >> 6, n = blockIdx.x & 63, k = threadIdx.x;  // k 0..71
  float v = (k < 64) ? W_out[(size_t)t * 64 * 64 + (size_t)k * 64 + n] : 0.f;
  WoutT[((size_t)t * 64 + n) * 72 + k] = (_Float16)v;
}

// ---------------- CSR build ----------------

__global__ void hist_kernel(const int* __restrict__ dst, int E,
                            unsigned* __restrict__ cnt, int base) {
  int i = blockIdx.x * blockDim.x + threadIdx.x;
  int stride = gridDim.x * blockDim.x;
  for (; i < E; i += stride) atomicAdd(&cnt[base + dst[i]], 1u);
}

__global__ __launch_bounds__(256) void scan1(unsigned* __restrict__ arr, int n,
                                             unsigned* __restrict__ bsums) {
  __shared__ unsigned sh[256];
  int t = threadIdx.x;
  int base = blockIdx.x * 1024 + t * 4;
  unsigned v[4];
  unsigned s = 0;
#pragma unroll
  for (int j = 0; j < 4; ++j) {
    v[j] = (base + j < n) ? arr[base + j] : 0u;
    s += v[j];
  }
  sh[t] = s;
  __syncthreads();
  for (int off = 1; off < 256; off <<= 1) {
    unsigned x = (t >= off) ? sh[t - off] : 0u;
    __syncthreads();
    sh[t] += x;
    __syncthreads();
  }
  unsigned run = sh[t] - s;
#pragma unroll
  for (int j = 0; j < 4; ++j) {
    if (base + j < n) arr[base + j] = run;
    run += v[j];
  }
  if (t == 255) bsums[blockIdx.x] = sh[255];
}

__global__ __launch_bounds__(256) void scan2(unsigned* __restrict__ bsums, int nb) {
  __shared__ unsigned sh[256];
  __shared__ unsigned carry;
  int t = threadIdx.x;
  if (t == 0) carry = 0;
  __syncthreads();
  for (int chunk = 0; chunk < nb; chunk += 256) {
    int i = chunk + t;
    unsigned v = (i < nb) ? bsums[i] : 0u;
    sh[t] = v;
    __syncthreads();
    for (int off = 1; off < 256; off <<= 1) {
      unsigned x = (t >= off) ? sh[t - off] : 0u;
      __syncthreads();
      sh[t] += x;
      __syncthreads();
    }
    unsigned inc = sh[t];
    unsigned c = carry;
    __syncthreads();
    if (i < nb) bsums[i] = c + inc - v;
    if (t == 255) carry = c + sh[255];
    __syncthreads();
  }
}

__global__ __launch_bounds__(256) void scan3(unsigned* __restrict__ arr,
                                             const unsigned* __restrict__ bsums,
                                             unsigned* __restrict__ cursor, int n) {
  int t = threadIdx.x;
  int base = blockIdx.x * 1024 + t * 4;
  unsigned add = bsums[blockIdx.x];
#pragma unroll
  for (int j = 0; j < 4; ++j) {
    int idx = base + j;
    if (idx < n) {
      unsigned r = arr[idx] + add;
      arr[idx] = r;
      cursor[idx] = r;
    }
  }
}

// payload = src elem-offset (src*ld) | slot<<31
__global__ void scatter_kernel(const int* __restrict__ src, const int* __restrict__ dst, int E,
                               unsigned* __restrict__ cursor, unsigned* __restrict__ eidx,
                               int dstbase, int srcld, unsigned slot) {
  int i = blockIdx.x * blockDim.x + threadIdx.x;
  int stride = gridDim.x * blockDim.x;
  for (; i < E; i += stride) {
    unsigned pos = atomicAdd(&cursor[dstbase + dst[i]], 1u);
    eidx[pos] = (unsigned)(src[i] * srcld) | (slot << 31);
  }
}

// ---------------- gather: softmax-weighted aggregation per dst node ----------------

template <int NREL>
__global__ __launch_bounds__(256) void gather_kernel(
    int N, int nodebase,
    const unsigned* __restrict__ row_start, const unsigned* __restrict__ row_end,
    const unsigned* __restrict__ eidx,
    const _Float16* __restrict__ baseA, int vofA,
    const _Float16* __restrict__ baseB, int vofB,
    const _Float16* __restrict__ qtA, int ldqA,
    const _Float16* __restrict__ qtB, int ldqB,
    const float* __restrict__ prelA, const float* __restrict__ prelB,
    _Float16* __restrict__ agg)
{
  int lane = threadIdx.x & 63;
  int h = lane >> 5, f = lane & 31;
  int idx2 = h * 32 + 2 * (f & 15);
  const float isd = 0.17677669529663687f;
  float pr0 = prelA[h] * isd;
  float pr1 = (NREL == 2) ? prelB[h] * isd : 0.f;

  int wid = (int)((blockIdx.x * blockDim.x + threadIdx.x) >> 6);
  int nw = (int)((gridDim.x * blockDim.x) >> 6);

  int n0 = wid;
  unsigned b0s = 0, b0e = 0, e00 = 0, e01 = 0;
  half2_t q00p = {}, q01p = {};
  if (n0 < N) {
    b0s = row_start[nodebase + n0];
    b0e = row_end[nodebase + n0];
    q00p = *(const half2_t*)&qtA[(size_t)n0 * ldqA + idx2];
    if (NREL == 2) q01p = *(const half2_t*)&qtB[(size_t)n0 * ldqB + idx2];
    e00 = eidx[b0s];
    e01 = eidx[b0s + 1];
  }
  int n1 = n0 + nw;
  unsigned b1s = 0, b1e = 0;
  half2_t q10p = {}, q11p = {};
  if (n0 < N && n1 < N) {
    b1s = row_start[nodebase + n1];
    b1e = row_end[nodebase + n1];
    q10p = *(const half2_t*)&qtA[(size_t)n1 * ldqA + idx2];
    if (NREL == 2) q11p = *(const half2_t*)&qtB[(size_t)n1 * ldqB + idx2];
  }

  while (n0 < N) {
    unsigned e10 = 0, e11 = 0;
    if (n1 < N) {
      e10 = eidx[b1s];
      e11 = eidx[b1s + 1];
    }
    int n2 = n1 + nw;
    unsigned b2s = 0, b2e = 0;
    half2_t q20p = {}, q21p = {};
    if (n2 < N) {
      b2s = row_start[nodebase + n2];
      b2e = row_end[nodebase + n2];
      q20p = *(const half2_t*)&qtA[(size_t)n2 * ldqA + idx2];
      if (NREL == 2) q21p = *(const half2_t*)&qtB[(size_t)n2 * ldqB + idx2];
    }

    float vs = 0.f, ss = 0.f;
    unsigned i = b0s;

    auto do_pair = [&](unsigned p1, unsigned p2) {
      unsigned o1 = p1 & 0x7FFFFFFFu, o2 = p2 & 0x7FFFFFFFu;
      bool r1 = (NREL == 2) && (p1 >> 31);
      bool r2 = (NREL == 2) && (p2 >> 31);
      const _Float16* b1 = (r1 ? baseB : baseA) + o1;
      const _Float16* b2 = (r2 ? baseB : baseA) + o2;
      half2_t k21 = *(const half2_t*)&b1[idx2];
      float v1 = (float)b1[(r1 ? vofB : vofA) + lane];
      half2_t k22 = *(const half2_t*)&b2[idx2];
      float v2 = (float)b2[(r2 ? vofB : vofA) + lane];
      float sa = __builtin_amdgcn_fdot2(k21, r1 ? q01p : q00p, 0.f, false);
      float sb = __builtin_amdgcn_fdot2(k22, r2 ? q01p : q00p, 0.f, false);
#pragma unroll
      for (int off = 1; off <= 8; off <<= 1) {
        sa += __shfl_xor(sa, off, 32);
        sb += __shfl_xor(sb, off, 32);
      }
      float w1 = __expf(sa * (r1 ? pr1 : pr0));
      float w2 = __expf(sb * (r2 ? pr1 : pr0));
      ss += w1 + w2;
      vs = fmaf(w1, v1, vs);
      vs = fmaf(w2, v2, vs);
    };
    auto do_single = [&](unsigned p1) {
      unsigned o1 = p1 & 0x7FFFFFFFu;
      bool r1 = (NREL == 2) && (p1 >> 31);
      const _Float16* b1 = (r1 ? baseB : baseA) + o1;
      half2_t k21 = *(const half2_t*)&b1[idx2];
      float v1 = (float)b1[(r1 ? vofB : vofA) + lane];
      float sa = __builtin_amdgcn_fdot2(k21, r1 ? q01p : q00p, 0.f, false);
#pragma unroll
      for (int off = 1; off <= 8; off <<= 1) sa += __shfl_xor(sa, off, 32);
      float w1 = __expf(sa * (r1 ? pr1 : pr0));
      ss += w1;
      vs = fmaf(w1, v1, vs);
    };

    if (i + 2 <= b0e) { do_pair(e00, e01); i += 2; }
    else if (i < b0e) { do_single(e00); i = b0e; }
    for (; i + 2 <= b0e; i += 2) do_pair(eidx[i], eidx[i + 1]);
    if (i < b0e) do_single(eidx[i]);

    float val = (ss > 0.f) ? vs / ss : 0.f;
    val = fast_gelu(val);
    agg[((size_t)(nodebase + n0)) * 64 + lane] = (_Float16)val;

    n0 = n1; b0s = b1s; b0e = b1e; q00p = q10p; q01p = q11p; e00 = e10; e01 = e11;
    n1 = n2; b1s = b2s; b1e = b2e; q10p = q20p; q11p = q21p;
  }
}

// ---------------- final predictions ----------------

__global__ void pred_kernel(const int* __restrict__ qi, const int* __restrict__ ai, int Np,
                            const float* __restrict__ zq, const float* __restrict__ za,
                            float* __restrict__ outp) {
  int i = blockIdx.x * blockDim.x + threadIdx.x;
  if (i >= Np) return;
  const float4* a = (const float4*)(zq + (size_t)qi[i] * 64);
  const float4* b = (const float4*)(za + (size_t)ai[i] * 64);
  float ssum = 0.f;
#pragma unroll
  for (int j = 0; j < 16; ++j) {
    float4 x = a[j], y = b[j];
    ssum += x.x * y.x + x.y * y.y + x.z * y.z + x.w * y.w;
  }
  outp[i] = ssum;
}

// ---------------- host launch ----------------

extern "C" void kernel_launch(void* const* d_in, const int* in_sizes, int n_in,
                              void* d_out, int out_size, void* d_ws, size_t ws_size,
                              hipStream_t stream) {
  const float* xq = (const float*)d_in[0];
  const float* xa = (const float*)d_in[1];
  const float* xe = (const float*)d_in[2];
  const int* e_e2q = (const int*)d_in[3];
  const int* e_e2e = (const int*)d_in[4];
  const int* e_e2a = (const int*)d_in[5];
  const int* e_q2a = (const int*)d_in[6];
  const int* pos_idx = (const int*)d_in[7];
  const int* neg_idx = (const int*)d_in[8];
  const float* W_in = (const float*)d_in[9];
  const float* b_in = (const float*)d_in[10];
  const float* bn_gamma = (const float*)d_in[11];
  const float* bn_beta = (const float*)d_in[12];
  const float* W_kqv = (const float*)d_in[13];
  const float* b_kqv = (const float*)d_in[14];
  const float* A_k = (const float*)d_in[15];
  const float* A_v = (const float*)d_in[16];
  const float* p_rel = (const float*)d_in[17];
  const float* W_out = (const float*)d_in[18];
  const float* b_out = (const float*)d_in[19];
  const float* skip = (const float*)d_in[20];
  float* out = (float*)d_out;

  float* ws = (float*)d_ws;
  size_t off = 0;
  _Float16* y_h = (_Float16*)(ws + off);    off += (size_t)NT_TOTAL * 32;
  _Float16* kqvQ = (_Float16*)(ws + off);   off += (size_t)NQ * 96;    // [NQ][192]
  _Float16* kqvE = (_Float16*)(ws + off);   off += (size_t)NE * 160;   // [NE][320]
  _Float16* kqvA = (_Float16*)(ws + off);   off += (size_t)NA * 64;    // [NA][128]
  _Float16* agg_h = (_Float16*)(ws + off);  off += (size_t)NT_TOTAL * 32;
  float* stats = ws + off;                  off += 384;
  float* scale = ws + off;                  off += 192;
  float* shift = ws + off;                  off += 192;
  float* bias2 = ws + off;                  off += 576;
  float* bias_big = ws + off;               off += 640;
  _Float16* WqT = (_Float16*)(ws + off);    off += 192 * 72 / 2;
  _Float16* WeT = (_Float16*)(ws + off);    off += 320 * 72 / 2;
  _Float16* WaT = (_Float16*)(ws + off);    off += 128 * 72 / 2;
  _Float16* WinT = (_Float16*)(ws + off);   off += 3 * 64 * 136 / 2;
  _Float16* WoutT = (_Float16*)(ws + off);  off += 3 * 64 * 72 / 2;
  float* bstats = ws + off;                 off += (size_t)(GIN_Q + GIN_A + GIN_E) * 128;
  unsigned* row_start = (unsigned*)(ws + off); off += NT_TOTAL;
  unsigned* cursor = (unsigned*)(ws + off);    off += NT_TOTAL;
  unsigned* bsums = (unsigned*)(ws + off);     off += 1024;
  unsigned* eidx = (unsigned*)(ws + off);      off += E_TOTAL + 8;  // +8 pad

  const int Ns[3] = {NQ, NA, NE};
  const float* xs[3] = {xq, xa, xe};
  const int gin[3] = {GIN_Q, GIN_A, GIN_E};
  const int bb[3] = {0, GIN_Q, GIN_Q + GIN_A};
  _Float16* yhb[3] = {y_h, y_h + (size_t)NQ * 64, y_h + (size_t)(NQ + NA) * 64};
  _Float16* aggb[3] = {agg_h, agg_h + (size_t)NQ * 64, agg_h + (size_t)(NQ + NA) * 64};
  float* zq_out = out + (N_POS + N_NEG);
  float* zbase[3] = {zq_out, zq_out + (size_t)NQ * 64, zq_out + (size_t)(NQ + NA) * 64};

  fill_kernel<<<dim3(128), dim3(256), 0, stream>>>((float*)row_start, 0.f, NT_TOTAL);
  wprep_in<<<dim3(192), dim3(136), 0, stream>>>(W_in, WinT);
  wprep_out<<<dim3(192), dim3(72), 0, stream>>>(W_out, WoutT);

  // ---- in-proj (LDS-staged MFMA, 3 blocks/CU) + relu -> y fp16, fused bstats ----
  for (int t = 0; t < 3; ++t) {
    gemm_inproj<<<dim3(gin[t]), dim3(256), SMEM_INPROJ, stream>>>(
        xs[t], WinT + (size_t)t * 64 * 136, b_in + t * 64, Ns[t], CDIV(Ns[t], 64),
        yhb[t], bstats + (size_t)bb[t] * 128);
  }
  stats_reduce<<<dim3(384), dim3(256), 0, stream>>>(bstats, stats);
  bn_finalize<<<dim3(1), dim3(192), 0, stream>>>(stats, bn_gamma, bn_beta, scale, shift);
  kqv_bias2<<<dim3(3), dim3(192), 0, stream>>>(b_kqv, W_kqv, shift, bias2);
  wprep_kqv<<<dim3(640), dim3(64), 0, stream>>>(W_kqv, bias2, A_k, A_v, scale,
                                                WqT, WeT, WaT, bias_big);

  // ---- kqv projections (staged 8-wave; LDS-transposed coalesced stores) ----
  gemm_mfma<256, 192, 64><<<dim3(CDIV(NQ, 256)), dim3(512), 0, stream>>>(
      yhb[0], WqT, bias_big, NQ, kqvQ, 192);
  gemm_mfma<256, 160, 64><<<dim3(CDIV(NE, 256), 2), dim3(512), 0, stream>>>(
      yhb[2], WeT, bias_big + 192, NE, kqvE, 320);
  gemm_mfma<256, 128, 64><<<dim3(CDIV(NA, 256)), dim3(512), 0, stream>>>(
      yhb[1], WaT, bias_big + 512, NA, kqvA, 128);

  // ---- CSR build ----
  struct Rel { const int* ei; int E; int dstbase; int srcld; unsigned slot; };
  Rel rels[4] = {{e_e2q, E_E2Q, BASE_Q, 320, 0u},
                 {e_e2e, E_E2E, BASE_E, 320, 0u},
                 {e_e2a, E_E2A, BASE_A, 320, 0u},
                 {e_q2a, E_Q2A, BASE_A, 192, 1u}};
  for (int r = 0; r < 4; ++r) {
    int blocks = CDIV(rels[r].E, 256); if (blocks > 2048) blocks = 2048;
    hist_kernel<<<dim3(blocks), dim3(256), 0, stream>>>(rels[r].ei + rels[r].E, rels[r].E,
                                                        row_start, rels[r].dstbase);
  }
  scan1<<<dim3(NBLK_SCAN), dim3(256), 0, stream>>>(row_start, NT_TOTAL, bsums);
  scan2<<<dim3(1), dim3(256), 0, stream>>>(bsums, NBLK_SCAN);
  scan3<<<dim3(NBLK_SCAN), dim3(256), 0, stream>>>(row_start, bsums, cursor, NT_TOTAL);
  for (int r = 0; r < 4; ++r) {
    int blocks = CDIV(rels[r].E, 256); if (blocks > 2048) blocks = 2048;
    scatter_kernel<<<dim3(blocks), dim3(256), 0, stream>>>(
        rels[r].ei, rels[r].ei + rels[r].E, rels[r].E, cursor, eidx,
        rels[r].dstbase, rels[r].srcld, rels[r].slot);
  }

  // ---- gathers (offset payloads + dot2 score) ----
  gather_kernel<1><<<dim3(CDIV(NQ, 4)), dim3(256), 0, stream>>>(
      NQ, BASE_Q, row_start, cursor, eidx,
      kqvE, 128, nullptr, 0,
      kqvQ + 64, 192, nullptr, 0, p_rel + 0, p_rel + 0, agg_h);
  gather_kernel<1><<<dim3(4096), dim3(256), 0, stream>>>(
      NE, BASE_E, row_start, cursor, eidx,
      kqvE, 192, nullptr, 0,
      kqvE + 64, 320, nullptr, 0, p_rel + 2, p_rel + 2, agg_h);
  gather_kernel<2><<<dim3(CDIV(NA, 4)), dim3(256), 0, stream>>>(
      NA, BASE_A, row_start, cursor, eidx,
      kqvE, 256, kqvQ, 128,
      kqvA, 128, kqvA + 64, 128, p_rel + 4, p_rel + 6, agg_h);

  // ---- out projection (direct-A MFMA) + skip blend -> fp32 z ----
  for (int t = 0; t < 3; ++t) {
    gemm_direct<64, 64, 3><<<dim3(CDIV(Ns[t], 128)), dim3(256), 0, stream>>>(
        nullptr, aggb[t], WoutT + (size_t)t * 64 * 72, b_out + t * 64, Ns[t],
        nullptr, 0, zbase[t], nullptr,
        yhb[t], scale + t * 64, shift + t * 64, skip, t);
  }

  // ---- predictions ----
  pred_kernel<<<dim3(CDIV(N_POS, 256)), dim3(256), 0, stream>>>(
      pos_idx, pos_idx + N_POS, N_POS, zbase[0], zbase[1], out);
  pred_kernel<<<dim3(CDIV(N_NEG, 256)), dim3(256), 0, stream>>>(
      neg_idx, neg_idx + N_NEG, N_NEG, zbase[0], zbase[1], out + N_POS);
}

// Round 17
// 728.136 us; speedup vs baseline: 2.6563x; 1.0142x over previous
//
#include <hip/hip_runtime.h>
#include <hip/hip_bf16.h>
#include <hip/hip_fp16.h>
#include <math.h>

#define NQ 8192
#define NA 32768
#define NE 500000
#define F_IN 128
#define E_E2Q 131072
#define E_E2E 800000
#define E_E2A 262144
#define E_Q2A 32768
#define N_POS 8192
#define N_NEG 24576

#define NT_TOTAL (NQ + NA + NE)                      // 540960
#define E_TOTAL (E_E2Q + E_E2E + E_E2A + E_Q2A)      // 1225984
#define NBLK_SCAN ((NT_TOTAL + 1023) / 1024)         // 529
#define CDIV(a, b) (((a) + (b) - 1) / (b))

// dst node index space: [question: 0) [answer: NQ) [entity: NQ+NA)
#define BASE_Q 0
#define BASE_A NQ
#define BASE_E (NQ + NA)

// in-proj grids (64-row tiles; 1 block per bstats row)
#define GIN_Q 128
#define GIN_A 512
#define GIN_E 768
#define SMEM_INPROJ (32768 + 17408 + 512)

// merged gather grid
#define GB_Q 2048
#define GB_E 4096
#define GB_A 8192

typedef _Float16 half8_t __attribute__((ext_vector_type(8)));
typedef _Float16 half4_t __attribute__((ext_vector_type(4)));
typedef _Float16 half2_t __attribute__((ext_vector_type(2)));
typedef float f32x4_t __attribute__((ext_vector_type(4)));

__device__ inline void load_lds16(const void* g, void* l) {
  __builtin_amdgcn_global_load_lds((const __attribute__((address_space(1))) void*)g,
                                   (__attribute__((address_space(3))) void*)l, 16, 0, 0);
}

__device__ inline float fast_gelu(float v) {
  float u = 1.5957691216057308f * fmaf(0.044715f * v * v, v, v);
  return v / (1.f + __expf(-u));
}

// ---------------- merged prep: zero row_start + wprep_in + wprep_out ----------------

__global__ __launch_bounds__(256) void prep_misc(
    float* __restrict__ row_start_f,
    const float* __restrict__ W_in, _Float16* __restrict__ WinT,
    const float* __restrict__ W_out, _Float16* __restrict__ WoutT)
{
  int bid = blockIdx.x;
  if (bid < 128) {
    size_t i = (size_t)bid * 256 + threadIdx.x;
    size_t stride = (size_t)128 * 256;
    for (; i < NT_TOTAL; i += stride) row_start_f[i] = 0.f;
  } else if (bid < 320) {
    int b = bid - 128;            // 0..191
    int t = b >> 6, n = b & 63, k = threadIdx.x;
    if (k < 136) {
      float v = (k < 128) ? W_in[(size_t)t * 128 * 64 + (size_t)k * 64 + n] : 0.f;
      WinT[((size_t)t * 64 + n) * 136 + k] = (_Float16)v;
    }
  } else {
    int b = bid - 320;            // 0..191
    int t = b >> 6, n = b & 63, k = threadIdx.x;
    if (k < 72) {
      float v = (k < 64) ? W_out[(size_t)t * 64 * 64 + (size_t)k * 64 + n] : 0.f;
      WoutT[((size_t)t * 64 + n) * 72 + k] = (_Float16)v;
    }
  }
}

// ---------------- in-proj: LDS-staged fp32 A (global_load_lds), MFMA, fused bstats ----------------

__global__ __launch_bounds__(256) void gemm_inproj(
    const float* __restrict__ Af, const _Float16* __restrict__ WT,
    const float* __restrict__ bias, int M, int ntiles,
    _Float16* __restrict__ oh, float* __restrict__ bstats)
{
  extern __shared__ char smem[];
  float* As32 = (float*)smem;                       // 64 x 128 fp32 = 32KB
  _Float16* Bs = (_Float16*)(smem + 32768);         // 64 x 136 fp16
  float* s1 = (float*)(smem + 32768 + 17408);
  float* s2 = s1 + 64;

  int tid = threadIdx.x;
  int w = tid >> 6, l = tid & 63;
  int lr = l & 15, lg = l >> 4;

  for (int idx = tid; idx < 64 * 136 / 8; idx += 256)
    *(half8_t*)&Bs[idx * 8] = *(const half8_t*)&WT[(size_t)idx * 8];
  if (tid < 64) { s1[tid] = 0.f; s2[tid] = 0.f; }

  float ps1[4] = {}, ps2[4] = {};
  float bval[4];
#pragma unroll
  for (int ct = 0; ct < 4; ++ct) bval[ct] = bias[ct * 16 + lr];

  for (int tile = blockIdx.x; tile < ntiles; tile += gridDim.x) {
    const char* srcbase = (const char*)Af + (size_t)tile * 64 * 512;
    int rowlim = M - tile * 64;
#pragma unroll
    for (int r = 0; r < 8; ++r) {
      int unit = r * 4 + w;
      char* ldst = (char*)As32 + unit * 1024;
      int p = unit * 1024 + l * 16;
      int row = p >> 9;
      const char* src = (row < rowlim) ? srcbase + (size_t)row * 512 + (p & 511)
                                       : srcbase;
      load_lds16(src, ldst);
    }
    __syncthreads();

    f32x4_t acc[4] = {};
#pragma unroll
    for (int ks = 0; ks < 4; ++ks) {
      const float4* pa = (const float4*)((const char*)As32 +
                          (w * 16 + lr) * 512 + ks * 128 + lg * 32);
      float4 x0 = pa[0], x1 = pa[1];
      half8_t a0 = {(_Float16)x0.x, (_Float16)x0.y, (_Float16)x0.z, (_Float16)x0.w,
                    (_Float16)x1.x, (_Float16)x1.y, (_Float16)x1.z, (_Float16)x1.w};
#pragma unroll
      for (int ct = 0; ct < 4; ++ct) {
        half8_t b = *(const half8_t*)&Bs[(ct * 16 + lr) * 136 + ks * 32 + lg * 8];
        acc[ct] = __builtin_amdgcn_mfma_f32_16x16x32_f16(a0, b, acc[ct], 0, 0, 0);
      }
    }

    int rbase = tile * 64 + w * 16 + lg * 4;
#pragma unroll
    for (int ct = 0; ct < 4; ++ct) {
      int col = ct * 16 + lr;
#pragma unroll
      for (int j = 0; j < 4; ++j) {
        int row = rbase + j;
        if (row >= M) continue;
        float val = fmaxf(acc[ct][j] + bval[ct], 0.f);
        oh[(size_t)row * 64 + col] = (_Float16)val;
        ps1[ct] += val;
        ps2[ct] += val * val;
      }
    }
    __syncthreads();
  }

#pragma unroll
  for (int ct = 0; ct < 4; ++ct) {
    atomicAdd(&s1[ct * 16 + lr], ps1[ct]);
    atomicAdd(&s2[ct * 16 + lr], ps2[ct]);
  }
  __syncthreads();
  if (tid < 64) {
    bstats[(size_t)blockIdx.x * 128 + tid] = s1[tid];
    bstats[(size_t)blockIdx.x * 128 + 64 + tid] = s2[tid];
  }
}

// ---------------- direct-A MFMA GEMM (out-proj, MODE 3) ----------------

template <int BNT, int KTOT, int MODE>
__global__ __launch_bounds__(256) void gemm_direct(
    const float* __restrict__ Af, const _Float16* __restrict__ Ah,
    const _Float16* __restrict__ WT, const float* __restrict__ bias, int M,
    _Float16* __restrict__ oh, int LDO,
    float* __restrict__ Cf,
    float* __restrict__ bstats,
    const _Float16* __restrict__ resh, const float* __restrict__ rsc,
    const float* __restrict__ rsh, const float* __restrict__ skip_ptr, int skip_idx)
{
  constexpr int KP = KTOT + 8;
  __shared__ _Float16 Bs[BNT * KP];
  int tid = threadIdx.x;
  int w = tid >> 6, l = tid & 63;
  int lr = l & 15, lg = l >> 4;
  int row0 = blockIdx.x * 128;

  for (int idx = tid; idx < BNT * KP / 8; idx += 256)
    *(half8_t*)&Bs[idx * 8] = *(const half8_t*)&WT[(size_t)idx * 8];

  constexpr int NKS = KTOT / 32;
  half8_t afrag[2][NKS];
#pragma unroll
  for (int rt = 0; rt < 2; ++rt) {
    int gr = row0 + w * 32 + rt * 16 + lr;
    bool ok = gr < M;
#pragma unroll
    for (int ks = 0; ks < NKS; ++ks) {
      half8_t h8 = {};
      if (ok) h8 = *(const half8_t*)&Ah[(size_t)gr * KTOT + ks * 32 + lg * 8];
      afrag[rt][ks] = h8;
    }
  }
  __syncthreads();

  constexpr int NCT = BNT / 16;
  f32x4_t acc[2][NCT] = {};
#pragma unroll
  for (int ks = 0; ks < NKS; ++ks) {
#pragma unroll
    for (int ct = 0; ct < NCT; ++ct) {
      half8_t b = *(const half8_t*)&Bs[(ct * 16 + lr) * KP + ks * 32 + lg * 8];
      acc[0][ct] = __builtin_amdgcn_mfma_f32_16x16x32_f16(afrag[0][ks], b, acc[0][ct], 0, 0, 0);
      acc[1][ct] = __builtin_amdgcn_mfma_f32_16x16x32_f16(afrag[1][ks], b, acc[1][ct], 0, 0, 0);
    }
  }

  float g = 1.f / (1.f + __expf(-skip_ptr[skip_idx]));
  float gb = 1.f - g;
#pragma unroll
  for (int rt = 0; rt < 2; ++rt) {
    int rbase = row0 + w * 32 + rt * 16 + lg * 4;
#pragma unroll
    for (int ct = 0; ct < NCT; ++ct) {
      int col = ct * 16 + lr;
      float bval = bias[col];
#pragma unroll
      for (int j = 0; j < 4; ++j) {
        int row = rbase + j;
        if (row >= M) continue;
        float val = acc[rt][ct][j] + bval;
        float rv = (float)resh[(size_t)row * 64 + col];
        Cf[(size_t)row * 64 + col] = g * val + gb * (rsc[col] * rv + rsh[col]);
      }
    }
  }
}

// ---------------- staged MFMA GEMM (kqv, 8 waves, col-tiled, LDS-transposed stores) ----------------

template <int BM, int BNT, int KTOT>
__global__ __launch_bounds__(BM * 2) void gemm_mfma(
    const _Float16* __restrict__ Ah,
    const _Float16* __restrict__ WT, const float* __restrict__ bias, int M,
    _Float16* __restrict__ oh, int LDO)
{
  constexpr int KP = KTOT + 8;
  constexpr int NTHR = BM * 2;
  constexpr int TP = BNT + 8;
  constexpr int SZ_AB = (BM * KP + BNT * KP) * 2;
  constexpr int SZ_T = 128 * TP * 2;
  constexpr int SZ = SZ_AB > SZ_T ? SZ_AB : SZ_T;
  __shared__ __align__(16) char smem[SZ];
  _Float16* As = (_Float16*)smem;
  _Float16* Bs = As + BM * KP;
  _Float16* Ts = (_Float16*)smem;
  int tid = threadIdx.x;
  int row0 = blockIdx.x * BM;
  int colbase = blockIdx.y * BNT;

  {
    constexpr int CH = KTOT / 8;
    for (int idx = tid; idx < BM * CH; idx += NTHR) {
      int row = idx / CH, c = idx % CH;
      int gr = row0 + row;
      half8_t a8 = {};
      if (gr < M) a8 = *(const half8_t*)&Ah[(size_t)gr * KTOT + c * 8];
      *(half8_t*)&As[row * KP + c * 8] = a8;
    }
  }
  {
    const _Float16* wsrc = WT + (size_t)colbase * KP;
    for (int idx = tid; idx < BNT * KP / 8; idx += NTHR)
      *(half8_t*)&Bs[idx * 8] = *(const half8_t*)&wsrc[(size_t)idx * 8];
  }
  __syncthreads();

  int w = tid >> 6, l = tid & 63;
  int lr = l & 15, lg = l >> 4;
  constexpr int NCT = BNT / 16;
  constexpr int NKS = KTOT / 32;
  f32x4_t acc[2][NCT] = {};
#pragma unroll
  for (int ks = 0; ks < NKS; ++ks) {
    half8_t a0 = *(const half8_t*)&As[(w * 32 + lr) * KP + ks * 32 + lg * 8];
    half8_t a1 = *(const half8_t*)&As[(w * 32 + 16 + lr) * KP + ks * 32 + lg * 8];
#pragma unroll
    for (int ct = 0; ct < NCT; ++ct) {
      half8_t b = *(const half8_t*)&Bs[(ct * 16 + lr) * KP + ks * 32 + lg * 8];
      acc[0][ct] = __builtin_amdgcn_mfma_f32_16x16x32_f16(a0, b, acc[0][ct], 0, 0, 0);
      acc[1][ct] = __builtin_amdgcn_mfma_f32_16x16x32_f16(a1, b, acc[1][ct], 0, 0, 0);
    }
  }

  float bval[NCT];
#pragma unroll
  for (int ct = 0; ct < NCT; ++ct) bval[ct] = bias[colbase + ct * 16 + lr];

#pragma unroll
  for (int rt = 0; rt < 2; ++rt) {
    __syncthreads();
    int r2base = w * 16 + lg * 4;
#pragma unroll
    for (int ct = 0; ct < NCT; ++ct) {
      int colL = ct * 16 + lr;
#pragma unroll
      for (int j = 0; j < 4; ++j)
        Ts[(r2base + j) * TP + colL] = (_Float16)(acc[rt][ct][j] + bval[ct]);
    }
    __syncthreads();
    constexpr int C8 = BNT / 8;
    for (int idx = tid; idx < 128 * C8; idx += NTHR) {
      int r2 = idx / C8, c8 = (idx % C8) * 8;
      int gr = row0 + (r2 >> 4) * 32 + rt * 16 + (r2 & 15);
      if (gr < M)
        *(half8_t*)&oh[(size_t)gr * LDO + colbase + c8] = *(const half8_t*)&Ts[r2 * TP + c8];
    }
  }
}

// ---------------- BN: reduce per-block stats ----------------

__global__ __launch_bounds__(256) void stats_reduce(const float* __restrict__ bstats,
                                                    float* __restrict__ stats) {
  __shared__ float sh[256];
  int t = blockIdx.x >> 7;
  int c = blockIdx.x & 127;
  int nb = (t == 0) ? GIN_Q : (t == 1) ? GIN_A : GIN_E;
  int base = (t == 0) ? 0 : (t == 1) ? GIN_Q : (GIN_Q + GIN_A);
  float s = 0.f;
  for (int i = threadIdx.x; i < nb; i += 256)
    s += bstats[(size_t)(base + i) * 128 + c];
  sh[threadIdx.x] = s;
  __syncthreads();
  for (int off2 = 128; off2 > 0; off2 >>= 1) {
    if (threadIdx.x < off2) sh[threadIdx.x] += sh[threadIdx.x + off2];
    __syncthreads();
  }
  if (threadIdx.x == 0) stats[t * 128 + c] = sh[0];
}

__global__ void bn_finalize(const float* __restrict__ stats,
                            const float* __restrict__ gamma, const float* __restrict__ beta,
                            float* __restrict__ scale, float* __restrict__ shift) {
  int t = threadIdx.x;
  if (t >= 192) return;
  int ty = t >> 6, c = t & 63;
  float invN = (ty == 0) ? (1.f / NQ) : (ty == 1) ? (1.f / NA) : (1.f / NE);
  float mu = stats[ty * 128 + c] * invN;
  float var = stats[ty * 128 + 64 + c] * invN - mu * mu;
  float rs = rsqrtf(var + 1e-5f);
  float gm = gamma[ty * 64 + c];
  scale[t] = gm * rs;
  shift[t] = beta[ty * 64 + c] - gm * mu * rs;
}

__global__ void kqv_bias2(const float* __restrict__ b_kqv, const float* __restrict__ W_kqv,
                          const float* __restrict__ shift, float* __restrict__ bias2) {
  int t = blockIdx.x, n = threadIdx.x;
  float s = b_kqv[t * 192 + n];
  for (int k = 0; k < 64; ++k)
    s += shift[t * 64 + k] * W_kqv[(size_t)t * 64 * 192 + k * 192 + n];
  bias2[t * 192 + n] = s;
}

// ---------------- weight prep ----------------

__global__ void wprep_kqv(const float* __restrict__ W_kqv, const float* __restrict__ bias2,
                          const float* __restrict__ A_k, const float* __restrict__ A_v,
                          const float* __restrict__ scale,
                          _Float16* __restrict__ WqT, _Float16* __restrict__ WeT,
                          _Float16* __restrict__ WaT, float* __restrict__ bias_big) {
  int j = blockIdx.x;   // 0..639
  int c = threadIdx.x;  // 0..63
  int t, jj, bofs;
  _Float16* W;
  if (j < 192)      { t = 0; jj = j;       W = WqT; bofs = 0; }
  else if (j < 512) { t = 2; jj = j - 192; W = WeT; bofs = 192; }
  else              { t = 1; jj = j - 512; W = WaT; bofs = 512; }
  const float* Wt = W_kqv + (size_t)t * 64 * 192;
  const float* b2 = bias2 + t * 192;
  int mode = 0, rel = 0, sub = 0;
  if (t == 1) { mode = 1; rel = (jj < 64) ? 2 : 3; sub = jj & 63; }
  else if (jj >= 64 && jj < 128) { mode = 1; rel = (t == 0) ? 0 : 1; sub = jj - 64; }
  else if (jj >= 128) {
    mode = 2; sub = (jj - 128) & 63;
    rel = (t == 0) ? 3 : ((jj - 128) >> 6);
  }
  int h = sub >> 5, x = sub & 31;
  float wv, bv;
  if (mode == 0) {
    wv = Wt[(size_t)c * 192 + jj];
    bv = b2[jj];
  } else if (mode == 1) {
    const float* Ar = A_k + ((size_t)rel * 2048 + h * 1024 + x * 32);
    float s = 0.f, sb = 0.f;
    for (int f = 0; f < 32; ++f) {
      float a = Ar[f];
      s = fmaf(a, Wt[(size_t)c * 192 + 64 + h * 32 + f], s);
      sb = fmaf(a, b2[64 + h * 32 + f], sb);
    }
    wv = s; bv = sb;
  } else {
    const float* Ar = A_v + ((size_t)rel * 2048 + h * 1024 + x);
    float s = 0.f, sb = 0.f;
    for (int d = 0; d < 32; ++d) {
      float a = Ar[d * 32];
      s = fmaf(a, Wt[(size_t)c * 192 + 128 + h * 32 + d], s);
      sb = fmaf(a, b2[128 + h * 32 + d], sb);
    }
    wv = s; bv = sb;
  }
  wv *= scale[t * 64 + c];
  W[(size_t)jj * 72 + c] = (_Float16)wv;
  if (c < 8) W[(size_t)jj * 72 + 64 + c] = (_Float16)0.f;
  if (c == 0) bias_big[bofs + jj] = bv;
}

// ---------------- CSR build (merged hist / scan / merged scatter) ----------------

__global__ __launch_bounds__(256) void hist_all(
    const int* __restrict__ d0, const int* __restrict__ d1,
    const int* __restrict__ d2, const int* __restrict__ d3,
    unsigned* __restrict__ cnt)
{
  int i = blockIdx.x * blockDim.x + threadIdx.x;
  int stride = gridDim.x * blockDim.x;
  for (; i < E_TOTAL; i += stride) {
    if (i < E_E2Q) atomicAdd(&cnt[BASE_Q + d0[i]], 1u);
    else if (i < E_E2Q + E_E2E) atomicAdd(&cnt[BASE_E + d1[i - E_E2Q]], 1u);
    else if (i < E_E2Q + E_E2E + E_E2A) atomicAdd(&cnt[BASE_A + d2[i - E_E2Q - E_E2E]], 1u);
    else atomicAdd(&cnt[BASE_A + d3[i - E_E2Q - E_E2E - E_E2A]], 1u);
  }
}

__global__ __launch_bounds__(256) void scan1(unsigned* __restrict__ arr, int n,
                                             unsigned* __restrict__ bsums) {
  __shared__ unsigned sh[256];
  int t = threadIdx.x;
  int base = blockIdx.x * 1024 + t * 4;
  unsigned v[4];
  unsigned s = 0;
#pragma unroll
  for (int j = 0; j < 4; ++j) {
    v[j] = (base + j < n) ? arr[base + j] : 0u;
    s += v[j];
  }
  sh[t] = s;
  __syncthreads();
  for (int off = 1; off < 256; off <<= 1) {
    unsigned x = (t >= off) ? sh[t - off] : 0u;
    __syncthreads();
    sh[t] += x;
    __syncthreads();
  }
  unsigned run = sh[t] - s;
#pragma unroll
  for (int j = 0; j < 4; ++j) {
    if (base + j < n) arr[base + j] = run;
    run += v[j];
  }
  if (t == 255) bsums[blockIdx.x] = sh[255];
}

__global__ __launch_bounds__(256) void scan2(unsigned* __restrict__ bsums, int nb) {
  __shared__ unsigned sh[256];
  __shared__ unsigned carry;
  int t = threadIdx.x;
  if (t == 0) carry = 0;
  __syncthreads();
  for (int chunk = 0; chunk < nb; chunk += 256) {
    int i = chunk + t;
    unsigned v = (i < nb) ? bsums[i] : 0u;
    sh[t] = v;
    __syncthreads();
    for (int off = 1; off < 256; off <<= 1) {
      unsigned x = (t >= off) ? sh[t - off] : 0u;
      __syncthreads();
      sh[t] += x;
      __syncthreads();
    }
    unsigned inc = sh[t];
    unsigned c = carry;
    __syncthreads();
    if (i < nb) bsums[i] = c + inc - v;
    if (t == 255) carry = c + sh[255];
    __syncthreads();
  }
}

__global__ __launch_bounds__(256) void scan3(unsigned* __restrict__ arr,
                                             const unsigned* __restrict__ bsums,
                                             unsigned* __restrict__ cursor, int n) {
  int t = threadIdx.x;
  int base = blockIdx.x * 1024 + t * 4;
  unsigned add = bsums[blockIdx.x];
#pragma unroll
  for (int j = 0; j < 4; ++j) {
    int idx = base + j;
    if (idx < n) {
      unsigned r = arr[idx] + add;
      arr[idx] = r;
      cursor[idx] = r;
    }
  }
}

// merged scatter; payload = src elem-offset (src*ld) | slot<<31
__global__ __launch_bounds__(256) void scatter_all(
    const int* __restrict__ s0, const int* __restrict__ d0,
    const int* __restrict__ s1, const int* __restrict__ d1,
    const int* __restrict__ s2, const int* __restrict__ d2,
    const int* __restrict__ s3, const int* __restrict__ d3,
    unsigned* __restrict__ cursor, unsigned* __restrict__ eidx)
{
  int i = blockIdx.x * blockDim.x + threadIdx.x;
  int stride = gridDim.x * blockDim.x;
  for (; i < E_TOTAL; i += stride) {
    unsigned pos, pay;
    if (i < E_E2Q) {
      pos = atomicAdd(&cursor[BASE_Q + d0[i]], 1u);
      pay = (unsigned)(s0[i] * 320);
    } else if (i < E_E2Q + E_E2E) {
      int k = i - E_E2Q;
      pos = atomicAdd(&cursor[BASE_E + d1[k]], 1u);
      pay = (unsigned)(s1[k] * 320);
    } else if (i < E_E2Q + E_E2E + E_E2A) {
      int k = i - E_E2Q - E_E2E;
      pos = atomicAdd(&cursor[BASE_A + d2[k]], 1u);
      pay = (unsigned)(s2[k] * 320);
    } else {
      int k = i - E_E2Q - E_E2E - E_E2A;
      pos = atomicAdd(&cursor[BASE_A + d3[k]], 1u);
      pay = (unsigned)(s3[k] * 192) | 0x80000000u;
    }
    eidx[pos] = pay;
  }
}

// ---------------- gather body (device fn) ----------------

template <int NREL>
__device__ __forceinline__ void gather_body(
    int bidLocal, int nblocks, int N, int nodebase,
    const unsigned* __restrict__ row_start, const unsigned* __restrict__ row_end,
    const unsigned* __restrict__ eidx,
    const _Float16* __restrict__ baseA, int vofA,
    const _Float16* __restrict__ baseB, int vofB,
    const _Float16* __restrict__ qtA, int ldqA,
    const _Float16* __restrict__ qtB, int ldqB,
    const float* __restrict__ prelA, const float* __restrict__ prelB,
    _Float16* __restrict__ agg)
{
  int lane = threadIdx.x & 63;
  int h = lane >> 5, f = lane & 31;
  int idx2 = h * 32 + 2 * (f & 15);
  const float isd = 0.17677669529663687f;
  float pr0 = prelA[h] * isd;
  float pr1 = (NREL == 2) ? prelB[h] * isd : 0.f;

  int wid = (int)(((size_t)bidLocal * 256 + threadIdx.x) >> 6);
  int nw = nblocks * 4;

  int n0 = wid;
  unsigned b0s = 0, b0e = 0, e00 = 0, e01 = 0;
  half2_t q00p = {}, q01p = {};
  if (n0 < N) {
    b0s = row_start[nodebase + n0];
    b0e = row_end[nodebase + n0];
    q00p = *(const half2_t*)&qtA[(size_t)n0 * ldqA + idx2];
    if (NREL == 2) q01p = *(const half2_t*)&qtB[(size_t)n0 * ldqB + idx2];
    e00 = eidx[b0s];
    e01 = eidx[b0s + 1];
  }
  int n1 = n0 + nw;
  unsigned b1s = 0, b1e = 0;
  half2_t q10p = {}, q11p = {};
  if (n0 < N && n1 < N) {
    b1s = row_start[nodebase + n1];
    b1e = row_end[nodebase + n1];
    q10p = *(const half2_t*)&qtA[(size_t)n1 * ldqA + idx2];
    if (NREL == 2) q11p = *(const half2_t*)&qtB[(size_t)n1 * ldqB + idx2];
  }

  while (n0 < N) {
    unsigned e10 = 0, e11 = 0;
    if (n1 < N) {
      e10 = eidx[b1s];
      e11 = eidx[b1s + 1];
    }
    int n2 = n1 + nw;
    unsigned b2s = 0, b2e = 0;
    half2_t q20p = {}, q21p = {};
    if (n2 < N) {
      b2s = row_start[nodebase + n2];
      b2e = row_end[nodebase + n2];
      q20p = *(const half2_t*)&qtA[(size_t)n2 * ldqA + idx2];
      if (NREL == 2) q21p = *(const half2_t*)&qtB[(size_t)n2 * ldqB + idx2];
    }

    float vs = 0.f, ss = 0.f;
    unsigned i = b0s;

    auto do_pair = [&](unsigned p1, unsigned p2) {
      unsigned o1 = p1 & 0x7FFFFFFFu, o2 = p2 & 0x7FFFFFFFu;
      bool r1 = (NREL == 2) && (p1 >> 31);
      bool r2 = (NREL == 2) && (p2 >> 31);
      const _Float16* b1 = (r1 ? baseB : baseA) + o1;
      const _Float16* b2 = (r2 ? baseB : baseA) + o2;
      half2_t k21 = *(const half2_t*)&b1[idx2];
      float v1 = (float)b1[(r1 ? vofB : vofA) + lane];
      half2_t k22 = *(const half2_t*)&b2[idx2];
      float v2 = (float)b2[(r2 ? vofB : vofA) + lane];
      float sa = __builtin_amdgcn_fdot2(k21, r1 ? q01p : q00p, 0.f, false);
      float sb = __builtin_amdgcn_fdot2(k22, r2 ? q01p : q00p, 0.f, false);
#pragma unroll
      for (int off = 1; off <= 8; off <<= 1) {
        sa += __shfl_xor(sa, off, 32);
        sb += __shfl_xor(sb, off, 32);
      }
      float w1 = __expf(sa * (r1 ? pr1 : pr0));
      float w2 = __expf(sb * (r2 ? pr1 : pr0));
      ss += w1 + w2;
      vs = fmaf(w1, v1, vs);
      vs = fmaf(w2, v2, vs);
    };
    auto do_single = [&](unsigned p1) {
      unsigned o1 = p1 & 0x7FFFFFFFu;
      bool r1 = (NREL == 2) && (p1 >> 31);
      const _Float16* b1 = (r1 ? baseB : baseA) + o1;
      half2_t k21 = *(const half2_t*)&b1[idx2];
      float v1 = (float)b1[(r1 ? vofB : vofA) + lane];
      float sa = __builtin_amdgcn_fdot2(k21, r1 ? q01p : q00p, 0.f, false);
#pragma unroll
      for (int off = 1; off <= 8; off <<= 1) sa += __shfl_xor(sa, off, 32);
      float w1 = __expf(sa * (r1 ? pr1 : pr0));
      ss += w1;
      vs = fmaf(w1, v1, vs);
    };

    if (i + 2 <= b0e) { do_pair(e00, e01); i += 2; }
    else if (i < b0e) { do_single(e00); i = b0e; }
    for (; i + 2 <= b0e; i += 2) do_pair(eidx[i], eidx[i + 1]);
    if (i < b0e) do_single(eidx[i]);

    float val = (ss > 0.f) ? vs / ss : 0.f;
    val = fast_gelu(val);
    agg[((size_t)(nodebase + n0)) * 64 + lane] = (_Float16)val;

    n0 = n1; b0s = b1s; b0e = b1e; q00p = q10p; q01p = q11p; e00 = e10; e01 = e11;
    n1 = n2; b1s = b2s; b1e = b2e; q10p = q20p; q11p = q21p;
  }
}

// merged gather: blocks [0,GB_Q) -> Q, [GB_Q, GB_Q+GB_E) -> E, rest -> A
__global__ __launch_bounds__(256) void gather_all(
    const unsigned* __restrict__ row_start, const unsigned* __restrict__ row_end,
    const unsigned* __restrict__ eidx,
    const _Float16* __restrict__ kqvQ, const _Float16* __restrict__ kqvE,
    const _Float16* __restrict__ kqvA,
    const float* __restrict__ p_rel, _Float16* __restrict__ agg)
{
  int bid = blockIdx.x;
  if (bid < GB_Q) {
    gather_body<1>(bid, GB_Q, NQ, BASE_Q, row_start, row_end, eidx,
                   kqvE, 128, kqvE, 128, kqvQ + 64, 192, kqvQ + 64, 192,
                   p_rel + 0, p_rel + 0, agg);
  } else if (bid < GB_Q + GB_E) {
    gather_body<1>(bid - GB_Q, GB_E, NE, BASE_E, row_start, row_end, eidx,
                   kqvE, 192, kqvE, 192, kqvE + 64, 320, kqvE + 64, 320,
                   p_rel + 2, p_rel + 2, agg);
  } else {
    gather_body<2>(bid - GB_Q - GB_E, GB_A, NA, BASE_A, row_start, row_end, eidx,
                   kqvE, 256, kqvQ, 128, kqvA, 128, kqvA + 64, 128,
                   p_rel + 4, p_rel + 6, agg);
  }
}

// ---------------- final predictions ----------------

__global__ void pred_kernel(const int* __restrict__ qi, const int* __restrict__ ai, int Np,
                            const float* __restrict__ zq, const float* __restrict__ za,
                            float* __restrict__ outp) {
  int i = blockIdx.x * blockDim.x + threadIdx.x;
  if (i >= Np) return;
  const float4* a = (const float4*)(zq + (size_t)qi[i] * 64);
  const float4* b = (const float4*)(za + (size_t)ai[i] * 64);
  float ssum = 0.f;
#pragma unroll
  for (int j = 0; j < 16; ++j) {
    float4 x = a[j], y = b[j];
    ssum += x.x * y.x + x.y * y.y + x.z * y.z + x.w * y.w;
  }
  outp[i] = ssum;
}

// ---------------- host launch ----------------

extern "C" void kernel_launch(void* const* d_in, const int* in_sizes, int n_in,
                              void* d_out, int out_size, void* d_ws, size_t ws_size,
                              hipStream_t stream) {
  const float* xq = (const float*)d_in[0];
  const float* xa = (const float*)d_in[1];
  const float* xe = (const float*)d_in[2];
  const int* e_e2q = (const int*)d_in[3];
  const int* e_e2e = (const int*)d_in[4];
  const int* e_e2a = (const int*)d_in[5];
  const int* e_q2a = (const int*)d_in[6];
  const int* pos_idx = (const int*)d_in[7];
  const int* neg_idx = (const int*)d_in[8];
  const float* W_in = (const float*)d_in[9];
  const float* b_in = (const float*)d_in[10];
  const float* bn_gamma = (const float*)d_in[11];
  const float* bn_beta = (const float*)d_in[12];
  const float* W_kqv = (const float*)d_in[13];
  const float* b_kqv = (const float*)d_in[14];
  const float* A_k = (const float*)d_in[15];
  const float* A_v = (const float*)d_in[16];
  const float* p_rel = (const float*)d_in[17];
  const float* W_out = (const float*)d_in[18];
  const float* b_out = (const float*)d_in[19];
  const float* skip = (const float*)d_in[20];
  float* out = (float*)d_out;

  float* ws = (float*)d_ws;
  size_t off = 0;
  _Float16* y_h = (_Float16*)(ws + off);    off += (size_t)NT_TOTAL * 32;
  _Float16* kqvQ = (_Float16*)(ws + off);   off += (size_t)NQ * 96;    // [NQ][192]
  _Float16* kqvE = (_Float16*)(ws + off);   off += (size_t)NE * 160;   // [NE][320]
  _Float16* kqvA = (_Float16*)(ws + off);   off += (size_t)NA * 64;    // [NA][128]
  _Float16* agg_h = (_Float16*)(ws + off);  off += (size_t)NT_TOTAL * 32;
  float* stats = ws + off;                  off += 384;
  float* scale = ws + off;                  off += 192;
  float* shift = ws + off;                  off += 192;
  float* bias2 = ws + off;                  off += 576;
  float* bias_big = ws + off;               off += 640;
  _Float16* WqT = (_Float16*)(ws + off);    off += 192 * 72 / 2;
  _Float16* WeT = (_Float16*)(ws + off);    off += 320 * 72 / 2;
  _Float16* WaT = (_Float16*)(ws + off);    off += 128 * 72 / 2;
  _Float16* WinT = (_Float16*)(ws + off);   off += 3 * 64 * 136 / 2;
  _Float16* WoutT = (_Float16*)(ws + off);  off += 3 * 64 * 72 / 2;
  float* bstats = ws + off;                 off += (size_t)(GIN_Q + GIN_A + GIN_E) * 128;
  unsigned* row_start = (unsigned*)(ws + off); off += NT_TOTAL;
  unsigned* cursor = (unsigned*)(ws + off);    off += NT_TOTAL;
  unsigned* bsums = (unsigned*)(ws + off);     off += 1024;
  unsigned* eidx = (unsigned*)(ws + off);      off += E_TOTAL + 8;  // +8 pad

  const int Ns[3] = {NQ, NA, NE};
  const float* xs[3] = {xq, xa, xe};
  const int gin[3] = {GIN_Q, GIN_A, GIN_E};
  const int bb[3] = {0, GIN_Q, GIN_Q + GIN_A};
  _Float16* yhb[3] = {y_h, y_h + (size_t)NQ * 64, y_h + (size_t)(NQ + NA) * 64};
  _Float16* aggb[3] = {agg_h, agg_h + (size_t)NQ * 64, agg_h + (size_t)(NQ + NA) * 64};
  float* zq_out = out + (N_POS + N_NEG);
  float* zbase[3] = {zq_out, zq_out + (size_t)NQ * 64, zq_out + (size_t)(NQ + NA) * 64};

  // merged: zero row_start + transpose W_in/W_out to fp16
  prep_misc<<<dim3(512), dim3(256), 0, stream>>>((float*)row_start, W_in, WinT, W_out, WoutT);

  // ---- in-proj (LDS-staged MFMA, 3 blocks/CU) + relu -> y fp16, fused bstats ----
  for (int t = 0; t < 3; ++t) {
    gemm_inproj<<<dim3(gin[t]), dim3(256), SMEM_INPROJ, stream>>>(
        xs[t], WinT + (size_t)t * 64 * 136, b_in + t * 64, Ns[t], CDIV(Ns[t], 64),
        yhb[t], bstats + (size_t)bb[t] * 128);
  }
  stats_reduce<<<dim3(384), dim3(256), 0, stream>>>(bstats, stats);
  bn_finalize<<<dim3(1), dim3(192), 0, stream>>>(stats, bn_gamma, bn_beta, scale, shift);
  kqv_bias2<<<dim3(3), dim3(192), 0, stream>>>(b_kqv, W_kqv, shift, bias2);
  wprep_kqv<<<dim3(640), dim3(64), 0, stream>>>(W_kqv, bias2, A_k, A_v, scale,
                                                WqT, WeT, WaT, bias_big);

  // ---- kqv projections (staged 8-wave; LDS-transposed coalesced stores) ----
  gemm_mfma<256, 192, 64><<<dim3(CDIV(NQ, 256)), dim3(512), 0, stream>>>(
      yhb[0], WqT, bias_big, NQ, kqvQ, 192);
  gemm_mfma<256, 160, 64><<<dim3(CDIV(NE, 256), 2), dim3(512), 0, stream>>>(
      yhb[2], WeT, bias_big + 192, NE, kqvE, 320);
  gemm_mfma<256, 128, 64><<<dim3(CDIV(NA, 256)), dim3(512), 0, stream>>>(
      yhb[1], WaT, bias_big + 512, NA, kqvA, 128);

  // ---- CSR build (merged) ----
  hist_all<<<dim3(2048), dim3(256), 0, stream>>>(
      e_e2q + E_E2Q, e_e2e + E_E2E, e_e2a + E_E2A, e_q2a + E_Q2A, row_start);
  scan1<<<dim3(NBLK_SCAN), dim3(256), 0, stream>>>(row_start, NT_TOTAL, bsums);
  scan2<<<dim3(1), dim3(256), 0, stream>>>(bsums, NBLK_SCAN);
  scan3<<<dim3(NBLK_SCAN), dim3(256), 0, stream>>>(row_start, bsums, cursor, NT_TOTAL);
  scatter_all<<<dim3(2048), dim3(256), 0, stream>>>(
      e_e2q, e_e2q + E_E2Q, e_e2e, e_e2e + E_E2E,
      e_e2a, e_e2a + E_E2A, e_q2a, e_q2a + E_Q2A, cursor, eidx);

  // ---- merged gather (Q + E + A co-scheduled) ----
  gather_all<<<dim3(GB_Q + GB_E + GB_A), dim3(256), 0, stream>>>(
      row_start, cursor, eidx, kqvQ, kqvE, kqvA, p_rel, agg_h);

  // ---- out projection (direct-A MFMA) + skip blend -> fp32 z ----
  for (int t = 0; t < 3; ++t) {
    gemm_direct<64, 64, 3><<<dim3(CDIV(Ns[t], 128)), dim3(256), 0, stream>>>(
        nullptr, aggb[t], WoutT + (size_t)t * 64 * 72, b_out + t * 64, Ns[t],
        nullptr, 0, zbase[t], nullptr,
        yhb[t], scale + t * 64, shift + t * 64, skip, t);
  }

  // ---- predictions ----
  pred_kernel<<<dim3(CDIV(N_POS, 256)), dim3(256), 0, stream>>>(
      pos_idx, pos_idx + N_POS, N_POS, zbase[0], zbase[1], out);
  pred_kernel<<<dim3(CDIV(N_NEG, 256)), dim3(256), 0, stream>>>(
      neg_idx, neg_idx + N_NEG, N_NEG, zbase[0], zbase[1], out + N_POS);
}

// Round 18
// 709.669 us; speedup vs baseline: 2.7254x; 1.0260x over previous
//
#include <hip/hip_runtime.h>
#include <hip/hip_bf16.h>
#include <hip/hip_fp16.h>
#include <math.h>

#define NQ 8192
#define NA 32768
#define NE 500000
#define F_IN 128
#define E_E2Q 131072
#define E_E2E 800000
#define E_E2A 262144
#define E_Q2A 32768
#define N_POS 8192
#define N_NEG 24576

#define NT_TOTAL (NQ + NA + NE)                      // 540960
#define E_TOTAL (E_E2Q + E_E2E + E_E2A + E_Q2A)      // 1225984
#define NBLK_SCAN ((NT_TOTAL + 1023) / 1024)         // 529
#define CDIV(a, b) (((a) + (b) - 1) / (b))

// dst node index space
#define BASE_Q 0
#define BASE_A NQ
#define BASE_E (NQ + NA)

// merged in-proj grid (1 block per bstats row)
#define GIN_Q 128
#define GIN_A 512
#define GIN_E 768

// merged gather grid
#define GB_Q 2048
#define GB_E 4096
#define GB_A 8192

// merged out-proj grid
#define TOP_Q 64     // CDIV(NQ,128)
#define TOP_A 256    // CDIV(NA,128)
#define TOP_E 3907   // CDIV(NE,128)

typedef _Float16 half8_t __attribute__((ext_vector_type(8)));
typedef _Float16 half4_t __attribute__((ext_vector_type(4)));
typedef _Float16 half2_t __attribute__((ext_vector_type(2)));
typedef float f32x4_t __attribute__((ext_vector_type(4)));

__device__ inline void load_lds16(const void* g, void* l) {
  __builtin_amdgcn_global_load_lds((const __attribute__((address_space(1))) void*)g,
                                   (__attribute__((address_space(3))) void*)l, 16, 0, 0);
}

__device__ inline float fast_gelu(float v) {
  float u = 1.5957691216057308f * fmaf(0.044715f * v * v, v, v);
  return v / (1.f + __expf(-u));
}

// ---------------- merged prep: zero row_start + wprep_in + wprep_out ----------------

__global__ __launch_bounds__(256) void prep_misc(
    float* __restrict__ row_start_f,
    const float* __restrict__ W_in, _Float16* __restrict__ WinT,
    const float* __restrict__ W_out, _Float16* __restrict__ WoutT)
{
  int bid = blockIdx.x;
  if (bid < 128) {
    size_t i = (size_t)bid * 256 + threadIdx.x;
    size_t stride = (size_t)128 * 256;
    for (; i < NT_TOTAL; i += stride) row_start_f[i] = 0.f;
  } else if (bid < 320) {
    int b = bid - 128;
    int t = b >> 6, n = b & 63, k = threadIdx.x;
    if (k < 136) {
      float v = (k < 128) ? W_in[(size_t)t * 128 * 64 + (size_t)k * 64 + n] : 0.f;
      WinT[((size_t)t * 64 + n) * 136 + k] = (_Float16)v;
    }
  } else {
    int b = bid - 320;
    int t = b >> 6, n = b & 63, k = threadIdx.x;
    if (k < 72) {
      float v = (k < 64) ? W_out[(size_t)t * 64 * 64 + (size_t)k * 64 + n] : 0.f;
      WoutT[((size_t)t * 64 + n) * 72 + k] = (_Float16)v;
    }
  }
}

// ---------------- merged in-proj: double-buffered LDS stage, counted vmcnt ----------------
// Per block: pipeline over 32-row halves. stage(next) -> vmcnt(4) -> s_barrier ->
// compute(cur) -> s_barrier. 2x16KB bufs + 17.4KB weights => 3 blocks/CU.

__global__ __launch_bounds__(256) void gemm_inproj_all(
    const float* __restrict__ xq, const float* __restrict__ xa,
    const float* __restrict__ xe,
    const _Float16* __restrict__ WinT, const float* __restrict__ b_in,
    _Float16* __restrict__ y_h, float* __restrict__ bstats)
{
  __shared__ __align__(16) float bufA[32 * 128];
  __shared__ __align__(16) float bufB[32 * 128];
  __shared__ _Float16 Bs[64 * 136];
  __shared__ float s1[64], s2[64];

  int bid = blockIdx.x;
  int t, lb, nb;
  const float* Af;
  _Float16* oh;
  if (bid < GIN_Q)              { t = 0; lb = bid;                 nb = GIN_Q; Af = xq; oh = y_h; }
  else if (bid < GIN_Q + GIN_A) { t = 1; lb = bid - GIN_Q;         nb = GIN_A; Af = xa; oh = y_h + (size_t)NQ * 64; }
  else                          { t = 2; lb = bid - GIN_Q - GIN_A; nb = GIN_E; Af = xe; oh = y_h + (size_t)(NQ + NA) * 64; }
  int M = (t == 0) ? NQ : (t == 1) ? NA : NE;
  int nh = CDIV(M, 32);
  const _Float16* WT = WinT + (size_t)t * 64 * 136;
  const float* bias = b_in + t * 64;

  int tid = threadIdx.x, w = tid >> 6, l = tid & 63;
  int lr = l & 15, lg = l >> 4;
  int wrow = (w & 1) * 16;    // row offset within half
  int wcol = (w >> 1) * 32;   // col offset

  // stage weights (normal loads + ds_writes)
  for (int idx = tid; idx < 64 * 136 / 8; idx += 256)
    *(half8_t*)&Bs[idx * 8] = *(const half8_t*)&WT[(size_t)idx * 8];
  if (tid < 64) { s1[tid] = 0.f; s2[tid] = 0.f; }

  float bval[2];
  bval[0] = bias[wcol + lr];
  bval[1] = bias[wcol + 16 + lr];
  float ps1[2] = {}, ps2[2] = {};

  auto stage = [&](float* buf, int h) {
    const char* srcbase = (const char*)Af + (size_t)h * 32 * 512;
    int rowlim = M - h * 32;
#pragma unroll
    for (int r = 0; r < 4; ++r) {
      int unit = r * 4 + w;                       // wave-uniform 0..15
      char* ldst = (char*)buf + unit * 1024;
      int p = unit * 1024 + l * 16;
      int row = p >> 9;
      const char* src = (row < rowlim) ? srcbase + (size_t)row * 512 + (p & 511)
                                       : srcbase;
      load_lds16(src, ldst);
    }
  };

  int h0 = lb;
  if (h0 < nh) stage(bufA, h0);
  __syncthreads();   // drains prologue stage + Bs ds_writes (full sync)

  float* cur = bufA;
  float* nxt = bufB;
  for (int h = h0; h < nh; h += nb) {
    int h2 = h + nb;
    bool more = h2 < nh;    // uniform across block
    if (more) {
      stage(nxt, h2);
      asm volatile("s_waitcnt vmcnt(4)" ::: "memory");   // cur's loads drained; nxt's in flight
    } else {
      asm volatile("s_waitcnt vmcnt(0)" ::: "memory");
    }
    __builtin_amdgcn_sched_barrier(0);
    __builtin_amdgcn_s_barrier();     // all waves' cur stage complete

    // ---- compute cur: wave w -> rows [wrow,wrow+16), cols [wcol,wcol+32) ----
    f32x4_t acc[2] = {};
#pragma unroll
    for (int ks = 0; ks < 4; ++ks) {
      const float4* pa = (const float4*)((const char*)cur +
                          (wrow + lr) * 512 + ks * 128 + lg * 32);
      float4 x0 = pa[0], x1 = pa[1];
      half8_t a0 = {(_Float16)x0.x, (_Float16)x0.y, (_Float16)x0.z, (_Float16)x0.w,
                    (_Float16)x1.x, (_Float16)x1.y, (_Float16)x1.z, (_Float16)x1.w};
#pragma unroll
      for (int ct = 0; ct < 2; ++ct) {
        half8_t b = *(const half8_t*)&Bs[(wcol + ct * 16 + lr) * 136 + ks * 32 + lg * 8];
        acc[ct] = __builtin_amdgcn_mfma_f32_16x16x32_f16(a0, b, acc[ct], 0, 0, 0);
      }
    }
    int rbase = h * 32 + wrow + lg * 4;
#pragma unroll
    for (int ct = 0; ct < 2; ++ct) {
      int col = wcol + ct * 16 + lr;
#pragma unroll
      for (int j = 0; j < 4; ++j) {
        int row = rbase + j;
        if (row >= M) continue;
        float val = fmaxf(acc[ct][j] + bval[ct], 0.f);
        oh[(size_t)row * 64 + col] = (_Float16)val;
        ps1[ct] += val;
        ps2[ct] += val * val;
      }
    }
    __builtin_amdgcn_s_barrier();     // all done reading cur before restage
    float* tmp = cur; cur = nxt; nxt = tmp;
  }

  // ---- block bstats ----
#pragma unroll
  for (int ct = 0; ct < 2; ++ct) {
    int col = wcol + ct * 16 + lr;
    atomicAdd(&s1[col], ps1[ct]);
    atomicAdd(&s2[col], ps2[ct]);
  }
  __syncthreads();
  if (tid < 64) {
    bstats[(size_t)blockIdx.x * 128 + tid] = s1[tid];
    bstats[(size_t)blockIdx.x * 128 + 64 + tid] = s2[tid];
  }
}

// ---------------- merged out-proj (direct-A MFMA, skip blend) ----------------

__global__ __launch_bounds__(256) void gemm_out_all(
    const _Float16* __restrict__ agg_h, const _Float16* __restrict__ y_h,
    const _Float16* __restrict__ WoutT, const float* __restrict__ b_out,
    const float* __restrict__ scale, const float* __restrict__ shift,
    const float* __restrict__ skip, float* __restrict__ zout)
{
  __shared__ _Float16 Bs[64 * 72];
  int bid = blockIdx.x;
  int t, row0, M;
  size_t nodeoff;
  if (bid < TOP_Q)              { t = 0; row0 = bid * 128;              M = NQ; nodeoff = 0; }
  else if (bid < TOP_Q + TOP_A) { t = 1; row0 = (bid - TOP_Q) * 128;    M = NA; nodeoff = NQ; }
  else                          { t = 2; row0 = (bid - TOP_Q - TOP_A) * 128; M = NE; nodeoff = NQ + NA; }
  const _Float16* Ah = agg_h + nodeoff * 64;
  const _Float16* resh = y_h + nodeoff * 64;
  float* Cf = zout + nodeoff * 64;
  const _Float16* WT = WoutT + (size_t)t * 64 * 72;
  const float* bias = b_out + t * 64;
  const float* rsc = scale + t * 64;
  const float* rsh = shift + t * 64;

  int tid = threadIdx.x;
  int w = tid >> 6, l = tid & 63;
  int lr = l & 15, lg = l >> 4;

  for (int idx = tid; idx < 64 * 72 / 8; idx += 256)
    *(half8_t*)&Bs[idx * 8] = *(const half8_t*)&WT[(size_t)idx * 8];

  half8_t afrag[2][2];
#pragma unroll
  for (int rt = 0; rt < 2; ++rt) {
    int gr = row0 + w * 32 + rt * 16 + lr;
    bool ok = gr < M;
#pragma unroll
    for (int ks = 0; ks < 2; ++ks) {
      half8_t h8 = {};
      if (ok) h8 = *(const half8_t*)&Ah[(size_t)gr * 64 + ks * 32 + lg * 8];
      afrag[rt][ks] = h8;
    }
  }
  __syncthreads();

  f32x4_t acc[2][4] = {};
#pragma unroll
  for (int ks = 0; ks < 2; ++ks) {
#pragma unroll
    for (int ct = 0; ct < 4; ++ct) {
      half8_t b = *(const half8_t*)&Bs[(ct * 16 + lr) * 72 + ks * 32 + lg * 8];
      acc[0][ct] = __builtin_amdgcn_mfma_f32_16x16x32_f16(afrag[0][ks], b, acc[0][ct], 0, 0, 0);
      acc[1][ct] = __builtin_amdgcn_mfma_f32_16x16x32_f16(afrag[1][ks], b, acc[1][ct], 0, 0, 0);
    }
  }

  float g = 1.f / (1.f + __expf(-skip[t]));
  float gb = 1.f - g;
#pragma unroll
  for (int rt = 0; rt < 2; ++rt) {
    int rbase = row0 + w * 32 + rt * 16 + lg * 4;
#pragma unroll
    for (int ct = 0; ct < 4; ++ct) {
      int col = ct * 16 + lr;
      float bval = bias[col];
#pragma unroll
      for (int j = 0; j < 4; ++j) {
        int row = rbase + j;
        if (row >= M) continue;
        float val = acc[rt][ct][j] + bval;
        float rv = (float)resh[(size_t)row * 64 + col];
        Cf[(size_t)row * 64 + col] = g * val + gb * (rsc[col] * rv + rsh[col]);
      }
    }
  }
}

// ---------------- staged MFMA GEMM (kqv, 8 waves, col-tiled, LDS-transposed stores) ----------------

template <int BM, int BNT, int KTOT>
__global__ __launch_bounds__(BM * 2) void gemm_mfma(
    const _Float16* __restrict__ Ah,
    const _Float16* __restrict__ WT, const float* __restrict__ bias, int M,
    _Float16* __restrict__ oh, int LDO)
{
  constexpr int KP = KTOT + 8;
  constexpr int NTHR = BM * 2;
  constexpr int TP = BNT + 8;
  constexpr int SZ_AB = (BM * KP + BNT * KP) * 2;
  constexpr int SZ_T = 128 * TP * 2;
  constexpr int SZ = SZ_AB > SZ_T ? SZ_AB : SZ_T;
  __shared__ __align__(16) char smem[SZ];
  _Float16* As = (_Float16*)smem;
  _Float16* Bs = As + BM * KP;
  _Float16* Ts = (_Float16*)smem;
  int tid = threadIdx.x;
  int row0 = blockIdx.x * BM;
  int colbase = blockIdx.y * BNT;

  {
    constexpr int CH = KTOT / 8;
    for (int idx = tid; idx < BM * CH; idx += NTHR) {
      int row = idx / CH, c = idx % CH;
      int gr = row0 + row;
      half8_t a8 = {};
      if (gr < M) a8 = *(const half8_t*)&Ah[(size_t)gr * KTOT + c * 8];
      *(half8_t*)&As[row * KP + c * 8] = a8;
    }
  }
  {
    const _Float16* wsrc = WT + (size_t)colbase * KP;
    for (int idx = tid; idx < BNT * KP / 8; idx += NTHR)
      *(half8_t*)&Bs[idx * 8] = *(const half8_t*)&wsrc[(size_t)idx * 8];
  }
  __syncthreads();

  int w = tid >> 6, l = tid & 63;
  int lr = l & 15, lg = l >> 4;
  constexpr int NCT = BNT / 16;
  constexpr int NKS = KTOT / 32;
  f32x4_t acc[2][NCT] = {};
#pragma unroll
  for (int ks = 0; ks < NKS; ++ks) {
    half8_t a0 = *(const half8_t*)&As[(w * 32 + lr) * KP + ks * 32 + lg * 8];
    half8_t a1 = *(const half8_t*)&As[(w * 32 + 16 + lr) * KP + ks * 32 + lg * 8];
#pragma unroll
    for (int ct = 0; ct < NCT; ++ct) {
      half8_t b = *(const half8_t*)&Bs[(ct * 16 + lr) * KP + ks * 32 + lg * 8];
      acc[0][ct] = __builtin_amdgcn_mfma_f32_16x16x32_f16(a0, b, acc[0][ct], 0, 0, 0);
      acc[1][ct] = __builtin_amdgcn_mfma_f32_16x16x32_f16(a1, b, acc[1][ct], 0, 0, 0);
    }
  }

  float bval[NCT];
#pragma unroll
  for (int ct = 0; ct < NCT; ++ct) bval[ct] = bias[colbase + ct * 16 + lr];

#pragma unroll
  for (int rt = 0; rt < 2; ++rt) {
    __syncthreads();
    int r2base = w * 16 + lg * 4;
#pragma unroll
    for (int ct = 0; ct < NCT; ++ct) {
      int colL = ct * 16 + lr;
#pragma unroll
      for (int j = 0; j < 4; ++j)
        Ts[(r2base + j) * TP + colL] = (_Float16)(acc[rt][ct][j] + bval[ct]);
    }
    __syncthreads();
    constexpr int C8 = BNT / 8;
    for (int idx = tid; idx < 128 * C8; idx += NTHR) {
      int r2 = idx / C8, c8 = (idx % C8) * 8;
      int gr = row0 + (r2 >> 4) * 32 + rt * 16 + (r2 & 15);
      if (gr < M)
        *(half8_t*)&oh[(size_t)gr * LDO + colbase + c8] = *(const half8_t*)&Ts[r2 * TP + c8];
    }
  }
}

// ---------------- BN: reduce per-block stats ----------------

__global__ __launch_bounds__(256) void stats_reduce(const float* __restrict__ bstats,
                                                    float* __restrict__ stats) {
  __shared__ float sh[256];
  int t = blockIdx.x >> 7;
  int c = blockIdx.x & 127;
  int nb = (t == 0) ? GIN_Q : (t == 1) ? GIN_A : GIN_E;
  int base = (t == 0) ? 0 : (t == 1) ? GIN_Q : (GIN_Q + GIN_A);
  float s = 0.f;
  for (int i = threadIdx.x; i < nb; i += 256)
    s += bstats[(size_t)(base + i) * 128 + c];
  sh[threadIdx.x] = s;
  __syncthreads();
  for (int off2 = 128; off2 > 0; off2 >>= 1) {
    if (threadIdx.x < off2) sh[threadIdx.x] += sh[threadIdx.x + off2];
    __syncthreads();
  }
  if (threadIdx.x == 0) stats[t * 128 + c] = sh[0];
}

__global__ void bn_finalize(const float* __restrict__ stats,
                            const float* __restrict__ gamma, const float* __restrict__ beta,
                            float* __restrict__ scale, float* __restrict__ shift) {
  int t = threadIdx.x;
  if (t >= 192) return;
  int ty = t >> 6, c = t & 63;
  float invN = (ty == 0) ? (1.f / NQ) : (ty == 1) ? (1.f / NA) : (1.f / NE);
  float mu = stats[ty * 128 + c] * invN;
  float var = stats[ty * 128 + 64 + c] * invN - mu * mu;
  float rs = rsqrtf(var + 1e-5f);
  float gm = gamma[ty * 64 + c];
  scale[t] = gm * rs;
  shift[t] = beta[ty * 64 + c] - gm * mu * rs;
}

__global__ void kqv_bias2(const float* __restrict__ b_kqv, const float* __restrict__ W_kqv,
                          const float* __restrict__ shift, float* __restrict__ bias2) {
  int t = blockIdx.x, n = threadIdx.x;
  float s = b_kqv[t * 192 + n];
  for (int k = 0; k < 64; ++k)
    s += shift[t * 64 + k] * W_kqv[(size_t)t * 64 * 192 + k * 192 + n];
  bias2[t * 192 + n] = s;
}

// ---------------- weight prep ----------------

__global__ void wprep_kqv(const float* __restrict__ W_kqv, const float* __restrict__ bias2,
                          const float* __restrict__ A_k, const float* __restrict__ A_v,
                          const float* __restrict__ scale,
                          _Float16* __restrict__ WqT, _Float16* __restrict__ WeT,
                          _Float16* __restrict__ WaT, float* __restrict__ bias_big) {
  int j = blockIdx.x;   // 0..639
  int c = threadIdx.x;  // 0..63
  int t, jj, bofs;
  _Float16* W;
  if (j < 192)      { t = 0; jj = j;       W = WqT; bofs = 0; }
  else if (j < 512) { t = 2; jj = j - 192; W = WeT; bofs = 192; }
  else              { t = 1; jj = j - 512; W = WaT; bofs = 512; }
  const float* Wt = W_kqv + (size_t)t * 64 * 192;
  const float* b2 = bias2 + t * 192;
  int mode = 0, rel = 0, sub = 0;
  if (t == 1) { mode = 1; rel = (jj < 64) ? 2 : 3; sub = jj & 63; }
  else if (jj >= 64 && jj < 128) { mode = 1; rel = (t == 0) ? 0 : 1; sub = jj - 64; }
  else if (jj >= 128) {
    mode = 2; sub = (jj - 128) & 63;
    rel = (t == 0) ? 3 : ((jj - 128) >> 6);
  }
  int h = sub >> 5, x = sub & 31;
  float wv, bv;
  if (mode == 0) {
    wv = Wt[(size_t)c * 192 + jj];
    bv = b2[jj];
  } else if (mode == 1) {
    const float* Ar = A_k + ((size_t)rel * 2048 + h * 1024 + x * 32);
    float s = 0.f, sb = 0.f;
    for (int f = 0; f < 32; ++f) {
      float a = Ar[f];
      s = fmaf(a, Wt[(size_t)c * 192 + 64 + h * 32 + f], s);
      sb = fmaf(a, b2[64 + h * 32 + f], sb);
    }
    wv = s; bv = sb;
  } else {
    const float* Ar = A_v + ((size_t)rel * 2048 + h * 1024 + x);
    float s = 0.f, sb = 0.f;
    for (int d = 0; d < 32; ++d) {
      float a = Ar[d * 32];
      s = fmaf(a, Wt[(size_t)c * 192 + 128 + h * 32 + d], s);
      sb = fmaf(a, b2[128 + h * 32 + d], sb);
    }
    wv = s; bv = sb;
  }
  wv *= scale[t * 64 + c];
  W[(size_t)jj * 72 + c] = (_Float16)wv;
  if (c < 8) W[(size_t)jj * 72 + 64 + c] = (_Float16)0.f;
  if (c == 0) bias_big[bofs + jj] = bv;
}

// ---------------- CSR build ----------------

__global__ __launch_bounds__(256) void hist_all(
    const int* __restrict__ d0, const int* __restrict__ d1,
    const int* __restrict__ d2, const int* __restrict__ d3,
    unsigned* __restrict__ cnt)
{
  int i = blockIdx.x * blockDim.x + threadIdx.x;
  int stride = gridDim.x * blockDim.x;
  for (; i < E_TOTAL; i += stride) {
    if (i < E_E2Q) atomicAdd(&cnt[BASE_Q + d0[i]], 1u);
    else if (i < E_E2Q + E_E2E) atomicAdd(&cnt[BASE_E + d1[i - E_E2Q]], 1u);
    else if (i < E_E2Q + E_E2E + E_E2A) atomicAdd(&cnt[BASE_A + d2[i - E_E2Q - E_E2E]], 1u);
    else atomicAdd(&cnt[BASE_A + d3[i - E_E2Q - E_E2E - E_E2A]], 1u);
  }
}

__global__ __launch_bounds__(256) void scan1(unsigned* __restrict__ arr, int n,
                                             unsigned* __restrict__ bsums) {
  __shared__ unsigned sh[256];
  int t = threadIdx.x;
  int base = blockIdx.x * 1024 + t * 4;
  unsigned v[4];
  unsigned s = 0;
#pragma unroll
  for (int j = 0; j < 4; ++j) {
    v[j] = (base + j < n) ? arr[base + j] : 0u;
    s += v[j];
  }
  sh[t] = s;
  __syncthreads();
  for (int off = 1; off < 256; off <<= 1) {
    unsigned x = (t >= off) ? sh[t - off] : 0u;
    __syncthreads();
    sh[t] += x;
    __syncthreads();
  }
  unsigned run = sh[t] - s;
#pragma unroll
  for (int j = 0; j < 4; ++j) {
    if (base + j < n) arr[base + j] = run;
    run += v[j];
  }
  if (t == 255) bsums[blockIdx.x] = sh[255];
}

__global__ __launch_bounds__(256) void scan2(unsigned* __restrict__ bsums, int nb) {
  __shared__ unsigned sh[256];
  __shared__ unsigned carry;
  int t = threadIdx.x;
  if (t == 0) carry = 0;
  __syncthreads();
  for (int chunk = 0; chunk < nb; chunk += 256) {
    int i = chunk + t;
    unsigned v = (i < nb) ? bsums[i] : 0u;
    sh[t] = v;
    __syncthreads();
    for (int off = 1; off < 256; off <<= 1) {
      unsigned x = (t >= off) ? sh[t - off] : 0u;
      __syncthreads();
      sh[t] += x;
      __syncthreads();
    }
    unsigned inc = sh[t];
    unsigned c = carry;
    __syncthreads();
    if (i < nb) bsums[i] = c + inc - v;
    if (t == 255) carry = c + sh[255];
    __syncthreads();
  }
}

__global__ __launch_bounds__(256) void scan3(unsigned* __restrict__ arr,
                                             const unsigned* __restrict__ bsums,
                                             unsigned* __restrict__ cursor, int n) {
  int t = threadIdx.x;
  int base = blockIdx.x * 1024 + t * 4;
  unsigned add = bsums[blockIdx.x];
#pragma unroll
  for (int j = 0; j < 4; ++j) {
    int idx = base + j;
    if (idx < n) {
      unsigned r = arr[idx] + add;
      arr[idx] = r;
      cursor[idx] = r;
    }
  }
}

__global__ __launch_bounds__(256) void scatter_all(
    const int* __restrict__ s0, const int* __restrict__ d0,
    const int* __restrict__ s1, const int* __restrict__ d1,
    const int* __restrict__ s2, const int* __restrict__ d2,
    const int* __restrict__ s3, const int* __restrict__ d3,
    unsigned* __restrict__ cursor, unsigned* __restrict__ eidx)
{
  int i = blockIdx.x * blockDim.x + threadIdx.x;
  int stride = gridDim.x * blockDim.x;
  for (; i < E_TOTAL; i += stride) {
    unsigned pos, pay;
    if (i < E_E2Q) {
      pos = atomicAdd(&cursor[BASE_Q + d0[i]], 1u);
      pay = (unsigned)(s0[i] * 320);
    } else if (i < E_E2Q + E_E2E) {
      int k = i - E_E2Q;
      pos = atomicAdd(&cursor[BASE_E + d1[k]], 1u);
      pay = (unsigned)(s1[k] * 320);
    } else if (i < E_E2Q + E_E2E + E_E2A) {
      int k = i - E_E2Q - E_E2E;
      pos = atomicAdd(&cursor[BASE_A + d2[k]], 1u);
      pay = (unsigned)(s2[k] * 320);
    } else {
      int k = i - E_E2Q - E_E2E - E_E2A;
      pos = atomicAdd(&cursor[BASE_A + d3[k]], 1u);
      pay = (unsigned)(s3[k] * 192) | 0x80000000u;
    }
    eidx[pos] = pay;
  }
}

// ---------------- gather body (device fn) ----------------

template <int NREL>
__device__ __forceinline__ void gather_body(
    int bidLocal, int nblocks, int N, int nodebase,
    const unsigned* __restrict__ row_start, const unsigned* __restrict__ row_end,
    const unsigned* __restrict__ eidx,
    const _Float16* __restrict__ baseA, int vofA,
    const _Float16* __restrict__ baseB, int vofB,
    const _Float16* __restrict__ qtA, int ldqA,
    const _Float16* __restrict__ qtB, int ldqB,
    const float* __restrict__ prelA, const float* __restrict__ prelB,
    _Float16* __restrict__ agg)
{
  int lane = threadIdx.x & 63;
  int h = lane >> 5, f = lane & 31;
  int idx2 = h * 32 + 2 * (f & 15);
  const float isd = 0.17677669529663687f;
  float pr0 = prelA[h] * isd;
  float pr1 = (NREL == 2) ? prelB[h] * isd : 0.f;

  int wid = (int)(((size_t)bidLocal * 256 + threadIdx.x) >> 6);
  int nw = nblocks * 4;

  int n0 = wid;
  unsigned b0s = 0, b0e = 0, e00 = 0, e01 = 0;
  half2_t q00p = {}, q01p = {};
  if (n0 < N) {
    b0s = row_start[nodebase + n0];
    b0e = row_end[nodebase + n0];
    q00p = *(const half2_t*)&qtA[(size_t)n0 * ldqA + idx2];
    if (NREL == 2) q01p = *(const half2_t*)&qtB[(size_t)n0 * ldqB + idx2];
    e00 = eidx[b0s];
    e01 = eidx[b0s + 1];
  }
  int n1 = n0 + nw;
  unsigned b1s = 0, b1e = 0;
  half2_t q10p = {}, q11p = {};
  if (n0 < N && n1 < N) {
    b1s = row_start[nodebase + n1];
    b1e = row_end[nodebase + n1];
    q10p = *(const half2_t*)&qtA[(size_t)n1 * ldqA + idx2];
    if (NREL == 2) q11p = *(const half2_t*)&qtB[(size_t)n1 * ldqB + idx2];
  }

  while (n0 < N) {
    unsigned e10 = 0, e11 = 0;
    if (n1 < N) {
      e10 = eidx[b1s];
      e11 = eidx[b1s + 1];
    }
    int n2 = n1 + nw;
    unsigned b2s = 0, b2e = 0;
    half2_t q20p = {}, q21p = {};
    if (n2 < N) {
      b2s = row_start[nodebase + n2];
      b2e = row_end[nodebase + n2];
      q20p = *(const half2_t*)&qtA[(size_t)n2 * ldqA + idx2];
      if (NREL == 2) q21p = *(const half2_t*)&qtB[(size_t)n2 * ldqB + idx2];
    }

    float vs = 0.f, ss = 0.f;
    unsigned i = b0s;

    auto do_pair = [&](unsigned p1, unsigned p2) {
      unsigned o1 = p1 & 0x7FFFFFFFu, o2 = p2 & 0x7FFFFFFFu;
      bool r1 = (NREL == 2) && (p1 >> 31);
      bool r2 = (NREL == 2) && (p2 >> 31);
      const _Float16* b1 = (r1 ? baseB : baseA) + o1;
      const _Float16* b2 = (r2 ? baseB : baseA) + o2;
      half2_t k21 = *(const half2_t*)&b1[idx2];
      float v1 = (float)b1[(r1 ? vofB : vofA) + lane];
      half2_t k22 = *(const half2_t*)&b2[idx2];
      float v2 = (float)b2[(r2 ? vofB : vofA) + lane];
      float sa = __builtin_amdgcn_fdot2(k21, r1 ? q01p : q00p, 0.f, false);
      float sb = __builtin_amdgcn_fdot2(k22, r2 ? q01p : q00p, 0.f, false);
#pragma unroll
      for (int off = 1; off <= 8; off <<= 1) {
        sa += __shfl_xor(sa, off, 32);
        sb += __shfl_xor(sb, off, 32);
      }
      float w1 = __expf(sa * (r1 ? pr1 : pr0));
      float w2 = __expf(sb * (r2 ? pr1 : pr0));
      ss += w1 + w2;
      vs = fmaf(w1, v1, vs);
      vs = fmaf(w2, v2, vs);
    };
    auto do_single = [&](unsigned p1) {
      unsigned o1 = p1 & 0x7FFFFFFFu;
      bool r1 = (NREL == 2) && (p1 >> 31);
      const _Float16* b1 = (r1 ? baseB : baseA) + o1;
      half2_t k21 = *(const half2_t*)&b1[idx2];
      float v1 = (float)b1[(r1 ? vofB : vofA) + lane];
      float sa = __builtin_amdgcn_fdot2(k21, r1 ? q01p : q00p, 0.f, false);
#pragma unroll
      for (int off = 1; off <= 8; off <<= 1) sa += __shfl_xor(sa, off, 32);
      float w1 = __expf(sa * (r1 ? pr1 : pr0));
      ss += w1;
      vs = fmaf(w1, v1, vs);
    };

    if (i + 2 <= b0e) { do_pair(e00, e01); i += 2; }
    else if (i < b0e) { do_single(e00); i = b0e; }
    for (; i + 2 <= b0e; i += 2) do_pair(eidx[i], eidx[i + 1]);
    if (i < b0e) do_single(eidx[i]);

    float val = (ss > 0.f) ? vs / ss : 0.f;
    val = fast_gelu(val);
    agg[((size_t)(nodebase + n0)) * 64 + lane] = (_Float16)val;

    n0 = n1; b0s = b1s; b0e = b1e; q00p = q10p; q01p = q11p; e00 = e10; e01 = e11;
    n1 = n2; b1s = b2s; b1e = b2e; q10p = q20p; q11p = q21p;
  }
}

__global__ __launch_bounds__(256) void gather_all(
    const unsigned* __restrict__ row_start, const unsigned* __restrict__ row_end,
    const unsigned* __restrict__ eidx,
    const _Float16* __restrict__ kqvQ, const _Float16* __restrict__ kqvE,
    const _Float16* __restrict__ kqvA,
    const float* __restrict__ p_rel, _Float16* __restrict__ agg)
{
  int bid = blockIdx.x;
  if (bid < GB_Q) {
    gather_body<1>(bid, GB_Q, NQ, BASE_Q, row_start, row_end, eidx,
                   kqvE, 128, kqvE, 128, kqvQ + 64, 192, kqvQ + 64, 192,
                   p_rel + 0, p_rel + 0, agg);
  } else if (bid < GB_Q + GB_E) {
    gather_body<1>(bid - GB_Q, GB_E, NE, BASE_E, row_start, row_end, eidx,
                   kqvE, 192, kqvE, 192, kqvE + 64, 320, kqvE + 64, 320,
                   p_rel + 2, p_rel + 2, agg);
  } else {
    gather_body<2>(bid - GB_Q - GB_E, GB_A, NA, BASE_A, row_start, row_end, eidx,
                   kqvE, 256, kqvQ, 128, kqvA, 128, kqvA + 64, 128,
                   p_rel + 4, p_rel + 6, agg);
  }
}

// ---------------- merged predictions ----------------

__global__ void pred_all(const int* __restrict__ pos, const int* __restrict__ neg,
                         const float* __restrict__ zq, const float* __restrict__ za,
                         float* __restrict__ outp) {
  int i = blockIdx.x * blockDim.x + threadIdx.x;
  if (i >= N_POS + N_NEG) return;
  int k; const int* qi; const int* ai; float* o;
  if (i < N_POS) { k = i; qi = pos; ai = pos + N_POS; o = outp; }
  else { k = i - N_POS; qi = neg; ai = neg + N_NEG; o = outp + N_POS; }
  const float4* a = (const float4*)(zq + (size_t)qi[k] * 64);
  const float4* b = (const float4*)(za + (size_t)ai[k] * 64);
  float ssum = 0.f;
#pragma unroll
  for (int j = 0; j < 16; ++j) {
    float4 x = a[j], y = b[j];
    ssum += x.x * y.x + x.y * y.y + x.z * y.z + x.w * y.w;
  }
  o[k] = ssum;
}

// ---------------- host launch ----------------

extern "C" void kernel_launch(void* const* d_in, const int* in_sizes, int n_in,
                              void* d_out, int out_size, void* d_ws, size_t ws_size,
                              hipStream_t stream) {
  const float* xq = (const float*)d_in[0];
  const float* xa = (const float*)d_in[1];
  const float* xe = (const float*)d_in[2];
  const int* e_e2q = (const int*)d_in[3];
  const int* e_e2e = (const int*)d_in[4];
  const int* e_e2a = (const int*)d_in[5];
  const int* e_q2a = (const int*)d_in[6];
  const int* pos_idx = (const int*)d_in[7];
  const int* neg_idx = (const int*)d_in[8];
  const float* W_in = (const float*)d_in[9];
  const float* b_in = (const float*)d_in[10];
  const float* bn_gamma = (const float*)d_in[11];
  const float* bn_beta = (const float*)d_in[12];
  const float* W_kqv = (const float*)d_in[13];
  const float* b_kqv = (const float*)d_in[14];
  const float* A_k = (const float*)d_in[15];
  const float* A_v = (const float*)d_in[16];
  const float* p_rel = (const float*)d_in[17];
  const float* W_out = (const float*)d_in[18];
  const float* b_out = (const float*)d_in[19];
  const float* skip = (const float*)d_in[20];
  float* out = (float*)d_out;

  float* ws = (float*)d_ws;
  size_t off = 0;
  _Float16* y_h = (_Float16*)(ws + off);    off += (size_t)NT_TOTAL * 32;
  _Float16* kqvQ = (_Float16*)(ws + off);   off += (size_t)NQ * 96;
  _Float16* kqvE = (_Float16*)(ws + off);   off += (size_t)NE * 160;
  _Float16* kqvA = (_Float16*)(ws + off);   off += (size_t)NA * 64;
  _Float16* agg_h = (_Float16*)(ws + off);  off += (size_t)NT_TOTAL * 32;
  float* stats = ws + off;                  off += 384;
  float* scale = ws + off;                  off += 192;
  float* shift = ws + off;                  off += 192;
  float* bias2 = ws + off;                  off += 576;
  float* bias_big = ws + off;               off += 640;
  _Float16* WqT = (_Float16*)(ws + off);    off += 192 * 72 / 2;
  _Float16* WeT = (_Float16*)(ws + off);    off += 320 * 72 / 2;
  _Float16* WaT = (_Float16*)(ws + off);    off += 128 * 72 / 2;
  _Float16* WinT = (_Float16*)(ws + off);   off += 3 * 64 * 136 / 2;
  _Float16* WoutT = (_Float16*)(ws + off);  off += 3 * 64 * 72 / 2;
  float* bstats = ws + off;                 off += (size_t)(GIN_Q + GIN_A + GIN_E) * 128;
  unsigned* row_start = (unsigned*)(ws + off); off += NT_TOTAL;
  unsigned* cursor = (unsigned*)(ws + off);    off += NT_TOTAL;
  unsigned* bsums = (unsigned*)(ws + off);     off += 1024;
  unsigned* eidx = (unsigned*)(ws + off);      off += E_TOTAL + 8;

  float* zq_out = out + (N_POS + N_NEG);

  prep_misc<<<dim3(512), dim3(256), 0, stream>>>((float*)row_start, W_in, WinT, W_out, WoutT);

  // ---- merged in-proj (pipelined LDS stage) ----
  gemm_inproj_all<<<dim3(GIN_Q + GIN_A + GIN_E), dim3(256), 0, stream>>>(
      xq, xa, xe, WinT, b_in, y_h, bstats);

  stats_reduce<<<dim3(384), dim3(256), 0, stream>>>(bstats, stats);
  bn_finalize<<<dim3(1), dim3(192), 0, stream>>>(stats, bn_gamma, bn_beta, scale, shift);
  kqv_bias2<<<dim3(3), dim3(192), 0, stream>>>(b_kqv, W_kqv, shift, bias2);
  wprep_kqv<<<dim3(640), dim3(64), 0, stream>>>(W_kqv, bias2, A_k, A_v, scale,
                                                WqT, WeT, WaT, bias_big);

  // ---- kqv projections ----
  gemm_mfma<256, 192, 64><<<dim3(CDIV(NQ, 256)), dim3(512), 0, stream>>>(
      y_h, WqT, bias_big, NQ, kqvQ, 192);
  gemm_mfma<256, 160, 64><<<dim3(CDIV(NE, 256), 2), dim3(512), 0, stream>>>(
      y_h + (size_t)(NQ + NA) * 64, WeT, bias_big + 192, NE, kqvE, 320);
  gemm_mfma<256, 128, 64><<<dim3(CDIV(NA, 256)), dim3(512), 0, stream>>>(
      y_h + (size_t)NQ * 64, WaT, bias_big + 512, NA, kqvA, 128);

  // ---- CSR build ----
  hist_all<<<dim3(2048), dim3(256), 0, stream>>>(
      e_e2q + E_E2Q, e_e2e + E_E2E, e_e2a + E_E2A, e_q2a + E_Q2A, row_start);
  scan1<<<dim3(NBLK_SCAN), dim3(256), 0, stream>>>(row_start, NT_TOTAL, bsums);
  scan2<<<dim3(1), dim3(256), 0, stream>>>(bsums, NBLK_SCAN);
  scan3<<<dim3(NBLK_SCAN), dim3(256), 0, stream>>>(row_start, bsums, cursor, NT_TOTAL);
  scatter_all<<<dim3(2048), dim3(256), 0, stream>>>(
      e_e2q, e_e2q + E_E2Q, e_e2e, e_e2e + E_E2E,
      e_e2a, e_e2a + E_E2A, e_q2a, e_q2a + E_Q2A, cursor, eidx);

  // ---- merged gather ----
  gather_all<<<dim3(GB_Q + GB_E + GB_A), dim3(256), 0, stream>>>(
      row_start, cursor, eidx, kqvQ, kqvE, kqvA, p_rel, agg_h);

  // ---- merged out projection ----
  gemm_out_all<<<dim3(TOP_Q + TOP_A + TOP_E), dim3(256), 0, stream>>>(
      agg_h, y_h, WoutT, b_out, scale, shift, skip, zq_out);

  // ---- merged predictions ----
  pred_all<<<dim3(CDIV(N_POS + N_NEG, 256)), dim3(256), 0, stream>>>(
      pos_idx, neg_idx, zq_out, zq_out + (size_t)NQ * 64, out);
}

// Round 19
// 655.119 us; speedup vs baseline: 2.9524x; 1.0833x over previous
//
#include <hip/hip_runtime.h>
#include <hip/hip_bf16.h>
#include <hip/hip_fp16.h>
#include <math.h>

#define NQ 8192
#define NA 32768
#define NE 500000
#define F_IN 128
#define E_E2Q 131072
#define E_E2E 800000
#define E_E2A 262144
#define E_Q2A 32768
#define N_POS 8192
#define N_NEG 24576

#define NT_TOTAL (NQ + NA + NE)
#define E_TOTAL (E_E2Q + E_E2E + E_E2A + E_Q2A)
#define NBLK_SCAN ((NT_TOTAL + 1023) / 1024)         // 529
#define CDIV(a, b) (((a) + (b) - 1) / (b))

#define BASE_Q 0
#define BASE_A NQ
#define BASE_E (NQ + NA)

// in-proj block counts (1 block per bstats row)
#define GIN_Q 128
#define GIN_A 512
#define GIN_E 768
#define GIN_TOT (GIN_Q + GIN_A + GIN_E)   // 1408
#define HB 1024                            // hist blocks appended

// gather grid
#define GB_Q 2048
#define GB_E 4096
#define GB_A 8192

// out-proj grid
#define TOP_Q 64
#define TOP_A 256
#define TOP_E 3907

// kqv_scatter grid
#define KQ_Q 32        // CDIV(NQ,256)
#define KQ_E 1954      // CDIV(NE,256), x2 col tiles
#define KQ_A 128       // CDIV(NA,256)
#define KQ_TOT (KQ_Q + 2 * KQ_E + KQ_A)   // 4068
#define SCB 2048
#define SMEM_KQV 64512

typedef _Float16 half8_t __attribute__((ext_vector_type(8)));
typedef _Float16 half2_t __attribute__((ext_vector_type(2)));
typedef float f32x4_t __attribute__((ext_vector_type(4)));

__device__ inline void load_lds16(const void* g, void* l) {
  __builtin_amdgcn_global_load_lds((const __attribute__((address_space(1))) void*)g,
                                   (__attribute__((address_space(3))) void*)l, 16, 0, 0);
}

__device__ inline float fast_gelu(float v) {
  float u = 1.5957691216057308f * fmaf(0.044715f * v * v, v, v);
  return v / (1.f + __expf(-u));
}

// ---------------- K1: prep (zero row_start + WinT + WoutT) ----------------

__global__ __launch_bounds__(256) void prep_misc(
    float* __restrict__ row_start_f,
    const float* __restrict__ W_in, _Float16* __restrict__ WinT,
    const float* __restrict__ W_out, _Float16* __restrict__ WoutT)
{
  int bid = blockIdx.x;
  if (bid < 128) {
    size_t i = (size_t)bid * 256 + threadIdx.x;
    size_t stride = (size_t)128 * 256;
    for (; i < NT_TOTAL; i += stride) row_start_f[i] = 0.f;
  } else if (bid < 320) {
    int b = bid - 128;
    int t = b >> 6, n = b & 63, k = threadIdx.x;
    if (k < 136) {
      float v = (k < 128) ? W_in[(size_t)t * 128 * 64 + (size_t)k * 64 + n] : 0.f;
      WinT[((size_t)t * 64 + n) * 136 + k] = (_Float16)v;
    }
  } else {
    int b = bid - 320;
    int t = b >> 6, n = b & 63, k = threadIdx.x;
    if (k < 72) {
      float v = (k < 64) ? W_out[(size_t)t * 64 * 64 + (size_t)k * 64 + n] : 0.f;
      WoutT[((size_t)t * 64 + n) * 72 + k] = (_Float16)v;
    }
  }
}

// ---------------- K2: in-proj (pipelined LDS stage) + hist, block-range merged ----------------

__global__ __launch_bounds__(256) void inproj_hist_all(
    const float* __restrict__ xq, const float* __restrict__ xa,
    const float* __restrict__ xe,
    const _Float16* __restrict__ WinT, const float* __restrict__ b_in,
    _Float16* __restrict__ y_h, float* __restrict__ bstats,
    const int* __restrict__ hd0, const int* __restrict__ hd1,
    const int* __restrict__ hd2, const int* __restrict__ hd3,
    unsigned* __restrict__ cnt)
{
  __shared__ __align__(16) float bufA[32 * 128];
  __shared__ __align__(16) float bufB[32 * 128];
  __shared__ _Float16 Bs[64 * 136];
  __shared__ float s1[64], s2[64];

  int bid = blockIdx.x;
  if (bid >= GIN_TOT) {
    // ---- hist range ----
    int i = (bid - GIN_TOT) * 256 + threadIdx.x;
    int stride = HB * 256;
    for (; i < E_TOTAL; i += stride) {
      if (i < E_E2Q) atomicAdd(&cnt[BASE_Q + hd0[i]], 1u);
      else if (i < E_E2Q + E_E2E) atomicAdd(&cnt[BASE_E + hd1[i - E_E2Q]], 1u);
      else if (i < E_E2Q + E_E2E + E_E2A)
        atomicAdd(&cnt[BASE_A + hd2[i - E_E2Q - E_E2E]], 1u);
      else atomicAdd(&cnt[BASE_A + hd3[i - E_E2Q - E_E2E - E_E2A]], 1u);
    }
    return;
  }

  // ---- in-proj range ----
  int t, lb, nb;
  const float* Af;
  _Float16* oh;
  if (bid < GIN_Q)              { t = 0; lb = bid;                 nb = GIN_Q; Af = xq; oh = y_h; }
  else if (bid < GIN_Q + GIN_A) { t = 1; lb = bid - GIN_Q;         nb = GIN_A; Af = xa; oh = y_h + (size_t)NQ * 64; }
  else                          { t = 2; lb = bid - GIN_Q - GIN_A; nb = GIN_E; Af = xe; oh = y_h + (size_t)(NQ + NA) * 64; }
  int M = (t == 0) ? NQ : (t == 1) ? NA : NE;
  int nh = CDIV(M, 32);
  const _Float16* WT = WinT + (size_t)t * 64 * 136;
  const float* bias = b_in + t * 64;

  int tid = threadIdx.x, w = tid >> 6, l = tid & 63;
  int lr = l & 15, lg = l >> 4;
  int wrow = (w & 1) * 16;
  int wcol = (w >> 1) * 32;

  for (int idx = tid; idx < 64 * 136 / 8; idx += 256)
    *(half8_t*)&Bs[idx * 8] = *(const half8_t*)&WT[(size_t)idx * 8];
  if (tid < 64) { s1[tid] = 0.f; s2[tid] = 0.f; }

  float bval[2];
  bval[0] = bias[wcol + lr];
  bval[1] = bias[wcol + 16 + lr];
  float ps1[2] = {}, ps2[2] = {};

  auto stage = [&](float* buf, int h) {
    const char* srcbase = (const char*)Af + (size_t)h * 32 * 512;
    int rowlim = M - h * 32;
#pragma unroll
    for (int r = 0; r < 4; ++r) {
      int unit = r * 4 + w;
      char* ldst = (char*)buf + unit * 1024;
      int p = unit * 1024 + l * 16;
      int row = p >> 9;
      const char* src = (row < rowlim) ? srcbase + (size_t)row * 512 + (p & 511)
                                       : srcbase;
      load_lds16(src, ldst);
    }
  };

  int h0 = lb;
  if (h0 < nh) stage(bufA, h0);
  __syncthreads();

  float* cur = bufA;
  float* nxt = bufB;
  for (int h = h0; h < nh; h += nb) {
    int h2 = h + nb;
    bool more = h2 < nh;
    if (more) {
      stage(nxt, h2);
      asm volatile("s_waitcnt vmcnt(4)" ::: "memory");
    } else {
      asm volatile("s_waitcnt vmcnt(0)" ::: "memory");
    }
    __builtin_amdgcn_sched_barrier(0);
    __builtin_amdgcn_s_barrier();

    f32x4_t acc[2] = {};
#pragma unroll
    for (int ks = 0; ks < 4; ++ks) {
      const float4* pa = (const float4*)((const char*)cur +
                          (wrow + lr) * 512 + ks * 128 + lg * 32);
      float4 x0 = pa[0], x1 = pa[1];
      half8_t a0 = {(_Float16)x0.x, (_Float16)x0.y, (_Float16)x0.z, (_Float16)x0.w,
                    (_Float16)x1.x, (_Float16)x1.y, (_Float16)x1.z, (_Float16)x1.w};
#pragma unroll
      for (int ct = 0; ct < 2; ++ct) {
        half8_t b = *(const half8_t*)&Bs[(wcol + ct * 16 + lr) * 136 + ks * 32 + lg * 8];
        acc[ct] = __builtin_amdgcn_mfma_f32_16x16x32_f16(a0, b, acc[ct], 0, 0, 0);
      }
    }
    int rbase = h * 32 + wrow + lg * 4;
#pragma unroll
    for (int ct = 0; ct < 2; ++ct) {
      int col = wcol + ct * 16 + lr;
#pragma unroll
      for (int j = 0; j < 4; ++j) {
        int row = rbase + j;
        if (row >= M) continue;
        float val = fmaxf(acc[ct][j] + bval[ct], 0.f);
        oh[(size_t)row * 64 + col] = (_Float16)val;
        ps1[ct] += val;
        ps2[ct] += val * val;
      }
    }
    __builtin_amdgcn_s_barrier();
    float* tmp = cur; cur = nxt; nxt = tmp;
  }

#pragma unroll
  for (int ct = 0; ct < 2; ++ct) {
    int col = wcol + ct * 16 + lr;
    atomicAdd(&s1[col], ps1[ct]);
    atomicAdd(&s2[col], ps2[ct]);
  }
  __syncthreads();
  if (tid < 64) {
    bstats[(size_t)blockIdx.x * 128 + tid] = s1[tid];
    bstats[(size_t)blockIdx.x * 128 + 64 + tid] = s2[tid];
  }
}

// ---------------- K3: stats_reduce + scan1 merged ----------------

__global__ __launch_bounds__(256) void reduce_scan1(
    const float* __restrict__ bstats, float* __restrict__ stats,
    unsigned* __restrict__ arr, unsigned* __restrict__ bsums)
{
  __shared__ __align__(16) char shbuf[1024];
  int bid = blockIdx.x;
  int t0 = threadIdx.x;
  if (bid < 384) {
    // stats_reduce
    float* sh = (float*)shbuf;
    int t = bid >> 7, c = bid & 127;
    int nb = (t == 0) ? GIN_Q : (t == 1) ? GIN_A : GIN_E;
    int base = (t == 0) ? 0 : (t == 1) ? GIN_Q : (GIN_Q + GIN_A);
    float s = 0.f;
    for (int i = t0; i < nb; i += 256)
      s += bstats[(size_t)(base + i) * 128 + c];
    sh[t0] = s;
    __syncthreads();
    for (int off2 = 128; off2 > 0; off2 >>= 1) {
      if (t0 < off2) sh[t0] += sh[t0 + off2];
      __syncthreads();
    }
    if (t0 == 0) stats[t * 128 + c] = sh[0];
  } else {
    // scan1
    unsigned* sh = (unsigned*)shbuf;
    int blk = bid - 384;
    int base = blk * 1024 + t0 * 4;
    unsigned v[4];
    unsigned s = 0;
#pragma unroll
    for (int j = 0; j < 4; ++j) {
      v[j] = (base + j < NT_TOTAL) ? arr[base + j] : 0u;
      s += v[j];
    }
    sh[t0] = s;
    __syncthreads();
    for (int off = 1; off < 256; off <<= 1) {
      unsigned x = (t0 >= off) ? sh[t0 - off] : 0u;
      __syncthreads();
      sh[t0] += x;
      __syncthreads();
    }
    unsigned run = sh[t0] - s;
#pragma unroll
    for (int j = 0; j < 4; ++j) {
      if (base + j < NT_TOTAL) arr[base + j] = run;
      run += v[j];
    }
    if (t0 == 255) bsums[blk] = sh[255];
  }
}

// ---------------- K4: scan2 (block 0) + bn_finalize+kqv_bias2 (block 1) ----------------

__global__ __launch_bounds__(256) void scan2_bn(
    unsigned* __restrict__ bsums, int nbk,
    const float* __restrict__ stats,
    const float* __restrict__ gamma, const float* __restrict__ beta,
    float* __restrict__ scale, float* __restrict__ shift,
    const float* __restrict__ b_kqv, const float* __restrict__ W_kqv,
    float* __restrict__ bias2)
{
  int t0 = threadIdx.x;
  if (blockIdx.x == 0) {
    __shared__ unsigned sh[256];
    __shared__ unsigned carry;
    if (t0 == 0) carry = 0;
    __syncthreads();
    for (int chunk = 0; chunk < nbk; chunk += 256) {
      int i = chunk + t0;
      unsigned v = (i < nbk) ? bsums[i] : 0u;
      sh[t0] = v;
      __syncthreads();
      for (int off = 1; off < 256; off <<= 1) {
        unsigned x = (t0 >= off) ? sh[t0 - off] : 0u;
        __syncthreads();
        sh[t0] += x;
        __syncthreads();
      }
      unsigned inc = sh[t0];
      unsigned c = carry;
      __syncthreads();
      if (i < nbk) bsums[i] = c + inc - v;
      if (t0 == 255) carry = c + sh[255];
      __syncthreads();
    }
  } else {
    __shared__ float sshift[192];
    if (t0 < 192) {
      int ty = t0 >> 6, c = t0 & 63;
      float invN = (ty == 0) ? (1.f / NQ) : (ty == 1) ? (1.f / NA) : (1.f / NE);
      float mu = stats[ty * 128 + c] * invN;
      float var = stats[ty * 128 + 64 + c] * invN - mu * mu;
      float rs = rsqrtf(var + 1e-5f);
      float gm = gamma[t0];
      float sc = gm * rs;
      float sf = beta[t0] - gm * mu * rs;
      scale[t0] = sc;
      shift[t0] = sf;
      sshift[t0] = sf;
    }
    __syncthreads();
    for (int idx = t0; idx < 576; idx += 256) {
      int t = idx / 192, n = idx % 192;
      float s = b_kqv[t * 192 + n];
      for (int k = 0; k < 64; ++k)
        s += sshift[t * 64 + k] * W_kqv[(size_t)t * 64 * 192 + k * 192 + n];
      bias2[t * 192 + n] = s;
    }
  }
}

// ---------------- K5: scan3 + wprep_kqv merged ----------------

__global__ __launch_bounds__(256) void scan3_wprep(
    unsigned* __restrict__ arr, const unsigned* __restrict__ bsums,
    unsigned* __restrict__ cursor,
    const float* __restrict__ W_kqv, const float* __restrict__ bias2,
    const float* __restrict__ A_k, const float* __restrict__ A_v,
    const float* __restrict__ scale,
    _Float16* __restrict__ WqT, _Float16* __restrict__ WeT,
    _Float16* __restrict__ WaT, float* __restrict__ bias_big)
{
  int bid = blockIdx.x;
  int t0 = threadIdx.x;
  if (bid < NBLK_SCAN) {
    int base = bid * 1024 + t0 * 4;
    unsigned add = bsums[bid];
#pragma unroll
    for (int j = 0; j < 4; ++j) {
      int idx = base + j;
      if (idx < NT_TOTAL) {
        unsigned r = arr[idx] + add;
        arr[idx] = r;
        cursor[idx] = r;
      }
    }
    return;
  }
  // wprep: j = (bid-NBLK_SCAN)*4 + (t0>>6), c = t0&63
  int j = (bid - NBLK_SCAN) * 4 + (t0 >> 6);
  int c = t0 & 63;
  if (j >= 640) return;
  int t, jj, bofs;
  _Float16* W;
  if (j < 192)      { t = 0; jj = j;       W = WqT; bofs = 0; }
  else if (j < 512) { t = 2; jj = j - 192; W = WeT; bofs = 192; }
  else              { t = 1; jj = j - 512; W = WaT; bofs = 512; }
  const float* Wt = W_kqv + (size_t)t * 64 * 192;
  const float* b2 = bias2 + t * 192;
  int mode = 0, rel = 0, sub = 0;
  if (t == 1) { mode = 1; rel = (jj < 64) ? 2 : 3; sub = jj & 63; }
  else if (jj >= 64 && jj < 128) { mode = 1; rel = (t == 0) ? 0 : 1; sub = jj - 64; }
  else if (jj >= 128) {
    mode = 2; sub = (jj - 128) & 63;
    rel = (t == 0) ? 3 : ((jj - 128) >> 6);
  }
  int h = sub >> 5, x = sub & 31;
  float wv, bv;
  if (mode == 0) {
    wv = Wt[(size_t)c * 192 + jj];
    bv = b2[jj];
  } else if (mode == 1) {
    const float* Ar = A_k + ((size_t)rel * 2048 + h * 1024 + x * 32);
    float s = 0.f, sb = 0.f;
    for (int f = 0; f < 32; ++f) {
      float a = Ar[f];
      s = fmaf(a, Wt[(size_t)c * 192 + 64 + h * 32 + f], s);
      sb = fmaf(a, b2[64 + h * 32 + f], sb);
    }
    wv = s; bv = sb;
  } else {
    const float* Ar = A_v + ((size_t)rel * 2048 + h * 1024 + x);
    float s = 0.f, sb = 0.f;
    for (int d = 0; d < 32; ++d) {
      float a = Ar[d * 32];
      s = fmaf(a, Wt[(size_t)c * 192 + 128 + h * 32 + d], s);
      sb = fmaf(a, b2[128 + h * 32 + d], sb);
    }
    wv = s; bv = sb;
  }
  wv *= scale[t * 64 + c];
  W[(size_t)jj * 72 + c] = (_Float16)wv;
  if (c < 8) W[(size_t)jj * 72 + 64 + c] = (_Float16)0.f;
  if (c == 0) bias_big[bofs + jj] = bv;
}

// ---------------- kqv GEMM body (device fn; 512 threads, BM=256) ----------------

template <int BNT>
__device__ __forceinline__ void kqv_body(
    char* smem,
    const _Float16* __restrict__ Ah,
    const _Float16* __restrict__ WT, const float* __restrict__ bias, int M,
    _Float16* __restrict__ oh, int LDO, int row0, int colbase)
{
  constexpr int KP = 72;
  constexpr int TP = BNT + 8;
  _Float16* As = (_Float16*)smem;          // 256*72
  _Float16* Bs = As + 256 * KP;            // BNT*72
  _Float16* Ts = (_Float16*)smem;          // overlays
  int tid = threadIdx.x;

  {
    for (int idx = tid; idx < 256 * 8; idx += 512) {
      int row = idx >> 3, c = (idx & 7);
      int gr = row0 + row;
      half8_t a8 = {};
      if (gr < M) a8 = *(const half8_t*)&Ah[(size_t)gr * 64 + c * 8];
      *(half8_t*)&As[row * KP + c * 8] = a8;
    }
  }
  {
    const _Float16* wsrc = WT + (size_t)colbase * KP;
    for (int idx = tid; idx < BNT * KP / 8; idx += 512)
      *(half8_t*)&Bs[idx * 8] = *(const half8_t*)&wsrc[(size_t)idx * 8];
  }
  __syncthreads();

  int w = tid >> 6, l = tid & 63;
  int lr = l & 15, lg = l >> 4;
  constexpr int NCT = BNT / 16;
  f32x4_t acc[2][NCT] = {};
#pragma unroll
  for (int ks = 0; ks < 2; ++ks) {
    half8_t a0 = *(const half8_t*)&As[(w * 32 + lr) * KP + ks * 32 + lg * 8];
    half8_t a1 = *(const half8_t*)&As[(w * 32 + 16 + lr) * KP + ks * 32 + lg * 8];
#pragma unroll
    for (int ct = 0; ct < NCT; ++ct) {
      half8_t b = *(const half8_t*)&Bs[(ct * 16 + lr) * KP + ks * 32 + lg * 8];
      acc[0][ct] = __builtin_amdgcn_mfma_f32_16x16x32_f16(a0, b, acc[0][ct], 0, 0, 0);
      acc[1][ct] = __builtin_amdgcn_mfma_f32_16x16x32_f16(a1, b, acc[1][ct], 0, 0, 0);
    }
  }

  float bval[NCT];
#pragma unroll
  for (int ct = 0; ct < NCT; ++ct) bval[ct] = bias[colbase + ct * 16 + lr];

#pragma unroll
  for (int rt = 0; rt < 2; ++rt) {
    __syncthreads();
    int r2base = w * 16 + lg * 4;
#pragma unroll
    for (int ct = 0; ct < NCT; ++ct) {
      int colL = ct * 16 + lr;
#pragma unroll
      for (int j = 0; j < 4; ++j)
        Ts[(r2base + j) * TP + colL] = (_Float16)(acc[rt][ct][j] + bval[ct]);
    }
    __syncthreads();
    constexpr int C8 = BNT / 8;
    for (int idx = tid; idx < 128 * C8; idx += 512) {
      int r2 = idx / C8, c8 = (idx % C8) * 8;
      int gr = row0 + (r2 >> 4) * 32 + rt * 16 + (r2 & 15);
      if (gr < M)
        *(half8_t*)&oh[(size_t)gr * LDO + colbase + c8] = *(const half8_t*)&Ts[r2 * TP + c8];
    }
  }
}

// ---------------- K6: kqv GEMMs + scatter, block-range merged (512 threads) ----------------

__global__ __launch_bounds__(512) void kqv_scatter(
    const _Float16* __restrict__ y_h,
    const _Float16* __restrict__ WqT, const _Float16* __restrict__ WeT,
    const _Float16* __restrict__ WaT, const float* __restrict__ bias_big,
    _Float16* __restrict__ kqvQ, _Float16* __restrict__ kqvE,
    _Float16* __restrict__ kqvA,
    const int* __restrict__ s0, const int* __restrict__ d0,
    const int* __restrict__ s1, const int* __restrict__ d1,
    const int* __restrict__ s2, const int* __restrict__ d2,
    const int* __restrict__ s3, const int* __restrict__ d3,
    unsigned* __restrict__ cursor, unsigned* __restrict__ eidx)
{
  extern __shared__ __align__(16) char smem[];
  int bid = blockIdx.x;
  if (bid < KQ_Q) {
    kqv_body<192>(smem, y_h, WqT, bias_big, NQ, kqvQ, 192, bid * 256, 0);
  } else if (bid < KQ_Q + 2 * KQ_E) {
    int b = bid - KQ_Q;
    int ct = b / KQ_E;          // col tile 0/1
    int rb = b % KQ_E;
    kqv_body<160>(smem, y_h + (size_t)(NQ + NA) * 64, WeT, bias_big + 192, NE,
                  kqvE, 320, rb * 256, ct * 160);
  } else if (bid < KQ_TOT) {
    int b = bid - KQ_Q - 2 * KQ_E;
    kqv_body<128>(smem, y_h + (size_t)NQ * 64, WaT, bias_big + 512, NA,
                  kqvA, 128, b * 256, 0);
  } else {
    // scatter range
    int i = (bid - KQ_TOT) * 512 + threadIdx.x;
    int stride = SCB * 512;
    for (; i < E_TOTAL; i += stride) {
      unsigned pos, pay;
      if (i < E_E2Q) {
        pos = atomicAdd(&cursor[BASE_Q + d0[i]], 1u);
        pay = (unsigned)(s0[i] * 320);
      } else if (i < E_E2Q + E_E2E) {
        int k = i - E_E2Q;
        pos = atomicAdd(&cursor[BASE_E + d1[k]], 1u);
        pay = (unsigned)(s1[k] * 320);
      } else if (i < E_E2Q + E_E2E + E_E2A) {
        int k = i - E_E2Q - E_E2E;
        pos = atomicAdd(&cursor[BASE_A + d2[k]], 1u);
        pay = (unsigned)(s2[k] * 320);
      } else {
        int k = i - E_E2Q - E_E2E - E_E2A;
        pos = atomicAdd(&cursor[BASE_A + d3[k]], 1u);
        pay = (unsigned)(s3[k] * 192) | 0x80000000u;
      }
      eidx[pos] = pay;
    }
  }
}

// ---------------- gather body ----------------

template <int NREL>
__device__ __forceinline__ void gather_body(
    int bidLocal, int nblocks, int N, int nodebase,
    const unsigned* __restrict__ row_start, const unsigned* __restrict__ row_end,
    const unsigned* __restrict__ eidx,
    const _Float16* __restrict__ baseA, int vofA,
    const _Float16* __restrict__ baseB, int vofB,
    const _Float16* __restrict__ qtA, int ldqA,
    const _Float16* __restrict__ qtB, int ldqB,
    const float* __restrict__ prelA, const float* __restrict__ prelB,
    _Float16* __restrict__ agg)
{
  int lane = threadIdx.x & 63;
  int h = lane >> 5, f = lane & 31;
  int idx2 = h * 32 + 2 * (f & 15);
  const float isd = 0.17677669529663687f;
  float pr0 = prelA[h] * isd;
  float pr1 = (NREL == 2) ? prelB[h] * isd : 0.f;

  int wid = (int)(((size_t)bidLocal * 256 + threadIdx.x) >> 6);
  int nw = nblocks * 4;

  int n0 = wid;
  unsigned b0s = 0, b0e = 0, e00 = 0, e01 = 0;
  half2_t q00p = {}, q01p = {};
  if (n0 < N) {
    b0s = row_start[nodebase + n0];
    b0e = row_end[nodebase + n0];
    q00p = *(const half2_t*)&qtA[(size_t)n0 * ldqA + idx2];
    if (NREL == 2) q01p = *(const half2_t*)&qtB[(size_t)n0 * ldqB + idx2];
    e00 = eidx[b0s];
    e01 = eidx[b0s + 1];
  }
  int n1 = n0 + nw;
  unsigned b1s = 0, b1e = 0;
  half2_t q10p = {}, q11p = {};
  if (n0 < N && n1 < N) {
    b1s = row_start[nodebase + n1];
    b1e = row_end[nodebase + n1];
    q10p = *(const half2_t*)&qtA[(size_t)n1 * ldqA + idx2];
    if (NREL == 2) q11p = *(const half2_t*)&qtB[(size_t)n1 * ldqB + idx2];
  }

  while (n0 < N) {
    unsigned e10 = 0, e11 = 0;
    if (n1 < N) {
      e10 = eidx[b1s];
      e11 = eidx[b1s + 1];
    }
    int n2 = n1 + nw;
    unsigned b2s = 0, b2e = 0;
    half2_t q20p = {}, q21p = {};
    if (n2 < N) {
      b2s = row_start[nodebase + n2];
      b2e = row_end[nodebase + n2];
      q20p = *(const half2_t*)&qtA[(size_t)n2 * ldqA + idx2];
      if (NREL == 2) q21p = *(const half2_t*)&qtB[(size_t)n2 * ldqB + idx2];
    }

    float vs = 0.f, ss = 0.f;
    unsigned i = b0s;

    auto do_pair = [&](unsigned p1, unsigned p2) {
      unsigned o1 = p1 & 0x7FFFFFFFu, o2 = p2 & 0x7FFFFFFFu;
      bool r1 = (NREL == 2) && (p1 >> 31);
      bool r2 = (NREL == 2) && (p2 >> 31);
      const _Float16* b1 = (r1 ? baseB : baseA) + o1;
      const _Float16* b2 = (r2 ? baseB : baseA) + o2;
      half2_t k21 = *(const half2_t*)&b1[idx2];
      float v1 = (float)b1[(r1 ? vofB : vofA) + lane];
      half2_t k22 = *(const half2_t*)&b2[idx2];
      float v2 = (float)b2[(r2 ? vofB : vofA) + lane];
      float sa = __builtin_amdgcn_fdot2(k21, r1 ? q01p : q00p, 0.f, false);
      float sb = __builtin_amdgcn_fdot2(k22, r2 ? q01p : q00p, 0.f, false);
#pragma unroll
      for (int off = 1; off <= 8; off <<= 1) {
        sa += __shfl_xor(sa, off, 32);
        sb += __shfl_xor(sb, off, 32);
      }
      float w1 = __expf(sa * (r1 ? pr1 : pr0));
      float w2 = __expf(sb * (r2 ? pr1 : pr0));
      ss += w1 + w2;
      vs = fmaf(w1, v1, vs);
      vs = fmaf(w2, v2, vs);
    };
    auto do_single = [&](unsigned p1) {
      unsigned o1 = p1 & 0x7FFFFFFFu;
      bool r1 = (NREL == 2) && (p1 >> 31);
      const _Float16* b1 = (r1 ? baseB : baseA) + o1;
      half2_t k21 = *(const half2_t*)&b1[idx2];
      float v1 = (float)b1[(r1 ? vofB : vofA) + lane];
      float sa = __builtin_amdgcn_fdot2(k21, r1 ? q01p : q00p, 0.f, false);
#pragma unroll
      for (int off = 1; off <= 8; off <<= 1) sa += __shfl_xor(sa, off, 32);
      float w1 = __expf(sa * (r1 ? pr1 : pr0));
      ss += w1;
      vs = fmaf(w1, v1, vs);
    };

    if (i + 2 <= b0e) { do_pair(e00, e01); i += 2; }
    else if (i < b0e) { do_single(e00); i = b0e; }
    for (; i + 2 <= b0e; i += 2) do_pair(eidx[i], eidx[i + 1]);
    if (i < b0e) do_single(eidx[i]);

    float val = (ss > 0.f) ? vs / ss : 0.f;
    val = fast_gelu(val);
    agg[((size_t)(nodebase + n0)) * 64 + lane] = (_Float16)val;

    n0 = n1; b0s = b1s; b0e = b1e; q00p = q10p; q01p = q11p; e00 = e10; e01 = e11;
    n1 = n2; b1s = b2s; b1e = b2e; q10p = q20p; q11p = q21p;
  }
}

__global__ __launch_bounds__(256) void gather_all(
    const unsigned* __restrict__ row_start, const unsigned* __restrict__ row_end,
    const unsigned* __restrict__ eidx,
    const _Float16* __restrict__ kqvQ, const _Float16* __restrict__ kqvE,
    const _Float16* __restrict__ kqvA,
    const float* __restrict__ p_rel, _Float16* __restrict__ agg)
{
  int bid = blockIdx.x;
  if (bid < GB_Q) {
    gather_body<1>(bid, GB_Q, NQ, BASE_Q, row_start, row_end, eidx,
                   kqvE, 128, kqvE, 128, kqvQ + 64, 192, kqvQ + 64, 192,
                   p_rel + 0, p_rel + 0, agg);
  } else if (bid < GB_Q + GB_E) {
    gather_body<1>(bid - GB_Q, GB_E, NE, BASE_E, row_start, row_end, eidx,
                   kqvE, 192, kqvE, 192, kqvE + 64, 320, kqvE + 64, 320,
                   p_rel + 2, p_rel + 2, agg);
  } else {
    gather_body<2>(bid - GB_Q - GB_E, GB_A, NA, BASE_A, row_start, row_end, eidx,
                   kqvE, 256, kqvQ, 128, kqvA, 128, kqvA + 64, 128,
                   p_rel + 4, p_rel + 6, agg);
  }
}

// ---------------- K8: merged out-proj ----------------

__global__ __launch_bounds__(256) void gemm_out_all(
    const _Float16* __restrict__ agg_h, const _Float16* __restrict__ y_h,
    const _Float16* __restrict__ WoutT, const float* __restrict__ b_out,
    const float* __restrict__ scale, const float* __restrict__ shift,
    const float* __restrict__ skip, float* __restrict__ zout)
{
  __shared__ _Float16 Bs[64 * 72];
  int bid = blockIdx.x;
  int t, row0, M;
  size_t nodeoff;
  if (bid < TOP_Q)              { t = 0; row0 = bid * 128;              M = NQ; nodeoff = 0; }
  else if (bid < TOP_Q + TOP_A) { t = 1; row0 = (bid - TOP_Q) * 128;    M = NA; nodeoff = NQ; }
  else                          { t = 2; row0 = (bid - TOP_Q - TOP_A) * 128; M = NE; nodeoff = NQ + NA; }
  const _Float16* Ah = agg_h + nodeoff * 64;
  const _Float16* resh = y_h + nodeoff * 64;
  float* Cf = zout + nodeoff * 64;
  const _Float16* WT = WoutT + (size_t)t * 64 * 72;
  const float* bias = b_out + t * 64;
  const float* rsc = scale + t * 64;
  const float* rsh = shift + t * 64;

  int tid = threadIdx.x;
  int w = tid >> 6, l = tid & 63;
  int lr = l & 15, lg = l >> 4;

  for (int idx = tid; idx < 64 * 72 / 8; idx += 256)
    *(half8_t*)&Bs[idx * 8] = *(const half8_t*)&WT[(size_t)idx * 8];

  half8_t afrag[2][2];
#pragma unroll
  for (int rt = 0; rt < 2; ++rt) {
    int gr = row0 + w * 32 + rt * 16 + lr;
    bool ok = gr < M;
#pragma unroll
    for (int ks = 0; ks < 2; ++ks) {
      half8_t h8 = {};
      if (ok) h8 = *(const half8_t*)&Ah[(size_t)gr * 64 + ks * 32 + lg * 8];
      afrag[rt][ks] = h8;
    }
  }
  __syncthreads();

  f32x4_t acc[2][4] = {};
#pragma unroll
  for (int ks = 0; ks < 2; ++ks) {
#pragma unroll
    for (int ct = 0; ct < 4; ++ct) {
      half8_t b = *(const half8_t*)&Bs[(ct * 16 + lr) * 72 + ks * 32 + lg * 8];
      acc[0][ct] = __builtin_amdgcn_mfma_f32_16x16x32_f16(afrag[0][ks], b, acc[0][ct], 0, 0, 0);
      acc[1][ct] = __builtin_amdgcn_mfma_f32_16x16x32_f16(afrag[1][ks], b, acc[1][ct], 0, 0, 0);
    }
  }

  float g = 1.f / (1.f + __expf(-skip[t]));
  float gb = 1.f - g;
#pragma unroll
  for (int rt = 0; rt < 2; ++rt) {
    int rbase = row0 + w * 32 + rt * 16 + lg * 4;
#pragma unroll
    for (int ct = 0; ct < 4; ++ct) {
      int col = ct * 16 + lr;
      float bval = bias[col];
#pragma unroll
      for (int j = 0; j < 4; ++j) {
        int row = rbase + j;
        if (row >= M) continue;
        float val = acc[rt][ct][j] + bval;
        float rv = (float)resh[(size_t)row * 64 + col];
        Cf[(size_t)row * 64 + col] = g * val + gb * (rsc[col] * rv + rsh[col]);
      }
    }
  }
}

// ---------------- K9: merged predictions ----------------

__global__ void pred_all(const int* __restrict__ pos, const int* __restrict__ neg,
                         const float* __restrict__ zq, const float* __restrict__ za,
                         float* __restrict__ outp) {
  int i = blockIdx.x * blockDim.x + threadIdx.x;
  if (i >= N_POS + N_NEG) return;
  int k; const int* qi; const int* ai; float* o;
  if (i < N_POS) { k = i; qi = pos; ai = pos + N_POS; o = outp; }
  else { k = i - N_POS; qi = neg; ai = neg + N_NEG; o = outp + N_POS; }
  const float4* a = (const float4*)(zq + (size_t)qi[k] * 64);
  const float4* b = (const float4*)(za + (size_t)ai[k] * 64);
  float ssum = 0.f;
#pragma unroll
  for (int j = 0; j < 16; ++j) {
    float4 x = a[j], y = b[j];
    ssum += x.x * y.x + x.y * y.y + x.z * y.z + x.w * y.w;
  }
  o[k] = ssum;
}

// ---------------- host launch ----------------

extern "C" void kernel_launch(void* const* d_in, const int* in_sizes, int n_in,
                              void* d_out, int out_size, void* d_ws, size_t ws_size,
                              hipStream_t stream) {
  const float* xq = (const float*)d_in[0];
  const float* xa = (const float*)d_in[1];
  const float* xe = (const float*)d_in[2];
  const int* e_e2q = (const int*)d_in[3];
  const int* e_e2e = (const int*)d_in[4];
  const int* e_e2a = (const int*)d_in[5];
  const int* e_q2a = (const int*)d_in[6];
  const int* pos_idx = (const int*)d_in[7];
  const int* neg_idx = (const int*)d_in[8];
  const float* W_in = (const float*)d_in[9];
  const float* b_in = (const float*)d_in[10];
  const float* bn_gamma = (const float*)d_in[11];
  const float* bn_beta = (const float*)d_in[12];
  const float* W_kqv = (const float*)d_in[13];
  const float* b_kqv = (const float*)d_in[14];
  const float* A_k = (const float*)d_in[15];
  const float* A_v = (const float*)d_in[16];
  const float* p_rel = (const float*)d_in[17];
  const float* W_out = (const float*)d_in[18];
  const float* b_out = (const float*)d_in[19];
  const float* skip = (const float*)d_in[20];
  float* out = (float*)d_out;

  float* ws = (float*)d_ws;
  size_t off = 0;
  _Float16* y_h = (_Float16*)(ws + off);    off += (size_t)NT_TOTAL * 32;
  _Float16* kqvQ = (_Float16*)(ws + off);   off += (size_t)NQ * 96;
  _Float16* kqvE = (_Float16*)(ws + off);   off += (size_t)NE * 160;
  _Float16* kqvA = (_Float16*)(ws + off);   off += (size_t)NA * 64;
  _Float16* agg_h = (_Float16*)(ws + off);  off += (size_t)NT_TOTAL * 32;
  float* stats = ws + off;                  off += 384;
  float* scale = ws + off;                  off += 192;
  float* shift = ws + off;                  off += 192;
  float* bias2 = ws + off;                  off += 576;
  float* bias_big = ws + off;               off += 640;
  _Float16* WqT = (_Float16*)(ws + off);    off += 192 * 72 / 2;
  _Float16* WeT = (_Float16*)(ws + off);    off += 320 * 72 / 2;
  _Float16* WaT = (_Float16*)(ws + off);    off += 128 * 72 / 2;
  _Float16* WinT = (_Float16*)(ws + off);   off += 3 * 64 * 136 / 2;
  _Float16* WoutT = (_Float16*)(ws + off);  off += 3 * 64 * 72 / 2;
  float* bstats = ws + off;                 off += (size_t)GIN_TOT * 128;
  unsigned* row_start = (unsigned*)(ws + off); off += NT_TOTAL;
  unsigned* cursor = (unsigned*)(ws + off);    off += NT_TOTAL;
  unsigned* bsums = (unsigned*)(ws + off);     off += 1024;
  unsigned* eidx = (unsigned*)(ws + off);      off += E_TOTAL + 8;

  float* zq_out = out + (N_POS + N_NEG);

  prep_misc<<<dim3(512), dim3(256), 0, stream>>>((float*)row_start, W_in, WinT, W_out, WoutT);

  inproj_hist_all<<<dim3(GIN_TOT + HB), dim3(256), 0, stream>>>(
      xq, xa, xe, WinT, b_in, y_h, bstats,
      e_e2q + E_E2Q, e_e2e + E_E2E, e_e2a + E_E2A, e_q2a + E_Q2A, row_start);

  reduce_scan1<<<dim3(384 + NBLK_SCAN), dim3(256), 0, stream>>>(
      bstats, stats, row_start, bsums);

  scan2_bn<<<dim3(2), dim3(256), 0, stream>>>(
      bsums, NBLK_SCAN, stats, bn_gamma, bn_beta, scale, shift, b_kqv, W_kqv, bias2);

  scan3_wprep<<<dim3(NBLK_SCAN + 160), dim3(256), 0, stream>>>(
      row_start, bsums, cursor, W_kqv, bias2, A_k, A_v, scale,
      WqT, WeT, WaT, bias_big);

  kqv_scatter<<<dim3(KQ_TOT + SCB), dim3(512), SMEM_KQV, stream>>>(
      y_h, WqT, WeT, WaT, bias_big, kqvQ, kqvE, kqvA,
      e_e2q, e_e2q + E_E2Q, e_e2e, e_e2e + E_E2E,
      e_e2a, e_e2a + E_E2A, e_q2a, e_q2a + E_Q2A, cursor, eidx);

  gather_all<<<dim3(GB_Q + GB_E + GB_A), dim3(256), 0, stream>>>(
      row_start, cursor, eidx, kqvQ, kqvE, kqvA, p_rel, agg_h);

  gemm_out_all<<<dim3(TOP_Q + TOP_A + TOP_E), dim3(256), 0, stream>>>(
      agg_h, y_h, WoutT, b_out, scale, shift, skip, zq_out);

  pred_all<<<dim3(CDIV(N_POS + N_NEG, 256)), dim3(256), 0, stream>>>(
      pos_idx, neg_idx, zq_out, zq_out + (size_t)NQ * 64, out);
}